// Round 1
// baseline (3427.171 us; speedup 1.0000x reference)
//
#include <hip/hip_runtime.h>
#include <math.h>

// ---------------- constants ----------------
constexpr int DM = 512, DS = 16, DC = 4, DI = 1024, DI4 = 256, KC = 5;
constexpr int Bb = 4, N = 1024, L4 = 4, TT = Bb * N;
constexpr float TEMP = 0.5f;

// ---------------- k-means ----------------
__global__ void initcen_k(const float* __restrict__ ci, float* __restrict__ centers) {
    int gid = blockIdx.x * 256 + threadIdx.x;           // B*KC*DM = 10240
    centers[gid] = ci[gid % (KC * DM)];
}

template <bool FINAL>
__global__ __launch_bounds__(64) void assign_k(const float* __restrict__ x,
                                               const float* __restrict__ centers,
                                               float* __restrict__ wgt,
                                               float* __restrict__ mind,
                                               float* __restrict__ keys) {
    int t = blockIdx.x;            // token 0..TT-1
    int b = t >> 10;
    int lane = threadIdx.x;
    const float* xr = x + (size_t)t * DM;
    const float* cen = centers + (size_t)b * KC * DM;
    float d2[KC] = {0.f, 0.f, 0.f, 0.f, 0.f};
    for (int c = lane; c < DM; c += 64) {
        float xv = xr[c];
#pragma unroll
        for (int k = 0; k < KC; ++k) {
            float df = xv - cen[k * DM + c];
            d2[k] += df * df;
        }
    }
#pragma unroll
    for (int k = 0; k < KC; ++k)
        for (int off = 32; off > 0; off >>= 1) d2[k] += __shfl_xor(d2[k], off);
    if (lane == 0) {
        float dist[KC], logit[KC], e[KC];
        float lm = -1e30f;
        for (int k = 0; k < KC; ++k) {
            dist[k] = sqrtf(d2[k] + 1e-12f);
            logit[k] = -dist[k] / TEMP;
            lm = fmaxf(lm, logit[k]);
        }
        float s = 0.f;
        for (int k = 0; k < KC; ++k) { e[k] = expf(logit[k] - lm); s += e[k]; }
        float inv = 1.f / s;
        for (int k = 0; k < KC; ++k) wgt[t * KC + k] = e[k] * inv;
        if (FINAL) {
            float md = dist[0];
            for (int k = 1; k < KC; ++k) md = fminf(md, dist[k]);
            int ca = 0; float best = e[0] * inv;
            for (int k = 1; k < KC; ++k) {
                float wv = e[k] * inv;
                if (wv > best) { best = wv; ca = k; }
            }
            mind[t] = md;
            keys[t] = (float)ca * 1000.0f + (1.0f - best);
        }
    }
}

__global__ __launch_bounds__(512) void update_k(const float* __restrict__ x,
                                                const float* __restrict__ wgt,
                                                float* __restrict__ centers) {
    int b = blockIdx.x / KC, k = blockIdx.x % KC;
    int c = threadIdx.x;    // 0..511
    __shared__ float sden[512];
    const float* xb = x + (size_t)b * N * DM;
    const float* wb = wgt + (size_t)b * N * KC + k;
    float acc = 0.f;
    for (int n = 0; n < N; ++n) acc += wb[(size_t)n * KC] * xb[(size_t)n * DM + c];
    float dn = wb[(size_t)c * KC] + wb[(size_t)(c + 512) * KC];
    sden[c] = dn; __syncthreads();
    for (int st = 256; st > 0; st >>= 1) { if (c < st) sden[c] += sden[c + st]; __syncthreads(); }
    float den = sden[0];
    centers[((size_t)b * KC + k) * DM + c] = acc / (den + 1e-8f);
}

__global__ __launch_bounds__(1024) void importance_k(const float* __restrict__ mind,
                                                     float* __restrict__ imp) {
    int b = blockIdx.x, n = threadIdx.x;
    __shared__ float red[1024];
    float v = -mind[b * N + n] / TEMP;
    red[n] = v; __syncthreads();
    for (int s = 512; s > 0; s >>= 1) { if (n < s) red[n] = fmaxf(red[n], red[n + s]); __syncthreads(); }
    float m = red[0]; __syncthreads();
    float e = expf(v - m);
    red[n] = e; __syncthreads();
    for (int s = 512; s > 0; s >>= 1) { if (n < s) red[n] += red[n + s]; __syncthreads(); }
    imp[b * N + n] = e / red[0];
}

__global__ __launch_bounds__(1024) void sort_k(const float* __restrict__ keys,
                                               int* __restrict__ ridx) {
    int b = blockIdx.x, tid = threadIdx.x;
    __shared__ unsigned long long a[1024];
    unsigned int kb = __float_as_uint(keys[b * N + tid]);   // keys >= 0
    a[tid] = ((unsigned long long)kb << 32) | (unsigned int)tid;
    __syncthreads();
    for (int k = 2; k <= 1024; k <<= 1) {
        for (int j = k >> 1; j > 0; j >>= 1) {
            int ixj = tid ^ j;
            if (ixj > tid) {
                unsigned long long x0 = a[tid], x1 = a[ixj];
                bool up = ((tid & k) == 0);
                bool sw = up ? (x0 > x1) : (x0 < x1);
                if (sw) { a[tid] = x1; a[ixj] = x0; }
            }
            __syncthreads();
        }
    }
    ridx[b * N + tid] = (int)(a[tid] & 0xffffffffu);
}

__global__ __launch_bounds__(512) void gather_k(const float* __restrict__ x,
                                                const float* __restrict__ imp,
                                                const int* __restrict__ ridx,
                                                float* __restrict__ rx, float* __restrict__ rxf,
                                                float* __restrict__ rimp, float* __restrict__ fimp) {
    int t = blockIdx.x;
    int b = t >> 10, j = t & (N - 1);
    int r = ridx[t];
    int c = threadIdx.x;
    float v = x[((size_t)(b << 10) + r) * DM + c];
    rx[(size_t)t * DM + c] = v;
    rxf[((size_t)(b << 10) + (N - 1 - j)) * DM + c] = v;
    if (c == 0) {
        float iv = imp[(b << 10) + r];
        rimp[t] = iv;
        fimp[(b << 10) + (N - 1 - j)] = iv;
    }
}

// ---------------- layernorm ----------------
__global__ __launch_bounds__(256) void ln_k(const float* __restrict__ xin,
                                            const float* __restrict__ g,
                                            const float* __restrict__ bt,
                                            float* __restrict__ out) {
    int t = blockIdx.x, tid = threadIdx.x;
    const float* xr = xin + (size_t)t * DM;
    __shared__ float red[256];
    float v0 = xr[tid], v1 = xr[tid + 256];
    red[tid] = v0 + v1; __syncthreads();
    for (int st = 128; st > 0; st >>= 1) { if (tid < st) red[tid] += red[tid + st]; __syncthreads(); }
    float mu = red[0] * (1.f / DM); __syncthreads();
    float d0 = v0 - mu, d1 = v1 - mu;
    red[tid] = d0 * d0 + d1 * d1; __syncthreads();
    for (int st = 128; st > 0; st >>= 1) { if (tid < st) red[tid] += red[tid + st]; __syncthreads(); }
    float rs = rsqrtf(red[0] * (1.f / DM) + 1e-5f);
    out[(size_t)t * DM + tid] = d0 * rs * g[tid] + bt[tid];
    out[(size_t)t * DM + tid + 256] = d1 * rs * g[tid + 256] + bt[tid + 256];
}

// ---------------- generic f32 GEMM: C[M=4096 x Nn] = A[. x K] * B[K x Nn] (+bias)(+add) ----------------
__global__ __launch_bounds__(256) void gemm_k(const float* __restrict__ A, int lda,
                                              const float* __restrict__ Bw, int ldb,
                                              const float* __restrict__ bias,
                                              const float* __restrict__ add, int ldadd,
                                              float* __restrict__ C, int ldc, int Kdim) {
    __shared__ float As[16][68];
    __shared__ float Bs[16][64];
    int tid = threadIdx.x;
    int tx = tid & 15, ty = tid >> 4;
    int row0 = blockIdx.y * 64, col0 = blockIdx.x * 64;
    float acc[4][4] = {};
    int ar = tid >> 2, ak = (tid & 3) * 4;
    int bcol = tid & 63, bk0 = (tid >> 6) * 4;
    for (int k0 = 0; k0 < Kdim; k0 += 16) {
        float4 av = *(const float4*)(A + (size_t)(row0 + ar) * lda + k0 + ak);
        As[ak + 0][ar] = av.x; As[ak + 1][ar] = av.y; As[ak + 2][ar] = av.z; As[ak + 3][ar] = av.w;
#pragma unroll
        for (int q = 0; q < 4; ++q)
            Bs[bk0 + q][bcol] = Bw[(size_t)(k0 + bk0 + q) * ldb + col0 + bcol];
        __syncthreads();
#pragma unroll
        for (int k = 0; k < 16; ++k) {
            const float4 bv = *(const float4*)&Bs[k][tx * 4];
            const float a0 = As[k][ty * 4 + 0];
            const float a1 = As[k][ty * 4 + 1];
            const float a2 = As[k][ty * 4 + 2];
            const float a3 = As[k][ty * 4 + 3];
            acc[0][0] = fmaf(a0, bv.x, acc[0][0]); acc[0][1] = fmaf(a0, bv.y, acc[0][1]);
            acc[0][2] = fmaf(a0, bv.z, acc[0][2]); acc[0][3] = fmaf(a0, bv.w, acc[0][3]);
            acc[1][0] = fmaf(a1, bv.x, acc[1][0]); acc[1][1] = fmaf(a1, bv.y, acc[1][1]);
            acc[1][2] = fmaf(a1, bv.z, acc[1][2]); acc[1][3] = fmaf(a1, bv.w, acc[1][3]);
            acc[2][0] = fmaf(a2, bv.x, acc[2][0]); acc[2][1] = fmaf(a2, bv.y, acc[2][1]);
            acc[2][2] = fmaf(a2, bv.z, acc[2][2]); acc[2][3] = fmaf(a2, bv.w, acc[2][3]);
            acc[3][0] = fmaf(a3, bv.x, acc[3][0]); acc[3][1] = fmaf(a3, bv.y, acc[3][1]);
            acc[3][2] = fmaf(a3, bv.z, acc[3][2]); acc[3][3] = fmaf(a3, bv.w, acc[3][3]);
        }
        __syncthreads();
    }
#pragma unroll
    for (int i = 0; i < 4; ++i) {
        int r = row0 + ty * 4 + i;
        int c = col0 + tx * 4;
        float4 o;
        o.x = acc[i][0]; o.y = acc[i][1]; o.z = acc[i][2]; o.w = acc[i][3];
        if (bias) { o.x += bias[c]; o.y += bias[c + 1]; o.z += bias[c + 2]; o.w += bias[c + 3]; }
        if (add) {
            const float* ad = add + (size_t)r * ldadd + c;
            o.x += ad[0]; o.y += ad[1]; o.z += ad[2]; o.w += ad[3];
        }
        *(float4*)(C + (size_t)r * ldc + c) = o;
    }
}

// ---------------- depthwise causal conv + silu ----------------
__global__ __launch_bounds__(256) void conv_k(const float* __restrict__ xz,
                                              const float* __restrict__ cw,
                                              const float* __restrict__ cb,
                                              float* __restrict__ xc) {
    int gid = blockIdx.x * 256 + threadIdx.x;
    int d = gid & (DI - 1);
    int t = gid >> 10;
    int n = t & (N - 1);
    float acc = cb[d];
    const float* base = xz + (size_t)t * (2 * DI) + d;
#pragma unroll
    for (int k = 0; k < DC; ++k) {
        int nn = n - (DC - 1) + k;
        if (nn >= 0) acc += base[(long)(nn - n) * (2 * DI)] * cw[d * DC + k];
    }
    float s = 1.f / (1.f + expf(-acc));
    xc[gid] = acc * s;
}

// ---------------- x_ssm = xc @ xp_w (1024 x 33) ----------------
__global__ __launch_bounds__(256) void xssm_k(const float* __restrict__ xc,
                                              const float* __restrict__ xpw,
                                              float* __restrict__ xssm) {
    int t = blockIdx.x;
    __shared__ float row[DI];
    int tid = threadIdx.x;
    for (int i = tid; i < DI; i += 256) row[i] = xc[(size_t)t * DI + i];
    __syncthreads();
    int j = tid >> 2;
    int part = tid & 3;
    if (j < 33) {
        float acc = 0.f;
        int c0 = part * 256;
        for (int c = c0; c < c0 + 256; ++c) acc += row[c] * xpw[c * 33 + j];
        acc += __shfl_xor(acc, 1);
        acc += __shfl_xor(acc, 2);
        if (part == 0) xssm[t * 33 + j] = acc;
    }
}

// ---------------- h1 (token scalar -> 256) ----------------
__global__ __launch_bounds__(256) void h1_k(const float* __restrict__ imp,
                                            const float* __restrict__ w1,
                                            const float* __restrict__ b1,
                                            float* __restrict__ h1) {
    int t = blockIdx.x, tid = threadIdx.x;
    float v = imp[t] * w1[tid] + b1[tid];
    h1[(size_t)t * DI4 + tid] = fmaxf(v, 0.f);
}

// ---------------- delta = softplus(draw*dt_w+dt_b) * (1 + sigmoid(modl)) ----------------
__global__ __launch_bounds__(256) void delta_k(const float* __restrict__ modl,
                                               const float* __restrict__ xssm,
                                               const float* __restrict__ dtw,
                                               const float* __restrict__ dtb,
                                               float* __restrict__ delta) {
    int gid = blockIdx.x * 256 + threadIdx.x;
    int t = gid >> 10, d = gid & (DI - 1);
    float draw = xssm[t * 33];
    float a = draw * dtw[d] + dtb[d];
    float sp = (a > 20.f) ? a : log1pf(expf(a));
    float mod = 1.f / (1.f + expf(-modl[gid]));
    delta[gid] = sp * (1.f + mod);
}

// ---------------- sequential SSM scan (fused y = (scan + xc*D) * silu(z)) ----------------
__global__ __launch_bounds__(256) void scan_k(const float* __restrict__ delta,
                                              const float* __restrict__ xc,
                                              const float* __restrict__ xssm,
                                              const float* __restrict__ Alog,
                                              const float* __restrict__ Dp,
                                              const float* __restrict__ xz,
                                              float* __restrict__ y) {
    int blk = blockIdx.x;            // 256 blocks
    int b = blk >> 6;
    int d0 = (blk & 63) * 16;
    int tid = threadIdx.x;
    int wave = tid >> 6;
    int lane = tid & 63;
    int s = lane & 15;
    int dd = lane >> 4;
    int d = d0 + wave * 4 + dd;
    float A = -expf(Alog[d * DS + s]);
    float dpv = Dp[d];
    float h = 0.f;
    size_t tokbase = (size_t)b * N;
    const float* dp = delta + tokbase * DI + d;
    const float* xcp = xc + tokbase * DI + d;
    const float* bp = xssm + tokbase * 33 + 1 + s;
    const float* cp = xssm + tokbase * 33 + 1 + DS + s;
    const float* zp = xz + tokbase * (2 * DI) + DI + d;
    float dlt = dp[0], xcv = xcp[0], Bv = bp[0], Cv = cp[0], zv = zp[0];
    for (int t = 0; t < N; ++t) {
        float n_dlt = 0.f, n_xc = 0.f, n_B = 0.f, n_C = 0.f, n_z = 0.f;
        if (t + 1 < N) {
            n_dlt = dp[(size_t)(t + 1) * DI];
            n_xc = xcp[(size_t)(t + 1) * DI];
            n_B = bp[(size_t)(t + 1) * 33];
            n_C = cp[(size_t)(t + 1) * 33];
            n_z = zp[(size_t)(t + 1) * 2 * DI];
        }
        float a = expf(dlt * A);
        h = a * h + dlt * Bv * xcv;
        float p = h * Cv;
        p += __shfl_xor(p, 1); p += __shfl_xor(p, 2);
        p += __shfl_xor(p, 4); p += __shfl_xor(p, 8);
        if (s == 0) {
            float yv = p + xcv * dpv;
            float sg = 1.f / (1.f + expf(-zv));
            y[(tokbase + t) * DI + d] = yv * (zv * sg);
        }
        dlt = n_dlt; xcv = n_xc; Bv = n_B; Cv = n_C; zv = n_z;
    }
}

// ---------------- concat [xf | flip(xb)] ----------------
__global__ __launch_bounds__(256) void concat_k(const float* __restrict__ xf,
                                                const float* __restrict__ xb,
                                                float* __restrict__ cat) {
    int gid = blockIdx.x * 256 + threadIdx.x;   // TT*DM
    int t = gid >> 9;
    int c = gid & (DM - 1);
    int b = t >> 10, j = t & (N - 1);
    cat[(size_t)t * (2 * DM) + c] = xf[gid];
    cat[(size_t)t * (2 * DM) + DM + c] = xb[((size_t)(b << 10) + (N - 1 - j)) * DM + c];
}

// ---------------- final: scatter by ridx + layernorm ----------------
__global__ __launch_bounds__(256) void final_k(const float* __restrict__ fus,
                                               const int* __restrict__ ridx,
                                               const float* __restrict__ g,
                                               const float* __restrict__ bt,
                                               float* __restrict__ out) {
    int t = blockIdx.x, tid = threadIdx.x;
    int b = t >> 10;
    int r = ridx[t];
    const float* xr = fus + (size_t)t * DM;
    __shared__ float red[256];
    float v0 = xr[tid], v1 = xr[tid + 256];
    red[tid] = v0 + v1; __syncthreads();
    for (int st = 128; st > 0; st >>= 1) { if (tid < st) red[tid] += red[tid + st]; __syncthreads(); }
    float mu = red[0] * (1.f / DM); __syncthreads();
    float d0 = v0 - mu, d1 = v1 - mu;
    red[tid] = d0 * d0 + d1 * d1; __syncthreads();
    for (int st = 128; st > 0; st >>= 1) { if (tid < st) red[tid] += red[tid + st]; __syncthreads(); }
    float rs = rsqrtf(red[0] * (1.f / DM) + 1e-5f);
    float* orow = out + ((size_t)(b << 10) + r) * DM;
    orow[tid] = d0 * rs * g[tid] + bt[tid];
    orow[tid + 256] = d1 * rs * g[tid + 256] + bt[tid + 256];
}

// ---------------- host ----------------
extern "C" void kernel_launch(void* const* d_in, const int* in_sizes, int n_in,
                              void* d_out, int out_size, void* d_ws, size_t ws_size,
                              hipStream_t stream) {
    const float* x            = (const float*)d_in[0];
    const float* centers_init = (const float*)d_in[1];
    const float* in_w         = (const float*)d_in[2];
    const float* conv_w       = (const float*)d_in[3];
    const float* conv_b       = (const float*)d_in[4];
    const float* xp_w         = (const float*)d_in[5];
    const float* dt_w         = (const float*)d_in[6];
    const float* dt_b         = (const float*)d_in[7];
    const float* cm_w1        = (const float*)d_in[8];
    const float* cm_b1        = (const float*)d_in[9];
    const float* cm_w2        = (const float*)d_in[10];
    const float* cm_b2        = (const float*)d_in[11];
    const float* A_log        = (const float*)d_in[12];
    const float* D_p          = (const float*)d_in[13];
    const float* out_w        = (const float*)d_in[14];
    const float* ln_g         = (const float*)d_in[15];
    const float* ln_b         = (const float*)d_in[16];
    const float* fusion_w     = (const float*)d_in[17];
    const float* fusion_b     = (const float*)d_in[18];
    const float* fn_g         = (const float*)d_in[19];
    const float* fn_b         = (const float*)d_in[20];

    float* W = (float*)d_ws;
    size_t off = 0;
    auto alloc = [&](size_t n) { float* p = W + off; off += n; return p; };
    float* centers = alloc((size_t)Bb * KC * DM);
    float* wgt     = alloc((size_t)TT * KC);
    float* mind    = alloc(TT);
    float* keys    = alloc(TT);
    float* imp     = alloc(TT);
    float* rimp    = alloc(TT);
    float* fimp    = alloc(TT);
    float* rx      = alloc((size_t)TT * DM);
    float* rxf     = alloc((size_t)TT * DM);
    float* bufA    = alloc((size_t)TT * DM);
    float* bufC    = alloc((size_t)TT * DM);
    float* xn      = alloc((size_t)TT * DM);       // reused as h1buf
    float* xz      = alloc((size_t)TT * 2 * DI);   // reused as cat
    float* xc      = alloc((size_t)TT * DI);       // reused as fus
    float* xssm    = alloc((size_t)TT * 33);
    float* modl    = alloc((size_t)TT * DI);       // reused as scan output y
    float* delta   = alloc((size_t)TT * DI);
    int* ridx = (int*)(W + off); off += TT;

    // ---- k-means ----
    initcen_k<<<(Bb * KC * DM) / 256, 256, 0, stream>>>(centers_init, centers);
    for (int it = 0; it < 3; ++it) {
        assign_k<false><<<TT, 64, 0, stream>>>(x, centers, wgt, nullptr, nullptr);
        update_k<<<Bb * KC, 512, 0, stream>>>(x, wgt, centers);
    }
    assign_k<true><<<TT, 64, 0, stream>>>(x, centers, wgt, mind, keys);
    importance_k<<<Bb, 1024, 0, stream>>>(mind, imp);
    sort_k<<<Bb, 1024, 0, stream>>>(keys, ridx);
    gather_k<<<TT, 512, 0, stream>>>(x, imp, ridx, rx, rxf, rimp, fimp);

    auto gemm = [&](const float* Ap, int lda, const float* Bp, int ldb,
                    const float* bias, const float* add, int ldadd,
                    float* Cp, int ldc, int Kd, int Nn) {
        dim3 g(Nn / 64, TT / 64);
        gemm_k<<<g, 256, 0, stream>>>(Ap, lda, Bp, ldb, bias, add, ldadd, Cp, ldc, Kd);
    };

    // ---- 4 mamba layers (2 fwd, 2 bwd on flipped) ----
    const float* lay_in[4]  = {rx, bufA, rxf, bufC};
    float*       lay_out[4] = {bufA, rx, bufC, rxf};
    for (int l = 0; l < L4; ++l) {
        const float* xin = lay_in[l];
        float* xout = lay_out[l];
        const float* impv = (l < 2) ? rimp : fimp;
        ln_k<<<TT, 256, 0, stream>>>(xin, ln_g + (size_t)l * DM, ln_b + (size_t)l * DM, xn);
        gemm(xn, DM, in_w + (size_t)l * DM * 2 * DI, 2 * DI, nullptr, nullptr, 0, xz, 2 * DI, DM, 2 * DI);
        conv_k<<<(TT * DI) / 256, 256, 0, stream>>>(xz, conv_w + (size_t)l * DI * DC, conv_b + (size_t)l * DI, xc);
        xssm_k<<<TT, 256, 0, stream>>>(xc, xp_w + (size_t)l * DI * 33, xssm);
        h1_k<<<TT, 256, 0, stream>>>(impv, cm_w1 + (size_t)l * DI4, cm_b1 + (size_t)l * DI4, xn);
        gemm(xn, DI4, cm_w2 + (size_t)l * DI4 * DI, DI, cm_b2 + (size_t)l * DI, nullptr, 0, modl, DI, DI4, DI);
        delta_k<<<(TT * DI) / 256, 256, 0, stream>>>(modl, xssm, dt_w + (size_t)l * DI, dt_b + (size_t)l * DI, delta);
        scan_k<<<256, 256, 0, stream>>>(delta, xc, xssm, A_log + (size_t)l * DI * DS, D_p + (size_t)l * DI, xz, modl);
        gemm(modl, DI, out_w + (size_t)l * DI * DM, DM, nullptr, xin, DM, xout, DM, DI, DM);
    }

    // ---- fusion + restore + final LN ----
    concat_k<<<(TT * DM) / 256, 256, 0, stream>>>(rx /*xf final*/, rxf /*xb final*/, xz /*cat*/);
    gemm(xz, 2 * DM, fusion_w, DM, fusion_b, nullptr, 0, xc /*fus*/, DM, 2 * DM, DM);
    final_k<<<TT, 256, 0, stream>>>(xc, ridx, fn_g, fn_b, (float*)d_out);
}

// Round 2
// 2833.342 us; speedup vs baseline: 1.2096x; 1.2096x over previous
//
#include <hip/hip_runtime.h>
#include <math.h>

// ---------------- constants ----------------
constexpr int DM = 512, DS = 16, DC = 4, DI = 1024, DI4 = 256, KC = 5;
constexpr int Bb = 4, N = 1024, L4 = 4, TT = Bb * N;
constexpr float TEMP = 0.5f;

// ---------------- k-means ----------------
__global__ void initcen_k(const float* __restrict__ ci, float* __restrict__ centers) {
    int gid = blockIdx.x * 256 + threadIdx.x;           // B*KC*DM = 10240
    centers[gid] = ci[gid % (KC * DM)];
}

template <bool FINAL>
__global__ __launch_bounds__(64) void assign_k(const float* __restrict__ x,
                                               const float* __restrict__ centers,
                                               float* __restrict__ wgt,
                                               float* __restrict__ mind,
                                               float* __restrict__ keys) {
    int t = blockIdx.x;            // token 0..TT-1
    int b = t >> 10;
    int lane = threadIdx.x;
    const float* xr = x + (size_t)t * DM;
    const float* cen = centers + (size_t)b * KC * DM;
    float d2[KC] = {0.f, 0.f, 0.f, 0.f, 0.f};
    for (int c = lane; c < DM; c += 64) {
        float xv = xr[c];
#pragma unroll
        for (int k = 0; k < KC; ++k) {
            float df = xv - cen[k * DM + c];
            d2[k] += df * df;
        }
    }
#pragma unroll
    for (int k = 0; k < KC; ++k)
        for (int off = 32; off > 0; off >>= 1) d2[k] += __shfl_xor(d2[k], off);
    if (lane == 0) {
        float dist[KC], logit[KC], e[KC];
        float lm = -1e30f;
        for (int k = 0; k < KC; ++k) {
            dist[k] = sqrtf(d2[k] + 1e-12f);
            logit[k] = -dist[k] / TEMP;
            lm = fmaxf(lm, logit[k]);
        }
        float s = 0.f;
        for (int k = 0; k < KC; ++k) { e[k] = expf(logit[k] - lm); s += e[k]; }
        float inv = 1.f / s;
        for (int k = 0; k < KC; ++k) wgt[t * KC + k] = e[k] * inv;
        if (FINAL) {
            float md = dist[0];
            for (int k = 1; k < KC; ++k) md = fminf(md, dist[k]);
            int ca = 0; float best = e[0] * inv;
            for (int k = 1; k < KC; ++k) {
                float wv = e[k] * inv;
                if (wv > best) { best = wv; ca = k; }
            }
            mind[t] = md;
            keys[t] = (float)ca * 1000.0f + (1.0f - best);
        }
    }
}

__global__ __launch_bounds__(512) void update_k(const float* __restrict__ x,
                                                const float* __restrict__ wgt,
                                                float* __restrict__ centers) {
    int b = blockIdx.x / KC, k = blockIdx.x % KC;
    int c = threadIdx.x;    // 0..511
    __shared__ float sden[512];
    const float* xb = x + (size_t)b * N * DM;
    const float* wb = wgt + (size_t)b * N * KC + k;
    float acc = 0.f;
    for (int n = 0; n < N; ++n) acc += wb[(size_t)n * KC] * xb[(size_t)n * DM + c];
    float dn = wb[(size_t)c * KC] + wb[(size_t)(c + 512) * KC];
    sden[c] = dn; __syncthreads();
    for (int st = 256; st > 0; st >>= 1) { if (c < st) sden[c] += sden[c + st]; __syncthreads(); }
    float den = sden[0];
    centers[((size_t)b * KC + k) * DM + c] = acc / (den + 1e-8f);
}

__global__ __launch_bounds__(1024) void importance_k(const float* __restrict__ mind,
                                                     float* __restrict__ imp) {
    int b = blockIdx.x, n = threadIdx.x;
    __shared__ float red[1024];
    float v = -mind[b * N + n] / TEMP;
    red[n] = v; __syncthreads();
    for (int s = 512; s > 0; s >>= 1) { if (n < s) red[n] = fmaxf(red[n], red[n + s]); __syncthreads(); }
    float m = red[0]; __syncthreads();
    float e = expf(v - m);
    red[n] = e; __syncthreads();
    for (int s = 512; s > 0; s >>= 1) { if (n < s) red[n] += red[n + s]; __syncthreads(); }
    imp[b * N + n] = e / red[0];
}

__global__ __launch_bounds__(1024) void sort_k(const float* __restrict__ keys,
                                               int* __restrict__ ridx) {
    int b = blockIdx.x, tid = threadIdx.x;
    __shared__ unsigned long long a[1024];
    unsigned int kb = __float_as_uint(keys[b * N + tid]);   // keys >= 0
    a[tid] = ((unsigned long long)kb << 32) | (unsigned int)tid;
    __syncthreads();
    for (int k = 2; k <= 1024; k <<= 1) {
        for (int j = k >> 1; j > 0; j >>= 1) {
            int ixj = tid ^ j;
            if (ixj > tid) {
                unsigned long long x0 = a[tid], x1 = a[ixj];
                bool up = ((tid & k) == 0);
                bool sw = up ? (x0 > x1) : (x0 < x1);
                if (sw) { a[tid] = x1; a[ixj] = x0; }
            }
            __syncthreads();
        }
    }
    ridx[b * N + tid] = (int)(a[tid] & 0xffffffffu);
}

__global__ __launch_bounds__(512) void gather_k(const float* __restrict__ x,
                                                const float* __restrict__ imp,
                                                const int* __restrict__ ridx,
                                                float* __restrict__ rx, float* __restrict__ rxf,
                                                float* __restrict__ rimp, float* __restrict__ fimp) {
    int t = blockIdx.x;
    int b = t >> 10, j = t & (N - 1);
    int r = ridx[t];
    int c = threadIdx.x;
    float v = x[((size_t)(b << 10) + r) * DM + c];
    rx[(size_t)t * DM + c] = v;
    rxf[((size_t)(b << 10) + (N - 1 - j)) * DM + c] = v;
    if (c == 0) {
        float iv = imp[(b << 10) + r];
        rimp[t] = iv;
        fimp[(b << 10) + (N - 1 - j)] = iv;
    }
}

// ---------------- layernorm ----------------
__global__ __launch_bounds__(256) void ln_k(const float* __restrict__ xin,
                                            const float* __restrict__ g,
                                            const float* __restrict__ bt,
                                            float* __restrict__ out) {
    int t = blockIdx.x, tid = threadIdx.x;
    const float* xr = xin + (size_t)t * DM;
    __shared__ float red[256];
    float v0 = xr[tid], v1 = xr[tid + 256];
    red[tid] = v0 + v1; __syncthreads();
    for (int st = 128; st > 0; st >>= 1) { if (tid < st) red[tid] += red[tid + st]; __syncthreads(); }
    float mu = red[0] * (1.f / DM); __syncthreads();
    float d0 = v0 - mu, d1 = v1 - mu;
    red[tid] = d0 * d0 + d1 * d1; __syncthreads();
    for (int st = 128; st > 0; st >>= 1) { if (tid < st) red[tid] += red[tid + st]; __syncthreads(); }
    float rs = rsqrtf(red[0] * (1.f / DM) + 1e-5f);
    out[(size_t)t * DM + tid] = d0 * rs * g[tid] + bt[tid];
    out[(size_t)t * DM + tid + 256] = d1 * rs * g[tid + 256] + bt[tid + 256];
}

// ---------------- generic f32 GEMM: C[M=4096 x Nn] = A[. x K] * B[K x Nn] (+bias)(+add) ----------------
__global__ __launch_bounds__(256) void gemm_k(const float* __restrict__ A, int lda,
                                              const float* __restrict__ Bw, int ldb,
                                              const float* __restrict__ bias,
                                              const float* __restrict__ add, int ldadd,
                                              float* __restrict__ C, int ldc, int Kdim) {
    __shared__ float As[16][68];
    __shared__ float Bs[16][64];
    int tid = threadIdx.x;
    int tx = tid & 15, ty = tid >> 4;
    int row0 = blockIdx.y * 64, col0 = blockIdx.x * 64;
    float acc[4][4] = {};
    int ar = tid >> 2, ak = (tid & 3) * 4;
    int bcol = tid & 63, bk0 = (tid >> 6) * 4;
    for (int k0 = 0; k0 < Kdim; k0 += 16) {
        float4 av = *(const float4*)(A + (size_t)(row0 + ar) * lda + k0 + ak);
        As[ak + 0][ar] = av.x; As[ak + 1][ar] = av.y; As[ak + 2][ar] = av.z; As[ak + 3][ar] = av.w;
#pragma unroll
        for (int q = 0; q < 4; ++q)
            Bs[bk0 + q][bcol] = Bw[(size_t)(k0 + bk0 + q) * ldb + col0 + bcol];
        __syncthreads();
#pragma unroll
        for (int k = 0; k < 16; ++k) {
            const float4 bv = *(const float4*)&Bs[k][tx * 4];
            const float a0 = As[k][ty * 4 + 0];
            const float a1 = As[k][ty * 4 + 1];
            const float a2 = As[k][ty * 4 + 2];
            const float a3 = As[k][ty * 4 + 3];
            acc[0][0] = fmaf(a0, bv.x, acc[0][0]); acc[0][1] = fmaf(a0, bv.y, acc[0][1]);
            acc[0][2] = fmaf(a0, bv.z, acc[0][2]); acc[0][3] = fmaf(a0, bv.w, acc[0][3]);
            acc[1][0] = fmaf(a1, bv.x, acc[1][0]); acc[1][1] = fmaf(a1, bv.y, acc[1][1]);
            acc[1][2] = fmaf(a1, bv.z, acc[1][2]); acc[1][3] = fmaf(a1, bv.w, acc[1][3]);
            acc[2][0] = fmaf(a2, bv.x, acc[2][0]); acc[2][1] = fmaf(a2, bv.y, acc[2][1]);
            acc[2][2] = fmaf(a2, bv.z, acc[2][2]); acc[2][3] = fmaf(a2, bv.w, acc[2][3]);
            acc[3][0] = fmaf(a3, bv.x, acc[3][0]); acc[3][1] = fmaf(a3, bv.y, acc[3][1]);
            acc[3][2] = fmaf(a3, bv.z, acc[3][2]); acc[3][3] = fmaf(a3, bv.w, acc[3][3]);
        }
        __syncthreads();
    }
#pragma unroll
    for (int i = 0; i < 4; ++i) {
        int r = row0 + ty * 4 + i;
        int c = col0 + tx * 4;
        float4 o;
        o.x = acc[i][0]; o.y = acc[i][1]; o.z = acc[i][2]; o.w = acc[i][3];
        if (bias) { o.x += bias[c]; o.y += bias[c + 1]; o.z += bias[c + 2]; o.w += bias[c + 3]; }
        if (add) {
            const float* ad = add + (size_t)r * ldadd + c;
            o.x += ad[0]; o.y += ad[1]; o.z += ad[2]; o.w += ad[3];
        }
        *(float4*)(C + (size_t)r * ldc + c) = o;
    }
}

// ---------------- depthwise causal conv + silu ----------------
__global__ __launch_bounds__(256) void conv_k(const float* __restrict__ xz,
                                              const float* __restrict__ cw,
                                              const float* __restrict__ cb,
                                              float* __restrict__ xc) {
    int gid = blockIdx.x * 256 + threadIdx.x;
    int d = gid & (DI - 1);
    int t = gid >> 10;
    int n = t & (N - 1);
    float acc = cb[d];
    const float* base = xz + (size_t)t * (2 * DI) + d;
#pragma unroll
    for (int k = 0; k < DC; ++k) {
        int nn = n - (DC - 1) + k;
        if (nn >= 0) acc += base[(long)(nn - n) * (2 * DI)] * cw[d * DC + k];
    }
    float s = 1.f / (1.f + expf(-acc));
    xc[gid] = acc * s;
}

// ---------------- x_ssm = xc @ xp_w (1024 x 33) ----------------
__global__ __launch_bounds__(256) void xssm_k(const float* __restrict__ xc,
                                              const float* __restrict__ xpw,
                                              float* __restrict__ xssm) {
    int t = blockIdx.x;
    __shared__ float row[DI];
    int tid = threadIdx.x;
    for (int i = tid; i < DI; i += 256) row[i] = xc[(size_t)t * DI + i];
    __syncthreads();
    int j = tid >> 2;
    int part = tid & 3;
    if (j < 33) {
        float acc = 0.f;
        int c0 = part * 256;
        for (int c = c0; c < c0 + 256; ++c) acc += row[c] * xpw[c * 33 + j];
        acc += __shfl_xor(acc, 1);
        acc += __shfl_xor(acc, 2);
        if (part == 0) xssm[t * 33 + j] = acc;
    }
}

// ---------------- h1 (token scalar -> 256) ----------------
__global__ __launch_bounds__(256) void h1_k(const float* __restrict__ imp,
                                            const float* __restrict__ w1,
                                            const float* __restrict__ b1,
                                            float* __restrict__ h1) {
    int t = blockIdx.x, tid = threadIdx.x;
    float v = imp[t] * w1[tid] + b1[tid];
    h1[(size_t)t * DI4 + tid] = fmaxf(v, 0.f);
}

// ---------------- delta = softplus(draw*dt_w+dt_b) * (1 + sigmoid(modl)) ----------------
__global__ __launch_bounds__(256) void delta_k(const float* __restrict__ modl,
                                               const float* __restrict__ xssm,
                                               const float* __restrict__ dtw,
                                               const float* __restrict__ dtb,
                                               float* __restrict__ delta) {
    int gid = blockIdx.x * 256 + threadIdx.x;
    int t = gid >> 10, d = gid & (DI - 1);
    float draw = xssm[t * 33];
    float a = draw * dtw[d] + dtb[d];
    float sp = (a > 20.f) ? a : log1pf(expf(a));
    float mod = 1.f / (1.f + expf(-modl[gid]));
    delta[gid] = sp * (1.f + mod);
}

// ---------------- sequential SSM scan, LDS chunk-staged double-buffered ----------------
// Block: 256 thr, handles batch b = blk>>6, channels d0..d0+15.
// Chunk = 64 tokens. Stage delta/xc/z/B/C for chunk k+1 while computing chunk k.
__global__ __launch_bounds__(256) void scan_k(const float* __restrict__ delta,
                                              const float* __restrict__ xc,
                                              const float* __restrict__ xssm,
                                              const float* __restrict__ Alog,
                                              const float* __restrict__ Dp,
                                              const float* __restrict__ xz,
                                              float* __restrict__ y) {
    int blk = blockIdx.x;            // 256 blocks
    int b = blk >> 6;
    int d0 = (blk & 63) * 16;
    int tid = threadIdx.x;
    int wave = tid >> 6;
    int lane = tid & 63;
    int s = lane & 15;               // state index
    int dd = lane >> 4;
    int dl = wave * 4 + dd;          // local channel 0..15
    int d = d0 + dl;
    float A = -__expf(Alog[d * DS + s]);
    float dpv = Dp[d];
    size_t tokbase = (size_t)b * N;

    __shared__ float sdel[2][64][16];
    __shared__ float sxcv[2][64][16];
    __shared__ float szv_[2][64][16];
    __shared__ float sBv_[2][64][16];
    __shared__ float sCv_[2][64][16];
    __shared__ float sY[64][16];

    // loader mapping: lc = channel 0..15, lr = token-row 0..15 (x4 passes = 64 tokens)
    int lc = tid & 15, lr = tid >> 4;
    float rdel[4], rxc[4], rz[4], rB[4], rC[4];

    const float* dbase = delta + tokbase * DI + d0 + lc;
    const float* xbase = xc + tokbase * DI + d0 + lc;
    const float* zbase = xz + tokbase * (2 * DI) + DI + d0 + lc;
    const float* sbase = xssm + tokbase * 33;

    auto issue = [&](int chunk) {
        int t0 = chunk * 64;
#pragma unroll
        for (int q = 0; q < 4; ++q) {
            int tok = t0 + q * 16 + lr;
            rdel[q] = dbase[(size_t)tok * DI];
            rxc[q]  = xbase[(size_t)tok * DI];
            rz[q]   = zbase[(size_t)tok * (2 * DI)];
            rB[q]   = sbase[(size_t)tok * 33 + 1 + lc];
            rC[q]   = sbase[(size_t)tok * 33 + 1 + DS + lc];
        }
    };
    auto commit = [&](int buf) {
#pragma unroll
        for (int q = 0; q < 4; ++q) {
            int tr = q * 16 + lr;
            sdel[buf][tr][lc] = rdel[q];
            sxcv[buf][tr][lc] = rxc[q];
            szv_[buf][tr][lc] = rz[q];
            sBv_[buf][tr][lc] = rB[q];
            sCv_[buf][tr][lc] = rC[q];
        }
    };

    issue(0);
    commit(0);
    __syncthreads();

    float h = 0.f;
    int cur = 0;
    for (int chunk = 0; chunk < 16; ++chunk) {
        if (chunk + 1 < 16) issue(chunk + 1);
        int t0 = chunk * 64;
#pragma unroll 4
        for (int t = 0; t < 64; ++t) {
            float dlt = sdel[cur][t][dl];
            float xcv = sxcv[cur][t][dl];
            float Bv  = sBv_[cur][t][s];
            float Cv  = sCv_[cur][t][s];
            float a = __expf(dlt * A);
            h = a * h + (dlt * Bv) * xcv;
            float p = h * Cv;
            p += __shfl_xor(p, 1); p += __shfl_xor(p, 2);
            p += __shfl_xor(p, 4); p += __shfl_xor(p, 8);
            if (s == 0) {
                float zv = szv_[cur][t][dl];
                float sg = 1.f / (1.f + __expf(-zv));
                sY[t][dl] = (p + xcv * dpv) * (zv * sg);
            }
        }
        __syncthreads();
        // coalesced y store for this chunk
        float* ybase = y + (tokbase + t0) * DI + d0 + lc;
#pragma unroll
        for (int q = 0; q < 4; ++q) {
            int tr = q * 16 + lr;
            ybase[(size_t)tr * DI] = sY[tr][lc];
        }
        if (chunk + 1 < 16) commit(cur ^ 1);
        __syncthreads();
        cur ^= 1;
    }
}

// ---------------- concat [xf | flip(xb)] ----------------
__global__ __launch_bounds__(256) void concat_k(const float* __restrict__ xf,
                                                const float* __restrict__ xb,
                                                float* __restrict__ cat) {
    int gid = blockIdx.x * 256 + threadIdx.x;   // TT*DM
    int t = gid >> 9;
    int c = gid & (DM - 1);
    int b = t >> 10, j = t & (N - 1);
    cat[(size_t)t * (2 * DM) + c] = xf[gid];
    cat[(size_t)t * (2 * DM) + DM + c] = xb[((size_t)(b << 10) + (N - 1 - j)) * DM + c];
}

// ---------------- final: scatter by ridx + layernorm ----------------
__global__ __launch_bounds__(256) void final_k(const float* __restrict__ fus,
                                               const int* __restrict__ ridx,
                                               const float* __restrict__ g,
                                               const float* __restrict__ bt,
                                               float* __restrict__ out) {
    int t = blockIdx.x, tid = threadIdx.x;
    int b = t >> 10;
    int r = ridx[t];
    const float* xr = fus + (size_t)t * DM;
    __shared__ float red[256];
    float v0 = xr[tid], v1 = xr[tid + 256];
    red[tid] = v0 + v1; __syncthreads();
    for (int st = 128; st > 0; st >>= 1) { if (tid < st) red[tid] += red[tid + st]; __syncthreads(); }
    float mu = red[0] * (1.f / DM); __syncthreads();
    float d0 = v0 - mu, d1 = v1 - mu;
    red[tid] = d0 * d0 + d1 * d1; __syncthreads();
    for (int st = 128; st > 0; st >>= 1) { if (tid < st) red[tid] += red[tid + st]; __syncthreads(); }
    float rs = rsqrtf(red[0] * (1.f / DM) + 1e-5f);
    float* orow = out + ((size_t)(b << 10) + r) * DM;
    orow[tid] = d0 * rs * g[tid] + bt[tid];
    orow[tid + 256] = d1 * rs * g[tid + 256] + bt[tid + 256];
}

// ---------------- host ----------------
extern "C" void kernel_launch(void* const* d_in, const int* in_sizes, int n_in,
                              void* d_out, int out_size, void* d_ws, size_t ws_size,
                              hipStream_t stream) {
    const float* x            = (const float*)d_in[0];
    const float* centers_init = (const float*)d_in[1];
    const float* in_w         = (const float*)d_in[2];
    const float* conv_w       = (const float*)d_in[3];
    const float* conv_b       = (const float*)d_in[4];
    const float* xp_w         = (const float*)d_in[5];
    const float* dt_w         = (const float*)d_in[6];
    const float* dt_b         = (const float*)d_in[7];
    const float* cm_w1        = (const float*)d_in[8];
    const float* cm_b1        = (const float*)d_in[9];
    const float* cm_w2        = (const float*)d_in[10];
    const float* cm_b2        = (const float*)d_in[11];
    const float* A_log        = (const float*)d_in[12];
    const float* D_p          = (const float*)d_in[13];
    const float* out_w        = (const float*)d_in[14];
    const float* ln_g         = (const float*)d_in[15];
    const float* ln_b         = (const float*)d_in[16];
    const float* fusion_w     = (const float*)d_in[17];
    const float* fusion_b     = (const float*)d_in[18];
    const float* fn_g         = (const float*)d_in[19];
    const float* fn_b         = (const float*)d_in[20];

    float* W = (float*)d_ws;
    size_t off = 0;
    auto alloc = [&](size_t n) { float* p = W + off; off += n; return p; };
    float* centers = alloc((size_t)Bb * KC * DM);
    float* wgt     = alloc((size_t)TT * KC);
    float* mind    = alloc(TT);
    float* keys    = alloc(TT);
    float* imp     = alloc(TT);
    float* rimp    = alloc(TT);
    float* fimp    = alloc(TT);
    float* rx      = alloc((size_t)TT * DM);
    float* rxf     = alloc((size_t)TT * DM);
    float* bufA    = alloc((size_t)TT * DM);
    float* bufC    = alloc((size_t)TT * DM);
    float* xn      = alloc((size_t)TT * DM);       // reused as h1buf
    float* xz      = alloc((size_t)TT * 2 * DI);   // reused as cat
    float* xc      = alloc((size_t)TT * DI);       // reused as fus
    float* xssm    = alloc((size_t)TT * 33);
    float* modl    = alloc((size_t)TT * DI);       // reused as scan output y
    float* delta   = alloc((size_t)TT * DI);
    int* ridx = (int*)(W + off); off += TT;

    // ---- k-means ----
    initcen_k<<<(Bb * KC * DM) / 256, 256, 0, stream>>>(centers_init, centers);
    for (int it = 0; it < 3; ++it) {
        assign_k<false><<<TT, 64, 0, stream>>>(x, centers, wgt, nullptr, nullptr);
        update_k<<<Bb * KC, 512, 0, stream>>>(x, wgt, centers);
    }
    assign_k<true><<<TT, 64, 0, stream>>>(x, centers, wgt, mind, keys);
    importance_k<<<Bb, 1024, 0, stream>>>(mind, imp);
    sort_k<<<Bb, 1024, 0, stream>>>(keys, ridx);
    gather_k<<<TT, 512, 0, stream>>>(x, imp, ridx, rx, rxf, rimp, fimp);

    auto gemm = [&](const float* Ap, int lda, const float* Bp, int ldb,
                    const float* bias, const float* add, int ldadd,
                    float* Cp, int ldc, int Kd, int Nn) {
        dim3 g(Nn / 64, TT / 64);
        gemm_k<<<g, 256, 0, stream>>>(Ap, lda, Bp, ldb, bias, add, ldadd, Cp, ldc, Kd);
    };

    // ---- 4 mamba layers (2 fwd, 2 bwd on flipped) ----
    const float* lay_in[4]  = {rx, bufA, rxf, bufC};
    float*       lay_out[4] = {bufA, rx, bufC, rxf};
    for (int l = 0; l < L4; ++l) {
        const float* xin = lay_in[l];
        float* xout = lay_out[l];
        const float* impv = (l < 2) ? rimp : fimp;
        ln_k<<<TT, 256, 0, stream>>>(xin, ln_g + (size_t)l * DM, ln_b + (size_t)l * DM, xn);
        gemm(xn, DM, in_w + (size_t)l * DM * 2 * DI, 2 * DI, nullptr, nullptr, 0, xz, 2 * DI, DM, 2 * DI);
        conv_k<<<(TT * DI) / 256, 256, 0, stream>>>(xz, conv_w + (size_t)l * DI * DC, conv_b + (size_t)l * DI, xc);
        xssm_k<<<TT, 256, 0, stream>>>(xc, xp_w + (size_t)l * DI * 33, xssm);
        h1_k<<<TT, 256, 0, stream>>>(impv, cm_w1 + (size_t)l * DI4, cm_b1 + (size_t)l * DI4, xn);
        gemm(xn, DI4, cm_w2 + (size_t)l * DI4 * DI, DI, cm_b2 + (size_t)l * DI, nullptr, 0, modl, DI, DI4, DI);
        delta_k<<<(TT * DI) / 256, 256, 0, stream>>>(modl, xssm, dt_w + (size_t)l * DI, dt_b + (size_t)l * DI, delta);
        scan_k<<<256, 256, 0, stream>>>(delta, xc, xssm, A_log + (size_t)l * DI * DS, D_p + (size_t)l * DI, xz, modl);
        gemm(modl, DI, out_w + (size_t)l * DI * DM, DM, nullptr, xin, DM, xout, DM, DI, DM);
    }

    // ---- fusion + restore + final LN ----
    concat_k<<<(TT * DM) / 256, 256, 0, stream>>>(rx /*xf final*/, rxf /*xb final*/, xz /*cat*/);
    gemm(xz, 2 * DM, fusion_w, DM, fusion_b, nullptr, 0, xc /*fus*/, DM, 2 * DM, DM);
    final_k<<<TT, 256, 0, stream>>>(xc, ridx, fn_g, fn_b, (float*)d_out);
}

// Round 3
// 2036.953 us; speedup vs baseline: 1.6825x; 1.3910x over previous
//
#include <hip/hip_runtime.h>
#include <math.h>

// ---------------- constants ----------------
constexpr int DM = 512, DS = 16, DC = 4, DI = 1024, DI4 = 256, KC = 5;
constexpr int Bb = 4, N = 1024, L4 = 4, TT = Bb * N;
constexpr float TEMP = 0.5f;

// ---------------- k-means ----------------
__global__ void initcen_k(const float* __restrict__ ci, float* __restrict__ centers) {
    int gid = blockIdx.x * 256 + threadIdx.x;           // B*KC*DM = 10240
    centers[gid] = ci[gid % (KC * DM)];
}

template <bool FINAL>
__global__ __launch_bounds__(64) void assign_k(const float* __restrict__ x,
                                               const float* __restrict__ centers,
                                               float* __restrict__ wgt,
                                               float* __restrict__ mind,
                                               float* __restrict__ keys) {
    int t = blockIdx.x;            // token 0..TT-1
    int b = t >> 10;
    int lane = threadIdx.x;
    const float* xr = x + (size_t)t * DM;
    const float* cen = centers + (size_t)b * KC * DM;
    float d2[KC] = {0.f, 0.f, 0.f, 0.f, 0.f};
    for (int c = lane; c < DM; c += 64) {
        float xv = xr[c];
#pragma unroll
        for (int k = 0; k < KC; ++k) {
            float df = xv - cen[k * DM + c];
            d2[k] += df * df;
        }
    }
#pragma unroll
    for (int k = 0; k < KC; ++k)
        for (int off = 32; off > 0; off >>= 1) d2[k] += __shfl_xor(d2[k], off);
    if (lane == 0) {
        float dist[KC], logit[KC], e[KC];
        float lm = -1e30f;
        for (int k = 0; k < KC; ++k) {
            dist[k] = sqrtf(d2[k] + 1e-12f);
            logit[k] = -dist[k] / TEMP;
            lm = fmaxf(lm, logit[k]);
        }
        float s = 0.f;
        for (int k = 0; k < KC; ++k) { e[k] = expf(logit[k] - lm); s += e[k]; }
        float inv = 1.f / s;
        for (int k = 0; k < KC; ++k) wgt[t * KC + k] = e[k] * inv;
        if (FINAL) {
            float md = dist[0];
            for (int k = 1; k < KC; ++k) md = fminf(md, dist[k]);
            int ca = 0; float best = e[0] * inv;
            for (int k = 1; k < KC; ++k) {
                float wv = e[k] * inv;
                if (wv > best) { best = wv; ca = k; }
            }
            mind[t] = md;
            keys[t] = (float)ca * 1000.0f + (1.0f - best);
        }
    }
}

__global__ __launch_bounds__(512) void update_k(const float* __restrict__ x,
                                                const float* __restrict__ wgt,
                                                float* __restrict__ centers) {
    int b = blockIdx.x / KC, k = blockIdx.x % KC;
    int c = threadIdx.x;    // 0..511
    __shared__ float sden[512];
    const float* xb = x + (size_t)b * N * DM;
    const float* wb = wgt + (size_t)b * N * KC + k;
    float acc = 0.f;
    for (int n = 0; n < N; ++n) acc += wb[(size_t)n * KC] * xb[(size_t)n * DM + c];
    float dn = wb[(size_t)c * KC] + wb[(size_t)(c + 512) * KC];
    sden[c] = dn; __syncthreads();
    for (int st = 256; st > 0; st >>= 1) { if (c < st) sden[c] += sden[c + st]; __syncthreads(); }
    float den = sden[0];
    centers[((size_t)b * KC + k) * DM + c] = acc / (den + 1e-8f);
}

__global__ __launch_bounds__(1024) void importance_k(const float* __restrict__ mind,
                                                     float* __restrict__ imp) {
    int b = blockIdx.x, n = threadIdx.x;
    __shared__ float red[1024];
    float v = -mind[b * N + n] / TEMP;
    red[n] = v; __syncthreads();
    for (int s = 512; s > 0; s >>= 1) { if (n < s) red[n] = fmaxf(red[n], red[n + s]); __syncthreads(); }
    float m = red[0]; __syncthreads();
    float e = expf(v - m);
    red[n] = e; __syncthreads();
    for (int s = 512; s > 0; s >>= 1) { if (n < s) red[n] += red[n + s]; __syncthreads(); }
    imp[b * N + n] = e / red[0];
}

__global__ __launch_bounds__(1024) void sort_k(const float* __restrict__ keys,
                                               int* __restrict__ ridx) {
    int b = blockIdx.x, tid = threadIdx.x;
    __shared__ unsigned long long a[1024];
    unsigned int kb = __float_as_uint(keys[b * N + tid]);   // keys >= 0
    a[tid] = ((unsigned long long)kb << 32) | (unsigned int)tid;
    __syncthreads();
    for (int k = 2; k <= 1024; k <<= 1) {
        for (int j = k >> 1; j > 0; j >>= 1) {
            int ixj = tid ^ j;
            if (ixj > tid) {
                unsigned long long x0 = a[tid], x1 = a[ixj];
                bool up = ((tid & k) == 0);
                bool sw = up ? (x0 > x1) : (x0 < x1);
                if (sw) { a[tid] = x1; a[ixj] = x0; }
            }
            __syncthreads();
        }
    }
    ridx[b * N + tid] = (int)(a[tid] & 0xffffffffu);
}

__global__ __launch_bounds__(512) void gather_k(const float* __restrict__ x,
                                                const float* __restrict__ imp,
                                                const int* __restrict__ ridx,
                                                float* __restrict__ rx, float* __restrict__ rxf,
                                                float* __restrict__ rimp, float* __restrict__ fimp) {
    int t = blockIdx.x;
    int b = t >> 10, j = t & (N - 1);
    int r = ridx[t];
    int c = threadIdx.x;
    float v = x[((size_t)(b << 10) + r) * DM + c];
    rx[(size_t)t * DM + c] = v;
    rxf[((size_t)(b << 10) + (N - 1 - j)) * DM + c] = v;
    if (c == 0) {
        float iv = imp[(b << 10) + r];
        rimp[t] = iv;
        fimp[(b << 10) + (N - 1 - j)] = iv;
    }
}

// ---------------- layernorm ----------------
__global__ __launch_bounds__(256) void ln_k(const float* __restrict__ xin,
                                            const float* __restrict__ g,
                                            const float* __restrict__ bt,
                                            float* __restrict__ out) {
    int t = blockIdx.x, tid = threadIdx.x;
    const float* xr = xin + (size_t)t * DM;
    __shared__ float red[256];
    float v0 = xr[tid], v1 = xr[tid + 256];
    red[tid] = v0 + v1; __syncthreads();
    for (int st = 128; st > 0; st >>= 1) { if (tid < st) red[tid] += red[tid + st]; __syncthreads(); }
    float mu = red[0] * (1.f / DM); __syncthreads();
    float d0 = v0 - mu, d1 = v1 - mu;
    red[tid] = d0 * d0 + d1 * d1; __syncthreads();
    for (int st = 128; st > 0; st >>= 1) { if (tid < st) red[tid] += red[tid + st]; __syncthreads(); }
    float rs = rsqrtf(red[0] * (1.f / DM) + 1e-5f);
    out[(size_t)t * DM + tid] = d0 * rs * g[tid] + bt[tid];
    out[(size_t)t * DM + tid + 256] = d1 * rs * g[tid + 256] + bt[tid + 256];
}

// ---------------- generic f32 GEMM: C[M=4096 x Nn] = A[. x K] * B[K x Nn] (+bias)(+add) ----------------
__global__ __launch_bounds__(256) void gemm_k(const float* __restrict__ A, int lda,
                                              const float* __restrict__ Bw, int ldb,
                                              const float* __restrict__ bias,
                                              const float* __restrict__ add, int ldadd,
                                              float* __restrict__ C, int ldc, int Kdim) {
    __shared__ float As[16][68];
    __shared__ float Bs[16][64];
    int tid = threadIdx.x;
    int tx = tid & 15, ty = tid >> 4;
    int row0 = blockIdx.y * 64, col0 = blockIdx.x * 64;
    float acc[4][4] = {};
    int ar = tid >> 2, ak = (tid & 3) * 4;
    int bcol = tid & 63, bk0 = (tid >> 6) * 4;
    for (int k0 = 0; k0 < Kdim; k0 += 16) {
        float4 av = *(const float4*)(A + (size_t)(row0 + ar) * lda + k0 + ak);
        As[ak + 0][ar] = av.x; As[ak + 1][ar] = av.y; As[ak + 2][ar] = av.z; As[ak + 3][ar] = av.w;
#pragma unroll
        for (int q = 0; q < 4; ++q)
            Bs[bk0 + q][bcol] = Bw[(size_t)(k0 + bk0 + q) * ldb + col0 + bcol];
        __syncthreads();
#pragma unroll
        for (int k = 0; k < 16; ++k) {
            const float4 bv = *(const float4*)&Bs[k][tx * 4];
            const float a0 = As[k][ty * 4 + 0];
            const float a1 = As[k][ty * 4 + 1];
            const float a2 = As[k][ty * 4 + 2];
            const float a3 = As[k][ty * 4 + 3];
            acc[0][0] = fmaf(a0, bv.x, acc[0][0]); acc[0][1] = fmaf(a0, bv.y, acc[0][1]);
            acc[0][2] = fmaf(a0, bv.z, acc[0][2]); acc[0][3] = fmaf(a0, bv.w, acc[0][3]);
            acc[1][0] = fmaf(a1, bv.x, acc[1][0]); acc[1][1] = fmaf(a1, bv.y, acc[1][1]);
            acc[1][2] = fmaf(a1, bv.z, acc[1][2]); acc[1][3] = fmaf(a1, bv.w, acc[1][3]);
            acc[2][0] = fmaf(a2, bv.x, acc[2][0]); acc[2][1] = fmaf(a2, bv.y, acc[2][1]);
            acc[2][2] = fmaf(a2, bv.z, acc[2][2]); acc[2][3] = fmaf(a2, bv.w, acc[2][3]);
            acc[3][0] = fmaf(a3, bv.x, acc[3][0]); acc[3][1] = fmaf(a3, bv.y, acc[3][1]);
            acc[3][2] = fmaf(a3, bv.z, acc[3][2]); acc[3][3] = fmaf(a3, bv.w, acc[3][3]);
        }
        __syncthreads();
    }
#pragma unroll
    for (int i = 0; i < 4; ++i) {
        int r = row0 + ty * 4 + i;
        int c = col0 + tx * 4;
        float4 o;
        o.x = acc[i][0]; o.y = acc[i][1]; o.z = acc[i][2]; o.w = acc[i][3];
        if (bias) { o.x += bias[c]; o.y += bias[c + 1]; o.z += bias[c + 2]; o.w += bias[c + 3]; }
        if (add) {
            const float* ad = add + (size_t)r * ldadd + c;
            o.x += ad[0]; o.y += ad[1]; o.z += ad[2]; o.w += ad[3];
        }
        *(float4*)(C + (size_t)r * ldc + c) = o;
    }
}

// ---------------- depthwise causal conv + silu ----------------
__global__ __launch_bounds__(256) void conv_k(const float* __restrict__ xz,
                                              const float* __restrict__ cw,
                                              const float* __restrict__ cb,
                                              float* __restrict__ xc) {
    int gid = blockIdx.x * 256 + threadIdx.x;
    int d = gid & (DI - 1);
    int t = gid >> 10;
    int n = t & (N - 1);
    float acc = cb[d];
    const float* base = xz + (size_t)t * (2 * DI) + d;
#pragma unroll
    for (int k = 0; k < DC; ++k) {
        int nn = n - (DC - 1) + k;
        if (nn >= 0) acc += base[(long)(nn - n) * (2 * DI)] * cw[d * DC + k];
    }
    float s = 1.f / (1.f + expf(-acc));
    xc[gid] = acc * s;
}

// ---------------- x_ssm = xc @ xp_w (1024 x 33) ----------------
__global__ __launch_bounds__(256) void xssm_k(const float* __restrict__ xc,
                                              const float* __restrict__ xpw,
                                              float* __restrict__ xssm) {
    int t = blockIdx.x;
    __shared__ float row[DI];
    int tid = threadIdx.x;
    for (int i = tid; i < DI; i += 256) row[i] = xc[(size_t)t * DI + i];
    __syncthreads();
    int j = tid >> 2;
    int part = tid & 3;
    if (j < 33) {
        float acc = 0.f;
        int c0 = part * 256;
        for (int c = c0; c < c0 + 256; ++c) acc += row[c] * xpw[c * 33 + j];
        acc += __shfl_xor(acc, 1);
        acc += __shfl_xor(acc, 2);
        if (part == 0) xssm[t * 33 + j] = acc;
    }
}

// ---------------- h1 (token scalar -> 256) ----------------
__global__ __launch_bounds__(256) void h1_k(const float* __restrict__ imp,
                                            const float* __restrict__ w1,
                                            const float* __restrict__ b1,
                                            float* __restrict__ h1) {
    int t = blockIdx.x, tid = threadIdx.x;
    float v = imp[t] * w1[tid] + b1[tid];
    h1[(size_t)t * DI4 + tid] = fmaxf(v, 0.f);
}

// ---------------- delta = softplus(draw*dt_w+dt_b) * (1 + sigmoid(modl)) ----------------
__global__ __launch_bounds__(256) void delta_k(const float* __restrict__ modl,
                                               const float* __restrict__ xssm,
                                               const float* __restrict__ dtw,
                                               const float* __restrict__ dtb,
                                               float* __restrict__ delta) {
    int gid = blockIdx.x * 256 + threadIdx.x;
    int t = gid >> 10, d = gid & (DI - 1);
    float draw = xssm[t * 33];
    float a = draw * dtw[d] + dtb[d];
    float sp = (a > 20.f) ? a : log1pf(expf(a));
    float mod = 1.f / (1.f + expf(-modl[gid]));
    delta[gid] = sp * (1.f + mod);
}

// ---------------- sequential SSM scan, LDS chunk-staged, DEFERRED s-reduction ----------------
// Block: 256 thr, batch b = blk>>6, channels d0..d0+15.
// Serial loop per lane (channel dl, state s): h = a*h + b, p = h*C -> sP.
// Per-chunk reduce pass sums sP over s, applies D_p + silu(z) gate, stores y.
__global__ __launch_bounds__(256) void scan_k(const float* __restrict__ delta,
                                              const float* __restrict__ xc,
                                              const float* __restrict__ xssm,
                                              const float* __restrict__ Alog,
                                              const float* __restrict__ Dp,
                                              const float* __restrict__ xz,
                                              float* __restrict__ y) {
    int blk = blockIdx.x;            // 256 blocks
    int b = blk >> 6;
    int d0 = (blk & 63) * 16;
    int tid = threadIdx.x;
    int wave = tid >> 6;
    int lane = tid & 63;
    int s = lane & 15;               // state index
    int dd = lane >> 4;
    int dl = wave * 4 + dd;          // local channel 0..15
    int d = d0 + dl;
    float A = -__expf(Alog[d * DS + s]);
    size_t tokbase = (size_t)b * N;

    __shared__ float sdel[2][64][16];
    __shared__ float sxcv[2][64][16];
    __shared__ float szv_[2][64][16];
    __shared__ float sBv_[2][64][16];
    __shared__ float sCv_[2][64][16];
    __shared__ float sP[64][16][17];   // [t][dl][s] padded: reduce reads are 2-way (free)

    // loader/reducer mapping: lc = channel 0..15, lr = token-row 0..15
    int lc = tid & 15, lr = tid >> 4;
    float dpv = Dp[d0 + lc];
    float rdel[4], rxc[4], rz[4], rB[4], rC[4];

    const float* dbase = delta + tokbase * DI + d0 + lc;
    const float* xbase = xc + tokbase * DI + d0 + lc;
    const float* zbase = xz + tokbase * (2 * DI) + DI + d0 + lc;
    const float* sbase = xssm + tokbase * 33;

    auto issue = [&](int chunk) {
        int t0 = chunk * 64;
#pragma unroll
        for (int q = 0; q < 4; ++q) {
            int tok = t0 + q * 16 + lr;
            rdel[q] = dbase[(size_t)tok * DI];
            rxc[q]  = xbase[(size_t)tok * DI];
            rz[q]   = zbase[(size_t)tok * (2 * DI)];
            rB[q]   = sbase[(size_t)tok * 33 + 1 + lc];
            rC[q]   = sbase[(size_t)tok * 33 + 1 + DS + lc];
        }
    };
    auto commit = [&](int buf) {
#pragma unroll
        for (int q = 0; q < 4; ++q) {
            int tr = q * 16 + lr;
            sdel[buf][tr][lc] = rdel[q];
            sxcv[buf][tr][lc] = rxc[q];
            szv_[buf][tr][lc] = rz[q];
            sBv_[buf][tr][lc] = rB[q];
            sCv_[buf][tr][lc] = rC[q];
        }
    };

    issue(0);
    commit(0);
    __syncthreads();

    float h = 0.f;
    int cur = 0;
    for (int chunk = 0; chunk < 16; ++chunk) {
        if (chunk + 1 < 16) issue(chunk + 1);
        // ---- serial phase: only loop-carried dep is one fmaf ----
#pragma unroll
        for (int g = 0; g < 8; ++g) {
            float a8[8], b8[8], c8[8];
#pragma unroll
            for (int j = 0; j < 8; ++j) {
                int t = g * 8 + j;
                float dlt = sdel[cur][t][dl];
                float xcv = sxcv[cur][t][dl];
                float Bv  = sBv_[cur][t][s];
                c8[j] = sCv_[cur][t][s];
                a8[j] = __expf(dlt * A);
                b8[j] = (dlt * Bv) * xcv;
            }
#pragma unroll
            for (int j = 0; j < 8; ++j) {
                int t = g * 8 + j;
                h = fmaf(a8[j], h, b8[j]);
                sP[t][dl][s] = h * c8[j];
            }
        }
        __syncthreads();
        // ---- parallel reduce + gate + store ----
        {
            int t0 = chunk * 64;
#pragma unroll
            for (int q = 0; q < 4; ++q) {
                int t = q * 16 + lr;
                float ssum = 0.f;
#pragma unroll
                for (int s2 = 0; s2 < 16; ++s2) ssum += sP[t][lc][s2];
                float xcv = sxcv[cur][t][lc];
                float zv  = szv_[cur][t][lc];
                float sg = 1.f / (1.f + __expf(-zv));
                y[(tokbase + t0 + t) * DI + d0 + lc] = (ssum + xcv * dpv) * (zv * sg);
            }
        }
        if (chunk + 1 < 16) commit(cur ^ 1);
        __syncthreads();
        cur ^= 1;
    }
}

// ---------------- concat [xf | flip(xb)] ----------------
__global__ __launch_bounds__(256) void concat_k(const float* __restrict__ xf,
                                                const float* __restrict__ xb,
                                                float* __restrict__ cat) {
    int gid = blockIdx.x * 256 + threadIdx.x;   // TT*DM
    int t = gid >> 9;
    int c = gid & (DM - 1);
    int b = t >> 10, j = t & (N - 1);
    cat[(size_t)t * (2 * DM) + c] = xf[gid];
    cat[(size_t)t * (2 * DM) + DM + c] = xb[((size_t)(b << 10) + (N - 1 - j)) * DM + c];
}

// ---------------- final: scatter by ridx + layernorm ----------------
__global__ __launch_bounds__(256) void final_k(const float* __restrict__ fus,
                                               const int* __restrict__ ridx,
                                               const float* __restrict__ g,
                                               const float* __restrict__ bt,
                                               float* __restrict__ out) {
    int t = blockIdx.x, tid = threadIdx.x;
    int b = t >> 10;
    int r = ridx[t];
    const float* xr = fus + (size_t)t * DM;
    __shared__ float red[256];
    float v0 = xr[tid], v1 = xr[tid + 256];
    red[tid] = v0 + v1; __syncthreads();
    for (int st = 128; st > 0; st >>= 1) { if (tid < st) red[tid] += red[tid + st]; __syncthreads(); }
    float mu = red[0] * (1.f / DM); __syncthreads();
    float d0 = v0 - mu, d1 = v1 - mu;
    red[tid] = d0 * d0 + d1 * d1; __syncthreads();
    for (int st = 128; st > 0; st >>= 1) { if (tid < st) red[tid] += red[tid + st]; __syncthreads(); }
    float rs = rsqrtf(red[0] * (1.f / DM) + 1e-5f);
    float* orow = out + ((size_t)(b << 10) + r) * DM;
    orow[tid] = d0 * rs * g[tid] + bt[tid];
    orow[tid + 256] = d1 * rs * g[tid + 256] + bt[tid + 256];
}

// ---------------- host ----------------
extern "C" void kernel_launch(void* const* d_in, const int* in_sizes, int n_in,
                              void* d_out, int out_size, void* d_ws, size_t ws_size,
                              hipStream_t stream) {
    const float* x            = (const float*)d_in[0];
    const float* centers_init = (const float*)d_in[1];
    const float* in_w         = (const float*)d_in[2];
    const float* conv_w       = (const float*)d_in[3];
    const float* conv_b       = (const float*)d_in[4];
    const float* xp_w         = (const float*)d_in[5];
    const float* dt_w         = (const float*)d_in[6];
    const float* dt_b         = (const float*)d_in[7];
    const float* cm_w1        = (const float*)d_in[8];
    const float* cm_b1        = (const float*)d_in[9];
    const float* cm_w2        = (const float*)d_in[10];
    const float* cm_b2        = (const float*)d_in[11];
    const float* A_log        = (const float*)d_in[12];
    const float* D_p          = (const float*)d_in[13];
    const float* out_w        = (const float*)d_in[14];
    const float* ln_g         = (const float*)d_in[15];
    const float* ln_b         = (const float*)d_in[16];
    const float* fusion_w     = (const float*)d_in[17];
    const float* fusion_b     = (const float*)d_in[18];
    const float* fn_g         = (const float*)d_in[19];
    const float* fn_b         = (const float*)d_in[20];

    float* W = (float*)d_ws;
    size_t off = 0;
    auto alloc = [&](size_t n) { float* p = W + off; off += n; return p; };
    float* centers = alloc((size_t)Bb * KC * DM);
    float* wgt     = alloc((size_t)TT * KC);
    float* mind    = alloc(TT);
    float* keys    = alloc(TT);
    float* imp     = alloc(TT);
    float* rimp    = alloc(TT);
    float* fimp    = alloc(TT);
    float* rx      = alloc((size_t)TT * DM);
    float* rxf     = alloc((size_t)TT * DM);
    float* bufA    = alloc((size_t)TT * DM);
    float* bufC    = alloc((size_t)TT * DM);
    float* xn      = alloc((size_t)TT * DM);       // reused as h1buf
    float* xz      = alloc((size_t)TT * 2 * DI);   // reused as cat
    float* xc      = alloc((size_t)TT * DI);       // reused as fus
    float* xssm    = alloc((size_t)TT * 33);
    float* modl    = alloc((size_t)TT * DI);       // reused as scan output y
    float* delta   = alloc((size_t)TT * DI);
    int* ridx = (int*)(W + off); off += TT;

    // ---- k-means ----
    initcen_k<<<(Bb * KC * DM) / 256, 256, 0, stream>>>(centers_init, centers);
    for (int it = 0; it < 3; ++it) {
        assign_k<false><<<TT, 64, 0, stream>>>(x, centers, wgt, nullptr, nullptr);
        update_k<<<Bb * KC, 512, 0, stream>>>(x, wgt, centers);
    }
    assign_k<true><<<TT, 64, 0, stream>>>(x, centers, wgt, mind, keys);
    importance_k<<<Bb, 1024, 0, stream>>>(mind, imp);
    sort_k<<<Bb, 1024, 0, stream>>>(keys, ridx);
    gather_k<<<TT, 512, 0, stream>>>(x, imp, ridx, rx, rxf, rimp, fimp);

    auto gemm = [&](const float* Ap, int lda, const float* Bp, int ldb,
                    const float* bias, const float* add, int ldadd,
                    float* Cp, int ldc, int Kd, int Nn) {
        dim3 g(Nn / 64, TT / 64);
        gemm_k<<<g, 256, 0, stream>>>(Ap, lda, Bp, ldb, bias, add, ldadd, Cp, ldc, Kd);
    };

    // ---- 4 mamba layers (2 fwd, 2 bwd on flipped) ----
    const float* lay_in[4]  = {rx, bufA, rxf, bufC};
    float*       lay_out[4] = {bufA, rx, bufC, rxf};
    for (int l = 0; l < L4; ++l) {
        const float* xin = lay_in[l];
        float* xout = lay_out[l];
        const float* impv = (l < 2) ? rimp : fimp;
        ln_k<<<TT, 256, 0, stream>>>(xin, ln_g + (size_t)l * DM, ln_b + (size_t)l * DM, xn);
        gemm(xn, DM, in_w + (size_t)l * DM * 2 * DI, 2 * DI, nullptr, nullptr, 0, xz, 2 * DI, DM, 2 * DI);
        conv_k<<<(TT * DI) / 256, 256, 0, stream>>>(xz, conv_w + (size_t)l * DI * DC, conv_b + (size_t)l * DI, xc);
        xssm_k<<<TT, 256, 0, stream>>>(xc, xp_w + (size_t)l * DI * 33, xssm);
        h1_k<<<TT, 256, 0, stream>>>(impv, cm_w1 + (size_t)l * DI4, cm_b1 + (size_t)l * DI4, xn);
        gemm(xn, DI4, cm_w2 + (size_t)l * DI4 * DI, DI, cm_b2 + (size_t)l * DI, nullptr, 0, modl, DI, DI4, DI);
        delta_k<<<(TT * DI) / 256, 256, 0, stream>>>(modl, xssm, dt_w + (size_t)l * DI, dt_b + (size_t)l * DI, delta);
        scan_k<<<256, 256, 0, stream>>>(delta, xc, xssm, A_log + (size_t)l * DI * DS, D_p + (size_t)l * DI, xz, modl);
        gemm(modl, DI, out_w + (size_t)l * DI * DM, DM, nullptr, xin, DM, xout, DM, DI, DM);
    }

    // ---- fusion + restore + final LN ----
    concat_k<<<(TT * DM) / 256, 256, 0, stream>>>(rx /*xf final*/, rxf /*xb final*/, xz /*cat*/);
    gemm(xz, 2 * DM, fusion_w, DM, fusion_b, nullptr, 0, xc /*fus*/, DM, 2 * DM, DM);
    final_k<<<TT, 256, 0, stream>>>(xc, ridx, fn_g, fn_b, (float*)d_out);
}

// Round 4
// 1384.325 us; speedup vs baseline: 2.4757x; 1.4714x over previous
//
#include <hip/hip_runtime.h>
#include <math.h>

// ---------------- constants ----------------
constexpr int DM = 512, DS = 16, DC = 4, DI = 1024, DI4 = 256, KC = 5;
constexpr int Bb = 4, N = 1024, L4 = 4, TT = Bb * N;
constexpr float TEMP = 0.5f;

typedef __attribute__((ext_vector_type(8))) short short8v;
typedef __attribute__((ext_vector_type(4))) float float4v;

__device__ inline ushort f2bf(float f) {
    union { float f; unsigned u; } v; v.f = f;
    unsigned r = v.u + 0x7FFFu + ((v.u >> 16) & 1u);
    return (ushort)(r >> 16);
}

// ---------------- k-means ----------------
__global__ void initcen_k(const float* __restrict__ ci, float* __restrict__ centers) {
    int gid = blockIdx.x * 256 + threadIdx.x;           // B*KC*DM = 10240
    centers[gid] = ci[gid % (KC * DM)];
}

template <bool FINAL>
__global__ __launch_bounds__(64) void assign_k(const float* __restrict__ x,
                                               const float* __restrict__ centers,
                                               float* __restrict__ wgt,
                                               float* __restrict__ mind,
                                               float* __restrict__ keys) {
    int t = blockIdx.x;            // token 0..TT-1
    int b = t >> 10;
    int lane = threadIdx.x;
    const float* xr = x + (size_t)t * DM;
    const float* cen = centers + (size_t)b * KC * DM;
    float d2[KC] = {0.f, 0.f, 0.f, 0.f, 0.f};
    for (int c = lane; c < DM; c += 64) {
        float xv = xr[c];
#pragma unroll
        for (int k = 0; k < KC; ++k) {
            float df = xv - cen[k * DM + c];
            d2[k] += df * df;
        }
    }
#pragma unroll
    for (int k = 0; k < KC; ++k)
        for (int off = 32; off > 0; off >>= 1) d2[k] += __shfl_xor(d2[k], off);
    if (lane == 0) {
        float dist[KC], logit[KC], e[KC];
        float lm = -1e30f;
        for (int k = 0; k < KC; ++k) {
            dist[k] = sqrtf(d2[k] + 1e-12f);
            logit[k] = -dist[k] / TEMP;
            lm = fmaxf(lm, logit[k]);
        }
        float s = 0.f;
        for (int k = 0; k < KC; ++k) { e[k] = expf(logit[k] - lm); s += e[k]; }
        float inv = 1.f / s;
        for (int k = 0; k < KC; ++k) wgt[t * KC + k] = e[k] * inv;
        if (FINAL) {
            float md = dist[0];
            for (int k = 1; k < KC; ++k) md = fminf(md, dist[k]);
            int ca = 0; float best = e[0] * inv;
            for (int k = 1; k < KC; ++k) {
                float wv = e[k] * inv;
                if (wv > best) { best = wv; ca = k; }
            }
            mind[t] = md;
            keys[t] = (float)ca * 1000.0f + (1.0f - best);
        }
    }
}

__global__ __launch_bounds__(512) void update_k(const float* __restrict__ x,
                                                const float* __restrict__ wgt,
                                                float* __restrict__ centers) {
    int b = blockIdx.x / KC, k = blockIdx.x % KC;
    int c = threadIdx.x;    // 0..511
    __shared__ float sden[512];
    const float* xb = x + (size_t)b * N * DM;
    const float* wb = wgt + (size_t)b * N * KC + k;
    float acc = 0.f;
    for (int n = 0; n < N; ++n) acc += wb[(size_t)n * KC] * xb[(size_t)n * DM + c];
    float dn = wb[(size_t)c * KC] + wb[(size_t)(c + 512) * KC];
    sden[c] = dn; __syncthreads();
    for (int st = 256; st > 0; st >>= 1) { if (c < st) sden[c] += sden[c + st]; __syncthreads(); }
    float den = sden[0];
    centers[((size_t)b * KC + k) * DM + c] = acc / (den + 1e-8f);
}

__global__ __launch_bounds__(1024) void importance_k(const float* __restrict__ mind,
                                                     float* __restrict__ imp) {
    int b = blockIdx.x, n = threadIdx.x;
    __shared__ float red[1024];
    float v = -mind[b * N + n] / TEMP;
    red[n] = v; __syncthreads();
    for (int s = 512; s > 0; s >>= 1) { if (n < s) red[n] = fmaxf(red[n], red[n + s]); __syncthreads(); }
    float m = red[0]; __syncthreads();
    float e = expf(v - m);
    red[n] = e; __syncthreads();
    for (int s = 512; s > 0; s >>= 1) { if (n < s) red[n] += red[n + s]; __syncthreads(); }
    imp[b * N + n] = e / red[0];
}

__global__ __launch_bounds__(1024) void sort_k(const float* __restrict__ keys,
                                               int* __restrict__ ridx) {
    int b = blockIdx.x, tid = threadIdx.x;
    __shared__ unsigned long long a[1024];
    unsigned int kb = __float_as_uint(keys[b * N + tid]);   // keys >= 0
    a[tid] = ((unsigned long long)kb << 32) | (unsigned int)tid;
    __syncthreads();
    for (int k = 2; k <= 1024; k <<= 1) {
        for (int j = k >> 1; j > 0; j >>= 1) {
            int ixj = tid ^ j;
            if (ixj > tid) {
                unsigned long long x0 = a[tid], x1 = a[ixj];
                bool up = ((tid & k) == 0);
                bool sw = up ? (x0 > x1) : (x0 < x1);
                if (sw) { a[tid] = x1; a[ixj] = x0; }
            }
            __syncthreads();
        }
    }
    ridx[b * N + tid] = (int)(a[tid] & 0xffffffffu);
}

__global__ __launch_bounds__(512) void gather_k(const float* __restrict__ x,
                                                const float* __restrict__ imp,
                                                const int* __restrict__ ridx,
                                                float* __restrict__ rx, float* __restrict__ rxf,
                                                float* __restrict__ rimp, float* __restrict__ fimp) {
    int t = blockIdx.x;
    int b = t >> 10, j = t & (N - 1);
    int r = ridx[t];
    int c = threadIdx.x;
    float v = x[((size_t)(b << 10) + r) * DM + c];
    rx[(size_t)t * DM + c] = v;
    rxf[((size_t)(b << 10) + (N - 1 - j)) * DM + c] = v;
    if (c == 0) {
        float iv = imp[(b << 10) + r];
        rimp[t] = iv;
        fimp[(b << 10) + (N - 1 - j)] = iv;
    }
}

// ---------------- transpose + f32->bf16: dst[C][R] = cvt(src[R][C]) ----------------
__global__ __launch_bounds__(256) void tconv_k(const float* __restrict__ src,
                                               ushort* __restrict__ dst, int R, int C) {
    __shared__ float tile[32][33];
    int c0 = blockIdx.x * 32, r0 = blockIdx.y * 32;
    int tx = threadIdx.x & 31, ty = threadIdx.x >> 5;
#pragma unroll
    for (int j = 0; j < 4; ++j)
        tile[ty + j * 8][tx] = src[(size_t)(r0 + ty + j * 8) * C + c0 + tx];
    __syncthreads();
#pragma unroll
    for (int j = 0; j < 4; ++j)
        dst[(size_t)(c0 + ty + j * 8) * R + r0 + tx] = f2bf(tile[tx][ty + j * 8]);
}

// ---------------- layernorm (bf16 out) ----------------
__global__ __launch_bounds__(256) void ln_k(const float* __restrict__ xin,
                                            const float* __restrict__ g,
                                            const float* __restrict__ bt,
                                            ushort* __restrict__ out) {
    int t = blockIdx.x, tid = threadIdx.x;
    const float* xr = xin + (size_t)t * DM;
    __shared__ float red[256];
    float v0 = xr[tid], v1 = xr[tid + 256];
    red[tid] = v0 + v1; __syncthreads();
    for (int st = 128; st > 0; st >>= 1) { if (tid < st) red[tid] += red[tid + st]; __syncthreads(); }
    float mu = red[0] * (1.f / DM); __syncthreads();
    float d0 = v0 - mu, d1 = v1 - mu;
    red[tid] = d0 * d0 + d1 * d1; __syncthreads();
    for (int st = 128; st > 0; st >>= 1) { if (tid < st) red[tid] += red[tid + st]; __syncthreads(); }
    float rs = rsqrtf(red[0] * (1.f / DM) + 1e-5f);
    out[(size_t)t * DM + tid] = f2bf(d0 * rs * g[tid] + bt[tid]);
    out[(size_t)t * DM + tid + 256] = f2bf(d1 * rs * g[tid + 256] + bt[tid + 256]);
}

// ---------------- MFMA bf16 GEMM: C[M x Nn](f32) = A[M x K](bf16) * Bt[Nn x K](bf16) ----------------
// 128x128 tile, BK=32, 256 thr = 4 waves, each wave 64x64 (4x4 frags of 16x16x32).
// LDS chunk-swizzle: 16B chunk index ^= (row>>1)&3  -> frag ds_read_b128 ~2-way (free).
__global__ __launch_bounds__(256) void mgemm_k(const ushort* __restrict__ A, int lda,
                                               const ushort* __restrict__ Bt, int ldb,
                                               const float* __restrict__ bias,
                                               const float* __restrict__ add, int ldadd,
                                               float* __restrict__ C, int ldc, int Kdim) {
    __shared__ short8v As[128 * 4];
    __shared__ short8v Bs[128 * 4];
    int tid = threadIdx.x;
    int lane = tid & 63, wid = tid >> 6;
    int row0 = blockIdx.y * 128, col0 = blockIdx.x * 128;
    int wr = (wid >> 1) * 64, wc = (wid & 1) * 64;
    float4v acc[4][4];
#pragma unroll
    for (int i = 0; i < 4; ++i)
#pragma unroll
        for (int j = 0; j < 4; ++j)
#pragma unroll
            for (int r = 0; r < 4; ++r) acc[i][j][r] = 0.f;

    // staging: thread t -> row tid>>1 (0..127), chunks {(tid&1)*2, +1}
    int srow = tid >> 1;
    int sch = (tid & 1) * 2;
    int swz = (srow >> 1) & 3;
    const ushort* arow = A + (size_t)(row0 + srow) * lda;
    const ushort* brow = Bt + (size_t)(col0 + srow) * ldb;
    // frag reads
    int fr = lane & 15, kg = lane >> 4;
    int sf = kg ^ ((fr >> 1) & 3);

    for (int k0 = 0; k0 < Kdim; k0 += 32) {
        short8v a0 = *(const short8v*)(arow + k0 + sch * 8);
        short8v a1 = *(const short8v*)(arow + k0 + sch * 8 + 8);
        short8v b0 = *(const short8v*)(brow + k0 + sch * 8);
        short8v b1 = *(const short8v*)(brow + k0 + sch * 8 + 8);
        __syncthreads();
        As[srow * 4 + (sch ^ swz)] = a0;
        As[srow * 4 + ((sch + 1) ^ swz)] = a1;
        Bs[srow * 4 + (sch ^ swz)] = b0;
        Bs[srow * 4 + ((sch + 1) ^ swz)] = b1;
        __syncthreads();
        short8v af[4], bf[4];
#pragma unroll
        for (int mb = 0; mb < 4; ++mb) af[mb] = As[(wr + mb * 16 + fr) * 4 + sf];
#pragma unroll
        for (int nb = 0; nb < 4; ++nb) bf[nb] = Bs[(wc + nb * 16 + fr) * 4 + sf];
#pragma unroll
        for (int mb = 0; mb < 4; ++mb)
#pragma unroll
            for (int nb = 0; nb < 4; ++nb)
                acc[mb][nb] = __builtin_amdgcn_mfma_f32_16x16x32_bf16(af[mb], bf[nb], acc[mb][nb], 0, 0, 0);
    }
    // epilogue: C/D layout col=lane&15, row=(lane>>4)*4+r
#pragma unroll
    for (int mb = 0; mb < 4; ++mb) {
        int r_ = row0 + wr + mb * 16 + kg * 4;
#pragma unroll
        for (int nb = 0; nb < 4; ++nb) {
            int c_ = col0 + wc + nb * 16 + fr;
            float bz = bias ? bias[c_] : 0.f;
#pragma unroll
            for (int r = 0; r < 4; ++r) {
                float o = acc[mb][nb][r] + bz;
                if (add) o += add[(size_t)(r_ + r) * ldadd + c_];
                C[(size_t)(r_ + r) * ldc + c_] = o;
            }
        }
    }
}

// ---------------- depthwise causal conv + silu ----------------
__global__ __launch_bounds__(256) void conv_k(const float* __restrict__ xz,
                                              const float* __restrict__ cw,
                                              const float* __restrict__ cb,
                                              float* __restrict__ xc) {
    int gid = blockIdx.x * 256 + threadIdx.x;
    int d = gid & (DI - 1);
    int t = gid >> 10;
    int n = t & (N - 1);
    float acc = cb[d];
    const float* base = xz + (size_t)t * (2 * DI) + d;
#pragma unroll
    for (int k = 0; k < DC; ++k) {
        int nn = n - (DC - 1) + k;
        if (nn >= 0) acc += base[(long)(nn - n) * (2 * DI)] * cw[d * DC + k];
    }
    float s = 1.f / (1.f + expf(-acc));
    xc[gid] = acc * s;
}

// ---------------- x_ssm = xc @ xp_w (1024 x 33) ----------------
__global__ __launch_bounds__(256) void xssm_k(const float* __restrict__ xc,
                                              const float* __restrict__ xpw,
                                              float* __restrict__ xssm) {
    int t = blockIdx.x;
    __shared__ float row[DI];
    int tid = threadIdx.x;
    for (int i = tid; i < DI; i += 256) row[i] = xc[(size_t)t * DI + i];
    __syncthreads();
    int j = tid >> 2;
    int part = tid & 3;
    if (j < 33) {
        float acc = 0.f;
        int c0 = part * 256;
        for (int c = c0; c < c0 + 256; ++c) acc += row[c] * xpw[c * 33 + j];
        acc += __shfl_xor(acc, 1);
        acc += __shfl_xor(acc, 2);
        if (part == 0) xssm[t * 33 + j] = acc;
    }
}

// ---------------- h1 (token scalar -> 256, bf16 out) ----------------
__global__ __launch_bounds__(256) void h1_k(const float* __restrict__ imp,
                                            const float* __restrict__ w1,
                                            const float* __restrict__ b1,
                                            ushort* __restrict__ h1) {
    int t = blockIdx.x, tid = threadIdx.x;
    float v = imp[t] * w1[tid] + b1[tid];
    h1[(size_t)t * DI4 + tid] = f2bf(fmaxf(v, 0.f));
}

// ---------------- sequential SSM scan; delta computed inline; bf16 y out ----------------
__global__ __launch_bounds__(256) void scan_k(const float* __restrict__ modl,
                                              const float* __restrict__ xc,
                                              const float* __restrict__ xssm,
                                              const float* __restrict__ Alog,
                                              const float* __restrict__ Dp,
                                              const float* __restrict__ xz,
                                              const float* __restrict__ dtw,
                                              const float* __restrict__ dtb,
                                              ushort* __restrict__ y) {
    int blk = blockIdx.x;            // 256 blocks
    int b = blk >> 6;
    int d0 = (blk & 63) * 16;
    int tid = threadIdx.x;
    int wave = tid >> 6;
    int lane = tid & 63;
    int s = lane & 15;               // state index
    int dd = lane >> 4;
    int dl = wave * 4 + dd;          // local channel 0..15
    int d = d0 + dl;
    float A = -__expf(Alog[d * DS + s]);
    size_t tokbase = (size_t)b * N;

    __shared__ float sdel[2][64][16];
    __shared__ float sxcv[2][64][16];
    __shared__ float szv_[2][64][16];
    __shared__ float sBv_[2][64][16];
    __shared__ float sCv_[2][64][16];
    __shared__ float sP[64][16][17];   // [t][dl][s] padded

    // loader/reducer mapping: lc = channel 0..15, lr = token-row 0..15
    int lc = tid & 15, lr = tid >> 4;
    float dpv = Dp[d0 + lc];
    float dtwv = dtw[d0 + lc], dtbv = dtb[d0 + lc];
    float rmo[4], rdraw[4], rxc[4], rz[4], rB[4], rC[4];

    const float* mbase = modl + tokbase * DI + d0 + lc;
    const float* xbase = xc + tokbase * DI + d0 + lc;
    const float* zbase = xz + tokbase * (2 * DI) + DI + d0 + lc;
    const float* sbase = xssm + tokbase * 33;

    auto issue = [&](int chunk) {
        int t0 = chunk * 64;
#pragma unroll
        for (int q = 0; q < 4; ++q) {
            int tok = t0 + q * 16 + lr;
            rmo[q]   = mbase[(size_t)tok * DI];
            rdraw[q] = sbase[(size_t)tok * 33];
            rxc[q]   = xbase[(size_t)tok * DI];
            rz[q]    = zbase[(size_t)tok * (2 * DI)];
            rB[q]    = sbase[(size_t)tok * 33 + 1 + lc];
            rC[q]    = sbase[(size_t)tok * 33 + 1 + DS + lc];
        }
    };
    auto commit = [&](int buf) {
#pragma unroll
        for (int q = 0; q < 4; ++q) {
            int tr = q * 16 + lr;
            float a = rdraw[q] * dtwv + dtbv;
            float sp = (a > 20.f) ? a : log1pf(__expf(a));
            float mod = 1.f / (1.f + __expf(-rmo[q]));
            sdel[buf][tr][lc] = sp * (1.f + mod);
            sxcv[buf][tr][lc] = rxc[q];
            szv_[buf][tr][lc] = rz[q];
            sBv_[buf][tr][lc] = rB[q];
            sCv_[buf][tr][lc] = rC[q];
        }
    };

    issue(0);
    commit(0);
    __syncthreads();

    float h = 0.f;
    int cur = 0;
    for (int chunk = 0; chunk < 16; ++chunk) {
        if (chunk + 1 < 16) issue(chunk + 1);
        // ---- serial phase: only loop-carried dep is one fmaf ----
#pragma unroll
        for (int g = 0; g < 8; ++g) {
            float a8[8], b8[8], c8[8];
#pragma unroll
            for (int j = 0; j < 8; ++j) {
                int t = g * 8 + j;
                float dlt = sdel[cur][t][dl];
                float xcv = sxcv[cur][t][dl];
                float Bv  = sBv_[cur][t][s];
                c8[j] = sCv_[cur][t][s];
                a8[j] = __expf(dlt * A);
                b8[j] = (dlt * Bv) * xcv;
            }
#pragma unroll
            for (int j = 0; j < 8; ++j) {
                int t = g * 8 + j;
                h = fmaf(a8[j], h, b8[j]);
                sP[t][dl][s] = h * c8[j];
            }
        }
        __syncthreads();
        // ---- parallel reduce + gate + store (bf16) ----
        {
            int t0 = chunk * 64;
#pragma unroll
            for (int q = 0; q < 4; ++q) {
                int t = q * 16 + lr;
                float ssum = 0.f;
#pragma unroll
                for (int s2 = 0; s2 < 16; ++s2) ssum += sP[t][lc][s2];
                float xcv = sxcv[cur][t][lc];
                float zv  = szv_[cur][t][lc];
                float sg = 1.f / (1.f + __expf(-zv));
                y[(tokbase + t0 + t) * DI + d0 + lc] = f2bf((ssum + xcv * dpv) * (zv * sg));
            }
        }
        if (chunk + 1 < 16) commit(cur ^ 1);
        __syncthreads();
        cur ^= 1;
    }
}

// ---------------- concat [xf | flip(xb)] -> bf16 ----------------
__global__ __launch_bounds__(256) void concat_k(const float* __restrict__ xf,
                                                const float* __restrict__ xb,
                                                ushort* __restrict__ cat) {
    int gid = blockIdx.x * 256 + threadIdx.x;   // TT*DM
    int t = gid >> 9;
    int c = gid & (DM - 1);
    int b = t >> 10, j = t & (N - 1);
    cat[(size_t)t * (2 * DM) + c] = f2bf(xf[gid]);
    cat[(size_t)t * (2 * DM) + DM + c] = f2bf(xb[((size_t)(b << 10) + (N - 1 - j)) * DM + c]);
}

// ---------------- final: scatter by ridx + layernorm ----------------
__global__ __launch_bounds__(256) void final_k(const float* __restrict__ fus,
                                               const int* __restrict__ ridx,
                                               const float* __restrict__ g,
                                               const float* __restrict__ bt,
                                               float* __restrict__ out) {
    int t = blockIdx.x, tid = threadIdx.x;
    int b = t >> 10;
    int r = ridx[t];
    const float* xr = fus + (size_t)t * DM;
    __shared__ float red[256];
    float v0 = xr[tid], v1 = xr[tid + 256];
    red[tid] = v0 + v1; __syncthreads();
    for (int st = 128; st > 0; st >>= 1) { if (tid < st) red[tid] += red[tid + st]; __syncthreads(); }
    float mu = red[0] * (1.f / DM); __syncthreads();
    float d0 = v0 - mu, d1 = v1 - mu;
    red[tid] = d0 * d0 + d1 * d1; __syncthreads();
    for (int st = 128; st > 0; st >>= 1) { if (tid < st) red[tid] += red[tid + st]; __syncthreads(); }
    float rs = rsqrtf(red[0] * (1.f / DM) + 1e-5f);
    float* orow = out + ((size_t)(b << 10) + r) * DM;
    orow[tid] = d0 * rs * g[tid] + bt[tid];
    orow[tid + 256] = d1 * rs * g[tid + 256] + bt[tid + 256];
}

// ---------------- host ----------------
extern "C" void kernel_launch(void* const* d_in, const int* in_sizes, int n_in,
                              void* d_out, int out_size, void* d_ws, size_t ws_size,
                              hipStream_t stream) {
    const float* x            = (const float*)d_in[0];
    const float* centers_init = (const float*)d_in[1];
    const float* in_w         = (const float*)d_in[2];
    const float* conv_w       = (const float*)d_in[3];
    const float* conv_b       = (const float*)d_in[4];
    const float* xp_w         = (const float*)d_in[5];
    const float* dt_w         = (const float*)d_in[6];
    const float* dt_b         = (const float*)d_in[7];
    const float* cm_w1        = (const float*)d_in[8];
    const float* cm_b1        = (const float*)d_in[9];
    const float* cm_w2        = (const float*)d_in[10];
    const float* cm_b2        = (const float*)d_in[11];
    const float* A_log        = (const float*)d_in[12];
    const float* D_p          = (const float*)d_in[13];
    const float* out_w        = (const float*)d_in[14];
    const float* ln_g         = (const float*)d_in[15];
    const float* ln_b         = (const float*)d_in[16];
    const float* fusion_w     = (const float*)d_in[17];
    const float* fusion_b     = (const float*)d_in[18];
    const float* fn_g         = (const float*)d_in[19];
    const float* fn_b         = (const float*)d_in[20];

    float* W = (float*)d_ws;
    size_t off = 0;
    auto alloc = [&](size_t n) { float* p = W + off; off += (n + 15) & ~(size_t)15; return p; };
    auto allocU = [&](size_t n) { ushort* p = (ushort*)(W + off); off += ((n + 1) / 2 + 15) & ~(size_t)15; return p; };
    float* centers = alloc((size_t)Bb * KC * DM);
    float* wgt     = alloc((size_t)TT * KC);
    float* mind    = alloc(TT);
    float* keys    = alloc(TT);
    float* imp     = alloc(TT);
    float* rimp    = alloc(TT);
    float* fimp    = alloc(TT);
    float* rx      = alloc((size_t)TT * DM);
    float* rxf     = alloc((size_t)TT * DM);
    float* tmp     = alloc((size_t)TT * DM);
    float* xz      = alloc((size_t)TT * 2 * DI);   // f32 xz; reused (cast) as bf16 cat
    float* xc      = alloc((size_t)TT * DI);       // reused as fus (f32)
    float* xssm    = alloc((size_t)TT * 33);
    float* modl    = alloc((size_t)TT * DI);
    ushort* xnb    = allocU((size_t)TT * DM);      // ln out (bf16); also h1 would fit but kept separate
    ushort* h1b    = allocU((size_t)TT * DI4);
    ushort* yb     = allocU((size_t)TT * DI);
    ushort* inwT   = allocU((size_t)L4 * 2 * DI * DM);
    ushort* cmw2T  = allocU((size_t)L4 * DI * DI4);
    ushort* outwT  = allocU((size_t)L4 * DM * DI);
    ushort* fusT   = allocU((size_t)DM * 2 * DM);
    int* ridx = (int*)(W + off); off += TT;

    // ---- weight transposes (f32 -> bf16 [N][K]) ----
    for (int l = 0; l < L4; ++l) {
        tconv_k<<<dim3(2 * DI / 32, DM / 32), 256, 0, stream>>>(in_w + (size_t)l * DM * 2 * DI, inwT + (size_t)l * 2 * DI * DM, DM, 2 * DI);
        tconv_k<<<dim3(DI / 32, DI4 / 32), 256, 0, stream>>>(cm_w2 + (size_t)l * DI4 * DI, cmw2T + (size_t)l * DI * DI4, DI4, DI);
        tconv_k<<<dim3(DM / 32, DI / 32), 256, 0, stream>>>(out_w + (size_t)l * DI * DM, outwT + (size_t)l * DM * DI, DI, DM);
    }
    tconv_k<<<dim3(DM / 32, 2 * DM / 32), 256, 0, stream>>>(fusion_w, fusT, 2 * DM, DM);

    // ---- k-means ----
    initcen_k<<<(Bb * KC * DM) / 256, 256, 0, stream>>>(centers_init, centers);
    for (int it = 0; it < 3; ++it) {
        assign_k<false><<<TT, 64, 0, stream>>>(x, centers, wgt, nullptr, nullptr);
        update_k<<<Bb * KC, 512, 0, stream>>>(x, wgt, centers);
    }
    assign_k<true><<<TT, 64, 0, stream>>>(x, centers, wgt, mind, keys);
    importance_k<<<Bb, 1024, 0, stream>>>(mind, imp);
    sort_k<<<Bb, 1024, 0, stream>>>(keys, ridx);
    gather_k<<<TT, 512, 0, stream>>>(x, imp, ridx, rx, rxf, rimp, fimp);

    auto gemm = [&](const ushort* Ap, int lda, const ushort* Bp, int ldb,
                    const float* bias, const float* add, int ldadd,
                    float* Cp, int ldc, int Kd, int Nn) {
        dim3 g(Nn / 128, TT / 128);
        mgemm_k<<<g, 256, 0, stream>>>(Ap, lda, Bp, ldb, bias, add, ldadd, Cp, ldc, Kd);
    };

    // ---- 4 mamba layers (2 fwd, 2 bwd on flipped) ----
    const float* lay_in[4]  = {rx, tmp, rxf, tmp};
    float*       lay_out[4] = {tmp, rx, tmp, rxf};
    for (int l = 0; l < L4; ++l) {
        const float* xin = lay_in[l];
        float* xout = lay_out[l];
        const float* impv = (l < 2) ? rimp : fimp;
        ln_k<<<TT, 256, 0, stream>>>(xin, ln_g + (size_t)l * DM, ln_b + (size_t)l * DM, xnb);
        gemm(xnb, DM, inwT + (size_t)l * 2 * DI * DM, DM, nullptr, nullptr, 0, xz, 2 * DI, DM, 2 * DI);
        conv_k<<<(TT * DI) / 256, 256, 0, stream>>>(xz, conv_w + (size_t)l * DI * DC, conv_b + (size_t)l * DI, xc);
        xssm_k<<<TT, 256, 0, stream>>>(xc, xp_w + (size_t)l * DI * 33, xssm);
        h1_k<<<TT, 256, 0, stream>>>(impv, cm_w1 + (size_t)l * DI4, cm_b1 + (size_t)l * DI4, h1b);
        gemm(h1b, DI4, cmw2T + (size_t)l * DI * DI4, DI4, cm_b2 + (size_t)l * DI, nullptr, 0, modl, DI, DI4, DI);
        scan_k<<<256, 256, 0, stream>>>(modl, xc, xssm, A_log + (size_t)l * DI * DS, D_p + (size_t)l * DI, xz,
                                        dt_w + (size_t)l * DI, dt_b + (size_t)l * DI, yb);
        gemm(yb, DI, outwT + (size_t)l * DM * DI, DI, nullptr, xin, DM, xout, DM, DI, DM);
    }

    // ---- fusion + restore + final LN ----
    ushort* catb = (ushort*)xz;
    concat_k<<<(TT * DM) / 256, 256, 0, stream>>>(rx /*xf final*/, rxf /*xb final*/, catb);
    gemm(catb, 2 * DM, fusT, 2 * DM, fusion_b, nullptr, 0, xc /*fus*/, DM, 2 * DM, DM);
    final_k<<<TT, 256, 0, stream>>>(xc, ridx, fn_g, fn_b, (float*)d_out);
}

// Round 5
// 1291.149 us; speedup vs baseline: 2.6544x; 1.0722x over previous
//
#include <hip/hip_runtime.h>
#include <math.h>

// ---------------- constants ----------------
constexpr int DM = 512, DS = 16, DC = 4, DI = 1024, DI4 = 256, KC = 5;
constexpr int Bb = 4, N = 1024, L4 = 4, TT = Bb * N;
constexpr float TEMP = 0.5f;
constexpr int SEG = 16;          // scan segments per sequence
constexpr int SLEN = N / SEG;    // 64 tokens per segment
constexpr int SEGU = 64;         // kmeans-update segments

typedef __attribute__((ext_vector_type(8))) short short8v;
typedef __attribute__((ext_vector_type(4))) float float4v;

__device__ inline ushort f2bf(float f) {
    union { float f; unsigned u; } v; v.f = f;
    unsigned r = v.u + 0x7FFFu + ((v.u >> 16) & 1u);
    return (ushort)(r >> 16);
}

// ---------------- k-means ----------------
__global__ void initcen_k(const float* __restrict__ ci, float* __restrict__ centers) {
    int gid = blockIdx.x * 256 + threadIdx.x;           // B*KC*DM = 10240
    centers[gid] = ci[gid % (KC * DM)];
}

template <bool FINAL>
__global__ __launch_bounds__(64) void assign_k(const float* __restrict__ x,
                                               const float* __restrict__ centers,
                                               float* __restrict__ wgt,
                                               float* __restrict__ mind,
                                               float* __restrict__ keys) {
    int t = blockIdx.x;            // token 0..TT-1
    int b = t >> 10;
    int lane = threadIdx.x;
    const float* xr = x + (size_t)t * DM;
    const float* cen = centers + (size_t)b * KC * DM;
    float d2[KC] = {0.f, 0.f, 0.f, 0.f, 0.f};
    for (int c = lane; c < DM; c += 64) {
        float xv = xr[c];
#pragma unroll
        for (int k = 0; k < KC; ++k) {
            float df = xv - cen[k * DM + c];
            d2[k] += df * df;
        }
    }
#pragma unroll
    for (int k = 0; k < KC; ++k)
        for (int off = 32; off > 0; off >>= 1) d2[k] += __shfl_xor(d2[k], off);
    if (lane == 0) {
        float dist[KC], logit[KC], e[KC];
        float lm = -1e30f;
        for (int k = 0; k < KC; ++k) {
            dist[k] = sqrtf(d2[k] + 1e-12f);
            logit[k] = -dist[k] / TEMP;
            lm = fmaxf(lm, logit[k]);
        }
        float s = 0.f;
        for (int k = 0; k < KC; ++k) { e[k] = expf(logit[k] - lm); s += e[k]; }
        float inv = 1.f / s;
        for (int k = 0; k < KC; ++k) wgt[t * KC + k] = e[k] * inv;
        if (FINAL) {
            float md = dist[0];
            for (int k = 1; k < KC; ++k) md = fminf(md, dist[k]);
            int ca = 0; float best = e[0] * inv;
            for (int k = 1; k < KC; ++k) {
                float wv = e[k] * inv;
                if (wv > best) { best = wv; ca = k; }
            }
            mind[t] = md;
            keys[t] = (float)ca * 1000.0f + (1.0f - best);
        }
    }
}

// ---- update: pass1 partials over 16-token segments (reads x once) ----
__global__ __launch_bounds__(512) void updp_k(const float* __restrict__ x,
                                              const float* __restrict__ wgt,
                                              float* __restrict__ part,
                                              float* __restrict__ denp) {
    int blk = blockIdx.x;        // b*SEGU + seg
    int b = blk >> 6, seg = blk & 63;
    int c = threadIdx.x;
    constexpr int TSEG = N / SEGU;   // 16
    __shared__ float sw[TSEG][KC];
    int n0 = seg * TSEG;
    if (c < TSEG * KC) sw[c / KC][c % KC] = wgt[((size_t)(b << 10) + n0 + c / KC) * KC + c % KC];
    __syncthreads();
    const float* xb = x + ((size_t)(b << 10) + n0) * DM + c;
    float acc[KC] = {};
    for (int n = 0; n < TSEG; ++n) {
        float xv = xb[(size_t)n * DM];
#pragma unroll
        for (int k = 0; k < KC; ++k) acc[k] = fmaf(sw[n][k], xv, acc[k]);
    }
#pragma unroll
    for (int k = 0; k < KC; ++k)
        part[(((size_t)b * KC + k) * SEGU + seg) * DM + c] = acc[k];
    if (c < KC) {
        float dn = 0.f;
        for (int n = 0; n < TSEG; ++n) dn += sw[n][c];
        denp[((size_t)b * KC + c) * SEGU + seg] = dn;
    }
}

// ---- update: pass2 reduce ----
__global__ __launch_bounds__(512) void updr_k(const float* __restrict__ part,
                                              const float* __restrict__ denp,
                                              float* __restrict__ centers) {
    int bk = blockIdx.x;         // 0..B*KC-1
    int c = threadIdx.x;
    const float* pb = part + (size_t)bk * SEGU * DM + c;
    float acc = 0.f;
    for (int g = 0; g < SEGU; ++g) acc += pb[(size_t)g * DM];
    __shared__ float sden;
    if (c == 0) {
        float dn = 0.f;
        const float* db = denp + (size_t)bk * SEGU;
        for (int g = 0; g < SEGU; ++g) dn += db[g];
        sden = dn;
    }
    __syncthreads();
    centers[(size_t)bk * DM + c] = acc / (sden + 1e-8f);
}

__global__ __launch_bounds__(1024) void importance_k(const float* __restrict__ mind,
                                                     float* __restrict__ imp) {
    int b = blockIdx.x, n = threadIdx.x;
    __shared__ float red[1024];
    float v = -mind[b * N + n] / TEMP;
    red[n] = v; __syncthreads();
    for (int s = 512; s > 0; s >>= 1) { if (n < s) red[n] = fmaxf(red[n], red[n + s]); __syncthreads(); }
    float m = red[0]; __syncthreads();
    float e = expf(v - m);
    red[n] = e; __syncthreads();
    for (int s = 512; s > 0; s >>= 1) { if (n < s) red[n] += red[n + s]; __syncthreads(); }
    imp[b * N + n] = e / red[0];
}

__global__ __launch_bounds__(1024) void sort_k(const float* __restrict__ keys,
                                               int* __restrict__ ridx) {
    int b = blockIdx.x, tid = threadIdx.x;
    __shared__ unsigned long long a[1024];
    unsigned int kb = __float_as_uint(keys[b * N + tid]);   // keys >= 0
    a[tid] = ((unsigned long long)kb << 32) | (unsigned int)tid;
    __syncthreads();
    for (int k = 2; k <= 1024; k <<= 1) {
        for (int j = k >> 1; j > 0; j >>= 1) {
            int ixj = tid ^ j;
            if (ixj > tid) {
                unsigned long long x0 = a[tid], x1 = a[ixj];
                bool up = ((tid & k) == 0);
                bool sw = up ? (x0 > x1) : (x0 < x1);
                if (sw) { a[tid] = x1; a[ixj] = x0; }
            }
            __syncthreads();
        }
    }
    ridx[b * N + tid] = (int)(a[tid] & 0xffffffffu);
}

__global__ __launch_bounds__(512) void gather_k(const float* __restrict__ x,
                                                const float* __restrict__ imp,
                                                const int* __restrict__ ridx,
                                                float* __restrict__ rx, float* __restrict__ rxf,
                                                float* __restrict__ rimp, float* __restrict__ fimp) {
    int t = blockIdx.x;
    int b = t >> 10, j = t & (N - 1);
    int r = ridx[t];
    int c = threadIdx.x;
    float v = x[((size_t)(b << 10) + r) * DM + c];
    rx[(size_t)t * DM + c] = v;
    rxf[((size_t)(b << 10) + (N - 1 - j)) * DM + c] = v;
    if (c == 0) {
        float iv = imp[(b << 10) + r];
        rimp[t] = iv;
        fimp[(b << 10) + (N - 1 - j)] = iv;
    }
}

// ---------------- transpose + f32->bf16: dst[C][R] = cvt(src[R][C]) ----------------
__global__ __launch_bounds__(256) void tconv_k(const float* __restrict__ src,
                                               ushort* __restrict__ dst, int R, int C) {
    __shared__ float tile[32][33];
    int c0 = blockIdx.x * 32, r0 = blockIdx.y * 32;
    int tx = threadIdx.x & 31, ty = threadIdx.x >> 5;
#pragma unroll
    for (int j = 0; j < 4; ++j)
        tile[ty + j * 8][tx] = src[(size_t)(r0 + ty + j * 8) * C + c0 + tx];
    __syncthreads();
#pragma unroll
    for (int j = 0; j < 4; ++j)
        dst[(size_t)(c0 + ty + j * 8) * R + r0 + tx] = f2bf(tile[tx][ty + j * 8]);
}

// ---------------- layernorm (bf16 out) ----------------
__global__ __launch_bounds__(256) void ln_k(const float* __restrict__ xin,
                                            const float* __restrict__ g,
                                            const float* __restrict__ bt,
                                            ushort* __restrict__ out) {
    int t = blockIdx.x, tid = threadIdx.x;
    const float* xr = xin + (size_t)t * DM;
    __shared__ float red[256];
    float v0 = xr[tid], v1 = xr[tid + 256];
    red[tid] = v0 + v1; __syncthreads();
    for (int st = 128; st > 0; st >>= 1) { if (tid < st) red[tid] += red[tid + st]; __syncthreads(); }
    float mu = red[0] * (1.f / DM); __syncthreads();
    float d0 = v0 - mu, d1 = v1 - mu;
    red[tid] = d0 * d0 + d1 * d1; __syncthreads();
    for (int st = 128; st > 0; st >>= 1) { if (tid < st) red[tid] += red[tid + st]; __syncthreads(); }
    float rs = rsqrtf(red[0] * (1.f / DM) + 1e-5f);
    out[(size_t)t * DM + tid] = f2bf(d0 * rs * g[tid] + bt[tid]);
    out[(size_t)t * DM + tid + 256] = f2bf(d1 * rs * g[tid + 256] + bt[tid + 256]);
}

// ---------------- MFMA bf16 GEMM ----------------
__global__ __launch_bounds__(256) void mgemm_k(const ushort* __restrict__ A, int lda,
                                               const ushort* __restrict__ Bt, int ldb,
                                               const float* __restrict__ bias,
                                               const float* __restrict__ add, int ldadd,
                                               float* __restrict__ C, int ldc, int Kdim) {
    __shared__ short8v As[128 * 4];
    __shared__ short8v Bs[128 * 4];
    int tid = threadIdx.x;
    int lane = tid & 63, wid = tid >> 6;
    int row0 = blockIdx.y * 128, col0 = blockIdx.x * 128;
    int wr = (wid >> 1) * 64, wc = (wid & 1) * 64;
    float4v acc[4][4];
#pragma unroll
    for (int i = 0; i < 4; ++i)
#pragma unroll
        for (int j = 0; j < 4; ++j)
#pragma unroll
            for (int r = 0; r < 4; ++r) acc[i][j][r] = 0.f;

    int srow = tid >> 1;
    int sch = (tid & 1) * 2;
    int swz = (srow >> 1) & 3;
    const ushort* arow = A + (size_t)(row0 + srow) * lda;
    const ushort* brow = Bt + (size_t)(col0 + srow) * ldb;
    int fr = lane & 15, kg = lane >> 4;
    int sf = kg ^ ((fr >> 1) & 3);

    for (int k0 = 0; k0 < Kdim; k0 += 32) {
        short8v a0 = *(const short8v*)(arow + k0 + sch * 8);
        short8v a1 = *(const short8v*)(arow + k0 + sch * 8 + 8);
        short8v b0 = *(const short8v*)(brow + k0 + sch * 8);
        short8v b1 = *(const short8v*)(brow + k0 + sch * 8 + 8);
        __syncthreads();
        As[srow * 4 + (sch ^ swz)] = a0;
        As[srow * 4 + ((sch + 1) ^ swz)] = a1;
        Bs[srow * 4 + (sch ^ swz)] = b0;
        Bs[srow * 4 + ((sch + 1) ^ swz)] = b1;
        __syncthreads();
        short8v af[4], bf[4];
#pragma unroll
        for (int mb = 0; mb < 4; ++mb) af[mb] = As[(wr + mb * 16 + fr) * 4 + sf];
#pragma unroll
        for (int nb = 0; nb < 4; ++nb) bf[nb] = Bs[(wc + nb * 16 + fr) * 4 + sf];
#pragma unroll
        for (int mb = 0; mb < 4; ++mb)
#pragma unroll
            for (int nb = 0; nb < 4; ++nb)
                acc[mb][nb] = __builtin_amdgcn_mfma_f32_16x16x32_bf16(af[mb], bf[nb], acc[mb][nb], 0, 0, 0);
    }
#pragma unroll
    for (int mb = 0; mb < 4; ++mb) {
        int r_ = row0 + wr + mb * 16 + kg * 4;
#pragma unroll
        for (int nb = 0; nb < 4; ++nb) {
            int c_ = col0 + wc + nb * 16 + fr;
            float bz = bias ? bias[c_] : 0.f;
#pragma unroll
            for (int r = 0; r < 4; ++r) {
                float o = acc[mb][nb][r] + bz;
                if (add) o += add[(size_t)(r_ + r) * ldadd + c_];
                C[(size_t)(r_ + r) * ldc + c_] = o;
            }
        }
    }
}

// ---------------- depthwise causal conv + silu ----------------
__global__ __launch_bounds__(256) void conv_k(const float* __restrict__ xz,
                                              const float* __restrict__ cw,
                                              const float* __restrict__ cb,
                                              float* __restrict__ xc) {
    int gid = blockIdx.x * 256 + threadIdx.x;
    int d = gid & (DI - 1);
    int t = gid >> 10;
    int n = t & (N - 1);
    float acc = cb[d];
    const float* base = xz + (size_t)t * (2 * DI) + d;
#pragma unroll
    for (int k = 0; k < DC; ++k) {
        int nn = n - (DC - 1) + k;
        if (nn >= 0) acc += base[(long)(nn - n) * (2 * DI)] * cw[d * DC + k];
    }
    float s = 1.f / (1.f + expf(-acc));
    xc[gid] = acc * s;
}

// ---------------- x_ssm = xc @ xp_w (1024 x 33) ----------------
__global__ __launch_bounds__(256) void xssm_k(const float* __restrict__ xc,
                                              const float* __restrict__ xpw,
                                              float* __restrict__ xssm) {
    int t = blockIdx.x;
    __shared__ float row[DI];
    int tid = threadIdx.x;
    for (int i = tid; i < DI; i += 256) row[i] = xc[(size_t)t * DI + i];
    __syncthreads();
    int j = tid >> 2;
    int part = tid & 3;
    if (j < 33) {
        float acc = 0.f;
        int c0 = part * 256;
        for (int c = c0; c < c0 + 256; ++c) acc += row[c] * xpw[c * 33 + j];
        acc += __shfl_xor(acc, 1);
        acc += __shfl_xor(acc, 2);
        if (part == 0) xssm[t * 33 + j] = acc;
    }
}

// ---------------- h1 (token scalar -> 256, bf16 out) ----------------
__global__ __launch_bounds__(256) void h1_k(const float* __restrict__ imp,
                                            const float* __restrict__ w1,
                                            const float* __restrict__ b1,
                                            ushort* __restrict__ h1) {
    int t = blockIdx.x, tid = threadIdx.x;
    float v = imp[t] * w1[tid] + b1[tid];
    h1[(size_t)t * DI4 + tid] = f2bf(fmaxf(v, 0.f));
}

// ================= segmented scan =================
// Phase A: per-segment local scan (h0=0) + transfer product P = prod(a).
// grid: b*1024 + dblk*16 + seg  (4096 blocks, 256 thr)
__global__ __launch_bounds__(256) void scanA_k(const float* __restrict__ modl,
                                               const float* __restrict__ xc,
                                               const float* __restrict__ xssm,
                                               const float* __restrict__ Alog,
                                               const float* __restrict__ dtw,
                                               const float* __restrict__ dtb,
                                               float* __restrict__ hloc,
                                               float* __restrict__ Pp) {
    int blk = blockIdx.x;
    int seg = blk & 15;
    int dblk = (blk >> 4) & 63;
    int b = blk >> 10;
    int d0 = dblk * 16;
    int tid = threadIdx.x;
    int lane = tid & 63, wave = tid >> 6;
    int s = lane & 15, dd = lane >> 4;
    int dl = wave * 4 + dd, d = d0 + dl;
    float A = -__expf(Alog[d * DS + s]);
    size_t tokbase = (size_t)b * N + (size_t)seg * SLEN;

    __shared__ float sdel[SLEN][16];
    __shared__ float sxcv[SLEN][16];
    __shared__ float sBv_[SLEN][16];

    int lc = tid & 15, lr = tid >> 4;
    float dtwv = dtw[d0 + lc], dtbv = dtb[d0 + lc];
    const float* mbase = modl + tokbase * DI + d0 + lc;
    const float* xbase = xc + tokbase * DI + d0 + lc;
    const float* sbase = xssm + tokbase * 33;
#pragma unroll
    for (int q = 0; q < 4; ++q) {
        int tok = q * 16 + lr;
        float mo   = mbase[(size_t)tok * DI];
        float draw = sbase[(size_t)tok * 33];
        float xcv  = xbase[(size_t)tok * DI];
        float Bv   = sbase[(size_t)tok * 33 + 1 + lc];
        float a = draw * dtwv + dtbv;
        float sp = (a > 20.f) ? a : log1pf(__expf(a));
        float mod = 1.f / (1.f + __expf(-mo));
        sdel[tok][lc] = sp * (1.f + mod);
        sxcv[tok][lc] = xcv;
        sBv_[tok][lc] = Bv;
    }
    __syncthreads();
    float h = 0.f, P = 1.f;
#pragma unroll
    for (int g = 0; g < 8; ++g) {
        float a8[8], b8[8];
#pragma unroll
        for (int j = 0; j < 8; ++j) {
            int t = g * 8 + j;
            float dlt = sdel[t][dl];
            a8[j] = __expf(dlt * A);
            b8[j] = (dlt * sBv_[t][s]) * sxcv[t][dl];
        }
#pragma unroll
        for (int j = 0; j < 8; ++j) { h = fmaf(a8[j], h, b8[j]); P *= a8[j]; }
    }
    size_t idx = (size_t)blk * 256 + tid;
    hloc[idx] = h;
    Pp[idx] = P;
}

// Phase B: sequential combine across 16 segments per (b,d,s); writes per-segment h0.
// grid: 256 blocks (b*64+dblk), 256 thr (tid = (dl,s))
__global__ __launch_bounds__(256) void scanB_k(const float* __restrict__ hloc,
                                               const float* __restrict__ Pp,
                                               float* __restrict__ h0g) {
    int blk = blockIdx.x;
    int tid = threadIdx.x;
    size_t base = (size_t)blk * SEG * 256 + tid;
    float h = 0.f;
    for (int g = 0; g < SEG; ++g) {
        size_t i = base + (size_t)g * 256;
        h0g[i] = h;
        h = fmaf(Pp[i], h, hloc[i]);
    }
}

// Phase C: re-run segment from true h0; shfl s-reduce; gate; bf16 y out.
__global__ __launch_bounds__(256) void scanC_k(const float* __restrict__ modl,
                                               const float* __restrict__ xc,
                                               const float* __restrict__ xssm,
                                               const float* __restrict__ Alog,
                                               const float* __restrict__ Dp,
                                               const float* __restrict__ xz,
                                               const float* __restrict__ dtw,
                                               const float* __restrict__ dtb,
                                               const float* __restrict__ h0g,
                                               ushort* __restrict__ y) {
    int blk = blockIdx.x;
    int seg = blk & 15;
    int dblk = (blk >> 4) & 63;
    int b = blk >> 10;
    int d0 = dblk * 16;
    int tid = threadIdx.x;
    int lane = tid & 63, wave = tid >> 6;
    int s = lane & 15, dd = lane >> 4;
    int dl = wave * 4 + dd, d = d0 + dl;
    float A = -__expf(Alog[d * DS + s]);
    size_t tokbase = (size_t)b * N + (size_t)seg * SLEN;

    __shared__ float sdel[SLEN][16];
    __shared__ float sxcv[SLEN][16];
    __shared__ float sBv_[SLEN][16];
    __shared__ float sCv_[SLEN][16];
    __shared__ float szv_[SLEN][16];
    __shared__ float sY[SLEN][16];

    int lc = tid & 15, lr = tid >> 4;
    float dtwv = dtw[d0 + lc], dtbv = dtb[d0 + lc];
    float dpv_lc = Dp[d0 + lc];
    const float* mbase = modl + tokbase * DI + d0 + lc;
    const float* xbase = xc + tokbase * DI + d0 + lc;
    const float* zbase = xz + tokbase * (2 * DI) + DI + d0 + lc;
    const float* sbase = xssm + tokbase * 33;
#pragma unroll
    for (int q = 0; q < 4; ++q) {
        int tok = q * 16 + lr;
        float mo   = mbase[(size_t)tok * DI];
        float draw = sbase[(size_t)tok * 33];
        float xcv  = xbase[(size_t)tok * DI];
        float Bv   = sbase[(size_t)tok * 33 + 1 + lc];
        float Cv   = sbase[(size_t)tok * 33 + 1 + DS + lc];
        float zv   = zbase[(size_t)tok * (2 * DI)];
        float a = draw * dtwv + dtbv;
        float sp = (a > 20.f) ? a : log1pf(__expf(a));
        float mod = 1.f / (1.f + __expf(-mo));
        sdel[tok][lc] = sp * (1.f + mod);
        sxcv[tok][lc] = xcv;
        sBv_[tok][lc] = Bv;
        sCv_[tok][lc] = Cv;
        szv_[tok][lc] = zv;
    }
    __syncthreads();
    float h = h0g[(size_t)blk * 256 + tid];
#pragma unroll
    for (int g = 0; g < 8; ++g) {
        float a8[8], b8[8], c8[8];
#pragma unroll
        for (int j = 0; j < 8; ++j) {
            int t = g * 8 + j;
            float dlt = sdel[t][dl];
            a8[j] = __expf(dlt * A);
            b8[j] = (dlt * sBv_[t][s]) * sxcv[t][dl];
            c8[j] = sCv_[t][s];
        }
#pragma unroll
        for (int j = 0; j < 8; ++j) {
            int t = g * 8 + j;
            h = fmaf(a8[j], h, b8[j]);
            float p = h * c8[j];
            p += __shfl_xor(p, 1); p += __shfl_xor(p, 2);
            p += __shfl_xor(p, 4); p += __shfl_xor(p, 8);
            if (s == 0) sY[t][dl] = p;
        }
    }
    __syncthreads();
#pragma unroll
    for (int q = 0; q < 4; ++q) {
        int t = q * 16 + lr;
        float ssum = sY[t][lc];
        float xcv = sxcv[t][lc];
        float zv  = szv_[t][lc];
        float sg = 1.f / (1.f + __expf(-zv));
        y[(tokbase + t) * DI + d0 + lc] = f2bf((ssum + xcv * dpv_lc) * (zv * sg));
    }
}

// ---------------- concat [xf | flip(xb)] -> bf16 ----------------
__global__ __launch_bounds__(256) void concat_k(const float* __restrict__ xf,
                                                const float* __restrict__ xb,
                                                ushort* __restrict__ cat) {
    int gid = blockIdx.x * 256 + threadIdx.x;   // TT*DM
    int t = gid >> 9;
    int c = gid & (DM - 1);
    int b = t >> 10, j = t & (N - 1);
    cat[(size_t)t * (2 * DM) + c] = f2bf(xf[gid]);
    cat[(size_t)t * (2 * DM) + DM + c] = f2bf(xb[((size_t)(b << 10) + (N - 1 - j)) * DM + c]);
}

// ---------------- final: scatter by ridx + layernorm ----------------
__global__ __launch_bounds__(256) void final_k(const float* __restrict__ fus,
                                               const int* __restrict__ ridx,
                                               const float* __restrict__ g,
                                               const float* __restrict__ bt,
                                               float* __restrict__ out) {
    int t = blockIdx.x, tid = threadIdx.x;
    int b = t >> 10;
    int r = ridx[t];
    const float* xr = fus + (size_t)t * DM;
    __shared__ float red[256];
    float v0 = xr[tid], v1 = xr[tid + 256];
    red[tid] = v0 + v1; __syncthreads();
    for (int st = 128; st > 0; st >>= 1) { if (tid < st) red[tid] += red[tid + st]; __syncthreads(); }
    float mu = red[0] * (1.f / DM); __syncthreads();
    float d0 = v0 - mu, d1 = v1 - mu;
    red[tid] = d0 * d0 + d1 * d1; __syncthreads();
    for (int st = 128; st > 0; st >>= 1) { if (tid < st) red[tid] += red[tid + st]; __syncthreads(); }
    float rs = rsqrtf(red[0] * (1.f / DM) + 1e-5f);
    float* orow = out + ((size_t)(b << 10) + r) * DM;
    orow[tid] = d0 * rs * g[tid] + bt[tid];
    orow[tid + 256] = d1 * rs * g[tid + 256] + bt[tid + 256];
}

// ---------------- host ----------------
extern "C" void kernel_launch(void* const* d_in, const int* in_sizes, int n_in,
                              void* d_out, int out_size, void* d_ws, size_t ws_size,
                              hipStream_t stream) {
    const float* x            = (const float*)d_in[0];
    const float* centers_init = (const float*)d_in[1];
    const float* in_w         = (const float*)d_in[2];
    const float* conv_w       = (const float*)d_in[3];
    const float* conv_b       = (const float*)d_in[4];
    const float* xp_w         = (const float*)d_in[5];
    const float* dt_w         = (const float*)d_in[6];
    const float* dt_b         = (const float*)d_in[7];
    const float* cm_w1        = (const float*)d_in[8];
    const float* cm_b1        = (const float*)d_in[9];
    const float* cm_w2        = (const float*)d_in[10];
    const float* cm_b2        = (const float*)d_in[11];
    const float* A_log        = (const float*)d_in[12];
    const float* D_p          = (const float*)d_in[13];
    const float* out_w        = (const float*)d_in[14];
    const float* ln_g         = (const float*)d_in[15];
    const float* ln_b         = (const float*)d_in[16];
    const float* fusion_w     = (const float*)d_in[17];
    const float* fusion_b     = (const float*)d_in[18];
    const float* fn_g         = (const float*)d_in[19];
    const float* fn_b         = (const float*)d_in[20];

    float* W = (float*)d_ws;
    size_t off = 0;
    auto alloc = [&](size_t n) { float* p = W + off; off += (n + 15) & ~(size_t)15; return p; };
    auto allocU = [&](size_t n) { ushort* p = (ushort*)(W + off); off += ((n + 1) / 2 + 15) & ~(size_t)15; return p; };
    float* centers = alloc((size_t)Bb * KC * DM);
    float* wgt     = alloc((size_t)TT * KC);
    float* mind    = alloc(TT);
    float* keys    = alloc(TT);
    float* imp     = alloc(TT);
    float* rimp    = alloc(TT);
    float* fimp    = alloc(TT);
    float* denp    = alloc((size_t)Bb * KC * SEGU);
    float* rx      = alloc((size_t)TT * DM);
    float* rxf     = alloc((size_t)TT * DM);
    float* tmp     = alloc((size_t)TT * DM);
    float* xz      = alloc((size_t)TT * 2 * DI);   // f32 xz; reused (cast) as bf16 cat
    float* xc      = alloc((size_t)TT * DI);       // reused as fus (f32)
    float* xssm    = alloc((size_t)TT * 33);
    float* modl    = alloc((size_t)TT * DI);       // also aliased by kmeans 'part' (disjoint in time)
    float* hloc    = alloc((size_t)Bb * 64 * SEG * 256);
    float* Pp      = alloc((size_t)Bb * 64 * SEG * 256);
    float* h0g     = alloc((size_t)Bb * 64 * SEG * 256);
    ushort* xnb    = allocU((size_t)TT * DM);
    ushort* h1b    = allocU((size_t)TT * DI4);
    ushort* yb     = allocU((size_t)TT * DI);
    ushort* inwT   = allocU((size_t)L4 * 2 * DI * DM);
    ushort* cmw2T  = allocU((size_t)L4 * DI * DI4);
    ushort* outwT  = allocU((size_t)L4 * DM * DI);
    ushort* fusT   = allocU((size_t)DM * 2 * DM);
    int* ridx = (int*)(W + off); off += TT;
    float* part = modl;   // kmeans partials alias modl (kmeans finishes before layers)

    // ---- weight transposes (f32 -> bf16 [N][K]) ----
    for (int l = 0; l < L4; ++l) {
        tconv_k<<<dim3(2 * DI / 32, DM / 32), 256, 0, stream>>>(in_w + (size_t)l * DM * 2 * DI, inwT + (size_t)l * 2 * DI * DM, DM, 2 * DI);
        tconv_k<<<dim3(DI / 32, DI4 / 32), 256, 0, stream>>>(cm_w2 + (size_t)l * DI4 * DI, cmw2T + (size_t)l * DI * DI4, DI4, DI);
        tconv_k<<<dim3(DM / 32, DI / 32), 256, 0, stream>>>(out_w + (size_t)l * DI * DM, outwT + (size_t)l * DM * DI, DI, DM);
    }
    tconv_k<<<dim3(DM / 32, 2 * DM / 32), 256, 0, stream>>>(fusion_w, fusT, 2 * DM, DM);

    // ---- k-means ----
    initcen_k<<<(Bb * KC * DM) / 256, 256, 0, stream>>>(centers_init, centers);
    for (int it = 0; it < 3; ++it) {
        assign_k<false><<<TT, 64, 0, stream>>>(x, centers, wgt, nullptr, nullptr);
        updp_k<<<Bb * SEGU, 512, 0, stream>>>(x, wgt, part, denp);
        updr_k<<<Bb * KC, 512, 0, stream>>>(part, denp, centers);
    }
    assign_k<true><<<TT, 64, 0, stream>>>(x, centers, wgt, mind, keys);
    importance_k<<<Bb, 1024, 0, stream>>>(mind, imp);
    sort_k<<<Bb, 1024, 0, stream>>>(keys, ridx);
    gather_k<<<TT, 512, 0, stream>>>(x, imp, ridx, rx, rxf, rimp, fimp);

    auto gemm = [&](const ushort* Ap, int lda, const ushort* Bp, int ldb,
                    const float* bias, const float* add, int ldadd,
                    float* Cp, int ldc, int Kd, int Nn) {
        dim3 g(Nn / 128, TT / 128);
        mgemm_k<<<g, 256, 0, stream>>>(Ap, lda, Bp, ldb, bias, add, ldadd, Cp, ldc, Kd);
    };

    // ---- 4 mamba layers (2 fwd, 2 bwd on flipped) ----
    const float* lay_in[4]  = {rx, tmp, rxf, tmp};
    float*       lay_out[4] = {tmp, rx, tmp, rxf};
    for (int l = 0; l < L4; ++l) {
        const float* xin = lay_in[l];
        float* xout = lay_out[l];
        const float* impv = (l < 2) ? rimp : fimp;
        ln_k<<<TT, 256, 0, stream>>>(xin, ln_g + (size_t)l * DM, ln_b + (size_t)l * DM, xnb);
        gemm(xnb, DM, inwT + (size_t)l * 2 * DI * DM, DM, nullptr, nullptr, 0, xz, 2 * DI, DM, 2 * DI);
        conv_k<<<(TT * DI) / 256, 256, 0, stream>>>(xz, conv_w + (size_t)l * DI * DC, conv_b + (size_t)l * DI, xc);
        xssm_k<<<TT, 256, 0, stream>>>(xc, xp_w + (size_t)l * DI * 33, xssm);
        h1_k<<<TT, 256, 0, stream>>>(impv, cm_w1 + (size_t)l * DI4, cm_b1 + (size_t)l * DI4, h1b);
        gemm(h1b, DI4, cmw2T + (size_t)l * DI * DI4, DI4, cm_b2 + (size_t)l * DI, nullptr, 0, modl, DI, DI4, DI);
        scanA_k<<<Bb * 64 * SEG, 256, 0, stream>>>(modl, xc, xssm, A_log + (size_t)l * DI * DS,
                                                   dt_w + (size_t)l * DI, dt_b + (size_t)l * DI, hloc, Pp);
        scanB_k<<<Bb * 64, 256, 0, stream>>>(hloc, Pp, h0g);
        scanC_k<<<Bb * 64 * SEG, 256, 0, stream>>>(modl, xc, xssm, A_log + (size_t)l * DI * DS,
                                                   D_p + (size_t)l * DI, xz,
                                                   dt_w + (size_t)l * DI, dt_b + (size_t)l * DI, h0g, yb);
        gemm(yb, DI, outwT + (size_t)l * DM * DI, DI, nullptr, xin, DM, xout, DM, DI, DM);
    }

    // ---- fusion + restore + final LN ----
    ushort* catb = (ushort*)xz;
    concat_k<<<(TT * DM) / 256, 256, 0, stream>>>(rx /*xf final*/, rxf /*xb final*/, catb);
    gemm(catb, 2 * DM, fusT, 2 * DM, fusion_b, nullptr, 0, xc /*fus*/, DM, 2 * DM, DM);
    final_k<<<TT, 256, 0, stream>>>(xc, ridx, fn_g, fn_b, (float*)d_out);
}

// Round 6
// 1154.984 us; speedup vs baseline: 2.9673x; 1.1179x over previous
//
#include <hip/hip_runtime.h>
#include <math.h>

// ---------------- constants ----------------
constexpr int DM = 512, DS = 16, DC = 4, DI = 1024, DI4 = 256, KC = 5;
constexpr int Bb = 4, N = 1024, L4 = 4, TT = Bb * N;
constexpr float TEMP = 0.5f;
constexpr int SEG = 16;          // scan segments per sequence
constexpr int SLEN = N / SEG;    // 64 tokens per segment
constexpr int SEGU = 64;         // kmeans-update segments

typedef __attribute__((ext_vector_type(8))) short short8v;
typedef __attribute__((ext_vector_type(4))) float float4v;

__device__ inline ushort f2bf(float f) {
    union { float f; unsigned u; } v; v.f = f;
    unsigned r = v.u + 0x7FFFu + ((v.u >> 16) & 1u);
    return (ushort)(r >> 16);
}

// ---------------- k-means ----------------
__global__ void initcen_k(const float* __restrict__ ci, float* __restrict__ centers) {
    int gid = blockIdx.x * 256 + threadIdx.x;           // B*KC*DM = 10240
    centers[gid] = ci[gid % (KC * DM)];
}

template <bool FINAL>
__global__ __launch_bounds__(64) void assign_k(const float* __restrict__ x,
                                               const float* __restrict__ centers,
                                               float* __restrict__ wgt,
                                               float* __restrict__ mind,
                                               float* __restrict__ keys) {
    int t = blockIdx.x;            // token 0..TT-1
    int b = t >> 10;
    int lane = threadIdx.x;
    const float* xr = x + (size_t)t * DM;
    const float* cen = centers + (size_t)b * KC * DM;
    float d2[KC] = {0.f, 0.f, 0.f, 0.f, 0.f};
    for (int c = lane; c < DM; c += 64) {
        float xv = xr[c];
#pragma unroll
        for (int k = 0; k < KC; ++k) {
            float df = xv - cen[k * DM + c];
            d2[k] += df * df;
        }
    }
#pragma unroll
    for (int k = 0; k < KC; ++k)
        for (int off = 32; off > 0; off >>= 1) d2[k] += __shfl_xor(d2[k], off);
    if (lane == 0) {
        float dist[KC], logit[KC], e[KC];
        float lm = -1e30f;
        for (int k = 0; k < KC; ++k) {
            dist[k] = sqrtf(d2[k] + 1e-12f);
            logit[k] = -dist[k] / TEMP;
            lm = fmaxf(lm, logit[k]);
        }
        float s = 0.f;
        for (int k = 0; k < KC; ++k) { e[k] = expf(logit[k] - lm); s += e[k]; }
        float inv = 1.f / s;
        for (int k = 0; k < KC; ++k) wgt[t * KC + k] = e[k] * inv;
        if (FINAL) {
            float md = dist[0];
            for (int k = 1; k < KC; ++k) md = fminf(md, dist[k]);
            int ca = 0; float best = e[0] * inv;
            for (int k = 1; k < KC; ++k) {
                float wv = e[k] * inv;
                if (wv > best) { best = wv; ca = k; }
            }
            mind[t] = md;
            keys[t] = (float)ca * 1000.0f + (1.0f - best);
        }
    }
}

// ---- update: pass1 partials over 16-token segments (reads x once) ----
__global__ __launch_bounds__(512) void updp_k(const float* __restrict__ x,
                                              const float* __restrict__ wgt,
                                              float* __restrict__ part,
                                              float* __restrict__ denp) {
    int blk = blockIdx.x;        // b*SEGU + seg
    int b = blk >> 6, seg = blk & 63;
    int c = threadIdx.x;
    constexpr int TSEG = N / SEGU;   // 16
    __shared__ float sw[TSEG][KC];
    int n0 = seg * TSEG;
    if (c < TSEG * KC) sw[c / KC][c % KC] = wgt[((size_t)(b << 10) + n0 + c / KC) * KC + c % KC];
    __syncthreads();
    const float* xb = x + ((size_t)(b << 10) + n0) * DM + c;
    float acc[KC] = {};
    for (int n = 0; n < TSEG; ++n) {
        float xv = xb[(size_t)n * DM];
#pragma unroll
        for (int k = 0; k < KC; ++k) acc[k] = fmaf(sw[n][k], xv, acc[k]);
    }
#pragma unroll
    for (int k = 0; k < KC; ++k)
        part[(((size_t)b * KC + k) * SEGU + seg) * DM + c] = acc[k];
    if (c < KC) {
        float dn = 0.f;
        for (int n = 0; n < TSEG; ++n) dn += sw[n][c];
        denp[((size_t)b * KC + c) * SEGU + seg] = dn;
    }
}

// ---- update: pass2 reduce ----
__global__ __launch_bounds__(512) void updr_k(const float* __restrict__ part,
                                              const float* __restrict__ denp,
                                              float* __restrict__ centers) {
    int bk = blockIdx.x;         // 0..B*KC-1
    int c = threadIdx.x;
    const float* pb = part + (size_t)bk * SEGU * DM + c;
    float acc = 0.f;
    for (int g = 0; g < SEGU; ++g) acc += pb[(size_t)g * DM];
    __shared__ float sden;
    if (c == 0) {
        float dn = 0.f;
        const float* db = denp + (size_t)bk * SEGU;
        for (int g = 0; g < SEGU; ++g) dn += db[g];
        sden = dn;
    }
    __syncthreads();
    centers[(size_t)bk * DM + c] = acc / (sden + 1e-8f);
}

__global__ __launch_bounds__(1024) void importance_k(const float* __restrict__ mind,
                                                     float* __restrict__ imp) {
    int b = blockIdx.x, n = threadIdx.x;
    __shared__ float red[1024];
    float v = -mind[b * N + n] / TEMP;
    red[n] = v; __syncthreads();
    for (int s = 512; s > 0; s >>= 1) { if (n < s) red[n] = fmaxf(red[n], red[n + s]); __syncthreads(); }
    float m = red[0]; __syncthreads();
    float e = expf(v - m);
    red[n] = e; __syncthreads();
    for (int s = 512; s > 0; s >>= 1) { if (n < s) red[n] += red[n + s]; __syncthreads(); }
    imp[b * N + n] = e / red[0];
}

__global__ __launch_bounds__(1024) void sort_k(const float* __restrict__ keys,
                                               int* __restrict__ ridx) {
    int b = blockIdx.x, tid = threadIdx.x;
    __shared__ unsigned long long a[1024];
    unsigned int kb = __float_as_uint(keys[b * N + tid]);   // keys >= 0
    a[tid] = ((unsigned long long)kb << 32) | (unsigned int)tid;
    __syncthreads();
    for (int k = 2; k <= 1024; k <<= 1) {
        for (int j = k >> 1; j > 0; j >>= 1) {
            int ixj = tid ^ j;
            if (ixj > tid) {
                unsigned long long x0 = a[tid], x1 = a[ixj];
                bool up = ((tid & k) == 0);
                bool sw = up ? (x0 > x1) : (x0 < x1);
                if (sw) { a[tid] = x1; a[ixj] = x0; }
            }
            __syncthreads();
        }
    }
    ridx[b * N + tid] = (int)(a[tid] & 0xffffffffu);
}

__global__ __launch_bounds__(512) void gather_k(const float* __restrict__ x,
                                                const float* __restrict__ imp,
                                                const int* __restrict__ ridx,
                                                float* __restrict__ rx, float* __restrict__ rxf,
                                                float* __restrict__ rimp, float* __restrict__ fimp) {
    int t = blockIdx.x;
    int b = t >> 10, j = t & (N - 1);
    int r = ridx[t];
    int c = threadIdx.x;
    float v = x[((size_t)(b << 10) + r) * DM + c];
    rx[(size_t)t * DM + c] = v;
    rxf[((size_t)(b << 10) + (N - 1 - j)) * DM + c] = v;
    if (c == 0) {
        float iv = imp[(b << 10) + r];
        rimp[t] = iv;
        fimp[(b << 10) + (N - 1 - j)] = iv;
    }
}

// ---------------- transpose + f32->bf16: dst[C][R] = cvt(src[R][C]) ----------------
__global__ __launch_bounds__(256) void tconv_k(const float* __restrict__ src,
                                               ushort* __restrict__ dst, int R, int C) {
    __shared__ float tile[32][33];
    int c0 = blockIdx.x * 32, r0 = blockIdx.y * 32;
    int tx = threadIdx.x & 31, ty = threadIdx.x >> 5;
#pragma unroll
    for (int j = 0; j < 4; ++j)
        tile[ty + j * 8][tx] = src[(size_t)(r0 + ty + j * 8) * C + c0 + tx];
    __syncthreads();
#pragma unroll
    for (int j = 0; j < 4; ++j)
        dst[(size_t)(c0 + ty + j * 8) * R + r0 + tx] = f2bf(tile[tx][ty + j * 8]);
}

// ---------------- layernorm (bf16 out) ----------------
__global__ __launch_bounds__(256) void ln_k(const float* __restrict__ xin,
                                            const float* __restrict__ g,
                                            const float* __restrict__ bt,
                                            ushort* __restrict__ out) {
    int t = blockIdx.x, tid = threadIdx.x;
    const float* xr = xin + (size_t)t * DM;
    __shared__ float red[256];
    float v0 = xr[tid], v1 = xr[tid + 256];
    red[tid] = v0 + v1; __syncthreads();
    for (int st = 128; st > 0; st >>= 1) { if (tid < st) red[tid] += red[tid + st]; __syncthreads(); }
    float mu = red[0] * (1.f / DM); __syncthreads();
    float d0 = v0 - mu, d1 = v1 - mu;
    red[tid] = d0 * d0 + d1 * d1; __syncthreads();
    for (int st = 128; st > 0; st >>= 1) { if (tid < st) red[tid] += red[tid + st]; __syncthreads(); }
    float rs = rsqrtf(red[0] * (1.f / DM) + 1e-5f);
    out[(size_t)t * DM + tid] = f2bf(d0 * rs * g[tid] + bt[tid]);
    out[(size_t)t * DM + tid + 256] = f2bf(d1 * rs * g[tid + 256] + bt[tid + 256]);
}

// ---------------- MFMA bf16 GEMM ----------------
__global__ __launch_bounds__(256) void mgemm_k(const ushort* __restrict__ A, int lda,
                                               const ushort* __restrict__ Bt, int ldb,
                                               const float* __restrict__ bias,
                                               const float* __restrict__ add, int ldadd,
                                               float* __restrict__ C, int ldc, int Kdim) {
    __shared__ short8v As[128 * 4];
    __shared__ short8v Bs[128 * 4];
    int tid = threadIdx.x;
    int lane = tid & 63, wid = tid >> 6;
    int row0 = blockIdx.y * 128, col0 = blockIdx.x * 128;
    int wr = (wid >> 1) * 64, wc = (wid & 1) * 64;
    float4v acc[4][4];
#pragma unroll
    for (int i = 0; i < 4; ++i)
#pragma unroll
        for (int j = 0; j < 4; ++j)
#pragma unroll
            for (int r = 0; r < 4; ++r) acc[i][j][r] = 0.f;

    int srow = tid >> 1;
    int sch = (tid & 1) * 2;
    int swz = (srow >> 1) & 3;
    const ushort* arow = A + (size_t)(row0 + srow) * lda;
    const ushort* brow = Bt + (size_t)(col0 + srow) * ldb;
    int fr = lane & 15, kg = lane >> 4;
    int sf = kg ^ ((fr >> 1) & 3);

    for (int k0 = 0; k0 < Kdim; k0 += 32) {
        short8v a0 = *(const short8v*)(arow + k0 + sch * 8);
        short8v a1 = *(const short8v*)(arow + k0 + sch * 8 + 8);
        short8v b0 = *(const short8v*)(brow + k0 + sch * 8);
        short8v b1 = *(const short8v*)(brow + k0 + sch * 8 + 8);
        __syncthreads();
        As[srow * 4 + (sch ^ swz)] = a0;
        As[srow * 4 + ((sch + 1) ^ swz)] = a1;
        Bs[srow * 4 + (sch ^ swz)] = b0;
        Bs[srow * 4 + ((sch + 1) ^ swz)] = b1;
        __syncthreads();
        short8v af[4], bf[4];
#pragma unroll
        for (int mb = 0; mb < 4; ++mb) af[mb] = As[(wr + mb * 16 + fr) * 4 + sf];
#pragma unroll
        for (int nb = 0; nb < 4; ++nb) bf[nb] = Bs[(wc + nb * 16 + fr) * 4 + sf];
#pragma unroll
        for (int mb = 0; mb < 4; ++mb)
#pragma unroll
            for (int nb = 0; nb < 4; ++nb)
                acc[mb][nb] = __builtin_amdgcn_mfma_f32_16x16x32_bf16(af[mb], bf[nb], acc[mb][nb], 0, 0, 0);
    }
#pragma unroll
    for (int mb = 0; mb < 4; ++mb) {
        int r_ = row0 + wr + mb * 16 + kg * 4;
#pragma unroll
        for (int nb = 0; nb < 4; ++nb) {
            int c_ = col0 + wc + nb * 16 + fr;
            float bz = bias ? bias[c_] : 0.f;
#pragma unroll
            for (int r = 0; r < 4; ++r) {
                float o = acc[mb][nb][r] + bz;
                if (add) o += add[(size_t)(r_ + r) * ldadd + c_];
                C[(size_t)(r_ + r) * ldc + c_] = o;
            }
        }
    }
}

// ---------------- depthwise causal conv + silu ----------------
__global__ __launch_bounds__(256) void conv_k(const float* __restrict__ xz,
                                              const float* __restrict__ cw,
                                              const float* __restrict__ cb,
                                              float* __restrict__ xc) {
    int gid = blockIdx.x * 256 + threadIdx.x;
    int d = gid & (DI - 1);
    int t = gid >> 10;
    int n = t & (N - 1);
    float acc = cb[d];
    const float* base = xz + (size_t)t * (2 * DI) + d;
#pragma unroll
    for (int k = 0; k < DC; ++k) {
        int nn = n - (DC - 1) + k;
        if (nn >= 0) acc += base[(long)(nn - n) * (2 * DI)] * cw[d * DC + k];
    }
    float s = 1.f / (1.f + expf(-acc));
    xc[gid] = acc * s;
}

// ---------------- x_ssmT[j][t] = (xc @ xp_w)[t][j]  (transposed output) ----------------
__global__ __launch_bounds__(256) void xssm_k(const float* __restrict__ xc,
                                              const float* __restrict__ xpw,
                                              float* __restrict__ xssmT) {
    int t = blockIdx.x;
    __shared__ float row[DI];
    int tid = threadIdx.x;
    for (int i = tid; i < DI; i += 256) row[i] = xc[(size_t)t * DI + i];
    __syncthreads();
    int j = tid >> 2;
    int part = tid & 3;
    if (j < 33) {
        float acc = 0.f;
        int c0 = part * 256;
        for (int c = c0; c < c0 + 256; ++c) acc += row[c] * xpw[c * 33 + j];
        acc += __shfl_xor(acc, 1);
        acc += __shfl_xor(acc, 2);
        if (part == 0) xssmT[(size_t)j * TT + t] = acc;
    }
}

// ---------------- h1 (token scalar -> 256, bf16 out) ----------------
__global__ __launch_bounds__(256) void h1_k(const float* __restrict__ imp,
                                            const float* __restrict__ w1,
                                            const float* __restrict__ b1,
                                            ushort* __restrict__ h1) {
    int t = blockIdx.x, tid = threadIdx.x;
    float v = imp[t] * w1[tid] + b1[tid];
    h1[(size_t)t * DI4 + tid] = f2bf(fmaxf(v, 0.f));
}

// ================= segmented scan =================
// Phase A: per-segment local scan (h0=0) + transfer product P = prod(a).
__global__ __launch_bounds__(256) void scanA_k(const float* __restrict__ modl,
                                               const float* __restrict__ xc,
                                               const float* __restrict__ xssmT,
                                               const float* __restrict__ Alog,
                                               const float* __restrict__ dtw,
                                               const float* __restrict__ dtb,
                                               float* __restrict__ hloc,
                                               float* __restrict__ Pp) {
    int blk = blockIdx.x;
    int seg = blk & 15;
    int dblk = (blk >> 4) & 63;
    int b = blk >> 10;
    int d0 = dblk * 16;
    int tid = threadIdx.x;
    int lane = tid & 63, wave = tid >> 6;
    int s = lane & 15, dd = lane >> 4;
    int dl = wave * 4 + dd, d = d0 + dl;
    float A = -__expf(Alog[d * DS + s]);
    size_t tokbase = (size_t)b * N + (size_t)seg * SLEN;

    __shared__ float sdel[SLEN][16];
    __shared__ float sxcv[SLEN][16];
    __shared__ float sBv_[SLEN][16];

    int lc = tid & 15, lr = tid >> 4;
    float dtwv = dtw[d0 + lc], dtbv = dtb[d0 + lc];
    const float* mbase = modl + tokbase * DI + d0 + lc;
    const float* xbase = xc + tokbase * DI + d0 + lc;
    const float* drow = xssmT + tokbase;
    const float* Brow = xssmT + (size_t)(1 + lc) * TT + tokbase;
#pragma unroll
    for (int q = 0; q < 4; ++q) {
        int tok = q * 16 + lr;
        float mo   = mbase[(size_t)tok * DI];
        float draw = drow[tok];
        float xcv  = xbase[(size_t)tok * DI];
        float Bv   = Brow[tok];
        float a = draw * dtwv + dtbv;
        float sp = (a > 20.f) ? a : log1pf(__expf(a));
        float mod = 1.f / (1.f + __expf(-mo));
        sdel[tok][lc] = sp * (1.f + mod);
        sxcv[tok][lc] = xcv;
        sBv_[tok][lc] = Bv;
    }
    __syncthreads();
    float h = 0.f, P = 1.f;
#pragma unroll
    for (int g = 0; g < 8; ++g) {
        float a8[8], b8[8];
#pragma unroll
        for (int j = 0; j < 8; ++j) {
            int t = g * 8 + j;
            float dlt = sdel[t][dl];
            a8[j] = __expf(dlt * A);
            b8[j] = (dlt * sBv_[t][s]) * sxcv[t][dl];
        }
#pragma unroll
        for (int j = 0; j < 8; ++j) { h = fmaf(a8[j], h, b8[j]); P *= a8[j]; }
    }
    size_t idx = (size_t)blk * 256 + tid;
    hloc[idx] = h;
    Pp[idx] = P;
}

// Phase B: sequential combine across 16 segments per (b,d,s); writes per-segment h0.
__global__ __launch_bounds__(256) void scanB_k(const float* __restrict__ hloc,
                                               const float* __restrict__ Pp,
                                               float* __restrict__ h0g) {
    int blk = blockIdx.x;
    int tid = threadIdx.x;
    size_t base = (size_t)blk * SEG * 256 + tid;
    float h = 0.f;
    for (int g = 0; g < SEG; ++g) {
        size_t i = base + (size_t)g * 256;
        h0g[i] = h;
        h = fmaf(Pp[i], h, hloc[i]);
    }
}

// Phase C: re-run segment from true h0; DEFERRED sP reduce (no dependent shfl chain).
__global__ __launch_bounds__(256) void scanC_k(const float* __restrict__ modl,
                                               const float* __restrict__ xc,
                                               const float* __restrict__ xssmT,
                                               const float* __restrict__ Alog,
                                               const float* __restrict__ Dp,
                                               const float* __restrict__ xz,
                                               const float* __restrict__ dtw,
                                               const float* __restrict__ dtb,
                                               const float* __restrict__ h0g,
                                               ushort* __restrict__ y) {
    int blk = blockIdx.x;
    int seg = blk & 15;
    int dblk = (blk >> 4) & 63;
    int b = blk >> 10;
    int d0 = dblk * 16;
    int tid = threadIdx.x;
    int lane = tid & 63, wave = tid >> 6;
    int s = lane & 15, dd = lane >> 4;
    int dl = wave * 4 + dd, d = d0 + dl;
    float A = -__expf(Alog[d * DS + s]);
    size_t tokbase = (size_t)b * N + (size_t)seg * SLEN;

    __shared__ float sdel[SLEN][16];
    __shared__ float sxcv[SLEN][16];
    __shared__ float sBv_[SLEN][16];
    __shared__ float sCv_[SLEN][16];
    __shared__ float szv_[SLEN][16];
    __shared__ float sP[16][16][17];   // [step-in-group][dl][s], 17-pad -> ~2-way banks

    int lc = tid & 15, lr = tid >> 4;
    float dtwv = dtw[d0 + lc], dtbv = dtb[d0 + lc];
    float dpv_lc = Dp[d0 + lc];
    const float* mbase = modl + tokbase * DI + d0 + lc;
    const float* xbase = xc + tokbase * DI + d0 + lc;
    const float* zbase = xz + tokbase * (2 * DI) + DI + d0 + lc;
    const float* drow = xssmT + tokbase;
    const float* Brow = xssmT + (size_t)(1 + lc) * TT + tokbase;
    const float* Crow = xssmT + (size_t)(1 + DS + lc) * TT + tokbase;
#pragma unroll
    for (int q = 0; q < 4; ++q) {
        int tok = q * 16 + lr;
        float mo   = mbase[(size_t)tok * DI];
        float draw = drow[tok];
        float xcv  = xbase[(size_t)tok * DI];
        float Bv   = Brow[tok];
        float Cv   = Crow[tok];
        float zv   = zbase[(size_t)tok * (2 * DI)];
        float a = draw * dtwv + dtbv;
        float sp = (a > 20.f) ? a : log1pf(__expf(a));
        float mod = 1.f / (1.f + __expf(-mo));
        sdel[tok][lc] = sp * (1.f + mod);
        sxcv[tok][lc] = xcv;
        sBv_[tok][lc] = Bv;
        sCv_[tok][lc] = Cv;
        szv_[tok][lc] = zv;
    }
    __syncthreads();
    float h = h0g[(size_t)blk * 256 + tid];
    for (int g = 0; g < 4; ++g) {              // 16-step groups
#pragma unroll
        for (int half = 0; half < 2; ++half) {
            float a8[8], b8[8], c8[8];
#pragma unroll
            for (int j = 0; j < 8; ++j) {
                int t = g * 16 + half * 8 + j;
                float dlt = sdel[t][dl];
                a8[j] = __expf(dlt * A);
                b8[j] = (dlt * sBv_[t][s]) * sxcv[t][dl];
                c8[j] = sCv_[t][s];
            }
#pragma unroll
            for (int j = 0; j < 8; ++j) {
                h = fmaf(a8[j], h, b8[j]);
                sP[half * 8 + j][dl][s] = h * c8[j];
            }
        }
        __syncthreads();
        {   // parallel s-reduce for these 16 tokens + gate + store
            int t = g * 16 + lr;
            float ssum = 0.f;
#pragma unroll
            for (int s2 = 0; s2 < 16; ++s2) ssum += sP[lr][lc][s2];
            float xcv = sxcv[t][lc];
            float zv  = szv_[t][lc];
            float sg = 1.f / (1.f + __expf(-zv));
            y[(tokbase + t) * DI + d0 + lc] = f2bf((ssum + xcv * dpv_lc) * (zv * sg));
        }
        __syncthreads();
    }
}

// ---------------- concat [xf | flip(xb)] -> bf16 ----------------
__global__ __launch_bounds__(256) void concat_k(const float* __restrict__ xf,
                                                const float* __restrict__ xb,
                                                ushort* __restrict__ cat) {
    int gid = blockIdx.x * 256 + threadIdx.x;   // TT*DM
    int t = gid >> 9;
    int c = gid & (DM - 1);
    int b = t >> 10, j = t & (N - 1);
    cat[(size_t)t * (2 * DM) + c] = f2bf(xf[gid]);
    cat[(size_t)t * (2 * DM) + DM + c] = f2bf(xb[((size_t)(b << 10) + (N - 1 - j)) * DM + c]);
}

// ---------------- final: scatter by ridx + layernorm ----------------
__global__ __launch_bounds__(256) void final_k(const float* __restrict__ fus,
                                               const int* __restrict__ ridx,
                                               const float* __restrict__ g,
                                               const float* __restrict__ bt,
                                               float* __restrict__ out) {
    int t = blockIdx.x, tid = threadIdx.x;
    int b = t >> 10;
    int r = ridx[t];
    const float* xr = fus + (size_t)t * DM;
    __shared__ float red[256];
    float v0 = xr[tid], v1 = xr[tid + 256];
    red[tid] = v0 + v1; __syncthreads();
    for (int st = 128; st > 0; st >>= 1) { if (tid < st) red[tid] += red[tid + st]; __syncthreads(); }
    float mu = red[0] * (1.f / DM); __syncthreads();
    float d0 = v0 - mu, d1 = v1 - mu;
    red[tid] = d0 * d0 + d1 * d1; __syncthreads();
    for (int st = 128; st > 0; st >>= 1) { if (tid < st) red[tid] += red[tid + st]; __syncthreads(); }
    float rs = rsqrtf(red[0] * (1.f / DM) + 1e-5f);
    float* orow = out + ((size_t)(b << 10) + r) * DM;
    orow[tid] = d0 * rs * g[tid] + bt[tid];
    orow[tid + 256] = d1 * rs * g[tid + 256] + bt[tid + 256];
}

// ---------------- host ----------------
extern "C" void kernel_launch(void* const* d_in, const int* in_sizes, int n_in,
                              void* d_out, int out_size, void* d_ws, size_t ws_size,
                              hipStream_t stream) {
    const float* x            = (const float*)d_in[0];
    const float* centers_init = (const float*)d_in[1];
    const float* in_w         = (const float*)d_in[2];
    const float* conv_w       = (const float*)d_in[3];
    const float* conv_b       = (const float*)d_in[4];
    const float* xp_w         = (const float*)d_in[5];
    const float* dt_w         = (const float*)d_in[6];
    const float* dt_b         = (const float*)d_in[7];
    const float* cm_w1        = (const float*)d_in[8];
    const float* cm_b1        = (const float*)d_in[9];
    const float* cm_w2        = (const float*)d_in[10];
    const float* cm_b2        = (const float*)d_in[11];
    const float* A_log        = (const float*)d_in[12];
    const float* D_p          = (const float*)d_in[13];
    const float* out_w        = (const float*)d_in[14];
    const float* ln_g         = (const float*)d_in[15];
    const float* ln_b         = (const float*)d_in[16];
    const float* fusion_w     = (const float*)d_in[17];
    const float* fusion_b     = (const float*)d_in[18];
    const float* fn_g         = (const float*)d_in[19];
    const float* fn_b         = (const float*)d_in[20];

    float* W = (float*)d_ws;
    size_t off = 0;
    auto alloc = [&](size_t n) { float* p = W + off; off += (n + 15) & ~(size_t)15; return p; };
    auto allocU = [&](size_t n) { ushort* p = (ushort*)(W + off); off += ((n + 1) / 2 + 15) & ~(size_t)15; return p; };
    float* centers = alloc((size_t)Bb * KC * DM);
    float* wgt     = alloc((size_t)TT * KC);
    float* mind    = alloc(TT);
    float* keys    = alloc(TT);
    float* imp     = alloc(TT);
    float* rimp    = alloc(TT);
    float* fimp    = alloc(TT);
    float* denp    = alloc((size_t)Bb * KC * SEGU);
    float* rx      = alloc((size_t)TT * DM);
    float* rxf     = alloc((size_t)TT * DM);
    float* tmp     = alloc((size_t)TT * DM);
    float* xz      = alloc((size_t)TT * 2 * DI);   // f32 xz; reused (cast) as bf16 cat
    float* xc      = alloc((size_t)TT * DI);       // reused as fus (f32)
    float* xssmT   = alloc((size_t)TT * 33);
    float* modl    = alloc((size_t)TT * DI);       // also aliased by kmeans 'part'
    float* hloc    = alloc((size_t)Bb * 64 * SEG * 256);
    float* Pp      = alloc((size_t)Bb * 64 * SEG * 256);
    float* h0g     = alloc((size_t)Bb * 64 * SEG * 256);
    ushort* xnb    = allocU((size_t)TT * DM);
    ushort* h1b    = allocU((size_t)TT * DI4);
    ushort* yb     = allocU((size_t)TT * DI);
    ushort* inwT   = allocU((size_t)L4 * 2 * DI * DM);
    ushort* cmw2T  = allocU((size_t)L4 * DI * DI4);
    ushort* outwT  = allocU((size_t)L4 * DM * DI);
    ushort* fusT   = allocU((size_t)DM * 2 * DM);
    int* ridx = (int*)(W + off); off += TT;
    float* part = modl;   // kmeans partials alias modl (kmeans finishes before layers)

    // ---- weight transposes (f32 -> bf16 [N][K]) ----
    for (int l = 0; l < L4; ++l) {
        tconv_k<<<dim3(2 * DI / 32, DM / 32), 256, 0, stream>>>(in_w + (size_t)l * DM * 2 * DI, inwT + (size_t)l * 2 * DI * DM, DM, 2 * DI);
        tconv_k<<<dim3(DI / 32, DI4 / 32), 256, 0, stream>>>(cm_w2 + (size_t)l * DI4 * DI, cmw2T + (size_t)l * DI * DI4, DI4, DI);
        tconv_k<<<dim3(DM / 32, DI / 32), 256, 0, stream>>>(out_w + (size_t)l * DI * DM, outwT + (size_t)l * DM * DI, DI, DM);
    }
    tconv_k<<<dim3(DM / 32, 2 * DM / 32), 256, 0, stream>>>(fusion_w, fusT, 2 * DM, DM);

    // ---- k-means ----
    initcen_k<<<(Bb * KC * DM) / 256, 256, 0, stream>>>(centers_init, centers);
    for (int it = 0; it < 3; ++it) {
        assign_k<false><<<TT, 64, 0, stream>>>(x, centers, wgt, nullptr, nullptr);
        updp_k<<<Bb * SEGU, 512, 0, stream>>>(x, wgt, part, denp);
        updr_k<<<Bb * KC, 512, 0, stream>>>(part, denp, centers);
    }
    assign_k<true><<<TT, 64, 0, stream>>>(x, centers, wgt, mind, keys);
    importance_k<<<Bb, 1024, 0, stream>>>(mind, imp);
    sort_k<<<Bb, 1024, 0, stream>>>(keys, ridx);
    gather_k<<<TT, 512, 0, stream>>>(x, imp, ridx, rx, rxf, rimp, fimp);

    auto gemm = [&](const ushort* Ap, int lda, const ushort* Bp, int ldb,
                    const float* bias, const float* add, int ldadd,
                    float* Cp, int ldc, int Kd, int Nn) {
        dim3 g(Nn / 128, TT / 128);
        mgemm_k<<<g, 256, 0, stream>>>(Ap, lda, Bp, ldb, bias, add, ldadd, Cp, ldc, Kd);
    };

    // ---- 4 mamba layers (2 fwd, 2 bwd on flipped) ----
    const float* lay_in[4]  = {rx, tmp, rxf, tmp};
    float*       lay_out[4] = {tmp, rx, tmp, rxf};
    for (int l = 0; l < L4; ++l) {
        const float* xin = lay_in[l];
        float* xout = lay_out[l];
        const float* impv = (l < 2) ? rimp : fimp;
        ln_k<<<TT, 256, 0, stream>>>(xin, ln_g + (size_t)l * DM, ln_b + (size_t)l * DM, xnb);
        gemm(xnb, DM, inwT + (size_t)l * 2 * DI * DM, DM, nullptr, nullptr, 0, xz, 2 * DI, DM, 2 * DI);
        conv_k<<<(TT * DI) / 256, 256, 0, stream>>>(xz, conv_w + (size_t)l * DI * DC, conv_b + (size_t)l * DI, xc);
        xssm_k<<<TT, 256, 0, stream>>>(xc, xp_w + (size_t)l * DI * 33, xssmT);
        h1_k<<<TT, 256, 0, stream>>>(impv, cm_w1 + (size_t)l * DI4, cm_b1 + (size_t)l * DI4, h1b);
        gemm(h1b, DI4, cmw2T + (size_t)l * DI * DI4, DI4, cm_b2 + (size_t)l * DI, nullptr, 0, modl, DI, DI4, DI);
        scanA_k<<<Bb * 64 * SEG, 256, 0, stream>>>(modl, xc, xssmT, A_log + (size_t)l * DI * DS,
                                                   dt_w + (size_t)l * DI, dt_b + (size_t)l * DI, hloc, Pp);
        scanB_k<<<Bb * 64, 256, 0, stream>>>(hloc, Pp, h0g);
        scanC_k<<<Bb * 64 * SEG, 256, 0, stream>>>(modl, xc, xssmT, A_log + (size_t)l * DI * DS,
                                                   D_p + (size_t)l * DI, xz,
                                                   dt_w + (size_t)l * DI, dt_b + (size_t)l * DI, h0g, yb);
        gemm(yb, DI, outwT + (size_t)l * DM * DI, DI, nullptr, xin, DM, xout, DM, DI, DM);
    }

    // ---- fusion + restore + final LN ----
    ushort* catb = (ushort*)xz;
    concat_k<<<(TT * DM) / 256, 256, 0, stream>>>(rx /*xf final*/, rxf /*xb final*/, catb);
    gemm(catb, 2 * DM, fusT, 2 * DM, fusion_b, nullptr, 0, xc /*fus*/, DM, 2 * DM, DM);
    final_k<<<TT, 256, 0, stream>>>(xc, ridx, fn_g, fn_b, (float*)d_out);
}

// Round 7
// 969.941 us; speedup vs baseline: 3.5334x; 1.1908x over previous
//
#include <hip/hip_runtime.h>
#include <math.h>

// ---------------- constants ----------------
constexpr int DM = 512, DS = 16, DC = 4, DI = 1024, DI4 = 256, KC = 5;
constexpr int Bb = 4, N = 1024, L4 = 4, TT = Bb * N;
constexpr float TEMP = 0.5f;
constexpr int SEG = 16;          // scan segments per sequence
constexpr int SLEN = N / SEG;    // 64 tokens per segment
constexpr int SEGU = 64;         // kmeans-update segments

typedef __attribute__((ext_vector_type(8))) short short8v;
typedef __attribute__((ext_vector_type(4))) float float4v;

__device__ inline ushort f2bf(float f) {
    union { float f; unsigned u; } v; v.f = f;
    unsigned r = v.u + 0x7FFFu + ((v.u >> 16) & 1u);
    return (ushort)(r >> 16);
}
__device__ inline float bf2f(ushort u) {
    union { unsigned u; float f; } v; v.u = ((unsigned)u) << 16;
    return v.f;
}

// ---------------- k-means ----------------
__global__ void initcen_k(const float* __restrict__ ci, float* __restrict__ centers) {
    int gid = blockIdx.x * 256 + threadIdx.x;           // B*KC*DM = 10240
    centers[gid] = ci[gid % (KC * DM)];
}

template <bool FINAL>
__global__ __launch_bounds__(64) void assign_k(const float* __restrict__ x,
                                               const float* __restrict__ centers,
                                               float* __restrict__ wgt,
                                               float* __restrict__ mind,
                                               float* __restrict__ keys) {
    int t = blockIdx.x;            // token 0..TT-1
    int b = t >> 10;
    int lane = threadIdx.x;
    const float* xr = x + (size_t)t * DM;
    const float* cen = centers + (size_t)b * KC * DM;
    float d2[KC] = {0.f, 0.f, 0.f, 0.f, 0.f};
    for (int c = lane; c < DM; c += 64) {
        float xv = xr[c];
#pragma unroll
        for (int k = 0; k < KC; ++k) {
            float df = xv - cen[k * DM + c];
            d2[k] += df * df;
        }
    }
#pragma unroll
    for (int k = 0; k < KC; ++k)
        for (int off = 32; off > 0; off >>= 1) d2[k] += __shfl_xor(d2[k], off);
    if (lane == 0) {
        float dist[KC], logit[KC], e[KC];
        float lm = -1e30f;
        for (int k = 0; k < KC; ++k) {
            dist[k] = sqrtf(d2[k] + 1e-12f);
            logit[k] = -dist[k] / TEMP;
            lm = fmaxf(lm, logit[k]);
        }
        float s = 0.f;
        for (int k = 0; k < KC; ++k) { e[k] = expf(logit[k] - lm); s += e[k]; }
        float inv = 1.f / s;
        for (int k = 0; k < KC; ++k) wgt[t * KC + k] = e[k] * inv;
        if (FINAL) {
            float md = dist[0];
            for (int k = 1; k < KC; ++k) md = fminf(md, dist[k]);
            int ca = 0; float best = e[0] * inv;
            for (int k = 1; k < KC; ++k) {
                float wv = e[k] * inv;
                if (wv > best) { best = wv; ca = k; }
            }
            mind[t] = md;
            keys[t] = (float)ca * 1000.0f + (1.0f - best);
        }
    }
}

// ---- update: pass1 partials over 16-token segments (reads x once) ----
__global__ __launch_bounds__(512) void updp_k(const float* __restrict__ x,
                                              const float* __restrict__ wgt,
                                              float* __restrict__ part,
                                              float* __restrict__ denp) {
    int blk = blockIdx.x;        // b*SEGU + seg
    int b = blk >> 6, seg = blk & 63;
    int c = threadIdx.x;
    constexpr int TSEG = N / SEGU;   // 16
    __shared__ float sw[TSEG][KC];
    int n0 = seg * TSEG;
    if (c < TSEG * KC) sw[c / KC][c % KC] = wgt[((size_t)(b << 10) + n0 + c / KC) * KC + c % KC];
    __syncthreads();
    const float* xb = x + ((size_t)(b << 10) + n0) * DM + c;
    float acc[KC] = {};
    for (int n = 0; n < TSEG; ++n) {
        float xv = xb[(size_t)n * DM];
#pragma unroll
        for (int k = 0; k < KC; ++k) acc[k] = fmaf(sw[n][k], xv, acc[k]);
    }
#pragma unroll
    for (int k = 0; k < KC; ++k)
        part[(((size_t)b * KC + k) * SEGU + seg) * DM + c] = acc[k];
    if (c < KC) {
        float dn = 0.f;
        for (int n = 0; n < TSEG; ++n) dn += sw[n][c];
        denp[((size_t)b * KC + c) * SEGU + seg] = dn;
    }
}

// ---- update: pass2 reduce ----
__global__ __launch_bounds__(512) void updr_k(const float* __restrict__ part,
                                              const float* __restrict__ denp,
                                              float* __restrict__ centers) {
    int bk = blockIdx.x;         // 0..B*KC-1
    int c = threadIdx.x;
    const float* pb = part + (size_t)bk * SEGU * DM + c;
    float acc = 0.f;
    for (int g = 0; g < SEGU; ++g) acc += pb[(size_t)g * DM];
    __shared__ float sden;
    if (c == 0) {
        float dn = 0.f;
        const float* db = denp + (size_t)bk * SEGU;
        for (int g = 0; g < SEGU; ++g) dn += db[g];
        sden = dn;
    }
    __syncthreads();
    centers[(size_t)bk * DM + c] = acc / (sden + 1e-8f);
}

__global__ __launch_bounds__(1024) void importance_k(const float* __restrict__ mind,
                                                     float* __restrict__ imp) {
    int b = blockIdx.x, n = threadIdx.x;
    __shared__ float red[1024];
    float v = -mind[b * N + n] / TEMP;
    red[n] = v; __syncthreads();
    for (int s = 512; s > 0; s >>= 1) { if (n < s) red[n] = fmaxf(red[n], red[n + s]); __syncthreads(); }
    float m = red[0]; __syncthreads();
    float e = expf(v - m);
    red[n] = e; __syncthreads();
    for (int s = 512; s > 0; s >>= 1) { if (n < s) red[n] += red[n + s]; __syncthreads(); }
    imp[b * N + n] = e / red[0];
}

__global__ __launch_bounds__(1024) void sort_k(const float* __restrict__ keys,
                                               int* __restrict__ ridx) {
    int b = blockIdx.x, tid = threadIdx.x;
    __shared__ unsigned long long a[1024];
    unsigned int kb = __float_as_uint(keys[b * N + tid]);   // keys >= 0
    a[tid] = ((unsigned long long)kb << 32) | (unsigned int)tid;
    __syncthreads();
    for (int k = 2; k <= 1024; k <<= 1) {
        for (int j = k >> 1; j > 0; j >>= 1) {
            int ixj = tid ^ j;
            if (ixj > tid) {
                unsigned long long x0 = a[tid], x1 = a[ixj];
                bool up = ((tid & k) == 0);
                bool sw = up ? (x0 > x1) : (x0 < x1);
                if (sw) { a[tid] = x1; a[ixj] = x0; }
            }
            __syncthreads();
        }
    }
    ridx[b * N + tid] = (int)(a[tid] & 0xffffffffu);
}

__global__ __launch_bounds__(512) void gather_k(const float* __restrict__ x,
                                                const float* __restrict__ imp,
                                                const int* __restrict__ ridx,
                                                float* __restrict__ rx, float* __restrict__ rxf,
                                                float* __restrict__ rimp, float* __restrict__ fimp) {
    int t = blockIdx.x;
    int b = t >> 10, j = t & (N - 1);
    int r = ridx[t];
    int c = threadIdx.x;
    float v = x[((size_t)(b << 10) + r) * DM + c];
    rx[(size_t)t * DM + c] = v;
    rxf[((size_t)(b << 10) + (N - 1 - j)) * DM + c] = v;
    if (c == 0) {
        float iv = imp[(b << 10) + r];
        rimp[t] = iv;
        fimp[(b << 10) + (N - 1 - j)] = iv;
    }
}

// ---------------- transpose + f32->bf16: dst[C][R] = cvt(src[R][C]) ----------------
__global__ __launch_bounds__(256) void tconv_k(const float* __restrict__ src,
                                               ushort* __restrict__ dst, int R, int C) {
    __shared__ float tile[32][33];
    int c0 = blockIdx.x * 32, r0 = blockIdx.y * 32;
    int tx = threadIdx.x & 31, ty = threadIdx.x >> 5;
#pragma unroll
    for (int j = 0; j < 4; ++j)
        tile[ty + j * 8][tx] = src[(size_t)(r0 + ty + j * 8) * C + c0 + tx];
    __syncthreads();
#pragma unroll
    for (int j = 0; j < 4; ++j)
        dst[(size_t)(c0 + ty + j * 8) * R + r0 + tx] = f2bf(tile[tx][ty + j * 8]);
}

// ---------------- xp_w -> padded transposed bf16 [128][1024] per layer ----------------
__global__ __launch_bounds__(256) void xpwprep_k(const float* __restrict__ xpw,
                                                 ushort* __restrict__ xpwT) {
    int l = blockIdx.x >> 2, chunk = blockIdx.x & 3;
    int c0 = chunk * 256, tid = threadIdx.x;
    __shared__ float lds[256 * 33];
    const float* src = xpw + (size_t)l * DI * 33 + (size_t)c0 * 33;
    for (int i = tid; i < 256 * 33; i += 256) lds[i] = src[i];
    __syncthreads();
    ushort* dst = xpwT + (size_t)l * 128 * DI;
    for (int j = 0; j < 128; ++j) {
        ushort v = (j < 33) ? f2bf(lds[tid * 33 + j]) : (ushort)0;
        dst[(size_t)j * DI + c0 + tid] = v;
    }
}

// ---------------- xssmP [TT][128] -> xssmT [33][TT] ----------------
__global__ __launch_bounds__(256) void tpose33_k(const float* __restrict__ xssmP,
                                                 float* __restrict__ xssmT) {
    int t0 = blockIdx.x * 64, tid = threadIdx.x;
    __shared__ float lds[64 * 129];
    const float* src = xssmP + (size_t)t0 * 128;
    for (int i = tid; i < 64 * 128; i += 256) lds[(i >> 7) * 129 + (i & 127)] = src[i];
    __syncthreads();
    int tk = tid & 63, jq = tid >> 6;
    for (int j = jq; j < 33; j += 4)
        xssmT[(size_t)j * TT + t0 + tk] = lds[tk * 129 + j];
}

// ---------------- layernorm (bf16 out) ----------------
__global__ __launch_bounds__(256) void ln_k(const float* __restrict__ xin,
                                            const float* __restrict__ g,
                                            const float* __restrict__ bt,
                                            ushort* __restrict__ out) {
    int t = blockIdx.x, tid = threadIdx.x;
    const float* xr = xin + (size_t)t * DM;
    __shared__ float red[256];
    float v0 = xr[tid], v1 = xr[tid + 256];
    red[tid] = v0 + v1; __syncthreads();
    for (int st = 128; st > 0; st >>= 1) { if (tid < st) red[tid] += red[tid + st]; __syncthreads(); }
    float mu = red[0] * (1.f / DM); __syncthreads();
    float d0 = v0 - mu, d1 = v1 - mu;
    red[tid] = d0 * d0 + d1 * d1; __syncthreads();
    for (int st = 128; st > 0; st >>= 1) { if (tid < st) red[tid] += red[tid + st]; __syncthreads(); }
    float rs = rsqrtf(red[0] * (1.f / DM) + 1e-5f);
    out[(size_t)t * DM + tid] = f2bf(d0 * rs * g[tid] + bt[tid]);
    out[(size_t)t * DM + tid + 256] = f2bf(d1 * rs * g[tid + 256] + bt[tid + 256]);
}

// ---------------- MFMA bf16 GEMM ----------------
__global__ __launch_bounds__(256) void mgemm_k(const ushort* __restrict__ A, int lda,
                                               const ushort* __restrict__ Bt, int ldb,
                                               const float* __restrict__ bias,
                                               const float* __restrict__ add, int ldadd,
                                               float* __restrict__ C, int ldc, int Kdim) {
    __shared__ short8v As[128 * 4];
    __shared__ short8v Bs[128 * 4];
    int tid = threadIdx.x;
    int lane = tid & 63, wid = tid >> 6;
    int row0 = blockIdx.y * 128, col0 = blockIdx.x * 128;
    int wr = (wid >> 1) * 64, wc = (wid & 1) * 64;
    float4v acc[4][4];
#pragma unroll
    for (int i = 0; i < 4; ++i)
#pragma unroll
        for (int j = 0; j < 4; ++j)
#pragma unroll
            for (int r = 0; r < 4; ++r) acc[i][j][r] = 0.f;

    int srow = tid >> 1;
    int sch = (tid & 1) * 2;
    int swz = (srow >> 1) & 3;
    const ushort* arow = A + (size_t)(row0 + srow) * lda;
    const ushort* brow = Bt + (size_t)(col0 + srow) * ldb;
    int fr = lane & 15, kg = lane >> 4;
    int sf = kg ^ ((fr >> 1) & 3);

    for (int k0 = 0; k0 < Kdim; k0 += 32) {
        short8v a0 = *(const short8v*)(arow + k0 + sch * 8);
        short8v a1 = *(const short8v*)(arow + k0 + sch * 8 + 8);
        short8v b0 = *(const short8v*)(brow + k0 + sch * 8);
        short8v b1 = *(const short8v*)(brow + k0 + sch * 8 + 8);
        __syncthreads();
        As[srow * 4 + (sch ^ swz)] = a0;
        As[srow * 4 + ((sch + 1) ^ swz)] = a1;
        Bs[srow * 4 + (sch ^ swz)] = b0;
        Bs[srow * 4 + ((sch + 1) ^ swz)] = b1;
        __syncthreads();
        short8v af[4], bf[4];
#pragma unroll
        for (int mb = 0; mb < 4; ++mb) af[mb] = As[(wr + mb * 16 + fr) * 4 + sf];
#pragma unroll
        for (int nb = 0; nb < 4; ++nb) bf[nb] = Bs[(wc + nb * 16 + fr) * 4 + sf];
#pragma unroll
        for (int mb = 0; mb < 4; ++mb)
#pragma unroll
            for (int nb = 0; nb < 4; ++nb)
                acc[mb][nb] = __builtin_amdgcn_mfma_f32_16x16x32_bf16(af[mb], bf[nb], acc[mb][nb], 0, 0, 0);
    }
#pragma unroll
    for (int mb = 0; mb < 4; ++mb) {
        int r_ = row0 + wr + mb * 16 + kg * 4;
#pragma unroll
        for (int nb = 0; nb < 4; ++nb) {
            int c_ = col0 + wc + nb * 16 + fr;
            float bz = bias ? bias[c_] : 0.f;
#pragma unroll
            for (int r = 0; r < 4; ++r) {
                float o = acc[mb][nb][r] + bz;
                if (add) o += add[(size_t)(r_ + r) * ldadd + c_];
                C[(size_t)(r_ + r) * ldc + c_] = o;
            }
        }
    }
}

// ---------------- depthwise causal conv + silu (bf16 out) ----------------
__global__ __launch_bounds__(256) void conv_k(const float* __restrict__ xz,
                                              const float* __restrict__ cw,
                                              const float* __restrict__ cb,
                                              ushort* __restrict__ xcb) {
    int gid = blockIdx.x * 256 + threadIdx.x;
    int d = gid & (DI - 1);
    int t = gid >> 10;
    int n = t & (N - 1);
    float acc = cb[d];
    const float* base = xz + (size_t)t * (2 * DI) + d;
#pragma unroll
    for (int k = 0; k < DC; ++k) {
        int nn = n - (DC - 1) + k;
        if (nn >= 0) acc += base[(long)(nn - n) * (2 * DI)] * cw[d * DC + k];
    }
    float s = 1.f / (1.f + expf(-acc));
    xcb[gid] = f2bf(acc * s);
}

// ---------------- h1 (token scalar -> 256, bf16 out) ----------------
__global__ __launch_bounds__(256) void h1_k(const float* __restrict__ imp,
                                            const float* __restrict__ w1,
                                            const float* __restrict__ b1,
                                            ushort* __restrict__ h1) {
    int t = blockIdx.x, tid = threadIdx.x;
    float v = imp[t] * w1[tid] + b1[tid];
    h1[(size_t)t * DI4 + tid] = f2bf(fmaxf(v, 0.f));
}

// ================= segmented scan =================
// Phase A: per-segment local scan (h0=0) + transfer product P = prod(a).
__global__ __launch_bounds__(256) void scanA_k(const float* __restrict__ modl,
                                               const ushort* __restrict__ xcb,
                                               const float* __restrict__ xssmT,
                                               const float* __restrict__ Alog,
                                               const float* __restrict__ dtw,
                                               const float* __restrict__ dtb,
                                               float* __restrict__ hloc,
                                               float* __restrict__ Pp) {
    int blk = blockIdx.x;
    int seg = blk & 15;
    int dblk = (blk >> 4) & 63;
    int b = blk >> 10;
    int d0 = dblk * 16;
    int tid = threadIdx.x;
    int lane = tid & 63, wave = tid >> 6;
    int s = lane & 15, dd = lane >> 4;
    int dl = wave * 4 + dd, d = d0 + dl;
    float A = -__expf(Alog[d * DS + s]);
    size_t tokbase = (size_t)b * N + (size_t)seg * SLEN;

    __shared__ float sdel[SLEN][16];
    __shared__ float sxcv[SLEN][16];
    __shared__ float sBv_[SLEN][16];

    int lc = tid & 15, lr = tid >> 4;
    float dtwv = dtw[d0 + lc], dtbv = dtb[d0 + lc];
    const float* mbase = modl + tokbase * DI + d0 + lc;
    const ushort* xbase = xcb + tokbase * DI + d0 + lc;
    const float* drow = xssmT + tokbase;
    const float* Brow = xssmT + (size_t)(1 + lc) * TT + tokbase;
#pragma unroll
    for (int q = 0; q < 4; ++q) {
        int tok = q * 16 + lr;
        float mo   = mbase[(size_t)tok * DI];
        float draw = drow[tok];
        float xcv  = bf2f(xbase[(size_t)tok * DI]);
        float Bv   = Brow[tok];
        float a = draw * dtwv + dtbv;
        float sp = (a > 20.f) ? a : log1pf(__expf(a));
        float mod = 1.f / (1.f + __expf(-mo));
        sdel[tok][lc] = sp * (1.f + mod);
        sxcv[tok][lc] = xcv;
        sBv_[tok][lc] = Bv;
    }
    __syncthreads();
    float h = 0.f, P = 1.f;
#pragma unroll
    for (int g = 0; g < 8; ++g) {
        float a8[8], b8[8];
#pragma unroll
        for (int j = 0; j < 8; ++j) {
            int t = g * 8 + j;
            float dlt = sdel[t][dl];
            a8[j] = __expf(dlt * A);
            b8[j] = (dlt * sBv_[t][s]) * sxcv[t][dl];
        }
#pragma unroll
        for (int j = 0; j < 8; ++j) { h = fmaf(a8[j], h, b8[j]); P *= a8[j]; }
    }
    size_t idx = (size_t)blk * 256 + tid;
    hloc[idx] = h;
    Pp[idx] = P;
}

// Phase B: sequential combine across 16 segments per (b,d,s); writes per-segment h0.
__global__ __launch_bounds__(256) void scanB_k(const float* __restrict__ hloc,
                                               const float* __restrict__ Pp,
                                               float* __restrict__ h0g) {
    int blk = blockIdx.x;
    int tid = threadIdx.x;
    size_t base = (size_t)blk * SEG * 256 + tid;
    float h = 0.f;
    for (int g = 0; g < SEG; ++g) {
        size_t i = base + (size_t)g * 256;
        h0g[i] = h;
        h = fmaf(Pp[i], h, hloc[i]);
    }
}

// Phase C: re-run segment from true h0; DEFERRED sP reduce (no dependent shfl chain).
__global__ __launch_bounds__(256) void scanC_k(const float* __restrict__ modl,
                                               const ushort* __restrict__ xcb,
                                               const float* __restrict__ xssmT,
                                               const float* __restrict__ Alog,
                                               const float* __restrict__ Dp,
                                               const float* __restrict__ xz,
                                               const float* __restrict__ dtw,
                                               const float* __restrict__ dtb,
                                               const float* __restrict__ h0g,
                                               ushort* __restrict__ y) {
    int blk = blockIdx.x;
    int seg = blk & 15;
    int dblk = (blk >> 4) & 63;
    int b = blk >> 10;
    int d0 = dblk * 16;
    int tid = threadIdx.x;
    int lane = tid & 63, wave = tid >> 6;
    int s = lane & 15, dd = lane >> 4;
    int dl = wave * 4 + dd, d = d0 + dl;
    float A = -__expf(Alog[d * DS + s]);
    size_t tokbase = (size_t)b * N + (size_t)seg * SLEN;

    __shared__ float sdel[SLEN][16];
    __shared__ float sxcv[SLEN][16];
    __shared__ float sBv_[SLEN][16];
    __shared__ float sCv_[SLEN][16];
    __shared__ float szv_[SLEN][16];
    __shared__ float sP[16][16][17];   // [step-in-group][dl][s], 17-pad

    int lc = tid & 15, lr = tid >> 4;
    float dtwv = dtw[d0 + lc], dtbv = dtb[d0 + lc];
    float dpv_lc = Dp[d0 + lc];
    const float* mbase = modl + tokbase * DI + d0 + lc;
    const ushort* xbase = xcb + tokbase * DI + d0 + lc;
    const float* zbase = xz + tokbase * (2 * DI) + DI + d0 + lc;
    const float* drow = xssmT + tokbase;
    const float* Brow = xssmT + (size_t)(1 + lc) * TT + tokbase;
    const float* Crow = xssmT + (size_t)(1 + DS + lc) * TT + tokbase;
#pragma unroll
    for (int q = 0; q < 4; ++q) {
        int tok = q * 16 + lr;
        float mo   = mbase[(size_t)tok * DI];
        float draw = drow[tok];
        float xcv  = bf2f(xbase[(size_t)tok * DI]);
        float Bv   = Brow[tok];
        float Cv   = Crow[tok];
        float zv   = zbase[(size_t)tok * (2 * DI)];
        float a = draw * dtwv + dtbv;
        float sp = (a > 20.f) ? a : log1pf(__expf(a));
        float mod = 1.f / (1.f + __expf(-mo));
        sdel[tok][lc] = sp * (1.f + mod);
        sxcv[tok][lc] = xcv;
        sBv_[tok][lc] = Bv;
        sCv_[tok][lc] = Cv;
        szv_[tok][lc] = zv;
    }
    __syncthreads();
    float h = h0g[(size_t)blk * 256 + tid];
    for (int g = 0; g < 4; ++g) {              // 16-step groups
#pragma unroll
        for (int half = 0; half < 2; ++half) {
            float a8[8], b8[8], c8[8];
#pragma unroll
            for (int j = 0; j < 8; ++j) {
                int t = g * 16 + half * 8 + j;
                float dlt = sdel[t][dl];
                a8[j] = __expf(dlt * A);
                b8[j] = (dlt * sBv_[t][s]) * sxcv[t][dl];
                c8[j] = sCv_[t][s];
            }
#pragma unroll
            for (int j = 0; j < 8; ++j) {
                h = fmaf(a8[j], h, b8[j]);
                sP[half * 8 + j][dl][s] = h * c8[j];
            }
        }
        __syncthreads();
        {   // parallel s-reduce for these 16 tokens + gate + store
            int t = g * 16 + lr;
            float ssum = 0.f;
#pragma unroll
            for (int s2 = 0; s2 < 16; ++s2) ssum += sP[lr][lc][s2];
            float xcv = sxcv[t][lc];
            float zv  = szv_[t][lc];
            float sg = 1.f / (1.f + __expf(-zv));
            y[(tokbase + t) * DI + d0 + lc] = f2bf((ssum + xcv * dpv_lc) * (zv * sg));
        }
        __syncthreads();
    }
}

// ---------------- concat [xf | flip(xb)] -> bf16 ----------------
__global__ __launch_bounds__(256) void concat_k(const float* __restrict__ xf,
                                                const float* __restrict__ xb,
                                                ushort* __restrict__ cat) {
    int gid = blockIdx.x * 256 + threadIdx.x;   // TT*DM
    int t = gid >> 9;
    int c = gid & (DM - 1);
    int b = t >> 10, j = t & (N - 1);
    cat[(size_t)t * (2 * DM) + c] = f2bf(xf[gid]);
    cat[(size_t)t * (2 * DM) + DM + c] = f2bf(xb[((size_t)(b << 10) + (N - 1 - j)) * DM + c]);
}

// ---------------- final: scatter by ridx + layernorm ----------------
__global__ __launch_bounds__(256) void final_k(const float* __restrict__ fus,
                                               const int* __restrict__ ridx,
                                               const float* __restrict__ g,
                                               const float* __restrict__ bt,
                                               float* __restrict__ out) {
    int t = blockIdx.x, tid = threadIdx.x;
    int b = t >> 10;
    int r = ridx[t];
    const float* xr = fus + (size_t)t * DM;
    __shared__ float red[256];
    float v0 = xr[tid], v1 = xr[tid + 256];
    red[tid] = v0 + v1; __syncthreads();
    for (int st = 128; st > 0; st >>= 1) { if (tid < st) red[tid] += red[tid + st]; __syncthreads(); }
    float mu = red[0] * (1.f / DM); __syncthreads();
    float d0 = v0 - mu, d1 = v1 - mu;
    red[tid] = d0 * d0 + d1 * d1; __syncthreads();
    for (int st = 128; st > 0; st >>= 1) { if (tid < st) red[tid] += red[tid + st]; __syncthreads(); }
    float rs = rsqrtf(red[0] * (1.f / DM) + 1e-5f);
    float* orow = out + ((size_t)(b << 10) + r) * DM;
    orow[tid] = d0 * rs * g[tid] + bt[tid];
    orow[tid + 256] = d1 * rs * g[tid + 256] + bt[tid + 256];
}

// ---------------- host ----------------
extern "C" void kernel_launch(void* const* d_in, const int* in_sizes, int n_in,
                              void* d_out, int out_size, void* d_ws, size_t ws_size,
                              hipStream_t stream) {
    const float* x            = (const float*)d_in[0];
    const float* centers_init = (const float*)d_in[1];
    const float* in_w         = (const float*)d_in[2];
    const float* conv_w       = (const float*)d_in[3];
    const float* conv_b       = (const float*)d_in[4];
    const float* xp_w         = (const float*)d_in[5];
    const float* dt_w         = (const float*)d_in[6];
    const float* dt_b         = (const float*)d_in[7];
    const float* cm_w1        = (const float*)d_in[8];
    const float* cm_b1        = (const float*)d_in[9];
    const float* cm_w2        = (const float*)d_in[10];
    const float* cm_b2        = (const float*)d_in[11];
    const float* A_log        = (const float*)d_in[12];
    const float* D_p          = (const float*)d_in[13];
    const float* out_w        = (const float*)d_in[14];
    const float* ln_g         = (const float*)d_in[15];
    const float* ln_b         = (const float*)d_in[16];
    const float* fusion_w     = (const float*)d_in[17];
    const float* fusion_b     = (const float*)d_in[18];
    const float* fn_g         = (const float*)d_in[19];
    const float* fn_b         = (const float*)d_in[20];

    float* W = (float*)d_ws;
    size_t off = 0;
    auto alloc = [&](size_t n) { float* p = W + off; off += (n + 15) & ~(size_t)15; return p; };
    auto allocU = [&](size_t n) { ushort* p = (ushort*)(W + off); off += ((n + 1) / 2 + 15) & ~(size_t)15; return p; };
    float* centers = alloc((size_t)Bb * KC * DM);
    float* wgt     = alloc((size_t)TT * KC);
    float* mind    = alloc(TT);
    float* keys    = alloc(TT);
    float* imp     = alloc(TT);
    float* rimp    = alloc(TT);
    float* fimp    = alloc(TT);
    float* denp    = alloc((size_t)Bb * KC * SEGU);
    float* rx      = alloc((size_t)TT * DM);
    float* rxf     = alloc((size_t)TT * DM);
    float* tmp     = alloc((size_t)TT * DM);
    float* xz      = alloc((size_t)TT * 2 * DI);   // f32 xz; reused (cast) as bf16 cat
    float* fus     = alloc((size_t)TT * DM);       // fusion output f32
    float* xssmT   = alloc((size_t)TT * 33);
    float* modl    = alloc((size_t)TT * DI);       // also aliased by kmeans 'part'
    float* hloc    = alloc((size_t)Bb * 64 * SEG * 256);   // also aliased by xssmP
    float* Pp      = alloc((size_t)Bb * 64 * SEG * 256);
    float* h0g     = alloc((size_t)Bb * 64 * SEG * 256);
    ushort* xnb    = allocU((size_t)TT * DM);
    ushort* h1b    = allocU((size_t)TT * DI4);
    ushort* yb     = allocU((size_t)TT * DI);
    ushort* xcb    = allocU((size_t)TT * DI);
    ushort* inwT   = allocU((size_t)L4 * 2 * DI * DM);
    ushort* cmw2T  = allocU((size_t)L4 * DI * DI4);
    ushort* outwT  = allocU((size_t)L4 * DM * DI);
    ushort* fusT   = allocU((size_t)DM * 2 * DM);
    ushort* xpwT   = allocU((size_t)L4 * 128 * DI);
    int* ridx = (int*)(W + off); off += TT;
    float* part = modl;    // kmeans partials alias modl (disjoint in time)
    float* xssmP = hloc;   // padded xssm GEMM out aliases hloc (disjoint in time)

    // ---- weight transposes (f32 -> bf16 [N][K]) ----
    for (int l = 0; l < L4; ++l) {
        tconv_k<<<dim3(2 * DI / 32, DM / 32), 256, 0, stream>>>(in_w + (size_t)l * DM * 2 * DI, inwT + (size_t)l * 2 * DI * DM, DM, 2 * DI);
        tconv_k<<<dim3(DI / 32, DI4 / 32), 256, 0, stream>>>(cm_w2 + (size_t)l * DI4 * DI, cmw2T + (size_t)l * DI * DI4, DI4, DI);
        tconv_k<<<dim3(DM / 32, DI / 32), 256, 0, stream>>>(out_w + (size_t)l * DI * DM, outwT + (size_t)l * DM * DI, DI, DM);
    }
    tconv_k<<<dim3(DM / 32, 2 * DM / 32), 256, 0, stream>>>(fusion_w, fusT, 2 * DM, DM);
    xpwprep_k<<<L4 * 4, 256, 0, stream>>>(xp_w, xpwT);

    // ---- k-means ----
    initcen_k<<<(Bb * KC * DM) / 256, 256, 0, stream>>>(centers_init, centers);
    for (int it = 0; it < 3; ++it) {
        assign_k<false><<<TT, 64, 0, stream>>>(x, centers, wgt, nullptr, nullptr);
        updp_k<<<Bb * SEGU, 512, 0, stream>>>(x, wgt, part, denp);
        updr_k<<<Bb * KC, 512, 0, stream>>>(part, denp, centers);
    }
    assign_k<true><<<TT, 64, 0, stream>>>(x, centers, wgt, mind, keys);
    importance_k<<<Bb, 1024, 0, stream>>>(mind, imp);
    sort_k<<<Bb, 1024, 0, stream>>>(keys, ridx);
    gather_k<<<TT, 512, 0, stream>>>(x, imp, ridx, rx, rxf, rimp, fimp);

    auto gemm = [&](const ushort* Ap, int lda, const ushort* Bp, int ldb,
                    const float* bias, const float* add, int ldadd,
                    float* Cp, int ldc, int Kd, int Nn) {
        dim3 g(Nn / 128, TT / 128);
        mgemm_k<<<g, 256, 0, stream>>>(Ap, lda, Bp, ldb, bias, add, ldadd, Cp, ldc, Kd);
    };

    // ---- 4 mamba layers (2 fwd, 2 bwd on flipped) ----
    const float* lay_in[4]  = {rx, tmp, rxf, tmp};
    float*       lay_out[4] = {tmp, rx, tmp, rxf};
    for (int l = 0; l < L4; ++l) {
        const float* xin = lay_in[l];
        float* xout = lay_out[l];
        const float* impv = (l < 2) ? rimp : fimp;
        ln_k<<<TT, 256, 0, stream>>>(xin, ln_g + (size_t)l * DM, ln_b + (size_t)l * DM, xnb);
        gemm(xnb, DM, inwT + (size_t)l * 2 * DI * DM, DM, nullptr, nullptr, 0, xz, 2 * DI, DM, 2 * DI);
        conv_k<<<(TT * DI) / 256, 256, 0, stream>>>(xz, conv_w + (size_t)l * DI * DC, conv_b + (size_t)l * DI, xcb);
        gemm(xcb, DI, xpwT + (size_t)l * 128 * DI, DI, nullptr, nullptr, 0, xssmP, 128, DI, 128);
        tpose33_k<<<TT / 64, 256, 0, stream>>>(xssmP, xssmT);
        h1_k<<<TT, 256, 0, stream>>>(impv, cm_w1 + (size_t)l * DI4, cm_b1 + (size_t)l * DI4, h1b);
        gemm(h1b, DI4, cmw2T + (size_t)l * DI * DI4, DI4, cm_b2 + (size_t)l * DI, nullptr, 0, modl, DI, DI4, DI);
        scanA_k<<<Bb * 64 * SEG, 256, 0, stream>>>(modl, xcb, xssmT, A_log + (size_t)l * DI * DS,
                                                   dt_w + (size_t)l * DI, dt_b + (size_t)l * DI, hloc, Pp);
        scanB_k<<<Bb * 64, 256, 0, stream>>>(hloc, Pp, h0g);
        scanC_k<<<Bb * 64 * SEG, 256, 0, stream>>>(modl, xcb, xssmT, A_log + (size_t)l * DI * DS,
                                                   D_p + (size_t)l * DI, xz,
                                                   dt_w + (size_t)l * DI, dt_b + (size_t)l * DI, h0g, yb);
        gemm(yb, DI, outwT + (size_t)l * DM * DI, DI, nullptr, xin, DM, xout, DM, DI, DM);
    }

    // ---- fusion + restore + final LN ----
    ushort* catb = (ushort*)xz;
    concat_k<<<(TT * DM) / 256, 256, 0, stream>>>(rx /*xf final*/, rxf /*xb final*/, catb);
    gemm(catb, 2 * DM, fusT, 2 * DM, fusion_b, nullptr, 0, fus, DM, 2 * DM, DM);
    final_k<<<TT, 256, 0, stream>>>(fus, ridx, fn_g, fn_b, (float*)d_out);
}

// Round 8
// 958.359 us; speedup vs baseline: 3.5761x; 1.0121x over previous
//
#include <hip/hip_runtime.h>
#include <math.h>

// ---------------- constants ----------------
constexpr int DM = 512, DS = 16, DC = 4, DI = 1024, DI4 = 256, KC = 5;
constexpr int Bb = 4, N = 1024, L4 = 4, TT = Bb * N;
constexpr float TEMP = 0.5f;
constexpr int SEG = 16;          // scan segments per sequence
constexpr int SLEN = N / SEG;    // 64 tokens per segment
constexpr int SEGU = 64;         // kmeans-update segments

typedef __attribute__((ext_vector_type(8))) short short8v;
typedef __attribute__((ext_vector_type(4))) float float4v;

__device__ inline ushort f2bf(float f) {
    union { float f; unsigned u; } v; v.f = f;
    unsigned r = v.u + 0x7FFFu + ((v.u >> 16) & 1u);
    return (ushort)(r >> 16);
}
__device__ inline float bf2f(ushort u) {
    union { unsigned u; float f; } v; v.u = ((unsigned)u) << 16;
    return v.f;
}

// ---------------- k-means ----------------
__global__ void initcen_k(const float* __restrict__ ci, float* __restrict__ centers) {
    int gid = blockIdx.x * 256 + threadIdx.x;           // B*KC*DM = 10240
    centers[gid] = ci[gid % (KC * DM)];
}

// wave-per-token, float4 loads
template <bool FINAL>
__global__ __launch_bounds__(256) void assign_k(const float* __restrict__ x,
                                                const float* __restrict__ centers,
                                                float* __restrict__ wgt,
                                                float* __restrict__ mind,
                                                float* __restrict__ keys) {
    int t = blockIdx.x * 4 + (threadIdx.x >> 6);   // token
    int b = t >> 10;
    int lane = threadIdx.x & 63;
    const float4* xr = (const float4*)(x + (size_t)t * DM);
    float4 xv0 = xr[lane], xv1 = xr[lane + 64];
    const float* cenb = centers + (size_t)b * KC * DM;
    float d2[KC];
#pragma unroll
    for (int k = 0; k < KC; ++k) {
        const float4* cr = (const float4*)(cenb + k * DM);
        float4 c0 = cr[lane], c1 = cr[lane + 64];
        float dx = xv0.x - c0.x, dy = xv0.y - c0.y, dz = xv0.z - c0.z, dw = xv0.w - c0.w;
        float acc = dx * dx + dy * dy + dz * dz + dw * dw;
        dx = xv1.x - c1.x; dy = xv1.y - c1.y; dz = xv1.z - c1.z; dw = xv1.w - c1.w;
        acc += dx * dx + dy * dy + dz * dz + dw * dw;
        d2[k] = acc;
    }
#pragma unroll
    for (int k = 0; k < KC; ++k)
        for (int off = 32; off > 0; off >>= 1) d2[k] += __shfl_xor(d2[k], off);
    if (lane == 0) {
        float dist[KC], logit[KC], e[KC];
        float lm = -1e30f;
        for (int k = 0; k < KC; ++k) {
            dist[k] = sqrtf(d2[k] + 1e-12f);
            logit[k] = -dist[k] / TEMP;
            lm = fmaxf(lm, logit[k]);
        }
        float s = 0.f;
        for (int k = 0; k < KC; ++k) { e[k] = expf(logit[k] - lm); s += e[k]; }
        float inv = 1.f / s;
        for (int k = 0; k < KC; ++k) wgt[t * KC + k] = e[k] * inv;
        if (FINAL) {
            float md = dist[0];
            for (int k = 1; k < KC; ++k) md = fminf(md, dist[k]);
            int ca = 0; float best = e[0] * inv;
            for (int k = 1; k < KC; ++k) {
                float wv = e[k] * inv;
                if (wv > best) { best = wv; ca = k; }
            }
            mind[t] = md;
            keys[t] = (float)ca * 1000.0f + (1.0f - best);
        }
    }
}

// ---- update: pass1 partials over 16-token segments (reads x once) ----
__global__ __launch_bounds__(512) void updp_k(const float* __restrict__ x,
                                              const float* __restrict__ wgt,
                                              float* __restrict__ part,
                                              float* __restrict__ denp) {
    int blk = blockIdx.x;        // b*SEGU + seg
    int b = blk >> 6, seg = blk & 63;
    int c = threadIdx.x;
    constexpr int TSEG = N / SEGU;   // 16
    __shared__ float sw[TSEG][KC];
    int n0 = seg * TSEG;
    if (c < TSEG * KC) sw[c / KC][c % KC] = wgt[((size_t)(b << 10) + n0 + c / KC) * KC + c % KC];
    __syncthreads();
    const float* xb = x + ((size_t)(b << 10) + n0) * DM + c;
    float acc[KC] = {};
    for (int n = 0; n < TSEG; ++n) {
        float xv = xb[(size_t)n * DM];
#pragma unroll
        for (int k = 0; k < KC; ++k) acc[k] = fmaf(sw[n][k], xv, acc[k]);
    }
#pragma unroll
    for (int k = 0; k < KC; ++k)
        part[(((size_t)b * KC + k) * SEGU + seg) * DM + c] = acc[k];
    if (c < KC) {
        float dn = 0.f;
        for (int n = 0; n < TSEG; ++n) dn += sw[n][c];
        denp[((size_t)b * KC + c) * SEGU + seg] = dn;
    }
}

// ---- update: pass2 reduce ----
__global__ __launch_bounds__(512) void updr_k(const float* __restrict__ part,
                                              const float* __restrict__ denp,
                                              float* __restrict__ centers) {
    int bk = blockIdx.x;         // 0..B*KC-1
    int c = threadIdx.x;
    const float* pb = part + (size_t)bk * SEGU * DM + c;
    float acc = 0.f;
    for (int g = 0; g < SEGU; ++g) acc += pb[(size_t)g * DM];
    __shared__ float sden;
    if (c == 0) {
        float dn = 0.f;
        const float* db = denp + (size_t)bk * SEGU;
        for (int g = 0; g < SEGU; ++g) dn += db[g];
        sden = dn;
    }
    __syncthreads();
    centers[(size_t)bk * DM + c] = acc / (sden + 1e-8f);
}

__global__ __launch_bounds__(1024) void importance_k(const float* __restrict__ mind,
                                                     float* __restrict__ imp) {
    int b = blockIdx.x, n = threadIdx.x;
    __shared__ float red[1024];
    float v = -mind[b * N + n] / TEMP;
    red[n] = v; __syncthreads();
    for (int s = 512; s > 0; s >>= 1) { if (n < s) red[n] = fmaxf(red[n], red[n + s]); __syncthreads(); }
    float m = red[0]; __syncthreads();
    float e = expf(v - m);
    red[n] = e; __syncthreads();
    for (int s = 512; s > 0; s >>= 1) { if (n < s) red[n] += red[n + s]; __syncthreads(); }
    imp[b * N + n] = e / red[0];
}

__global__ __launch_bounds__(1024) void sort_k(const float* __restrict__ keys,
                                               int* __restrict__ ridx) {
    int b = blockIdx.x, tid = threadIdx.x;
    __shared__ unsigned long long a[1024];
    unsigned int kb = __float_as_uint(keys[b * N + tid]);   // keys >= 0
    a[tid] = ((unsigned long long)kb << 32) | (unsigned int)tid;
    __syncthreads();
    for (int k = 2; k <= 1024; k <<= 1) {
        for (int j = k >> 1; j > 0; j >>= 1) {
            int ixj = tid ^ j;
            if (ixj > tid) {
                unsigned long long x0 = a[tid], x1 = a[ixj];
                bool up = ((tid & k) == 0);
                bool sw = up ? (x0 > x1) : (x0 < x1);
                if (sw) { a[tid] = x1; a[ixj] = x0; }
            }
            __syncthreads();
        }
    }
    ridx[b * N + tid] = (int)(a[tid] & 0xffffffffu);
}

__global__ __launch_bounds__(512) void gather_k(const float* __restrict__ x,
                                                const float* __restrict__ imp,
                                                const int* __restrict__ ridx,
                                                float* __restrict__ rx, float* __restrict__ rxf,
                                                float* __restrict__ rimp, float* __restrict__ fimp) {
    int t = blockIdx.x;
    int b = t >> 10, j = t & (N - 1);
    int r = ridx[t];
    int c = threadIdx.x;
    float v = x[((size_t)(b << 10) + r) * DM + c];
    rx[(size_t)t * DM + c] = v;
    rxf[((size_t)(b << 10) + (N - 1 - j)) * DM + c] = v;
    if (c == 0) {
        float iv = imp[(b << 10) + r];
        rimp[t] = iv;
        fimp[(b << 10) + (N - 1 - j)] = iv;
    }
}

// ---------------- transpose + f32->bf16: dst[C][R] = cvt(src[R][C]) ----------------
__global__ __launch_bounds__(256) void tconv_k(const float* __restrict__ src,
                                               ushort* __restrict__ dst, int R, int C) {
    __shared__ float tile[32][33];
    int c0 = blockIdx.x * 32, r0 = blockIdx.y * 32;
    int tx = threadIdx.x & 31, ty = threadIdx.x >> 5;
#pragma unroll
    for (int j = 0; j < 4; ++j)
        tile[ty + j * 8][tx] = src[(size_t)(r0 + ty + j * 8) * C + c0 + tx];
    __syncthreads();
#pragma unroll
    for (int j = 0; j < 4; ++j)
        dst[(size_t)(c0 + ty + j * 8) * R + r0 + tx] = f2bf(tile[tx][ty + j * 8]);
}

// ---------------- xp_w -> padded transposed bf16 [128][1024] per layer ----------------
__global__ __launch_bounds__(256) void xpwprep_k(const float* __restrict__ xpw,
                                                 ushort* __restrict__ xpwT) {
    int l = blockIdx.x >> 2, chunk = blockIdx.x & 3;
    int c0 = chunk * 256, tid = threadIdx.x;
    __shared__ float lds[256 * 33];
    const float* src = xpw + (size_t)l * DI * 33 + (size_t)c0 * 33;
    for (int i = tid; i < 256 * 33; i += 256) lds[i] = src[i];
    __syncthreads();
    ushort* dst = xpwT + (size_t)l * 128 * DI;
    for (int j = 0; j < 128; ++j) {
        ushort v = (j < 33) ? f2bf(lds[tid * 33 + j]) : (ushort)0;
        dst[(size_t)j * DI + c0 + tid] = v;
    }
}

// ---------------- xssmP [TT][128] -> xssmT [33][TT] ----------------
__global__ __launch_bounds__(256) void tpose33_k(const float* __restrict__ xssmP,
                                                 float* __restrict__ xssmT) {
    int t0 = blockIdx.x * 64, tid = threadIdx.x;
    __shared__ float lds[64 * 129];
    const float* src = xssmP + (size_t)t0 * 128;
    for (int i = tid; i < 64 * 128; i += 256) lds[(i >> 7) * 129 + (i & 127)] = src[i];
    __syncthreads();
    int tk = tid & 63, jq = tid >> 6;
    for (int j = jq; j < 33; j += 4)
        xssmT[(size_t)j * TT + t0 + tk] = lds[tk * 129 + j];
}

// ---------------- layernorm (bf16 out) ----------------
__global__ __launch_bounds__(256) void ln_k(const float* __restrict__ xin,
                                            const float* __restrict__ g,
                                            const float* __restrict__ bt,
                                            ushort* __restrict__ out) {
    int t = blockIdx.x, tid = threadIdx.x;
    const float* xr = xin + (size_t)t * DM;
    __shared__ float red[256];
    float v0 = xr[tid], v1 = xr[tid + 256];
    red[tid] = v0 + v1; __syncthreads();
    for (int st = 128; st > 0; st >>= 1) { if (tid < st) red[tid] += red[tid + st]; __syncthreads(); }
    float mu = red[0] * (1.f / DM); __syncthreads();
    float d0 = v0 - mu, d1 = v1 - mu;
    red[tid] = d0 * d0 + d1 * d1; __syncthreads();
    for (int st = 128; st > 0; st >>= 1) { if (tid < st) red[tid] += red[tid + st]; __syncthreads(); }
    float rs = rsqrtf(red[0] * (1.f / DM) + 1e-5f);
    out[(size_t)t * DM + tid] = f2bf(d0 * rs * g[tid] + bt[tid]);
    out[(size_t)t * DM + tid + 256] = f2bf(d1 * rs * g[tid + 256] + bt[tid + 256]);
}

// ---------------- MFMA bf16 GEMM ----------------
__global__ __launch_bounds__(256) void mgemm_k(const ushort* __restrict__ A, int lda,
                                               const ushort* __restrict__ Bt, int ldb,
                                               const float* __restrict__ bias,
                                               const float* __restrict__ add, int ldadd,
                                               float* __restrict__ C, int ldc, int Kdim) {
    __shared__ short8v As[128 * 4];
    __shared__ short8v Bs[128 * 4];
    int tid = threadIdx.x;
    int lane = tid & 63, wid = tid >> 6;
    int row0 = blockIdx.y * 128, col0 = blockIdx.x * 128;
    int wr = (wid >> 1) * 64, wc = (wid & 1) * 64;
    float4v acc[4][4];
#pragma unroll
    for (int i = 0; i < 4; ++i)
#pragma unroll
        for (int j = 0; j < 4; ++j)
#pragma unroll
            for (int r = 0; r < 4; ++r) acc[i][j][r] = 0.f;

    int srow = tid >> 1;
    int sch = (tid & 1) * 2;
    int swz = (srow >> 1) & 3;
    const ushort* arow = A + (size_t)(row0 + srow) * lda;
    const ushort* brow = Bt + (size_t)(col0 + srow) * ldb;
    int fr = lane & 15, kg = lane >> 4;
    int sf = kg ^ ((fr >> 1) & 3);

    for (int k0 = 0; k0 < Kdim; k0 += 32) {
        short8v a0 = *(const short8v*)(arow + k0 + sch * 8);
        short8v a1 = *(const short8v*)(arow + k0 + sch * 8 + 8);
        short8v b0 = *(const short8v*)(brow + k0 + sch * 8);
        short8v b1 = *(const short8v*)(brow + k0 + sch * 8 + 8);
        __syncthreads();
        As[srow * 4 + (sch ^ swz)] = a0;
        As[srow * 4 + ((sch + 1) ^ swz)] = a1;
        Bs[srow * 4 + (sch ^ swz)] = b0;
        Bs[srow * 4 + ((sch + 1) ^ swz)] = b1;
        __syncthreads();
        short8v af[4], bf[4];
#pragma unroll
        for (int mb = 0; mb < 4; ++mb) af[mb] = As[(wr + mb * 16 + fr) * 4 + sf];
#pragma unroll
        for (int nb = 0; nb < 4; ++nb) bf[nb] = Bs[(wc + nb * 16 + fr) * 4 + sf];
#pragma unroll
        for (int mb = 0; mb < 4; ++mb)
#pragma unroll
            for (int nb = 0; nb < 4; ++nb)
                acc[mb][nb] = __builtin_amdgcn_mfma_f32_16x16x32_bf16(af[mb], bf[nb], acc[mb][nb], 0, 0, 0);
    }
#pragma unroll
    for (int mb = 0; mb < 4; ++mb) {
        int r_ = row0 + wr + mb * 16 + kg * 4;
#pragma unroll
        for (int nb = 0; nb < 4; ++nb) {
            int c_ = col0 + wc + nb * 16 + fr;
            float bz = bias ? bias[c_] : 0.f;
#pragma unroll
            for (int r = 0; r < 4; ++r) {
                float o = acc[mb][nb][r] + bz;
                if (add) o += add[(size_t)(r_ + r) * ldadd + c_];
                C[(size_t)(r_ + r) * ldc + c_] = o;
            }
        }
    }
}

// ---------------- depthwise causal conv + silu (bf16 out) ----------------
__global__ __launch_bounds__(256) void conv_k(const float* __restrict__ xz,
                                              const float* __restrict__ cw,
                                              const float* __restrict__ cb,
                                              ushort* __restrict__ xcb) {
    int gid = blockIdx.x * 256 + threadIdx.x;
    int d = gid & (DI - 1);
    int t = gid >> 10;
    int n = t & (N - 1);
    float acc = cb[d];
    const float* base = xz + (size_t)t * (2 * DI) + d;
#pragma unroll
    for (int k = 0; k < DC; ++k) {
        int nn = n - (DC - 1) + k;
        if (nn >= 0) acc += base[(long)(nn - n) * (2 * DI)] * cw[d * DC + k];
    }
    float s = 1.f / (1.f + expf(-acc));
    xcb[gid] = f2bf(acc * s);
}

// ---------------- h1 (token scalar -> 256, bf16 out) ----------------
__global__ __launch_bounds__(256) void h1_k(const float* __restrict__ imp,
                                            const float* __restrict__ w1,
                                            const float* __restrict__ b1,
                                            ushort* __restrict__ h1) {
    int t = blockIdx.x, tid = threadIdx.x;
    float v = imp[t] * w1[tid] + b1[tid];
    h1[(size_t)t * DI4 + tid] = f2bf(fmaxf(v, 0.f));
}

// ================= segmented scan ([dim][t] LDS layout, b128 reads) =================
// Phase A: per-segment local scan (h0=0) + transfer product P = prod(a).
__global__ __launch_bounds__(256) void scanA_k(const float* __restrict__ modl,
                                               const ushort* __restrict__ xcb,
                                               const float* __restrict__ xssmT,
                                               const float* __restrict__ Alog,
                                               const float* __restrict__ dtw,
                                               const float* __restrict__ dtb,
                                               float* __restrict__ hloc,
                                               float* __restrict__ Pp) {
    int blk = blockIdx.x;
    int seg = blk & 15;
    int dblk = (blk >> 4) & 63;
    int b = blk >> 10;
    int d0 = dblk * 16;
    int tid = threadIdx.x;
    int lane = tid & 63, wave = tid >> 6;
    int s = lane & 15, dd = lane >> 4;
    int dl = wave * 4 + dd, d = d0 + dl;
    float A = -__expf(Alog[d * DS + s]);
    size_t tokbase = (size_t)b * N + (size_t)seg * SLEN;

    __shared__ float sdl[16][68];   // [dl][t] delta
    __shared__ float sxc[16][68];   // [dl][t] xc
    __shared__ float sBv[16][68];   // [s][t]  B

    int lc = tid & 15, lr = tid >> 4;
    float dtwv = dtw[d0 + lc], dtbv = dtb[d0 + lc];
    const float* mbase = modl + tokbase * DI + d0 + lc;
    const ushort* xbase = xcb + tokbase * DI + d0 + lc;
    const float* drow = xssmT + tokbase;
    const float* Brow = xssmT + (size_t)(1 + lc) * TT + tokbase;
#pragma unroll
    for (int q = 0; q < 4; ++q) {
        int tok = q * 16 + lr;
        float mo   = mbase[(size_t)tok * DI];
        float draw = drow[tok];
        float xcv  = bf2f(xbase[(size_t)tok * DI]);
        float Bv   = Brow[tok];
        float a = draw * dtwv + dtbv;
        float sp = (a > 20.f) ? a : log1pf(__expf(a));
        float mod = 1.f / (1.f + __expf(-mo));
        sdl[lc][tok] = sp * (1.f + mod);
        sxc[lc][tok] = xcv;
        sBv[lc][tok] = Bv;
    }
    __syncthreads();
    float h = 0.f, P = 1.f;
#pragma unroll
    for (int g = 0; g < 8; ++g) {
        float4 dl4a = *(const float4*)&sdl[dl][g * 8];
        float4 dl4b = *(const float4*)&sdl[dl][g * 8 + 4];
        float4 xc4a = *(const float4*)&sxc[dl][g * 8];
        float4 xc4b = *(const float4*)&sxc[dl][g * 8 + 4];
        float4 B4a  = *(const float4*)&sBv[s][g * 8];
        float4 B4b  = *(const float4*)&sBv[s][g * 8 + 4];
        float dlt[8] = {dl4a.x, dl4a.y, dl4a.z, dl4a.w, dl4b.x, dl4b.y, dl4b.z, dl4b.w};
        float xcv[8] = {xc4a.x, xc4a.y, xc4a.z, xc4a.w, xc4b.x, xc4b.y, xc4b.z, xc4b.w};
        float Bv8[8] = {B4a.x, B4a.y, B4a.z, B4a.w, B4b.x, B4b.y, B4b.z, B4b.w};
        float a8[8], b8[8];
#pragma unroll
        for (int j = 0; j < 8; ++j) {
            a8[j] = __expf(dlt[j] * A);
            b8[j] = (dlt[j] * Bv8[j]) * xcv[j];
        }
#pragma unroll
        for (int j = 0; j < 8; ++j) { h = fmaf(a8[j], h, b8[j]); P *= a8[j]; }
    }
    size_t idx = (size_t)blk * 256 + tid;
    hloc[idx] = h;
    Pp[idx] = P;
}

// Phase B: sequential combine across 16 segments per (b,d,s); writes per-segment h0.
__global__ __launch_bounds__(256) void scanB_k(const float* __restrict__ hloc,
                                               const float* __restrict__ Pp,
                                               float* __restrict__ h0g) {
    int blk = blockIdx.x;
    int tid = threadIdx.x;
    size_t base = (size_t)blk * SEG * 256 + tid;
    float h = 0.f;
    for (int g = 0; g < SEG; ++g) {
        size_t i = base + (size_t)g * 256;
        h0g[i] = h;
        h = fmaf(Pp[i], h, hloc[i]);
    }
}

// Phase C: re-run segment from true h0; deferred sP reduce; b128 LDS reads.
__global__ __launch_bounds__(256) void scanC_k(const float* __restrict__ modl,
                                               const ushort* __restrict__ xcb,
                                               const float* __restrict__ xssmT,
                                               const float* __restrict__ Alog,
                                               const float* __restrict__ Dp,
                                               const float* __restrict__ xz,
                                               const float* __restrict__ dtw,
                                               const float* __restrict__ dtb,
                                               const float* __restrict__ h0g,
                                               ushort* __restrict__ y) {
    int blk = blockIdx.x;
    int seg = blk & 15;
    int dblk = (blk >> 4) & 63;
    int b = blk >> 10;
    int d0 = dblk * 16;
    int tid = threadIdx.x;
    int lane = tid & 63, wave = tid >> 6;
    int s = lane & 15, dd = lane >> 4;
    int dl = wave * 4 + dd, d = d0 + dl;
    float A = -__expf(Alog[d * DS + s]);
    size_t tokbase = (size_t)b * N + (size_t)seg * SLEN;

    __shared__ float sdl[16][68];   // [dl][t]
    __shared__ float sxc[16][68];   // [dl][t]
    __shared__ float sBv[16][68];   // [s][t]
    __shared__ float sCv[16][68];   // [s][t]
    __shared__ float szv[16][68];   // [dl][t]
    __shared__ float sP[16][16][17];   // [step-in-group][dl][s]

    int lc = tid & 15, lr = tid >> 4;
    float dtwv = dtw[d0 + lc], dtbv = dtb[d0 + lc];
    float dpv_lc = Dp[d0 + lc];
    const float* mbase = modl + tokbase * DI + d0 + lc;
    const ushort* xbase = xcb + tokbase * DI + d0 + lc;
    const float* zbase = xz + tokbase * (2 * DI) + DI + d0 + lc;
    const float* drow = xssmT + tokbase;
    const float* Brow = xssmT + (size_t)(1 + lc) * TT + tokbase;
    const float* Crow = xssmT + (size_t)(1 + DS + lc) * TT + tokbase;
#pragma unroll
    for (int q = 0; q < 4; ++q) {
        int tok = q * 16 + lr;
        float mo   = mbase[(size_t)tok * DI];
        float draw = drow[tok];
        float xcv  = bf2f(xbase[(size_t)tok * DI]);
        float Bv   = Brow[tok];
        float Cv   = Crow[tok];
        float zv   = zbase[(size_t)tok * (2 * DI)];
        float a = draw * dtwv + dtbv;
        float sp = (a > 20.f) ? a : log1pf(__expf(a));
        float mod = 1.f / (1.f + __expf(-mo));
        sdl[lc][tok] = sp * (1.f + mod);
        sxc[lc][tok] = xcv;
        sBv[lc][tok] = Bv;
        sCv[lc][tok] = Cv;
        szv[lc][tok] = zv;
    }
    __syncthreads();
    float h = h0g[(size_t)blk * 256 + tid];
    for (int g = 0; g < 4; ++g) {              // 16-token groups
#pragma unroll
        for (int half = 0; half < 2; ++half) {
            int t0 = g * 16 + half * 8;
            float4 dl4a = *(const float4*)&sdl[dl][t0];
            float4 dl4b = *(const float4*)&sdl[dl][t0 + 4];
            float4 xc4a = *(const float4*)&sxc[dl][t0];
            float4 xc4b = *(const float4*)&sxc[dl][t0 + 4];
            float4 B4a  = *(const float4*)&sBv[s][t0];
            float4 B4b  = *(const float4*)&sBv[s][t0 + 4];
            float4 C4a  = *(const float4*)&sCv[s][t0];
            float4 C4b  = *(const float4*)&sCv[s][t0 + 4];
            float dlt[8] = {dl4a.x, dl4a.y, dl4a.z, dl4a.w, dl4b.x, dl4b.y, dl4b.z, dl4b.w};
            float xcv[8] = {xc4a.x, xc4a.y, xc4a.z, xc4a.w, xc4b.x, xc4b.y, xc4b.z, xc4b.w};
            float Bv8[8] = {B4a.x, B4a.y, B4a.z, B4a.w, B4b.x, B4b.y, B4b.z, B4b.w};
            float Cv8[8] = {C4a.x, C4a.y, C4a.z, C4a.w, C4b.x, C4b.y, C4b.z, C4b.w};
            float a8[8], b8[8];
#pragma unroll
            for (int j = 0; j < 8; ++j) {
                a8[j] = __expf(dlt[j] * A);
                b8[j] = (dlt[j] * Bv8[j]) * xcv[j];
            }
#pragma unroll
            for (int j = 0; j < 8; ++j) {
                h = fmaf(a8[j], h, b8[j]);
                sP[half * 8 + j][dl][s] = h * Cv8[j];
            }
        }
        __syncthreads();
        {   // parallel s-reduce for these 16 tokens + gate + store
            int t = g * 16 + lr;
            float ssum = 0.f;
#pragma unroll
            for (int s2 = 0; s2 < 16; ++s2) ssum += sP[lr][lc][s2];
            float xcv = sxc[lc][t];
            float zv  = szv[lc][t];
            float sg = 1.f / (1.f + __expf(-zv));
            y[(tokbase + t) * DI + d0 + lc] = f2bf((ssum + xcv * dpv_lc) * (zv * sg));
        }
        __syncthreads();
    }
}

// ---------------- concat [xf | flip(xb)] -> bf16 ----------------
__global__ __launch_bounds__(256) void concat_k(const float* __restrict__ xf,
                                                const float* __restrict__ xb,
                                                ushort* __restrict__ cat) {
    int gid = blockIdx.x * 256 + threadIdx.x;   // TT*DM
    int t = gid >> 9;
    int c = gid & (DM - 1);
    int b = t >> 10, j = t & (N - 1);
    cat[(size_t)t * (2 * DM) + c] = f2bf(xf[gid]);
    cat[(size_t)t * (2 * DM) + DM + c] = f2bf(xb[((size_t)(b << 10) + (N - 1 - j)) * DM + c]);
}

// ---------------- final: scatter by ridx + layernorm ----------------
__global__ __launch_bounds__(256) void final_k(const float* __restrict__ fus,
                                               const int* __restrict__ ridx,
                                               const float* __restrict__ g,
                                               const float* __restrict__ bt,
                                               float* __restrict__ out) {
    int t = blockIdx.x, tid = threadIdx.x;
    int b = t >> 10;
    int r = ridx[t];
    const float* xr = fus + (size_t)t * DM;
    __shared__ float red[256];
    float v0 = xr[tid], v1 = xr[tid + 256];
    red[tid] = v0 + v1; __syncthreads();
    for (int st = 128; st > 0; st >>= 1) { if (tid < st) red[tid] += red[tid + st]; __syncthreads(); }
    float mu = red[0] * (1.f / DM); __syncthreads();
    float d0 = v0 - mu, d1 = v1 - mu;
    red[tid] = d0 * d0 + d1 * d1; __syncthreads();
    for (int st = 128; st > 0; st >>= 1) { if (tid < st) red[tid] += red[tid + st]; __syncthreads(); }
    float rs = rsqrtf(red[0] * (1.f / DM) + 1e-5f);
    float* orow = out + ((size_t)(b << 10) + r) * DM;
    orow[tid] = d0 * rs * g[tid] + bt[tid];
    orow[tid + 256] = d1 * rs * g[tid + 256] + bt[tid + 256];
}

// ---------------- host ----------------
extern "C" void kernel_launch(void* const* d_in, const int* in_sizes, int n_in,
                              void* d_out, int out_size, void* d_ws, size_t ws_size,
                              hipStream_t stream) {
    const float* x            = (const float*)d_in[0];
    const float* centers_init = (const float*)d_in[1];
    const float* in_w         = (const float*)d_in[2];
    const float* conv_w       = (const float*)d_in[3];
    const float* conv_b       = (const float*)d_in[4];
    const float* xp_w         = (const float*)d_in[5];
    const float* dt_w         = (const float*)d_in[6];
    const float* dt_b         = (const float*)d_in[7];
    const float* cm_w1        = (const float*)d_in[8];
    const float* cm_b1        = (const float*)d_in[9];
    const float* cm_w2        = (const float*)d_in[10];
    const float* cm_b2        = (const float*)d_in[11];
    const float* A_log        = (const float*)d_in[12];
    const float* D_p          = (const float*)d_in[13];
    const float* out_w        = (const float*)d_in[14];
    const float* ln_g         = (const float*)d_in[15];
    const float* ln_b         = (const float*)d_in[16];
    const float* fusion_w     = (const float*)d_in[17];
    const float* fusion_b     = (const float*)d_in[18];
    const float* fn_g         = (const float*)d_in[19];
    const float* fn_b         = (const float*)d_in[20];

    float* W = (float*)d_ws;
    size_t off = 0;
    auto alloc = [&](size_t n) { float* p = W + off; off += (n + 15) & ~(size_t)15; return p; };
    auto allocU = [&](size_t n) { ushort* p = (ushort*)(W + off); off += ((n + 1) / 2 + 15) & ~(size_t)15; return p; };
    float* centers = alloc((size_t)Bb * KC * DM);
    float* wgt     = alloc((size_t)TT * KC);
    float* mind    = alloc(TT);
    float* keys    = alloc(TT);
    float* imp     = alloc(TT);
    float* rimp    = alloc(TT);
    float* fimp    = alloc(TT);
    float* denp    = alloc((size_t)Bb * KC * SEGU);
    float* rx      = alloc((size_t)TT * DM);
    float* rxf     = alloc((size_t)TT * DM);
    float* tmp     = alloc((size_t)TT * DM);
    float* xz      = alloc((size_t)TT * 2 * DI);   // f32 xz; reused (cast) as bf16 cat
    float* fus     = alloc((size_t)TT * DM);       // fusion output f32
    float* xssmT   = alloc((size_t)TT * 33);
    float* modl    = alloc((size_t)TT * DI);       // also aliased by kmeans 'part'
    float* hloc    = alloc((size_t)Bb * 64 * SEG * 256);   // also aliased by xssmP
    float* Pp      = alloc((size_t)Bb * 64 * SEG * 256);
    float* h0g     = alloc((size_t)Bb * 64 * SEG * 256);
    ushort* xnb    = allocU((size_t)TT * DM);
    ushort* h1b    = allocU((size_t)TT * DI4);
    ushort* yb     = allocU((size_t)TT * DI);
    ushort* xcb    = allocU((size_t)TT * DI);
    ushort* inwT   = allocU((size_t)L4 * 2 * DI * DM);
    ushort* cmw2T  = allocU((size_t)L4 * DI * DI4);
    ushort* outwT  = allocU((size_t)L4 * DM * DI);
    ushort* fusT   = allocU((size_t)DM * 2 * DM);
    ushort* xpwT   = allocU((size_t)L4 * 128 * DI);
    int* ridx = (int*)(W + off); off += TT;
    float* part = modl;    // kmeans partials alias modl (disjoint in time)
    float* xssmP = hloc;   // padded xssm GEMM out aliases hloc (disjoint in time)

    // ---- weight transposes (f32 -> bf16 [N][K]) ----
    for (int l = 0; l < L4; ++l) {
        tconv_k<<<dim3(2 * DI / 32, DM / 32), 256, 0, stream>>>(in_w + (size_t)l * DM * 2 * DI, inwT + (size_t)l * 2 * DI * DM, DM, 2 * DI);
        tconv_k<<<dim3(DI / 32, DI4 / 32), 256, 0, stream>>>(cm_w2 + (size_t)l * DI4 * DI, cmw2T + (size_t)l * DI * DI4, DI4, DI);
        tconv_k<<<dim3(DM / 32, DI / 32), 256, 0, stream>>>(out_w + (size_t)l * DI * DM, outwT + (size_t)l * DM * DI, DI, DM);
    }
    tconv_k<<<dim3(DM / 32, 2 * DM / 32), 256, 0, stream>>>(fusion_w, fusT, 2 * DM, DM);
    xpwprep_k<<<L4 * 4, 256, 0, stream>>>(xp_w, xpwT);

    // ---- k-means ----
    initcen_k<<<(Bb * KC * DM) / 256, 256, 0, stream>>>(centers_init, centers);
    for (int it = 0; it < 3; ++it) {
        assign_k<false><<<TT / 4, 256, 0, stream>>>(x, centers, wgt, nullptr, nullptr);
        updp_k<<<Bb * SEGU, 512, 0, stream>>>(x, wgt, part, denp);
        updr_k<<<Bb * KC, 512, 0, stream>>>(part, denp, centers);
    }
    assign_k<true><<<TT / 4, 256, 0, stream>>>(x, centers, wgt, mind, keys);
    importance_k<<<Bb, 1024, 0, stream>>>(mind, imp);
    sort_k<<<Bb, 1024, 0, stream>>>(keys, ridx);
    gather_k<<<TT, 512, 0, stream>>>(x, imp, ridx, rx, rxf, rimp, fimp);

    auto gemm = [&](const ushort* Ap, int lda, const ushort* Bp, int ldb,
                    const float* bias, const float* add, int ldadd,
                    float* Cp, int ldc, int Kd, int Nn) {
        dim3 g(Nn / 128, TT / 128);
        mgemm_k<<<g, 256, 0, stream>>>(Ap, lda, Bp, ldb, bias, add, ldadd, Cp, ldc, Kd);
    };

    // ---- 4 mamba layers (2 fwd, 2 bwd on flipped) ----
    const float* lay_in[4]  = {rx, tmp, rxf, tmp};
    float*       lay_out[4] = {tmp, rx, tmp, rxf};
    for (int l = 0; l < L4; ++l) {
        const float* xin = lay_in[l];
        float* xout = lay_out[l];
        const float* impv = (l < 2) ? rimp : fimp;
        ln_k<<<TT, 256, 0, stream>>>(xin, ln_g + (size_t)l * DM, ln_b + (size_t)l * DM, xnb);
        gemm(xnb, DM, inwT + (size_t)l * 2 * DI * DM, DM, nullptr, nullptr, 0, xz, 2 * DI, DM, 2 * DI);
        conv_k<<<(TT * DI) / 256, 256, 0, stream>>>(xz, conv_w + (size_t)l * DI * DC, conv_b + (size_t)l * DI, xcb);
        gemm(xcb, DI, xpwT + (size_t)l * 128 * DI, DI, nullptr, nullptr, 0, xssmP, 128, DI, 128);
        tpose33_k<<<TT / 64, 256, 0, stream>>>(xssmP, xssmT);
        h1_k<<<TT, 256, 0, stream>>>(impv, cm_w1 + (size_t)l * DI4, cm_b1 + (size_t)l * DI4, h1b);
        gemm(h1b, DI4, cmw2T + (size_t)l * DI * DI4, DI4, cm_b2 + (size_t)l * DI, nullptr, 0, modl, DI, DI4, DI);
        scanA_k<<<Bb * 64 * SEG, 256, 0, stream>>>(modl, xcb, xssmT, A_log + (size_t)l * DI * DS,
                                                   dt_w + (size_t)l * DI, dt_b + (size_t)l * DI, hloc, Pp);
        scanB_k<<<Bb * 64, 256, 0, stream>>>(hloc, Pp, h0g);
        scanC_k<<<Bb * 64 * SEG, 256, 0, stream>>>(modl, xcb, xssmT, A_log + (size_t)l * DI * DS,
                                                   D_p + (size_t)l * DI, xz,
                                                   dt_w + (size_t)l * DI, dt_b + (size_t)l * DI, h0g, yb);
        gemm(yb, DI, outwT + (size_t)l * DM * DI, DI, nullptr, xin, DM, xout, DM, DI, DM);
    }

    // ---- fusion + restore + final LN ----
    ushort* catb = (ushort*)xz;
    concat_k<<<(TT * DM) / 256, 256, 0, stream>>>(rx /*xf final*/, rxf /*xb final*/, catb);
    gemm(catb, 2 * DM, fusT, 2 * DM, fusion_b, nullptr, 0, fus, DM, 2 * DM, DM);
    final_k<<<TT, 256, 0, stream>>>(fus, ridx, fn_g, fn_b, (float*)d_out);
}

// Round 9
// 922.894 us; speedup vs baseline: 3.7135x; 1.0384x over previous
//
#include <hip/hip_runtime.h>
#include <math.h>

// ---------------- constants ----------------
constexpr int DM = 512, DS = 16, DC = 4, DI = 1024, DI4 = 256, KC = 5;
constexpr int Bb = 4, N = 1024, L4 = 4, TT = Bb * N;
constexpr float TEMP = 0.5f;
constexpr int SEG = 16;          // scan segments per sequence
constexpr int SLEN = N / SEG;    // 64 tokens per segment
constexpr int SEGU = 64;         // kmeans-update segments

typedef __attribute__((ext_vector_type(8))) short short8v;
typedef __attribute__((ext_vector_type(4))) float float4v;

__device__ inline ushort f2bf(float f) {
    union { float f; unsigned u; } v; v.f = f;
    unsigned r = v.u + 0x7FFFu + ((v.u >> 16) & 1u);
    return (ushort)(r >> 16);
}
__device__ inline float bf2f(ushort u) {
    union { unsigned u; float f; } v; v.u = ((unsigned)u) << 16;
    return v.f;
}
__device__ inline void gld16(const void* g, void* lds) {
    __builtin_amdgcn_global_load_lds(
        (const __attribute__((address_space(1))) unsigned int*)g,
        (__attribute__((address_space(3))) unsigned int*)lds, 16, 0, 0);
}

// ---------------- k-means ----------------
__global__ void initcen_k(const float* __restrict__ ci, float* __restrict__ centers) {
    int gid = blockIdx.x * 256 + threadIdx.x;           // B*KC*DM = 10240
    centers[gid] = ci[gid % (KC * DM)];
}

// wave-per-token, float4 loads
template <bool FINAL>
__global__ __launch_bounds__(256) void assign_k(const float* __restrict__ x,
                                                const float* __restrict__ centers,
                                                float* __restrict__ wgt,
                                                float* __restrict__ mind,
                                                float* __restrict__ keys) {
    int t = blockIdx.x * 4 + (threadIdx.x >> 6);   // token
    int b = t >> 10;
    int lane = threadIdx.x & 63;
    const float4* xr = (const float4*)(x + (size_t)t * DM);
    float4 xv0 = xr[lane], xv1 = xr[lane + 64];
    const float* cenb = centers + (size_t)b * KC * DM;
    float d2[KC];
#pragma unroll
    for (int k = 0; k < KC; ++k) {
        const float4* cr = (const float4*)(cenb + k * DM);
        float4 c0 = cr[lane], c1 = cr[lane + 64];
        float dx = xv0.x - c0.x, dy = xv0.y - c0.y, dz = xv0.z - c0.z, dw = xv0.w - c0.w;
        float acc = dx * dx + dy * dy + dz * dz + dw * dw;
        dx = xv1.x - c1.x; dy = xv1.y - c1.y; dz = xv1.z - c1.z; dw = xv1.w - c1.w;
        acc += dx * dx + dy * dy + dz * dz + dw * dw;
        d2[k] = acc;
    }
#pragma unroll
    for (int k = 0; k < KC; ++k)
        for (int off = 32; off > 0; off >>= 1) d2[k] += __shfl_xor(d2[k], off);
    if (lane == 0) {
        float dist[KC], logit[KC], e[KC];
        float lm = -1e30f;
        for (int k = 0; k < KC; ++k) {
            dist[k] = sqrtf(d2[k] + 1e-12f);
            logit[k] = -dist[k] / TEMP;
            lm = fmaxf(lm, logit[k]);
        }
        float s = 0.f;
        for (int k = 0; k < KC; ++k) { e[k] = expf(logit[k] - lm); s += e[k]; }
        float inv = 1.f / s;
        for (int k = 0; k < KC; ++k) wgt[t * KC + k] = e[k] * inv;
        if (FINAL) {
            float md = dist[0];
            for (int k = 1; k < KC; ++k) md = fminf(md, dist[k]);
            int ca = 0; float best = e[0] * inv;
            for (int k = 1; k < KC; ++k) {
                float wv = e[k] * inv;
                if (wv > best) { best = wv; ca = k; }
            }
            mind[t] = md;
            keys[t] = (float)ca * 1000.0f + (1.0f - best);
        }
    }
}

// ---- update: pass1 partials over 16-token segments (reads x once) ----
__global__ __launch_bounds__(512) void updp_k(const float* __restrict__ x,
                                              const float* __restrict__ wgt,
                                              float* __restrict__ part,
                                              float* __restrict__ denp) {
    int blk = blockIdx.x;        // b*SEGU + seg
    int b = blk >> 6, seg = blk & 63;
    int c = threadIdx.x;
    constexpr int TSEG = N / SEGU;   // 16
    __shared__ float sw[TSEG][KC];
    int n0 = seg * TSEG;
    if (c < TSEG * KC) sw[c / KC][c % KC] = wgt[((size_t)(b << 10) + n0 + c / KC) * KC + c % KC];
    __syncthreads();
    const float* xb = x + ((size_t)(b << 10) + n0) * DM + c;
    float acc[KC] = {};
    for (int n = 0; n < TSEG; ++n) {
        float xv = xb[(size_t)n * DM];
#pragma unroll
        for (int k = 0; k < KC; ++k) acc[k] = fmaf(sw[n][k], xv, acc[k]);
    }
#pragma unroll
    for (int k = 0; k < KC; ++k)
        part[(((size_t)b * KC + k) * SEGU + seg) * DM + c] = acc[k];
    if (c < KC) {
        float dn = 0.f;
        for (int n = 0; n < TSEG; ++n) dn += sw[n][c];
        denp[((size_t)b * KC + c) * SEGU + seg] = dn;
    }
}

// ---- update: pass2 reduce ----
__global__ __launch_bounds__(512) void updr_k(const float* __restrict__ part,
                                              const float* __restrict__ denp,
                                              float* __restrict__ centers) {
    int bk = blockIdx.x;         // 0..B*KC-1
    int c = threadIdx.x;
    const float* pb = part + (size_t)bk * SEGU * DM + c;
    float acc = 0.f;
    for (int g = 0; g < SEGU; ++g) acc += pb[(size_t)g * DM];
    __shared__ float sden;
    if (c == 0) {
        float dn = 0.f;
        const float* db = denp + (size_t)bk * SEGU;
        for (int g = 0; g < SEGU; ++g) dn += db[g];
        sden = dn;
    }
    __syncthreads();
    centers[(size_t)bk * DM + c] = acc / (sden + 1e-8f);
}

__global__ __launch_bounds__(1024) void importance_k(const float* __restrict__ mind,
                                                     float* __restrict__ imp) {
    int b = blockIdx.x, n = threadIdx.x;
    __shared__ float red[1024];
    float v = -mind[b * N + n] / TEMP;
    red[n] = v; __syncthreads();
    for (int s = 512; s > 0; s >>= 1) { if (n < s) red[n] = fmaxf(red[n], red[n + s]); __syncthreads(); }
    float m = red[0]; __syncthreads();
    float e = expf(v - m);
    red[n] = e; __syncthreads();
    for (int s = 512; s > 0; s >>= 1) { if (n < s) red[n] += red[n + s]; __syncthreads(); }
    imp[b * N + n] = e / red[0];
}

__global__ __launch_bounds__(1024) void sort_k(const float* __restrict__ keys,
                                               int* __restrict__ ridx) {
    int b = blockIdx.x, tid = threadIdx.x;
    __shared__ unsigned long long a[1024];
    unsigned int kb = __float_as_uint(keys[b * N + tid]);   // keys >= 0
    a[tid] = ((unsigned long long)kb << 32) | (unsigned int)tid;
    __syncthreads();
    for (int k = 2; k <= 1024; k <<= 1) {
        for (int j = k >> 1; j > 0; j >>= 1) {
            int ixj = tid ^ j;
            if (ixj > tid) {
                unsigned long long x0 = a[tid], x1 = a[ixj];
                bool up = ((tid & k) == 0);
                bool sw = up ? (x0 > x1) : (x0 < x1);
                if (sw) { a[tid] = x1; a[ixj] = x0; }
            }
            __syncthreads();
        }
    }
    ridx[b * N + tid] = (int)(a[tid] & 0xffffffffu);
}

__global__ __launch_bounds__(512) void gather_k(const float* __restrict__ x,
                                                const float* __restrict__ imp,
                                                const int* __restrict__ ridx,
                                                float* __restrict__ rx, float* __restrict__ rxf,
                                                float* __restrict__ rimp, float* __restrict__ fimp) {
    int t = blockIdx.x;
    int b = t >> 10, j = t & (N - 1);
    int r = ridx[t];
    int c = threadIdx.x;
    float v = x[((size_t)(b << 10) + r) * DM + c];
    rx[(size_t)t * DM + c] = v;
    rxf[((size_t)(b << 10) + (N - 1 - j)) * DM + c] = v;
    if (c == 0) {
        float iv = imp[(b << 10) + r];
        rimp[t] = iv;
        fimp[(b << 10) + (N - 1 - j)] = iv;
    }
}

// ---------------- transpose + f32->bf16: dst[C][R] = cvt(src[R][C]) ----------------
__global__ __launch_bounds__(256) void tconv_k(const float* __restrict__ src,
                                               ushort* __restrict__ dst, int R, int C) {
    __shared__ float tile[32][33];
    int c0 = blockIdx.x * 32, r0 = blockIdx.y * 32;
    int tx = threadIdx.x & 31, ty = threadIdx.x >> 5;
#pragma unroll
    for (int j = 0; j < 4; ++j)
        tile[ty + j * 8][tx] = src[(size_t)(r0 + ty + j * 8) * C + c0 + tx];
    __syncthreads();
#pragma unroll
    for (int j = 0; j < 4; ++j)
        dst[(size_t)(c0 + ty + j * 8) * R + r0 + tx] = f2bf(tile[tx][ty + j * 8]);
}

// ---------------- xp_w -> padded transposed bf16 [128][1024] per layer ----------------
__global__ __launch_bounds__(256) void xpwprep_k(const float* __restrict__ xpw,
                                                 ushort* __restrict__ xpwT) {
    int l = blockIdx.x >> 2, chunk = blockIdx.x & 3;
    int c0 = chunk * 256, tid = threadIdx.x;
    __shared__ float lds[256 * 33];
    const float* src = xpw + (size_t)l * DI * 33 + (size_t)c0 * 33;
    for (int i = tid; i < 256 * 33; i += 256) lds[i] = src[i];
    __syncthreads();
    ushort* dst = xpwT + (size_t)l * 128 * DI;
    for (int j = 0; j < 128; ++j) {
        ushort v = (j < 33) ? f2bf(lds[tid * 33 + j]) : (ushort)0;
        dst[(size_t)j * DI + c0 + tid] = v;
    }
}

// ---------------- xssmP [TT][128] -> xssmT [33][TT] ----------------
__global__ __launch_bounds__(256) void tpose33_k(const float* __restrict__ xssmP,
                                                 float* __restrict__ xssmT) {
    int t0 = blockIdx.x * 64, tid = threadIdx.x;
    __shared__ float lds[64 * 129];
    const float* src = xssmP + (size_t)t0 * 128;
    for (int i = tid; i < 64 * 128; i += 256) lds[(i >> 7) * 129 + (i & 127)] = src[i];
    __syncthreads();
    int tk = tid & 63, jq = tid >> 6;
    for (int j = jq; j < 33; j += 4)
        xssmT[(size_t)j * TT + t0 + tk] = lds[tk * 129 + j];
}

// ---------------- layernorm (bf16 out) ----------------
__global__ __launch_bounds__(256) void ln_k(const float* __restrict__ xin,
                                            const float* __restrict__ g,
                                            const float* __restrict__ bt,
                                            ushort* __restrict__ out) {
    int t = blockIdx.x, tid = threadIdx.x;
    const float* xr = xin + (size_t)t * DM;
    __shared__ float red[256];
    float v0 = xr[tid], v1 = xr[tid + 256];
    red[tid] = v0 + v1; __syncthreads();
    for (int st = 128; st > 0; st >>= 1) { if (tid < st) red[tid] += red[tid + st]; __syncthreads(); }
    float mu = red[0] * (1.f / DM); __syncthreads();
    float d0 = v0 - mu, d1 = v1 - mu;
    red[tid] = d0 * d0 + d1 * d1; __syncthreads();
    for (int st = 128; st > 0; st >>= 1) { if (tid < st) red[tid] += red[tid + st]; __syncthreads(); }
    float rs = rsqrtf(red[0] * (1.f / DM) + 1e-5f);
    out[(size_t)t * DM + tid] = f2bf(d0 * rs * g[tid] + bt[tid]);
    out[(size_t)t * DM + tid + 256] = f2bf(d1 * rs * g[tid + 256] + bt[tid + 256]);
}

// ---------------- MFMA bf16 GEMM, global_load_lds staging ----------------
// LDS slot (row*4 + c) holds global chunk (c ^ swz(row)), swz(row)=(row>>1)&3.
// gld: linear dest (wave base + lane*16B), pre-swizzled per-lane global source.
template <bool BF16OUT>
__global__ __launch_bounds__(256) void mgemm_k(const ushort* __restrict__ A, int lda,
                                               const ushort* __restrict__ Bt, int ldb,
                                               const float* __restrict__ bias,
                                               const float* __restrict__ add, int ldadd,
                                               void* __restrict__ Cout, int ldc, int Kdim) {
    __shared__ short8v As[128 * 4];
    __shared__ short8v Bs[128 * 4];
    int tid = threadIdx.x;
    int lane = tid & 63, wid = tid >> 6;
    int row0 = blockIdx.y * 128, col0 = blockIdx.x * 128;
    int wr = (wid >> 1) * 64, wc = (wid & 1) * 64;
    float4v acc[4][4];
#pragma unroll
    for (int i = 0; i < 4; ++i)
#pragma unroll
        for (int j = 0; j < 4; ++j)
#pragma unroll
            for (int r = 0; r < 4; ++r) acc[i][j][r] = 0.f;

    // staging geometry: wave wid covers rows [wid*32, wid*32+32), 2 glds each for A and B
    int rq0 = wid * 32 + (lane >> 2);
    int rq1 = rq0 + 16;
    int clds = lane & 3;
    int cs0 = clds ^ ((rq0 >> 1) & 3);
    int cs1 = clds ^ ((rq1 >> 1) & 3);
    const ushort* aSrc0 = A + (size_t)(row0 + rq0) * lda + cs0 * 8;
    const ushort* aSrc1 = A + (size_t)(row0 + rq1) * lda + cs1 * 8;
    const ushort* bSrc0 = Bt + (size_t)(col0 + rq0) * ldb + cs0 * 8;
    const ushort* bSrc1 = Bt + (size_t)(col0 + rq1) * ldb + cs1 * 8;
    short8v* aDst0 = &As[wid * 128];
    short8v* aDst1 = &As[wid * 128 + 64];
    short8v* bDst0 = &Bs[wid * 128];
    short8v* bDst1 = &Bs[wid * 128 + 64];

    int fr = lane & 15, kg = lane >> 4;
    int sf = kg ^ ((fr >> 1) & 3);

    for (int k0 = 0; k0 < Kdim; k0 += 32) {
        __syncthreads();                 // all waves done reading previous tile
        gld16(aSrc0 + k0, aDst0);
        gld16(aSrc1 + k0, aDst1);
        gld16(bSrc0 + k0, bDst0);
        gld16(bSrc1 + k0, bDst1);
        __syncthreads();                 // vmcnt(0) drain -> LDS writes visible
        short8v af[4], bf[4];
#pragma unroll
        for (int mb = 0; mb < 4; ++mb) af[mb] = As[(wr + mb * 16 + fr) * 4 + sf];
#pragma unroll
        for (int nb = 0; nb < 4; ++nb) bf[nb] = Bs[(wc + nb * 16 + fr) * 4 + sf];
#pragma unroll
        for (int mb = 0; mb < 4; ++mb)
#pragma unroll
            for (int nb = 0; nb < 4; ++nb)
                acc[mb][nb] = __builtin_amdgcn_mfma_f32_16x16x32_bf16(af[mb], bf[nb], acc[mb][nb], 0, 0, 0);
    }
#pragma unroll
    for (int mb = 0; mb < 4; ++mb) {
        int r_ = row0 + wr + mb * 16 + kg * 4;
#pragma unroll
        for (int nb = 0; nb < 4; ++nb) {
            int c_ = col0 + wc + nb * 16 + fr;
            float bz = bias ? bias[c_] : 0.f;
#pragma unroll
            for (int r = 0; r < 4; ++r) {
                float o = acc[mb][nb][r] + bz;
                if (add) o += add[(size_t)(r_ + r) * ldadd + c_];
                if (BF16OUT) ((ushort*)Cout)[(size_t)(r_ + r) * ldc + c_] = f2bf(o);
                else         ((float*)Cout)[(size_t)(r_ + r) * ldc + c_] = o;
            }
        }
    }
}

// ---------------- depthwise causal conv + silu (bf16 in/out) ----------------
__global__ __launch_bounds__(256) void conv_k(const ushort* __restrict__ xz,
                                              const float* __restrict__ cw,
                                              const float* __restrict__ cb,
                                              ushort* __restrict__ xcb) {
    int gid = blockIdx.x * 256 + threadIdx.x;
    int d = gid & (DI - 1);
    int t = gid >> 10;
    int n = t & (N - 1);
    float acc = cb[d];
    const ushort* base = xz + (size_t)t * (2 * DI) + d;
#pragma unroll
    for (int k = 0; k < DC; ++k) {
        int nn = n - (DC - 1) + k;
        if (nn >= 0) acc += bf2f(base[(long)(nn - n) * (2 * DI)]) * cw[d * DC + k];
    }
    float s = 1.f / (1.f + expf(-acc));
    xcb[gid] = f2bf(acc * s);
}

// ---------------- h1 (token scalar -> 256, bf16 out) ----------------
__global__ __launch_bounds__(256) void h1_k(const float* __restrict__ imp,
                                            const float* __restrict__ w1,
                                            const float* __restrict__ b1,
                                            ushort* __restrict__ h1) {
    int t = blockIdx.x, tid = threadIdx.x;
    float v = imp[t] * w1[tid] + b1[tid];
    h1[(size_t)t * DI4 + tid] = f2bf(fmaxf(v, 0.f));
}

// ================= segmented scan ([dim][t] LDS layout, b128 reads) =================
// Phase A: per-segment local scan (h0=0) + transfer product P = prod(a).
__global__ __launch_bounds__(256) void scanA_k(const ushort* __restrict__ modl,
                                               const ushort* __restrict__ xcb,
                                               const float* __restrict__ xssmT,
                                               const float* __restrict__ Alog,
                                               const float* __restrict__ dtw,
                                               const float* __restrict__ dtb,
                                               float* __restrict__ hloc,
                                               float* __restrict__ Pp) {
    int blk = blockIdx.x;
    int seg = blk & 15;
    int dblk = (blk >> 4) & 63;
    int b = blk >> 10;
    int d0 = dblk * 16;
    int tid = threadIdx.x;
    int lane = tid & 63, wave = tid >> 6;
    int s = lane & 15, dd = lane >> 4;
    int dl = wave * 4 + dd, d = d0 + dl;
    float A = -__expf(Alog[d * DS + s]);
    size_t tokbase = (size_t)b * N + (size_t)seg * SLEN;

    __shared__ float sdl[16][68];   // [dl][t] delta
    __shared__ float sxc[16][68];   // [dl][t] xc
    __shared__ float sBv[16][68];   // [s][t]  B

    int lc = tid & 15, lr = tid >> 4;
    float dtwv = dtw[d0 + lc], dtbv = dtb[d0 + lc];
    const ushort* mbase = modl + tokbase * DI + d0 + lc;
    const ushort* xbase = xcb + tokbase * DI + d0 + lc;
    const float* drow = xssmT + tokbase;
    const float* Brow = xssmT + (size_t)(1 + lc) * TT + tokbase;
#pragma unroll
    for (int q = 0; q < 4; ++q) {
        int tok = q * 16 + lr;
        float mo   = bf2f(mbase[(size_t)tok * DI]);
        float draw = drow[tok];
        float xcv  = bf2f(xbase[(size_t)tok * DI]);
        float Bv   = Brow[tok];
        float a = draw * dtwv + dtbv;
        float sp = (a > 20.f) ? a : log1pf(__expf(a));
        float mod = 1.f / (1.f + __expf(-mo));
        sdl[lc][tok] = sp * (1.f + mod);
        sxc[lc][tok] = xcv;
        sBv[lc][tok] = Bv;
    }
    __syncthreads();
    float h = 0.f, P = 1.f;
#pragma unroll
    for (int g = 0; g < 8; ++g) {
        float4 dl4a = *(const float4*)&sdl[dl][g * 8];
        float4 dl4b = *(const float4*)&sdl[dl][g * 8 + 4];
        float4 xc4a = *(const float4*)&sxc[dl][g * 8];
        float4 xc4b = *(const float4*)&sxc[dl][g * 8 + 4];
        float4 B4a  = *(const float4*)&sBv[s][g * 8];
        float4 B4b  = *(const float4*)&sBv[s][g * 8 + 4];
        float dlt[8] = {dl4a.x, dl4a.y, dl4a.z, dl4a.w, dl4b.x, dl4b.y, dl4b.z, dl4b.w};
        float xcv[8] = {xc4a.x, xc4a.y, xc4a.z, xc4a.w, xc4b.x, xc4b.y, xc4b.z, xc4b.w};
        float Bv8[8] = {B4a.x, B4a.y, B4a.z, B4a.w, B4b.x, B4b.y, B4b.z, B4b.w};
        float a8[8], b8[8];
#pragma unroll
        for (int j = 0; j < 8; ++j) {
            a8[j] = __expf(dlt[j] * A);
            b8[j] = (dlt[j] * Bv8[j]) * xcv[j];
        }
#pragma unroll
        for (int j = 0; j < 8; ++j) { h = fmaf(a8[j], h, b8[j]); P *= a8[j]; }
    }
    size_t idx = (size_t)blk * 256 + tid;
    hloc[idx] = h;
    Pp[idx] = P;
}

// Phase B: sequential combine across 16 segments per (b,d,s); writes per-segment h0.
__global__ __launch_bounds__(256) void scanB_k(const float* __restrict__ hloc,
                                               const float* __restrict__ Pp,
                                               float* __restrict__ h0g) {
    int blk = blockIdx.x;
    int tid = threadIdx.x;
    size_t base = (size_t)blk * SEG * 256 + tid;
    float h = 0.f;
    for (int g = 0; g < SEG; ++g) {
        size_t i = base + (size_t)g * 256;
        h0g[i] = h;
        h = fmaf(Pp[i], h, hloc[i]);
    }
}

// Phase C: re-run segment from true h0; deferred sP reduce; b128 LDS reads.
__global__ __launch_bounds__(256) void scanC_k(const ushort* __restrict__ modl,
                                               const ushort* __restrict__ xcb,
                                               const float* __restrict__ xssmT,
                                               const float* __restrict__ Alog,
                                               const float* __restrict__ Dp,
                                               const ushort* __restrict__ xz,
                                               const float* __restrict__ dtw,
                                               const float* __restrict__ dtb,
                                               const float* __restrict__ h0g,
                                               ushort* __restrict__ y) {
    int blk = blockIdx.x;
    int seg = blk & 15;
    int dblk = (blk >> 4) & 63;
    int b = blk >> 10;
    int d0 = dblk * 16;
    int tid = threadIdx.x;
    int lane = tid & 63, wave = tid >> 6;
    int s = lane & 15, dd = lane >> 4;
    int dl = wave * 4 + dd, d = d0 + dl;
    float A = -__expf(Alog[d * DS + s]);
    size_t tokbase = (size_t)b * N + (size_t)seg * SLEN;

    __shared__ float sdl[16][68];   // [dl][t]
    __shared__ float sxc[16][68];   // [dl][t]
    __shared__ float sBv[16][68];   // [s][t]
    __shared__ float sCv[16][68];   // [s][t]
    __shared__ float szv[16][68];   // [dl][t]
    __shared__ float sP[16][16][17];   // [step-in-group][dl][s]

    int lc = tid & 15, lr = tid >> 4;
    float dtwv = dtw[d0 + lc], dtbv = dtb[d0 + lc];
    float dpv_lc = Dp[d0 + lc];
    const ushort* mbase = modl + tokbase * DI + d0 + lc;
    const ushort* xbase = xcb + tokbase * DI + d0 + lc;
    const ushort* zbase = xz + tokbase * (2 * DI) + DI + d0 + lc;
    const float* drow = xssmT + tokbase;
    const float* Brow = xssmT + (size_t)(1 + lc) * TT + tokbase;
    const float* Crow = xssmT + (size_t)(1 + DS + lc) * TT + tokbase;
#pragma unroll
    for (int q = 0; q < 4; ++q) {
        int tok = q * 16 + lr;
        float mo   = bf2f(mbase[(size_t)tok * DI]);
        float draw = drow[tok];
        float xcv  = bf2f(xbase[(size_t)tok * DI]);
        float Bv   = Brow[tok];
        float Cv   = Crow[tok];
        float zv   = bf2f(zbase[(size_t)tok * (2 * DI)]);
        float a = draw * dtwv + dtbv;
        float sp = (a > 20.f) ? a : log1pf(__expf(a));
        float mod = 1.f / (1.f + __expf(-mo));
        sdl[lc][tok] = sp * (1.f + mod);
        sxc[lc][tok] = xcv;
        sBv[lc][tok] = Bv;
        sCv[lc][tok] = Cv;
        szv[lc][tok] = zv;
    }
    __syncthreads();
    float h = h0g[(size_t)blk * 256 + tid];
    for (int g = 0; g < 4; ++g) {              // 16-token groups
#pragma unroll
        for (int half = 0; half < 2; ++half) {
            int t0 = g * 16 + half * 8;
            float4 dl4a = *(const float4*)&sdl[dl][t0];
            float4 dl4b = *(const float4*)&sdl[dl][t0 + 4];
            float4 xc4a = *(const float4*)&sxc[dl][t0];
            float4 xc4b = *(const float4*)&sxc[dl][t0 + 4];
            float4 B4a  = *(const float4*)&sBv[s][t0];
            float4 B4b  = *(const float4*)&sBv[s][t0 + 4];
            float4 C4a  = *(const float4*)&sCv[s][t0];
            float4 C4b  = *(const float4*)&sCv[s][t0 + 4];
            float dlt[8] = {dl4a.x, dl4a.y, dl4a.z, dl4a.w, dl4b.x, dl4b.y, dl4b.z, dl4b.w};
            float xcv[8] = {xc4a.x, xc4a.y, xc4a.z, xc4a.w, xc4b.x, xc4b.y, xc4b.z, xc4b.w};
            float Bv8[8] = {B4a.x, B4a.y, B4a.z, B4a.w, B4b.x, B4b.y, B4b.z, B4b.w};
            float Cv8[8] = {C4a.x, C4a.y, C4a.z, C4a.w, C4b.x, C4b.y, C4b.z, C4b.w};
            float a8[8], b8[8];
#pragma unroll
            for (int j = 0; j < 8; ++j) {
                a8[j] = __expf(dlt[j] * A);
                b8[j] = (dlt[j] * Bv8[j]) * xcv[j];
            }
#pragma unroll
            for (int j = 0; j < 8; ++j) {
                h = fmaf(a8[j], h, b8[j]);
                sP[half * 8 + j][dl][s] = h * Cv8[j];
            }
        }
        __syncthreads();
        {   // parallel s-reduce for these 16 tokens + gate + store
            int t = g * 16 + lr;
            float ssum = 0.f;
#pragma unroll
            for (int s2 = 0; s2 < 16; ++s2) ssum += sP[lr][lc][s2];
            float xcv = sxc[lc][t];
            float zv  = szv[lc][t];
            float sg = 1.f / (1.f + __expf(-zv));
            y[(tokbase + t) * DI + d0 + lc] = f2bf((ssum + xcv * dpv_lc) * (zv * sg));
        }
        __syncthreads();
    }
}

// ---------------- concat [xf | flip(xb)] -> bf16 ----------------
__global__ __launch_bounds__(256) void concat_k(const float* __restrict__ xf,
                                                const float* __restrict__ xb,
                                                ushort* __restrict__ cat) {
    int gid = blockIdx.x * 256 + threadIdx.x;   // TT*DM
    int t = gid >> 9;
    int c = gid & (DM - 1);
    int b = t >> 10, j = t & (N - 1);
    cat[(size_t)t * (2 * DM) + c] = f2bf(xf[gid]);
    cat[(size_t)t * (2 * DM) + DM + c] = f2bf(xb[((size_t)(b << 10) + (N - 1 - j)) * DM + c]);
}

// ---------------- final: scatter by ridx + layernorm ----------------
__global__ __launch_bounds__(256) void final_k(const float* __restrict__ fus,
                                               const int* __restrict__ ridx,
                                               const float* __restrict__ g,
                                               const float* __restrict__ bt,
                                               float* __restrict__ out) {
    int t = blockIdx.x, tid = threadIdx.x;
    int b = t >> 10;
    int r = ridx[t];
    const float* xr = fus + (size_t)t * DM;
    __shared__ float red[256];
    float v0 = xr[tid], v1 = xr[tid + 256];
    red[tid] = v0 + v1; __syncthreads();
    for (int st = 128; st > 0; st >>= 1) { if (tid < st) red[tid] += red[tid + st]; __syncthreads(); }
    float mu = red[0] * (1.f / DM); __syncthreads();
    float d0 = v0 - mu, d1 = v1 - mu;
    red[tid] = d0 * d0 + d1 * d1; __syncthreads();
    for (int st = 128; st > 0; st >>= 1) { if (tid < st) red[tid] += red[tid + st]; __syncthreads(); }
    float rs = rsqrtf(red[0] * (1.f / DM) + 1e-5f);
    float* orow = out + ((size_t)(b << 10) + r) * DM;
    orow[tid] = d0 * rs * g[tid] + bt[tid];
    orow[tid + 256] = d1 * rs * g[tid + 256] + bt[tid + 256];
}

// ---------------- host ----------------
extern "C" void kernel_launch(void* const* d_in, const int* in_sizes, int n_in,
                              void* d_out, int out_size, void* d_ws, size_t ws_size,
                              hipStream_t stream) {
    const float* x            = (const float*)d_in[0];
    const float* centers_init = (const float*)d_in[1];
    const float* in_w         = (const float*)d_in[2];
    const float* conv_w       = (const float*)d_in[3];
    const float* conv_b       = (const float*)d_in[4];
    const float* xp_w         = (const float*)d_in[5];
    const float* dt_w         = (const float*)d_in[6];
    const float* dt_b         = (const float*)d_in[7];
    const float* cm_w1        = (const float*)d_in[8];
    const float* cm_b1        = (const float*)d_in[9];
    const float* cm_w2        = (const float*)d_in[10];
    const float* cm_b2        = (const float*)d_in[11];
    const float* A_log        = (const float*)d_in[12];
    const float* D_p          = (const float*)d_in[13];
    const float* out_w        = (const float*)d_in[14];
    const float* ln_g         = (const float*)d_in[15];
    const float* ln_b         = (const float*)d_in[16];
    const float* fusion_w     = (const float*)d_in[17];
    const float* fusion_b     = (const float*)d_in[18];
    const float* fn_g         = (const float*)d_in[19];
    const float* fn_b         = (const float*)d_in[20];

    float* W = (float*)d_ws;
    size_t off = 0;
    auto alloc = [&](size_t n) { float* p = W + off; off += (n + 15) & ~(size_t)15; return p; };
    auto allocU = [&](size_t n) { ushort* p = (ushort*)(W + off); off += ((n + 1) / 2 + 15) & ~(size_t)15; return p; };
    float* centers = alloc((size_t)Bb * KC * DM);
    float* wgt     = alloc((size_t)TT * KC);
    float* mind    = alloc(TT);
    float* keys    = alloc(TT);
    float* imp     = alloc(TT);
    float* rimp    = alloc(TT);
    float* fimp    = alloc(TT);
    float* denp    = alloc((size_t)Bb * KC * SEGU);
    float* rx      = alloc((size_t)TT * DM);
    float* rxf     = alloc((size_t)TT * DM);
    float* tmp     = alloc((size_t)TT * DM);
    float* fus     = alloc((size_t)TT * DM);       // fusion output f32
    float* xssmT   = alloc((size_t)TT * 33);
    float* hloc    = alloc((size_t)Bb * 64 * SEG * 256);   // also aliased by xssmP
    float* Pp      = alloc((size_t)Bb * 64 * SEG * 256);
    float* h0g     = alloc((size_t)Bb * 64 * SEG * 256);
    ushort* xz     = allocU((size_t)TT * 2 * DI);  // bf16 xz; reused as bf16 cat
    ushort* modl   = allocU((size_t)TT * DI);      // bf16; aliased by kmeans 'part' (f32, smaller)
    ushort* xnb    = allocU((size_t)TT * DM);
    ushort* h1b    = allocU((size_t)TT * DI4);
    ushort* yb     = allocU((size_t)TT * DI);
    ushort* xcb    = allocU((size_t)TT * DI);
    ushort* inwT   = allocU((size_t)L4 * 2 * DI * DM);
    ushort* cmw2T  = allocU((size_t)L4 * DI * DI4);
    ushort* outwT  = allocU((size_t)L4 * DM * DI);
    ushort* fusT   = allocU((size_t)DM * 2 * DM);
    ushort* xpwT   = allocU((size_t)L4 * 128 * DI);
    int* ridx = (int*)(W + off); off += TT;
    float* part = (float*)modl;   // kmeans partials alias modl region (2.6MB < 8MB, disjoint in time)
    float* xssmP = hloc;          // padded xssm GEMM out aliases hloc (disjoint in time)

    // ---- weight transposes (f32 -> bf16 [N][K]) ----
    for (int l = 0; l < L4; ++l) {
        tconv_k<<<dim3(2 * DI / 32, DM / 32), 256, 0, stream>>>(in_w + (size_t)l * DM * 2 * DI, inwT + (size_t)l * 2 * DI * DM, DM, 2 * DI);
        tconv_k<<<dim3(DI / 32, DI4 / 32), 256, 0, stream>>>(cm_w2 + (size_t)l * DI4 * DI, cmw2T + (size_t)l * DI * DI4, DI4, DI);
        tconv_k<<<dim3(DM / 32, DI / 32), 256, 0, stream>>>(out_w + (size_t)l * DI * DM, outwT + (size_t)l * DM * DI, DI, DM);
    }
    tconv_k<<<dim3(DM / 32, 2 * DM / 32), 256, 0, stream>>>(fusion_w, fusT, 2 * DM, DM);
    xpwprep_k<<<L4 * 4, 256, 0, stream>>>(xp_w, xpwT);

    // ---- k-means ----
    initcen_k<<<(Bb * KC * DM) / 256, 256, 0, stream>>>(centers_init, centers);
    for (int it = 0; it < 3; ++it) {
        assign_k<false><<<TT / 4, 256, 0, stream>>>(x, centers, wgt, nullptr, nullptr);
        updp_k<<<Bb * SEGU, 512, 0, stream>>>(x, wgt, part, denp);
        updr_k<<<Bb * KC, 512, 0, stream>>>(part, denp, centers);
    }
    assign_k<true><<<TT / 4, 256, 0, stream>>>(x, centers, wgt, mind, keys);
    importance_k<<<Bb, 1024, 0, stream>>>(mind, imp);
    sort_k<<<Bb, 1024, 0, stream>>>(keys, ridx);
    gather_k<<<TT, 512, 0, stream>>>(x, imp, ridx, rx, rxf, rimp, fimp);

    auto gemmF = [&](const ushort* Ap, int lda, const ushort* Bp, int ldb,
                     const float* bias, const float* add, int ldadd,
                     float* Cp, int ldc, int Kd, int Nn) {
        dim3 g(Nn / 128, TT / 128);
        mgemm_k<false><<<g, 256, 0, stream>>>(Ap, lda, Bp, ldb, bias, add, ldadd, Cp, ldc, Kd);
    };
    auto gemmB = [&](const ushort* Ap, int lda, const ushort* Bp, int ldb,
                     const float* bias,
                     ushort* Cp, int ldc, int Kd, int Nn) {
        dim3 g(Nn / 128, TT / 128);
        mgemm_k<true><<<g, 256, 0, stream>>>(Ap, lda, Bp, ldb, bias, nullptr, 0, Cp, ldc, Kd);
    };

    // ---- 4 mamba layers (2 fwd, 2 bwd on flipped) ----
    const float* lay_in[4]  = {rx, tmp, rxf, tmp};
    float*       lay_out[4] = {tmp, rx, tmp, rxf};
    for (int l = 0; l < L4; ++l) {
        const float* xin = lay_in[l];
        float* xout = lay_out[l];
        const float* impv = (l < 2) ? rimp : fimp;
        ln_k<<<TT, 256, 0, stream>>>(xin, ln_g + (size_t)l * DM, ln_b + (size_t)l * DM, xnb);
        gemmB(xnb, DM, inwT + (size_t)l * 2 * DI * DM, DM, nullptr, xz, 2 * DI, DM, 2 * DI);
        conv_k<<<(TT * DI) / 256, 256, 0, stream>>>(xz, conv_w + (size_t)l * DI * DC, conv_b + (size_t)l * DI, xcb);
        gemmF(xcb, DI, xpwT + (size_t)l * 128 * DI, DI, nullptr, nullptr, 0, xssmP, 128, DI, 128);
        tpose33_k<<<TT / 64, 256, 0, stream>>>(xssmP, xssmT);
        h1_k<<<TT, 256, 0, stream>>>(impv, cm_w1 + (size_t)l * DI4, cm_b1 + (size_t)l * DI4, h1b);
        gemmB(h1b, DI4, cmw2T + (size_t)l * DI * DI4, DI4, cm_b2 + (size_t)l * DI, modl, DI, DI4, DI);
        scanA_k<<<Bb * 64 * SEG, 256, 0, stream>>>(modl, xcb, xssmT, A_log + (size_t)l * DI * DS,
                                                   dt_w + (size_t)l * DI, dt_b + (size_t)l * DI, hloc, Pp);
        scanB_k<<<Bb * 64, 256, 0, stream>>>(hloc, Pp, h0g);
        scanC_k<<<Bb * 64 * SEG, 256, 0, stream>>>(modl, xcb, xssmT, A_log + (size_t)l * DI * DS,
                                                   D_p + (size_t)l * DI, xz,
                                                   dt_w + (size_t)l * DI, dt_b + (size_t)l * DI, h0g, yb);
        gemmF(yb, DI, outwT + (size_t)l * DM * DI, DI, nullptr, xin, DM, xout, DM, DI, DM);
    }

    // ---- fusion + restore + final LN ----
    ushort* catb = xz;
    concat_k<<<(TT * DM) / 256, 256, 0, stream>>>(rx /*xf final*/, rxf /*xb final*/, catb);
    gemmF(catb, 2 * DM, fusT, 2 * DM, fusion_b, nullptr, 0, fus, DM, 2 * DM, DM);
    final_k<<<TT, 256, 0, stream>>>(fus, ridx, fn_g, fn_b, (float*)d_out);
}

// Round 10
// 853.900 us; speedup vs baseline: 4.0136x; 1.0808x over previous
//
#include <hip/hip_runtime.h>
#include <math.h>

// ---------------- constants ----------------
constexpr int DM = 512, DS = 16, DC = 4, DI = 1024, DI4 = 256, KC = 5;
constexpr int Bb = 4, N = 1024, L4 = 4, TT = Bb * N;
constexpr float TEMP = 0.5f;
constexpr int SEG = 16;          // scan segments per sequence
constexpr int SLEN = N / SEG;    // 64 tokens per segment
constexpr int SEGU = 64;         // kmeans-update segments

typedef __attribute__((ext_vector_type(8))) short short8v;
typedef __attribute__((ext_vector_type(4))) float float4v;

__device__ inline ushort f2bf(float f) {
    union { float f; unsigned u; } v; v.f = f;
    unsigned r = v.u + 0x7FFFu + ((v.u >> 16) & 1u);
    return (ushort)(r >> 16);
}
__device__ inline float bf2f(ushort u) {
    union { unsigned u; float f; } v; v.u = ((unsigned)u) << 16;
    return v.f;
}
__device__ inline void gld16(const void* g, void* lds) {
    __builtin_amdgcn_global_load_lds(
        (const __attribute__((address_space(1))) unsigned int*)g,
        (__attribute__((address_space(3))) unsigned int*)lds, 16, 0, 0);
}

// ---------------- k-means assign (wave-per-token, float4) ----------------
template <bool FINAL>
__global__ __launch_bounds__(256) void assign_k(const float* __restrict__ x,
                                                const float* __restrict__ cen0,
                                                int cbstride,
                                                float* __restrict__ wgt,
                                                float* __restrict__ mind,
                                                float* __restrict__ keys) {
    int t = blockIdx.x * 4 + (threadIdx.x >> 6);   // token
    int b = t >> 10;
    int lane = threadIdx.x & 63;
    const float4* xr = (const float4*)(x + (size_t)t * DM);
    float4 xv0 = xr[lane], xv1 = xr[lane + 64];
    const float* cenb = cen0 + (size_t)b * cbstride;
    float d2[KC];
#pragma unroll
    for (int k = 0; k < KC; ++k) {
        const float4* cr = (const float4*)(cenb + k * DM);
        float4 c0 = cr[lane], c1 = cr[lane + 64];
        float dx = xv0.x - c0.x, dy = xv0.y - c0.y, dz = xv0.z - c0.z, dw = xv0.w - c0.w;
        float acc = dx * dx + dy * dy + dz * dz + dw * dw;
        dx = xv1.x - c1.x; dy = xv1.y - c1.y; dz = xv1.z - c1.z; dw = xv1.w - c1.w;
        acc += dx * dx + dy * dy + dz * dz + dw * dw;
        d2[k] = acc;
    }
#pragma unroll
    for (int k = 0; k < KC; ++k)
        for (int off = 32; off > 0; off >>= 1) d2[k] += __shfl_xor(d2[k], off);
    if (lane == 0) {
        float dist[KC], logit[KC], e[KC];
        float lm = -1e30f;
        for (int k = 0; k < KC; ++k) {
            dist[k] = sqrtf(d2[k] + 1e-12f);
            logit[k] = -dist[k] / TEMP;
            lm = fmaxf(lm, logit[k]);
        }
        float s = 0.f;
        for (int k = 0; k < KC; ++k) { e[k] = expf(logit[k] - lm); s += e[k]; }
        float inv = 1.f / s;
        for (int k = 0; k < KC; ++k) wgt[t * KC + k] = e[k] * inv;
        if (FINAL) {
            float md = dist[0];
            for (int k = 1; k < KC; ++k) md = fminf(md, dist[k]);
            int ca = 0; float best = e[0] * inv;
            for (int k = 1; k < KC; ++k) {
                float wv = e[k] * inv;
                if (wv > best) { best = wv; ca = k; }
            }
            mind[t] = md;
            keys[t] = (float)ca * 1000.0f + (1.0f - best);
        }
    }
}

// ---- update: pass1 partials over 16-token segments ----
__global__ __launch_bounds__(512) void updp_k(const float* __restrict__ x,
                                              const float* __restrict__ wgt,
                                              float* __restrict__ part,
                                              float* __restrict__ denp) {
    int blk = blockIdx.x;        // b*SEGU + seg
    int b = blk >> 6, seg = blk & 63;
    int c = threadIdx.x;
    constexpr int TSEG = N / SEGU;   // 16
    __shared__ float sw[TSEG][KC];
    int n0 = seg * TSEG;
    if (c < TSEG * KC) sw[c / KC][c % KC] = wgt[((size_t)(b << 10) + n0 + c / KC) * KC + c % KC];
    __syncthreads();
    const float* xb = x + ((size_t)(b << 10) + n0) * DM + c;
    float acc[KC] = {};
    for (int n = 0; n < TSEG; ++n) {
        float xv = xb[(size_t)n * DM];
#pragma unroll
        for (int k = 0; k < KC; ++k) acc[k] = fmaf(sw[n][k], xv, acc[k]);
    }
#pragma unroll
    for (int k = 0; k < KC; ++k)
        part[(((size_t)b * KC + k) * SEGU + seg) * DM + c] = acc[k];
    if (c < KC) {
        float dn = 0.f;
        for (int n = 0; n < TSEG; ++n) dn += sw[n][c];
        denp[((size_t)b * KC + c) * SEGU + seg] = dn;
    }
}

// ---- update: pass2 reduce ----
__global__ __launch_bounds__(512) void updr_k(const float* __restrict__ part,
                                              const float* __restrict__ denp,
                                              float* __restrict__ centers) {
    int bk = blockIdx.x;         // 0..B*KC-1
    int c = threadIdx.x;
    const float* pb = part + (size_t)bk * SEGU * DM + c;
    float acc = 0.f;
    for (int g = 0; g < SEGU; ++g) acc += pb[(size_t)g * DM];
    __shared__ float sden;
    if (c == 0) {
        float dn = 0.f;
        const float* db = denp + (size_t)bk * SEGU;
        for (int g = 0; g < SEGU; ++g) dn += db[g];
        sden = dn;
    }
    __syncthreads();
    centers[(size_t)bk * DM + c] = acc / (sden + 1e-8f);
}

// ---- merged sort (blocks 0..3) + importance (blocks 4..7) ----
__global__ __launch_bounds__(1024) void sortimp_k(const float* __restrict__ keys,
                                                  const float* __restrict__ mind,
                                                  int* __restrict__ ridx,
                                                  float* __restrict__ imp) {
    __shared__ unsigned long long a[1024];
    int tid = threadIdx.x;
    if (blockIdx.x < 4) {
        int b = blockIdx.x;
        unsigned int kb = __float_as_uint(keys[b * N + tid]);   // keys >= 0
        a[tid] = ((unsigned long long)kb << 32) | (unsigned int)tid;
        __syncthreads();
        for (int k = 2; k <= 1024; k <<= 1) {
            for (int j = k >> 1; j > 0; j >>= 1) {
                int ixj = tid ^ j;
                if (ixj > tid) {
                    unsigned long long x0 = a[tid], x1 = a[ixj];
                    bool up = ((tid & k) == 0);
                    bool sw = up ? (x0 > x1) : (x0 < x1);
                    if (sw) { a[tid] = x1; a[ixj] = x0; }
                }
                __syncthreads();
            }
        }
        ridx[b * N + tid] = (int)(a[tid] & 0xffffffffu);
    } else {
        int b = blockIdx.x - 4;
        float* red = (float*)a;
        float v = -mind[b * N + tid] / TEMP;
        red[tid] = v; __syncthreads();
        for (int s = 512; s > 0; s >>= 1) { if (tid < s) red[tid] = fmaxf(red[tid], red[tid + s]); __syncthreads(); }
        float m = red[0]; __syncthreads();
        float e = expf(v - m);
        red[tid] = e; __syncthreads();
        for (int s = 512; s > 0; s >>= 1) { if (tid < s) red[tid] += red[tid + s]; __syncthreads(); }
        imp[b * N + tid] = e / red[0];
    }
}

__global__ __launch_bounds__(512) void gather_k(const float* __restrict__ x,
                                                const float* __restrict__ imp,
                                                const int* __restrict__ ridx,
                                                float* __restrict__ rx, float* __restrict__ rxf,
                                                float* __restrict__ rimp, float* __restrict__ fimp) {
    int t = blockIdx.x;
    int b = t >> 10, j = t & (N - 1);
    int r = ridx[t];
    int c = threadIdx.x;
    float v = x[((size_t)(b << 10) + r) * DM + c];
    rx[(size_t)t * DM + c] = v;
    rxf[((size_t)(b << 10) + (N - 1 - j)) * DM + c] = v;
    if (c == 0) {
        float iv = imp[(b << 10) + r];
        rimp[t] = iv;
        fimp[(b << 10) + (N - 1 - j)] = iv;
    }
}

// ---------------- merged weight prep ----------------
__device__ inline void tconv_body(const float* __restrict__ src, ushort* __restrict__ dst,
                                  int R, int C, int c0, int r0, float* tile /*32x33*/) {
    int tx = threadIdx.x & 31, ty = threadIdx.x >> 5;
#pragma unroll
    for (int j = 0; j < 4; ++j)
        tile[(ty + j * 8) * 33 + tx] = src[(size_t)(r0 + ty + j * 8) * C + c0 + tx];
    __syncthreads();
#pragma unroll
    for (int j = 0; j < 4; ++j)
        dst[(size_t)(c0 + ty + j * 8) * R + r0 + tx] = f2bf(tile[tx * 33 + ty + j * 8]);
}

__global__ __launch_bounds__(256) void prep_k(const float* __restrict__ in_w,
                                              const float* __restrict__ cm_w2,
                                              const float* __restrict__ out_w,
                                              const float* __restrict__ fusion_w,
                                              const float* __restrict__ xp_w,
                                              ushort* __restrict__ inwT, ushort* __restrict__ cmw2T,
                                              ushort* __restrict__ outwT, ushort* __restrict__ fusT,
                                              ushort* __restrict__ xpwT) {
    __shared__ float lds[256 * 33];
    int bx = blockIdx.x;
    if (bx < 4096) {                       // in_w: 4 layers x (64 x 16)
        int l = bx >> 10, i = bx & 1023;
        tconv_body(in_w + (size_t)l * DM * 2 * DI, inwT + (size_t)l * 2 * DI * DM,
                   DM, 2 * DI, (i & 63) * 32, (i >> 6) * 32, lds);
        return;
    }
    bx -= 4096;
    if (bx < 1024) {                       // cm_w2: 4 x (32 x 8)
        int l = bx >> 8, i = bx & 255;
        tconv_body(cm_w2 + (size_t)l * DI4 * DI, cmw2T + (size_t)l * DI * DI4,
                   DI4, DI, (i & 31) * 32, (i >> 5) * 32, lds);
        return;
    }
    bx -= 1024;
    if (bx < 2048) {                       // out_w: 4 x (16 x 32)
        int l = bx >> 9, i = bx & 511;
        tconv_body(out_w + (size_t)l * DI * DM, outwT + (size_t)l * DM * DI,
                   DI, DM, (i & 15) * 32, (i >> 4) * 32, lds);
        return;
    }
    bx -= 2048;
    if (bx < 512) {                        // fusion: 16 x 32
        tconv_body(fusion_w, fusT, 2 * DM, DM, (bx & 15) * 32, (bx >> 4) * 32, lds);
        return;
    }
    bx -= 512;
    {                                      // xp_w prep: 16 blocks
        int l = bx >> 2, chunk = bx & 3;
        int c0 = chunk * 256, tid = threadIdx.x;
        const float* src = xp_w + (size_t)l * DI * 33 + (size_t)c0 * 33;
        for (int i = tid; i < 256 * 33; i += 256) lds[i] = src[i];
        __syncthreads();
        ushort* dst = xpwT + (size_t)l * 128 * DI;
        for (int j = 0; j < 128; ++j) {
            ushort v = (j < 33) ? f2bf(lds[tid * 33 + j]) : (ushort)0;
            dst[(size_t)j * DI + c0 + tid] = v;
        }
    }
}

// ---------------- xssmP partials [4][TT][128] -> xssmT [33][TT] ----------------
__global__ __launch_bounds__(256) void tpose33_k(const float* __restrict__ xssmP,
                                                 float* __restrict__ xssmT) {
    int t0 = blockIdx.x * 64, tid = threadIdx.x;
    __shared__ float lds[64 * 129];
    const float* src = xssmP + (size_t)t0 * 128;
    const size_t PS = (size_t)TT * 128;
    for (int i = tid; i < 64 * 128; i += 256) {
        float v = src[i] + src[i + PS] + src[i + 2 * PS] + src[i + 3 * PS];
        lds[(i >> 7) * 129 + (i & 127)] = v;
    }
    __syncthreads();
    int tk = tid & 63, jq = tid >> 6;
    for (int j = jq; j < 33; j += 4)
        xssmT[(size_t)j * TT + t0 + tk] = lds[tk * 129 + j];
}

// ---------------- layernorm (bf16 out) ----------------
__global__ __launch_bounds__(256) void ln_k(const float* __restrict__ xin,
                                            const float* __restrict__ g,
                                            const float* __restrict__ bt,
                                            ushort* __restrict__ out) {
    int t = blockIdx.x, tid = threadIdx.x;
    const float* xr = xin + (size_t)t * DM;
    __shared__ float red[256];
    float v0 = xr[tid], v1 = xr[tid + 256];
    red[tid] = v0 + v1; __syncthreads();
    for (int st = 128; st > 0; st >>= 1) { if (tid < st) red[tid] += red[tid + st]; __syncthreads(); }
    float mu = red[0] * (1.f / DM); __syncthreads();
    float d0 = v0 - mu, d1 = v1 - mu;
    red[tid] = d0 * d0 + d1 * d1; __syncthreads();
    for (int st = 128; st > 0; st >>= 1) { if (tid < st) red[tid] += red[tid + st]; __syncthreads(); }
    float rs = rsqrtf(red[0] * (1.f / DM) + 1e-5f);
    out[(size_t)t * DM + tid] = f2bf(d0 * rs * g[tid] + bt[tid]);
    out[(size_t)t * DM + tid + 256] = f2bf(d1 * rs * g[tid + 256] + bt[tid + 256]);
}

// ---------------- MFMA bf16 GEMM, gld16 staging, optional split-K via gridDim.z ----------------
template <bool BF16OUT>
__global__ __launch_bounds__(256) void mgemm_k(const ushort* __restrict__ A, int lda,
                                               const ushort* __restrict__ Bt, int ldb,
                                               const float* __restrict__ bias,
                                               const float* __restrict__ add, int ldadd,
                                               void* __restrict__ Cout, int ldc, int Kdim,
                                               size_t czs) {
    __shared__ short8v As[128 * 4];
    __shared__ short8v Bs[128 * 4];
    int tid = threadIdx.x;
    int lane = tid & 63, wid = tid >> 6;
    int row0 = blockIdx.y * 128, col0 = blockIdx.x * 128;
    int wr = (wid >> 1) * 64, wc = (wid & 1) * 64;
    float4v acc[4][4];
#pragma unroll
    for (int i = 0; i < 4; ++i)
#pragma unroll
        for (int j = 0; j < 4; ++j)
#pragma unroll
            for (int r = 0; r < 4; ++r) acc[i][j][r] = 0.f;

    int rq0 = wid * 32 + (lane >> 2);
    int rq1 = rq0 + 16;
    int clds = lane & 3;
    int cs0 = clds ^ ((rq0 >> 1) & 3);
    int cs1 = clds ^ ((rq1 >> 1) & 3);
    const ushort* aSrc0 = A + (size_t)(row0 + rq0) * lda + cs0 * 8;
    const ushort* aSrc1 = A + (size_t)(row0 + rq1) * lda + cs1 * 8;
    const ushort* bSrc0 = Bt + (size_t)(col0 + rq0) * ldb + cs0 * 8;
    const ushort* bSrc1 = Bt + (size_t)(col0 + rq1) * ldb + cs1 * 8;
    short8v* aDst0 = &As[wid * 128];
    short8v* aDst1 = &As[wid * 128 + 64];
    short8v* bDst0 = &Bs[wid * 128];
    short8v* bDst1 = &Bs[wid * 128 + 64];

    int fr = lane & 15, kg = lane >> 4;
    int sf = kg ^ ((fr >> 1) & 3);

    int kslice = Kdim / (int)gridDim.z;
    int kbeg = (int)blockIdx.z * kslice;
    for (int k0 = kbeg; k0 < kbeg + kslice; k0 += 32) {
        __syncthreads();
        gld16(aSrc0 + k0, aDst0);
        gld16(aSrc1 + k0, aDst1);
        gld16(bSrc0 + k0, bDst0);
        gld16(bSrc1 + k0, bDst1);
        __syncthreads();
        short8v af[4], bf[4];
#pragma unroll
        for (int mb = 0; mb < 4; ++mb) af[mb] = As[(wr + mb * 16 + fr) * 4 + sf];
#pragma unroll
        for (int nb = 0; nb < 4; ++nb) bf[nb] = Bs[(wc + nb * 16 + fr) * 4 + sf];
#pragma unroll
        for (int mb = 0; mb < 4; ++mb)
#pragma unroll
            for (int nb = 0; nb < 4; ++nb)
                acc[mb][nb] = __builtin_amdgcn_mfma_f32_16x16x32_bf16(af[mb], bf[nb], acc[mb][nb], 0, 0, 0);
    }
    ushort* cu = (ushort*)Cout + (size_t)blockIdx.z * czs;
    float* cf = (float*)Cout + (size_t)blockIdx.z * czs;
#pragma unroll
    for (int mb = 0; mb < 4; ++mb) {
        int r_ = row0 + wr + mb * 16 + kg * 4;
#pragma unroll
        for (int nb = 0; nb < 4; ++nb) {
            int c_ = col0 + wc + nb * 16 + fr;
            float bz = bias ? bias[c_] : 0.f;
#pragma unroll
            for (int r = 0; r < 4; ++r) {
                float o = acc[mb][nb][r] + bz;
                if (add) o += add[(size_t)(r_ + r) * ldadd + c_];
                if (BF16OUT) cu[(size_t)(r_ + r) * ldc + c_] = f2bf(o);
                else         cf[(size_t)(r_ + r) * ldc + c_] = o;
            }
        }
    }
}

// ---------------- h1-fused cm_w2 GEMM: A[t][k]=relu(imp[t]*w1[k]+b1[k]) computed in staging ----------------
__global__ __launch_bounds__(256) void mgemmH_k(const float* __restrict__ imp,
                                                const float* __restrict__ w1,
                                                const float* __restrict__ b1,
                                                const ushort* __restrict__ Bt,
                                                const float* __restrict__ bias,
                                                ushort* __restrict__ Cout, int ldc) {
    __shared__ short8v As[128 * 4];
    __shared__ short8v Bs[128 * 4];
    int tid = threadIdx.x;
    int lane = tid & 63, wid = tid >> 6;
    int row0 = blockIdx.y * 128, col0 = blockIdx.x * 128;
    int wr = (wid >> 1) * 64, wc = (wid & 1) * 64;
    float4v acc[4][4];
#pragma unroll
    for (int i = 0; i < 4; ++i)
#pragma unroll
        for (int j = 0; j < 4; ++j)
#pragma unroll
            for (int r = 0; r < 4; ++r) acc[i][j][r] = 0.f;

    int rq0 = wid * 32 + (lane >> 2);
    int rq1 = rq0 + 16;
    int clds = lane & 3;
    int cs0 = clds ^ ((rq0 >> 1) & 3);
    int cs1 = clds ^ ((rq1 >> 1) & 3);
    float imp0 = imp[row0 + rq0];
    float imp1 = imp[row0 + rq1];
    const ushort* bSrc0 = Bt + (size_t)(col0 + rq0) * DI4 + cs0 * 8;
    const ushort* bSrc1 = Bt + (size_t)(col0 + rq1) * DI4 + cs1 * 8;
    short8v* bDst0 = &Bs[wid * 128];
    short8v* bDst1 = &Bs[wid * 128 + 64];

    int fr = lane & 15, kg = lane >> 4;
    int sf = kg ^ ((fr >> 1) & 3);

    for (int k0 = 0; k0 < DI4; k0 += 32) {
        float4 wa0 = *(const float4*)(w1 + k0 + cs0 * 8);
        float4 wa1 = *(const float4*)(w1 + k0 + cs0 * 8 + 4);
        float4 ba0 = *(const float4*)(b1 + k0 + cs0 * 8);
        float4 ba1 = *(const float4*)(b1 + k0 + cs0 * 8 + 4);
        float4 wb0 = *(const float4*)(w1 + k0 + cs1 * 8);
        float4 wb1 = *(const float4*)(w1 + k0 + cs1 * 8 + 4);
        float4 bb0 = *(const float4*)(b1 + k0 + cs1 * 8);
        float4 bb1 = *(const float4*)(b1 + k0 + cs1 * 8 + 4);
        short8v pa, pb;
        pa[0] = (short)f2bf(fmaxf(fmaf(imp0, wa0.x, ba0.x), 0.f));
        pa[1] = (short)f2bf(fmaxf(fmaf(imp0, wa0.y, ba0.y), 0.f));
        pa[2] = (short)f2bf(fmaxf(fmaf(imp0, wa0.z, ba0.z), 0.f));
        pa[3] = (short)f2bf(fmaxf(fmaf(imp0, wa0.w, ba0.w), 0.f));
        pa[4] = (short)f2bf(fmaxf(fmaf(imp0, wa1.x, ba1.x), 0.f));
        pa[5] = (short)f2bf(fmaxf(fmaf(imp0, wa1.y, ba1.y), 0.f));
        pa[6] = (short)f2bf(fmaxf(fmaf(imp0, wa1.z, ba1.z), 0.f));
        pa[7] = (short)f2bf(fmaxf(fmaf(imp0, wa1.w, ba1.w), 0.f));
        pb[0] = (short)f2bf(fmaxf(fmaf(imp1, wb0.x, bb0.x), 0.f));
        pb[1] = (short)f2bf(fmaxf(fmaf(imp1, wb0.y, bb0.y), 0.f));
        pb[2] = (short)f2bf(fmaxf(fmaf(imp1, wb0.z, bb0.z), 0.f));
        pb[3] = (short)f2bf(fmaxf(fmaf(imp1, wb0.w, bb0.w), 0.f));
        pb[4] = (short)f2bf(fmaxf(fmaf(imp1, wb1.x, bb1.x), 0.f));
        pb[5] = (short)f2bf(fmaxf(fmaf(imp1, wb1.y, bb1.y), 0.f));
        pb[6] = (short)f2bf(fmaxf(fmaf(imp1, wb1.z, bb1.z), 0.f));
        pb[7] = (short)f2bf(fmaxf(fmaf(imp1, wb1.w, bb1.w), 0.f));
        __syncthreads();
        As[rq0 * 4 + clds] = pa;
        As[rq1 * 4 + clds] = pb;
        gld16(bSrc0 + k0, bDst0);
        gld16(bSrc1 + k0, bDst1);
        __syncthreads();
        short8v af[4], bf[4];
#pragma unroll
        for (int mb = 0; mb < 4; ++mb) af[mb] = As[(wr + mb * 16 + fr) * 4 + sf];
#pragma unroll
        for (int nb = 0; nb < 4; ++nb) bf[nb] = Bs[(wc + nb * 16 + fr) * 4 + sf];
#pragma unroll
        for (int mb = 0; mb < 4; ++mb)
#pragma unroll
            for (int nb = 0; nb < 4; ++nb)
                acc[mb][nb] = __builtin_amdgcn_mfma_f32_16x16x32_bf16(af[mb], bf[nb], acc[mb][nb], 0, 0, 0);
    }
#pragma unroll
    for (int mb = 0; mb < 4; ++mb) {
        int r_ = row0 + wr + mb * 16 + kg * 4;
#pragma unroll
        for (int nb = 0; nb < 4; ++nb) {
            int c_ = col0 + wc + nb * 16 + fr;
            float bz = bias[c_];
#pragma unroll
            for (int r = 0; r < 4; ++r)
                Cout[(size_t)(r_ + r) * ldc + c_] = f2bf(acc[mb][nb][r] + bz);
        }
    }
}

// ---------------- depthwise causal conv + silu (bf16 in/out) ----------------
__global__ __launch_bounds__(256) void conv_k(const ushort* __restrict__ xz,
                                              const float* __restrict__ cw,
                                              const float* __restrict__ cb,
                                              ushort* __restrict__ xcb) {
    int gid = blockIdx.x * 256 + threadIdx.x;
    int d = gid & (DI - 1);
    int t = gid >> 10;
    int n = t & (N - 1);
    float acc = cb[d];
    const ushort* base = xz + (size_t)t * (2 * DI) + d;
#pragma unroll
    for (int k = 0; k < DC; ++k) {
        int nn = n - (DC - 1) + k;
        if (nn >= 0) acc += bf2f(base[(long)(nn - n) * (2 * DI)]) * cw[d * DC + k];
    }
    float s = 1.f / (1.f + expf(-acc));
    xcb[gid] = f2bf(acc * s);
}

// ================= segmented scan =================
// Phase A: per-segment local scan (h0=0) + transfer product P = prod(a).
__global__ __launch_bounds__(256) void scanA_k(const ushort* __restrict__ modl,
                                               const ushort* __restrict__ xcb,
                                               const float* __restrict__ xssmT,
                                               const float* __restrict__ Alog,
                                               const float* __restrict__ dtw,
                                               const float* __restrict__ dtb,
                                               float* __restrict__ hloc,
                                               float* __restrict__ Pp) {
    int blk = blockIdx.x;
    int seg = blk & 15;
    int dblk = (blk >> 4) & 63;
    int b = blk >> 10;
    int d0 = dblk * 16;
    int tid = threadIdx.x;
    int lane = tid & 63, wave = tid >> 6;
    int s = lane & 15, dd = lane >> 4;
    int dl = wave * 4 + dd, d = d0 + dl;
    float A = -__expf(Alog[d * DS + s]);
    size_t tokbase = (size_t)b * N + (size_t)seg * SLEN;

    __shared__ float sdl[16][68];   // [dl][t] delta
    __shared__ float sxc[16][68];   // [dl][t] xc
    __shared__ float sBv[16][68];   // [s][t]  B

    int lc = tid & 15, lr = tid >> 4;
    float dtwv = dtw[d0 + lc], dtbv = dtb[d0 + lc];
    const ushort* mbase = modl + tokbase * DI + d0 + lc;
    const ushort* xbase = xcb + tokbase * DI + d0 + lc;
    const float* drow = xssmT + tokbase;
    const float* Brow = xssmT + (size_t)(1 + lc) * TT + tokbase;
#pragma unroll
    for (int q = 0; q < 4; ++q) {
        int tok = q * 16 + lr;
        float mo   = bf2f(mbase[(size_t)tok * DI]);
        float draw = drow[tok];
        float xcv  = bf2f(xbase[(size_t)tok * DI]);
        float Bv   = Brow[tok];
        float a = draw * dtwv + dtbv;
        float sp = (a > 20.f) ? a : log1pf(__expf(a));
        float mod = 1.f / (1.f + __expf(-mo));
        sdl[lc][tok] = sp * (1.f + mod);
        sxc[lc][tok] = xcv;
        sBv[lc][tok] = Bv;
    }
    __syncthreads();
    float h = 0.f, P = 1.f;
#pragma unroll
    for (int g = 0; g < 8; ++g) {
        float4 dl4a = *(const float4*)&sdl[dl][g * 8];
        float4 dl4b = *(const float4*)&sdl[dl][g * 8 + 4];
        float4 xc4a = *(const float4*)&sxc[dl][g * 8];
        float4 xc4b = *(const float4*)&sxc[dl][g * 8 + 4];
        float4 B4a  = *(const float4*)&sBv[s][g * 8];
        float4 B4b  = *(const float4*)&sBv[s][g * 8 + 4];
        float dlt[8] = {dl4a.x, dl4a.y, dl4a.z, dl4a.w, dl4b.x, dl4b.y, dl4b.z, dl4b.w};
        float xcv[8] = {xc4a.x, xc4a.y, xc4a.z, xc4a.w, xc4b.x, xc4b.y, xc4b.z, xc4b.w};
        float Bv8[8] = {B4a.x, B4a.y, B4a.z, B4a.w, B4b.x, B4b.y, B4b.z, B4b.w};
        float a8[8], b8[8];
#pragma unroll
        for (int j = 0; j < 8; ++j) {
            a8[j] = __expf(dlt[j] * A);
            b8[j] = (dlt[j] * Bv8[j]) * xcv[j];
        }
#pragma unroll
        for (int j = 0; j < 8; ++j) { h = fmaf(a8[j], h, b8[j]); P *= a8[j]; }
    }
    size_t idx = (size_t)blk * 256 + tid;
    hloc[idx] = h;
    Pp[idx] = P;
}

// Phase C: inline prefix combine (replaces scanB) + re-run segment; deferred sP reduce.
__global__ __launch_bounds__(256) void scanC_k(const ushort* __restrict__ modl,
                                               const ushort* __restrict__ xcb,
                                               const float* __restrict__ xssmT,
                                               const float* __restrict__ Alog,
                                               const float* __restrict__ Dp,
                                               const ushort* __restrict__ xz,
                                               const float* __restrict__ dtw,
                                               const float* __restrict__ dtb,
                                               const float* __restrict__ hloc,
                                               const float* __restrict__ Pp,
                                               ushort* __restrict__ y) {
    int blk = blockIdx.x;
    int seg = blk & 15;
    int dblk = (blk >> 4) & 63;
    int b = blk >> 10;
    int d0 = dblk * 16;
    int tid = threadIdx.x;
    int lane = tid & 63, wave = tid >> 6;
    int s = lane & 15, dd = lane >> 4;
    int dl = wave * 4 + dd, d = d0 + dl;
    float A = -__expf(Alog[d * DS + s]);
    size_t tokbase = (size_t)b * N + (size_t)seg * SLEN;

    __shared__ float sdl[16][68];   // [dl][t]
    __shared__ float sxc[16][68];   // [dl][t]
    __shared__ float sBv[16][68];   // [s][t]
    __shared__ float sCv[16][68];   // [s][t]
    __shared__ float szv[16][68];   // [dl][t]
    __shared__ float sP[16][16][20];   // [step-in-group][dl][s], 20-pad (float4-aligned)

    // ---- prefix combine from hloc/Pp (replaces scanB) ----
    size_t pb = ((size_t)(blk & ~15)) * 256 + tid;
    float hl[15], pw[15];
#pragma unroll
    for (int g2 = 0; g2 < 15; ++g2)
        if (g2 < seg) { hl[g2] = hloc[pb + (size_t)g2 * 256]; pw[g2] = Pp[pb + (size_t)g2 * 256]; }

    int lc = tid & 15, lr = tid >> 4;
    float dtwv = dtw[d0 + lc], dtbv = dtb[d0 + lc];
    float dpv_lc = Dp[d0 + lc];
    const ushort* mbase = modl + tokbase * DI + d0 + lc;
    const ushort* xbase = xcb + tokbase * DI + d0 + lc;
    const ushort* zbase = xz + tokbase * (2 * DI) + DI + d0 + lc;
    const float* drow = xssmT + tokbase;
    const float* Brow = xssmT + (size_t)(1 + lc) * TT + tokbase;
    const float* Crow = xssmT + (size_t)(1 + DS + lc) * TT + tokbase;
#pragma unroll
    for (int q = 0; q < 4; ++q) {
        int tok = q * 16 + lr;
        float mo   = bf2f(mbase[(size_t)tok * DI]);
        float draw = drow[tok];
        float xcv  = bf2f(xbase[(size_t)tok * DI]);
        float Bv   = Brow[tok];
        float Cv   = Crow[tok];
        float zv   = bf2f(zbase[(size_t)tok * (2 * DI)]);
        float a = draw * dtwv + dtbv;
        float sp = (a > 20.f) ? a : log1pf(__expf(a));
        float mod = 1.f / (1.f + __expf(-mo));
        sdl[lc][tok] = sp * (1.f + mod);
        sxc[lc][tok] = xcv;
        sBv[lc][tok] = Bv;
        sCv[lc][tok] = Cv;
        szv[lc][tok] = zv;
    }
    float h = 0.f;
#pragma unroll
    for (int g2 = 0; g2 < 15; ++g2)
        if (g2 < seg) h = fmaf(pw[g2], h, hl[g2]);
    __syncthreads();
    for (int g = 0; g < 4; ++g) {              // 16-token groups
#pragma unroll
        for (int half = 0; half < 2; ++half) {
            int t0 = g * 16 + half * 8;
            float4 dl4a = *(const float4*)&sdl[dl][t0];
            float4 dl4b = *(const float4*)&sdl[dl][t0 + 4];
            float4 xc4a = *(const float4*)&sxc[dl][t0];
            float4 xc4b = *(const float4*)&sxc[dl][t0 + 4];
            float4 B4a  = *(const float4*)&sBv[s][t0];
            float4 B4b  = *(const float4*)&sBv[s][t0 + 4];
            float4 C4a  = *(const float4*)&sCv[s][t0];
            float4 C4b  = *(const float4*)&sCv[s][t0 + 4];
            float dlt[8] = {dl4a.x, dl4a.y, dl4a.z, dl4a.w, dl4b.x, dl4b.y, dl4b.z, dl4b.w};
            float xcv[8] = {xc4a.x, xc4a.y, xc4a.z, xc4a.w, xc4b.x, xc4b.y, xc4b.z, xc4b.w};
            float Bv8[8] = {B4a.x, B4a.y, B4a.z, B4a.w, B4b.x, B4b.y, B4b.z, B4b.w};
            float Cv8[8] = {C4a.x, C4a.y, C4a.z, C4a.w, C4b.x, C4b.y, C4b.z, C4b.w};
            float a8[8], b8[8];
#pragma unroll
            for (int j = 0; j < 8; ++j) {
                a8[j] = __expf(dlt[j] * A);
                b8[j] = (dlt[j] * Bv8[j]) * xcv[j];
            }
#pragma unroll
            for (int j = 0; j < 8; ++j) {
                h = fmaf(a8[j], h, b8[j]);
                sP[half * 8 + j][dl][s] = h * Cv8[j];
            }
        }
        __syncthreads();
        {   // parallel s-reduce (float4) + gate + store
            int t = g * 16 + lr;
            const float4* pr = (const float4*)&sP[lr][lc][0];
            float4 p0 = pr[0], p1 = pr[1], p2 = pr[2], p3 = pr[3];
            float ssum = ((p0.x + p0.y) + (p0.z + p0.w)) + ((p1.x + p1.y) + (p1.z + p1.w))
                       + ((p2.x + p2.y) + (p2.z + p2.w)) + ((p3.x + p3.y) + (p3.z + p3.w));
            float xcv = sxc[lc][t];
            float zv  = szv[lc][t];
            float sg = 1.f / (1.f + __expf(-zv));
            y[(tokbase + t) * DI + d0 + lc] = f2bf((ssum + xcv * dpv_lc) * (zv * sg));
        }
        __syncthreads();
    }
}

// ---------------- concat [xf | flip(xb)] -> bf16 ----------------
__global__ __launch_bounds__(256) void concat_k(const float* __restrict__ xf,
                                                const float* __restrict__ xb,
                                                ushort* __restrict__ cat) {
    int gid = blockIdx.x * 256 + threadIdx.x;   // TT*DM
    int t = gid >> 9;
    int c = gid & (DM - 1);
    int b = t >> 10, j = t & (N - 1);
    cat[(size_t)t * (2 * DM) + c] = f2bf(xf[gid]);
    cat[(size_t)t * (2 * DM) + DM + c] = f2bf(xb[((size_t)(b << 10) + (N - 1 - j)) * DM + c]);
}

// ---------------- final: scatter by ridx + layernorm ----------------
__global__ __launch_bounds__(256) void final_k(const float* __restrict__ fus,
                                               const int* __restrict__ ridx,
                                               const float* __restrict__ g,
                                               const float* __restrict__ bt,
                                               float* __restrict__ out) {
    int t = blockIdx.x, tid = threadIdx.x;
    int b = t >> 10;
    int r = ridx[t];
    const float* xr = fus + (size_t)t * DM;
    __shared__ float red[256];
    float v0 = xr[tid], v1 = xr[tid + 256];
    red[tid] = v0 + v1; __syncthreads();
    for (int st = 128; st > 0; st >>= 1) { if (tid < st) red[tid] += red[tid + st]; __syncthreads(); }
    float mu = red[0] * (1.f / DM); __syncthreads();
    float d0 = v0 - mu, d1 = v1 - mu;
    red[tid] = d0 * d0 + d1 * d1; __syncthreads();
    for (int st = 128; st > 0; st >>= 1) { if (tid < st) red[tid] += red[tid + st]; __syncthreads(); }
    float rs = rsqrtf(red[0] * (1.f / DM) + 1e-5f);
    float* orow = out + ((size_t)(b << 10) + r) * DM;
    orow[tid] = d0 * rs * g[tid] + bt[tid];
    orow[tid + 256] = d1 * rs * g[tid + 256] + bt[tid + 256];
}

// ---------------- host ----------------
extern "C" void kernel_launch(void* const* d_in, const int* in_sizes, int n_in,
                              void* d_out, int out_size, void* d_ws, size_t ws_size,
                              hipStream_t stream) {
    const float* x            = (const float*)d_in[0];
    const float* centers_init = (const float*)d_in[1];
    const float* in_w         = (const float*)d_in[2];
    const float* conv_w       = (const float*)d_in[3];
    const float* conv_b       = (const float*)d_in[4];
    const float* xp_w         = (const float*)d_in[5];
    const float* dt_w         = (const float*)d_in[6];
    const float* dt_b         = (const float*)d_in[7];
    const float* cm_w1        = (const float*)d_in[8];
    const float* cm_b1        = (const float*)d_in[9];
    const float* cm_w2        = (const float*)d_in[10];
    const float* cm_b2        = (const float*)d_in[11];
    const float* A_log        = (const float*)d_in[12];
    const float* D_p          = (const float*)d_in[13];
    const float* out_w        = (const float*)d_in[14];
    const float* ln_g         = (const float*)d_in[15];
    const float* ln_b         = (const float*)d_in[16];
    const float* fusion_w     = (const float*)d_in[17];
    const float* fusion_b     = (const float*)d_in[18];
    const float* fn_g         = (const float*)d_in[19];
    const float* fn_b         = (const float*)d_in[20];

    float* W = (float*)d_ws;
    size_t off = 0;
    auto alloc = [&](size_t n) { float* p = W + off; off += (n + 15) & ~(size_t)15; return p; };
    auto allocU = [&](size_t n) { ushort* p = (ushort*)(W + off); off += ((n + 1) / 2 + 15) & ~(size_t)15; return p; };
    float* centers = alloc((size_t)Bb * KC * DM);
    float* wgt     = alloc((size_t)TT * KC);
    float* mind    = alloc(TT);
    float* keys    = alloc(TT);
    float* imp     = alloc(TT);
    float* rimp    = alloc(TT);
    float* fimp    = alloc(TT);
    float* denp    = alloc((size_t)Bb * KC * SEGU);
    float* rx      = alloc((size_t)TT * DM);
    float* rxf     = alloc((size_t)TT * DM);
    float* tmp     = alloc((size_t)TT * DM);
    float* fus     = alloc((size_t)TT * DM);       // fusion output f32
    float* xssmT   = alloc((size_t)TT * 33);
    float* hloc    = alloc((size_t)Bb * 64 * SEG * 256);   // hloc+Pp contiguous: aliased by xssmP (4 partials, 8MB)
    float* Pp      = alloc((size_t)Bb * 64 * SEG * 256);
    ushort* xz     = allocU((size_t)TT * 2 * DI);  // bf16 xz; reused as bf16 cat
    ushort* modl   = allocU((size_t)TT * DI);      // bf16; aliased by kmeans 'part' (f32, smaller)
    ushort* xnb    = allocU((size_t)TT * DM);
    ushort* yb     = allocU((size_t)TT * DI);
    ushort* xcb    = allocU((size_t)TT * DI);
    ushort* inwT   = allocU((size_t)L4 * 2 * DI * DM);
    ushort* cmw2T  = allocU((size_t)L4 * DI * DI4);
    ushort* outwT  = allocU((size_t)L4 * DM * DI);
    ushort* fusT   = allocU((size_t)DM * 2 * DM);
    ushort* xpwT   = allocU((size_t)L4 * 128 * DI);
    int* ridx = (int*)(W + off); off += TT;
    float* part = (float*)modl;   // kmeans partials alias modl region (2.6MB < 8MB, disjoint in time)
    float* xssmP = hloc;          // 4 split-K partials (8MB) alias hloc+Pp (8.4MB), disjoint in time

    // ---- merged weight prep: 4096 + 1024 + 2048 + 512 + 16 = 7696 blocks ----
    prep_k<<<7696, 256, 0, stream>>>(in_w, cm_w2, out_w, fusion_w, xp_w,
                                     inwT, cmw2T, outwT, fusT, xpwT);

    // ---- k-means ----
    for (int it = 0; it < 3; ++it) {
        if (it == 0) assign_k<false><<<TT / 4, 256, 0, stream>>>(x, centers_init, 0, wgt, nullptr, nullptr);
        else         assign_k<false><<<TT / 4, 256, 0, stream>>>(x, centers, KC * DM, wgt, nullptr, nullptr);
        updp_k<<<Bb * SEGU, 512, 0, stream>>>(x, wgt, part, denp);
        updr_k<<<Bb * KC, 512, 0, stream>>>(part, denp, centers);
    }
    assign_k<true><<<TT / 4, 256, 0, stream>>>(x, centers, KC * DM, wgt, mind, keys);
    sortimp_k<<<8, 1024, 0, stream>>>(keys, mind, ridx, imp);
    gather_k<<<TT, 512, 0, stream>>>(x, imp, ridx, rx, rxf, rimp, fimp);

    auto gemmF = [&](const ushort* Ap, int lda, const ushort* Bp, int ldb,
                     const float* bias, const float* add, int ldadd,
                     float* Cp, int ldc, int Kd, int Nn) {
        dim3 g(Nn / 128, TT / 128, 1);
        mgemm_k<false><<<g, 256, 0, stream>>>(Ap, lda, Bp, ldb, bias, add, ldadd, Cp, ldc, Kd, 0);
    };
    auto gemmB = [&](const ushort* Ap, int lda, const ushort* Bp, int ldb,
                     const float* bias,
                     ushort* Cp, int ldc, int Kd, int Nn) {
        dim3 g(Nn / 128, TT / 128, 1);
        mgemm_k<true><<<g, 256, 0, stream>>>(Ap, lda, Bp, ldb, bias, nullptr, 0, Cp, ldc, Kd, 0);
    };

    // ---- 4 mamba layers (2 fwd, 2 bwd on flipped) ----
    const float* lay_in[4]  = {rx, tmp, rxf, tmp};
    float*       lay_out[4] = {tmp, rx, tmp, rxf};
    for (int l = 0; l < L4; ++l) {
        const float* xin = lay_in[l];
        float* xout = lay_out[l];
        const float* impv = (l < 2) ? rimp : fimp;
        ln_k<<<TT, 256, 0, stream>>>(xin, ln_g + (size_t)l * DM, ln_b + (size_t)l * DM, xnb);
        gemmB(xnb, DM, inwT + (size_t)l * 2 * DI * DM, DM, nullptr, xz, 2 * DI, DM, 2 * DI);
        conv_k<<<(TT * DI) / 256, 256, 0, stream>>>(xz, conv_w + (size_t)l * DI * DC, conv_b + (size_t)l * DI, xcb);
        {   // xssm GEMM, split-K = 4 (32 -> 128 blocks)
            dim3 g(1, TT / 128, 4);
            mgemm_k<false><<<g, 256, 0, stream>>>(xcb, DI, xpwT + (size_t)l * 128 * DI, DI,
                                                  nullptr, nullptr, 0, xssmP, 128, DI, (size_t)TT * 128);
        }
        tpose33_k<<<TT / 64, 256, 0, stream>>>(xssmP, xssmT);
        mgemmH_k<<<dim3(DI / 128, TT / 128), 256, 0, stream>>>(impv, cm_w1 + (size_t)l * DI4,
                                                               cm_b1 + (size_t)l * DI4,
                                                               cmw2T + (size_t)l * DI * DI4,
                                                               cm_b2 + (size_t)l * DI, modl, DI);
        scanA_k<<<Bb * 64 * SEG, 256, 0, stream>>>(modl, xcb, xssmT, A_log + (size_t)l * DI * DS,
                                                   dt_w + (size_t)l * DI, dt_b + (size_t)l * DI, hloc, Pp);
        scanC_k<<<Bb * 64 * SEG, 256, 0, stream>>>(modl, xcb, xssmT, A_log + (size_t)l * DI * DS,
                                                   D_p + (size_t)l * DI, xz,
                                                   dt_w + (size_t)l * DI, dt_b + (size_t)l * DI,
                                                   hloc, Pp, yb);
        gemmF(yb, DI, outwT + (size_t)l * DM * DI, DI, nullptr, xin, DM, xout, DM, DI, DM);
    }

    // ---- fusion + restore + final LN ----
    ushort* catb = xz;
    concat_k<<<(TT * DM) / 256, 256, 0, stream>>>(rx /*xf final*/, rxf /*xb final*/, catb);
    gemmF(catb, 2 * DM, fusT, 2 * DM, fusion_b, nullptr, 0, fus, DM, 2 * DM, DM);
    final_k<<<TT, 256, 0, stream>>>(fus, ridx, fn_g, fn_b, (float*)d_out);
}

// Round 11
// 823.181 us; speedup vs baseline: 4.1633x; 1.0373x over previous
//
#include <hip/hip_runtime.h>
#include <math.h>

// ---------------- constants ----------------
constexpr int DM = 512, DS = 16, DC = 4, DI = 1024, DI4 = 256, KC = 5;
constexpr int Bb = 4, N = 1024, L4 = 4, TT = Bb * N;
constexpr float TEMP = 0.5f;
constexpr int SEG = 16;          // scan segments per sequence
constexpr int SLEN = N / SEG;    // 64 tokens per segment
constexpr int SEGU = 64;         // kmeans-update segments

typedef __attribute__((ext_vector_type(8))) short short8v;
typedef __attribute__((ext_vector_type(4))) float float4v;

__device__ inline ushort f2bf(float f) {
    union { float f; unsigned u; } v; v.f = f;
    unsigned r = v.u + 0x7FFFu + ((v.u >> 16) & 1u);
    return (ushort)(r >> 16);
}
__device__ inline float bf2f(ushort u) {
    union { unsigned u; float f; } v; v.u = ((unsigned)u) << 16;
    return v.f;
}
__device__ inline void gld16(const void* g, void* lds) {
    __builtin_amdgcn_global_load_lds(
        (const __attribute__((address_space(1))) unsigned int*)g,
        (__attribute__((address_space(3))) unsigned int*)lds, 16, 0, 0);
}

// ---------------- k-means assign (wave-per-token, float4) ----------------
template <bool FINAL>
__global__ __launch_bounds__(256) void assign_k(const float* __restrict__ x,
                                                const float* __restrict__ cen0,
                                                int cbstride,
                                                float* __restrict__ wgt,
                                                float* __restrict__ mind,
                                                float* __restrict__ keys) {
    int t = blockIdx.x * 4 + (threadIdx.x >> 6);   // token
    int b = t >> 10;
    int lane = threadIdx.x & 63;
    const float4* xr = (const float4*)(x + (size_t)t * DM);
    float4 xv0 = xr[lane], xv1 = xr[lane + 64];
    const float* cenb = cen0 + (size_t)b * cbstride;
    float d2[KC];
#pragma unroll
    for (int k = 0; k < KC; ++k) {
        const float4* cr = (const float4*)(cenb + k * DM);
        float4 c0 = cr[lane], c1 = cr[lane + 64];
        float dx = xv0.x - c0.x, dy = xv0.y - c0.y, dz = xv0.z - c0.z, dw = xv0.w - c0.w;
        float acc = dx * dx + dy * dy + dz * dz + dw * dw;
        dx = xv1.x - c1.x; dy = xv1.y - c1.y; dz = xv1.z - c1.z; dw = xv1.w - c1.w;
        acc += dx * dx + dy * dy + dz * dz + dw * dw;
        d2[k] = acc;
    }
#pragma unroll
    for (int k = 0; k < KC; ++k)
        for (int off = 32; off > 0; off >>= 1) d2[k] += __shfl_xor(d2[k], off);
    if (lane == 0) {
        float dist[KC], logit[KC], e[KC];
        float lm = -1e30f;
        for (int k = 0; k < KC; ++k) {
            dist[k] = sqrtf(d2[k] + 1e-12f);
            logit[k] = -dist[k] / TEMP;
            lm = fmaxf(lm, logit[k]);
        }
        float s = 0.f;
        for (int k = 0; k < KC; ++k) { e[k] = expf(logit[k] - lm); s += e[k]; }
        float inv = 1.f / s;
        for (int k = 0; k < KC; ++k) wgt[t * KC + k] = e[k] * inv;
        if (FINAL) {
            float md = dist[0];
            for (int k = 1; k < KC; ++k) md = fminf(md, dist[k]);
            int ca = 0; float best = e[0] * inv;
            for (int k = 1; k < KC; ++k) {
                float wv = e[k] * inv;
                if (wv > best) { best = wv; ca = k; }
            }
            mind[t] = md;
            keys[t] = (float)ca * 1000.0f + (1.0f - best);
        }
    }
}

// ---- update: pass1 partials over 16-token segments ----
__global__ __launch_bounds__(512) void updp_k(const float* __restrict__ x,
                                              const float* __restrict__ wgt,
                                              float* __restrict__ part,
                                              float* __restrict__ denp) {
    int blk = blockIdx.x;        // b*SEGU + seg
    int b = blk >> 6, seg = blk & 63;
    int c = threadIdx.x;
    constexpr int TSEG = N / SEGU;   // 16
    __shared__ float sw[TSEG][KC];
    int n0 = seg * TSEG;
    if (c < TSEG * KC) sw[c / KC][c % KC] = wgt[((size_t)(b << 10) + n0 + c / KC) * KC + c % KC];
    __syncthreads();
    const float* xb = x + ((size_t)(b << 10) + n0) * DM + c;
    float acc[KC] = {};
    for (int n = 0; n < TSEG; ++n) {
        float xv = xb[(size_t)n * DM];
#pragma unroll
        for (int k = 0; k < KC; ++k) acc[k] = fmaf(sw[n][k], xv, acc[k]);
    }
#pragma unroll
    for (int k = 0; k < KC; ++k)
        part[(((size_t)b * KC + k) * SEGU + seg) * DM + c] = acc[k];
    if (c < KC) {
        float dn = 0.f;
        for (int n = 0; n < TSEG; ++n) dn += sw[n][c];
        denp[((size_t)b * KC + c) * SEGU + seg] = dn;
    }
}

// ---- update: pass2 reduce ----
__global__ __launch_bounds__(512) void updr_k(const float* __restrict__ part,
                                              const float* __restrict__ denp,
                                              float* __restrict__ centers) {
    int bk = blockIdx.x;         // 0..B*KC-1
    int c = threadIdx.x;
    const float* pb = part + (size_t)bk * SEGU * DM + c;
    float acc = 0.f;
    for (int g = 0; g < SEGU; ++g) acc += pb[(size_t)g * DM];
    __shared__ float sden;
    if (c == 0) {
        float dn = 0.f;
        const float* db = denp + (size_t)bk * SEGU;
        for (int g = 0; g < SEGU; ++g) dn += db[g];
        sden = dn;
    }
    __syncthreads();
    centers[(size_t)bk * DM + c] = acc / (sden + 1e-8f);
}

// ---- merged sort (blocks 0..3) + importance (blocks 4..7) ----
__global__ __launch_bounds__(1024) void sortimp_k(const float* __restrict__ keys,
                                                  const float* __restrict__ mind,
                                                  int* __restrict__ ridx,
                                                  float* __restrict__ imp) {
    __shared__ unsigned long long a[1024];
    int tid = threadIdx.x;
    if (blockIdx.x < 4) {
        int b = blockIdx.x;
        unsigned int kb = __float_as_uint(keys[b * N + tid]);   // keys >= 0
        a[tid] = ((unsigned long long)kb << 32) | (unsigned int)tid;
        __syncthreads();
        for (int k = 2; k <= 1024; k <<= 1) {
            for (int j = k >> 1; j > 0; j >>= 1) {
                int ixj = tid ^ j;
                if (ixj > tid) {
                    unsigned long long x0 = a[tid], x1 = a[ixj];
                    bool up = ((tid & k) == 0);
                    bool sw = up ? (x0 > x1) : (x0 < x1);
                    if (sw) { a[tid] = x1; a[ixj] = x0; }
                }
                __syncthreads();
            }
        }
        ridx[b * N + tid] = (int)(a[tid] & 0xffffffffu);
    } else {
        int b = blockIdx.x - 4;
        float* red = (float*)a;
        float v = -mind[b * N + tid] / TEMP;
        red[tid] = v; __syncthreads();
        for (int s = 512; s > 0; s >>= 1) { if (tid < s) red[tid] = fmaxf(red[tid], red[tid + s]); __syncthreads(); }
        float m = red[0]; __syncthreads();
        float e = expf(v - m);
        red[tid] = e; __syncthreads();
        for (int s = 512; s > 0; s >>= 1) { if (tid < s) red[tid] += red[tid + s]; __syncthreads(); }
        imp[b * N + tid] = e / red[0];
    }
}

__global__ __launch_bounds__(512) void gather_k(const float* __restrict__ x,
                                                const float* __restrict__ imp,
                                                const int* __restrict__ ridx,
                                                float* __restrict__ rx, float* __restrict__ rxf,
                                                float* __restrict__ rimp, float* __restrict__ fimp) {
    int t = blockIdx.x;
    int b = t >> 10, j = t & (N - 1);
    int r = ridx[t];
    int c = threadIdx.x;
    float v = x[((size_t)(b << 10) + r) * DM + c];
    rx[(size_t)t * DM + c] = v;
    rxf[((size_t)(b << 10) + (N - 1 - j)) * DM + c] = v;
    if (c == 0) {
        float iv = imp[(b << 10) + r];
        rimp[t] = iv;
        fimp[(b << 10) + (N - 1 - j)] = iv;
    }
}

// ---------------- merged weight prep ----------------
__device__ inline void tconv_body(const float* __restrict__ src, ushort* __restrict__ dst,
                                  int R, int C, int c0, int r0, float* tile /*32x33*/) {
    int tx = threadIdx.x & 31, ty = threadIdx.x >> 5;
#pragma unroll
    for (int j = 0; j < 4; ++j)
        tile[(ty + j * 8) * 33 + tx] = src[(size_t)(r0 + ty + j * 8) * C + c0 + tx];
    __syncthreads();
#pragma unroll
    for (int j = 0; j < 4; ++j)
        dst[(size_t)(c0 + ty + j * 8) * R + r0 + tx] = f2bf(tile[tx * 33 + ty + j * 8]);
}

__global__ __launch_bounds__(256) void prep_k(const float* __restrict__ in_w,
                                              const float* __restrict__ cm_w2,
                                              const float* __restrict__ out_w,
                                              const float* __restrict__ fusion_w,
                                              const float* __restrict__ xp_w,
                                              ushort* __restrict__ inwT, ushort* __restrict__ cmw2T,
                                              ushort* __restrict__ outwT, ushort* __restrict__ fusT,
                                              ushort* __restrict__ xpwT) {
    __shared__ float lds[256 * 33];
    int bx = blockIdx.x;
    if (bx < 4096) {                       // in_w: 4 layers x (64 x 16)
        int l = bx >> 10, i = bx & 1023;
        tconv_body(in_w + (size_t)l * DM * 2 * DI, inwT + (size_t)l * 2 * DI * DM,
                   DM, 2 * DI, (i & 63) * 32, (i >> 6) * 32, lds);
        return;
    }
    bx -= 4096;
    if (bx < 1024) {                       // cm_w2: 4 x (32 x 8)
        int l = bx >> 8, i = bx & 255;
        tconv_body(cm_w2 + (size_t)l * DI4 * DI, cmw2T + (size_t)l * DI * DI4,
                   DI4, DI, (i & 31) * 32, (i >> 5) * 32, lds);
        return;
    }
    bx -= 1024;
    if (bx < 2048) {                       // out_w: 4 x (16 x 32)
        int l = bx >> 9, i = bx & 511;
        tconv_body(out_w + (size_t)l * DI * DM, outwT + (size_t)l * DM * DI,
                   DI, DM, (i & 15) * 32, (i >> 4) * 32, lds);
        return;
    }
    bx -= 2048;
    if (bx < 512) {                        // fusion: 16 x 32
        tconv_body(fusion_w, fusT, 2 * DM, DM, (bx & 15) * 32, (bx >> 4) * 32, lds);
        return;
    }
    bx -= 512;
    {                                      // xp_w prep: 16 blocks
        int l = bx >> 2, chunk = bx & 3;
        int c0 = chunk * 256, tid = threadIdx.x;
        const float* src = xp_w + (size_t)l * DI * 33 + (size_t)c0 * 33;
        for (int i = tid; i < 256 * 33; i += 256) lds[i] = src[i];
        __syncthreads();
        ushort* dst = xpwT + (size_t)l * 128 * DI;
        for (int j = 0; j < 128; ++j) {
            ushort v = (j < 33) ? f2bf(lds[tid * 33 + j]) : (ushort)0;
            dst[(size_t)j * DI + c0 + tid] = v;
        }
    }
}

// ---------------- xssmP partials [4][TT][128] -> xssmT [33][TT] ----------------
__global__ __launch_bounds__(256) void tpose33_k(const float* __restrict__ xssmP,
                                                 float* __restrict__ xssmT) {
    int t0 = blockIdx.x * 64, tid = threadIdx.x;
    __shared__ float lds[64 * 129];
    const float* src = xssmP + (size_t)t0 * 128;
    const size_t PS = (size_t)TT * 128;
    for (int i = tid; i < 64 * 128; i += 256) {
        float v = src[i] + src[i + PS] + src[i + 2 * PS] + src[i + 3 * PS];
        lds[(i >> 7) * 129 + (i & 127)] = v;
    }
    __syncthreads();
    int tk = tid & 63, jq = tid >> 6;
    for (int j = jq; j < 33; j += 4)
        xssmT[(size_t)j * TT + t0 + tk] = lds[tk * 129 + j];
}

// ---------------- layernorm: wave-per-token, shfl-only, packed bf16 stores ----------------
__global__ __launch_bounds__(256) void ln_k(const float* __restrict__ xin,
                                            const float* __restrict__ g,
                                            const float* __restrict__ bt,
                                            ushort* __restrict__ out) {
    int t = blockIdx.x * 4 + (threadIdx.x >> 6);
    int lane = threadIdx.x & 63;
    const float4* xr = (const float4*)(xin + (size_t)t * DM);
    float4 v0 = xr[lane * 2], v1 = xr[lane * 2 + 1];   // 8 contiguous floats
    float s = ((v0.x + v0.y) + (v0.z + v0.w)) + ((v1.x + v1.y) + (v1.z + v1.w));
#pragma unroll
    for (int off = 32; off > 0; off >>= 1) s += __shfl_xor(s, off);
    float mu = s * (1.f / DM);
    float d0 = v0.x - mu, d1 = v0.y - mu, d2 = v0.z - mu, d3 = v0.w - mu;
    float d4 = v1.x - mu, d5 = v1.y - mu, d6 = v1.z - mu, d7 = v1.w - mu;
    float q = ((d0 * d0 + d1 * d1) + (d2 * d2 + d3 * d3)) + ((d4 * d4 + d5 * d5) + (d6 * d6 + d7 * d7));
#pragma unroll
    for (int off = 32; off > 0; off >>= 1) q += __shfl_xor(q, off);
    float rs = rsqrtf(q * (1.f / DM) + 1e-5f);
    const float4* gr = (const float4*)g;
    const float4* br = (const float4*)bt;
    float4 g0 = gr[lane * 2], g1 = gr[lane * 2 + 1];
    float4 b0 = br[lane * 2], b1 = br[lane * 2 + 1];
    uint4 pk;
    pk.x = (unsigned)f2bf(d0 * rs * g0.x + b0.x) | ((unsigned)f2bf(d1 * rs * g0.y + b0.y) << 16);
    pk.y = (unsigned)f2bf(d2 * rs * g0.z + b0.z) | ((unsigned)f2bf(d3 * rs * g0.w + b0.w) << 16);
    pk.z = (unsigned)f2bf(d4 * rs * g1.x + b1.x) | ((unsigned)f2bf(d5 * rs * g1.y + b1.y) << 16);
    pk.w = (unsigned)f2bf(d6 * rs * g1.z + b1.z) | ((unsigned)f2bf(d7 * rs * g1.w + b1.w) << 16);
    *(uint4*)(out + (size_t)t * DM + lane * 8) = pk;
}

// ---------------- MFMA bf16 GEMM, gld16 staging, optional split-K via gridDim.z ----------------
template <bool BF16OUT>
__global__ __launch_bounds__(256) void mgemm_k(const ushort* __restrict__ A, int lda,
                                               const ushort* __restrict__ Bt, int ldb,
                                               const float* __restrict__ bias,
                                               const float* __restrict__ add, int ldadd,
                                               void* __restrict__ Cout, int ldc, int Kdim,
                                               size_t czs) {
    __shared__ short8v As[128 * 4];
    __shared__ short8v Bs[128 * 4];
    int tid = threadIdx.x;
    int lane = tid & 63, wid = tid >> 6;
    int row0 = blockIdx.y * 128, col0 = blockIdx.x * 128;
    int wr = (wid >> 1) * 64, wc = (wid & 1) * 64;
    float4v acc[4][4];
#pragma unroll
    for (int i = 0; i < 4; ++i)
#pragma unroll
        for (int j = 0; j < 4; ++j)
#pragma unroll
            for (int r = 0; r < 4; ++r) acc[i][j][r] = 0.f;

    int rq0 = wid * 32 + (lane >> 2);
    int rq1 = rq0 + 16;
    int clds = lane & 3;
    int cs0 = clds ^ ((rq0 >> 1) & 3);
    int cs1 = clds ^ ((rq1 >> 1) & 3);
    const ushort* aSrc0 = A + (size_t)(row0 + rq0) * lda + cs0 * 8;
    const ushort* aSrc1 = A + (size_t)(row0 + rq1) * lda + cs1 * 8;
    const ushort* bSrc0 = Bt + (size_t)(col0 + rq0) * ldb + cs0 * 8;
    const ushort* bSrc1 = Bt + (size_t)(col0 + rq1) * ldb + cs1 * 8;
    short8v* aDst0 = &As[wid * 128];
    short8v* aDst1 = &As[wid * 128 + 64];
    short8v* bDst0 = &Bs[wid * 128];
    short8v* bDst1 = &Bs[wid * 128 + 64];

    int fr = lane & 15, kg = lane >> 4;
    int sf = kg ^ ((fr >> 1) & 3);

    int kslice = Kdim / (int)gridDim.z;
    int kbeg = (int)blockIdx.z * kslice;
    for (int k0 = kbeg; k0 < kbeg + kslice; k0 += 32) {
        __syncthreads();
        gld16(aSrc0 + k0, aDst0);
        gld16(aSrc1 + k0, aDst1);
        gld16(bSrc0 + k0, bDst0);
        gld16(bSrc1 + k0, bDst1);
        __syncthreads();
        short8v af[4], bf[4];
#pragma unroll
        for (int mb = 0; mb < 4; ++mb) af[mb] = As[(wr + mb * 16 + fr) * 4 + sf];
#pragma unroll
        for (int nb = 0; nb < 4; ++nb) bf[nb] = Bs[(wc + nb * 16 + fr) * 4 + sf];
#pragma unroll
        for (int mb = 0; mb < 4; ++mb)
#pragma unroll
            for (int nb = 0; nb < 4; ++nb)
                acc[mb][nb] = __builtin_amdgcn_mfma_f32_16x16x32_bf16(af[mb], bf[nb], acc[mb][nb], 0, 0, 0);
    }
    ushort* cu = (ushort*)Cout + (size_t)blockIdx.z * czs;
    float* cf = (float*)Cout + (size_t)blockIdx.z * czs;
#pragma unroll
    for (int mb = 0; mb < 4; ++mb) {
        int r_ = row0 + wr + mb * 16 + kg * 4;
#pragma unroll
        for (int nb = 0; nb < 4; ++nb) {
            int c_ = col0 + wc + nb * 16 + fr;
            float bz = bias ? bias[c_] : 0.f;
#pragma unroll
            for (int r = 0; r < 4; ++r) {
                float o = acc[mb][nb][r] + bz;
                if (add) o += add[(size_t)(r_ + r) * ldadd + c_];
                if (BF16OUT) cu[(size_t)(r_ + r) * ldc + c_] = f2bf(o);
                else         cf[(size_t)(r_ + r) * ldc + c_] = o;
            }
        }
    }
}

// ---------------- h1-fused cm_w2 GEMM ----------------
__global__ __launch_bounds__(256) void mgemmH_k(const float* __restrict__ imp,
                                                const float* __restrict__ w1,
                                                const float* __restrict__ b1,
                                                const ushort* __restrict__ Bt,
                                                const float* __restrict__ bias,
                                                ushort* __restrict__ Cout, int ldc) {
    __shared__ short8v As[128 * 4];
    __shared__ short8v Bs[128 * 4];
    int tid = threadIdx.x;
    int lane = tid & 63, wid = tid >> 6;
    int row0 = blockIdx.y * 128, col0 = blockIdx.x * 128;
    int wr = (wid >> 1) * 64, wc = (wid & 1) * 64;
    float4v acc[4][4];
#pragma unroll
    for (int i = 0; i < 4; ++i)
#pragma unroll
        for (int j = 0; j < 4; ++j)
#pragma unroll
            for (int r = 0; r < 4; ++r) acc[i][j][r] = 0.f;

    int rq0 = wid * 32 + (lane >> 2);
    int rq1 = rq0 + 16;
    int clds = lane & 3;
    int cs0 = clds ^ ((rq0 >> 1) & 3);
    int cs1 = clds ^ ((rq1 >> 1) & 3);
    float imp0 = imp[row0 + rq0];
    float imp1 = imp[row0 + rq1];
    const ushort* bSrc0 = Bt + (size_t)(col0 + rq0) * DI4 + cs0 * 8;
    const ushort* bSrc1 = Bt + (size_t)(col0 + rq1) * DI4 + cs1 * 8;
    short8v* bDst0 = &Bs[wid * 128];
    short8v* bDst1 = &Bs[wid * 128 + 64];

    int fr = lane & 15, kg = lane >> 4;
    int sf = kg ^ ((fr >> 1) & 3);

    for (int k0 = 0; k0 < DI4; k0 += 32) {
        float4 wa0 = *(const float4*)(w1 + k0 + cs0 * 8);
        float4 wa1 = *(const float4*)(w1 + k0 + cs0 * 8 + 4);
        float4 ba0 = *(const float4*)(b1 + k0 + cs0 * 8);
        float4 ba1 = *(const float4*)(b1 + k0 + cs0 * 8 + 4);
        float4 wb0 = *(const float4*)(w1 + k0 + cs1 * 8);
        float4 wb1 = *(const float4*)(w1 + k0 + cs1 * 8 + 4);
        float4 bb0 = *(const float4*)(b1 + k0 + cs1 * 8);
        float4 bb1 = *(const float4*)(b1 + k0 + cs1 * 8 + 4);
        short8v pa, pb;
        pa[0] = (short)f2bf(fmaxf(fmaf(imp0, wa0.x, ba0.x), 0.f));
        pa[1] = (short)f2bf(fmaxf(fmaf(imp0, wa0.y, ba0.y), 0.f));
        pa[2] = (short)f2bf(fmaxf(fmaf(imp0, wa0.z, ba0.z), 0.f));
        pa[3] = (short)f2bf(fmaxf(fmaf(imp0, wa0.w, ba0.w), 0.f));
        pa[4] = (short)f2bf(fmaxf(fmaf(imp0, wa1.x, ba1.x), 0.f));
        pa[5] = (short)f2bf(fmaxf(fmaf(imp0, wa1.y, ba1.y), 0.f));
        pa[6] = (short)f2bf(fmaxf(fmaf(imp0, wa1.z, ba1.z), 0.f));
        pa[7] = (short)f2bf(fmaxf(fmaf(imp0, wa1.w, ba1.w), 0.f));
        pb[0] = (short)f2bf(fmaxf(fmaf(imp1, wb0.x, bb0.x), 0.f));
        pb[1] = (short)f2bf(fmaxf(fmaf(imp1, wb0.y, bb0.y), 0.f));
        pb[2] = (short)f2bf(fmaxf(fmaf(imp1, wb0.z, bb0.z), 0.f));
        pb[3] = (short)f2bf(fmaxf(fmaf(imp1, wb0.w, bb0.w), 0.f));
        pb[4] = (short)f2bf(fmaxf(fmaf(imp1, wb1.x, bb1.x), 0.f));
        pb[5] = (short)f2bf(fmaxf(fmaf(imp1, wb1.y, bb1.y), 0.f));
        pb[6] = (short)f2bf(fmaxf(fmaf(imp1, wb1.z, bb1.z), 0.f));
        pb[7] = (short)f2bf(fmaxf(fmaf(imp1, wb1.w, bb1.w), 0.f));
        __syncthreads();
        As[rq0 * 4 + clds] = pa;
        As[rq1 * 4 + clds] = pb;
        gld16(bSrc0 + k0, bDst0);
        gld16(bSrc1 + k0, bDst1);
        __syncthreads();
        short8v af[4], bf[4];
#pragma unroll
        for (int mb = 0; mb < 4; ++mb) af[mb] = As[(wr + mb * 16 + fr) * 4 + sf];
#pragma unroll
        for (int nb = 0; nb < 4; ++nb) bf[nb] = Bs[(wc + nb * 16 + fr) * 4 + sf];
#pragma unroll
        for (int mb = 0; mb < 4; ++mb)
#pragma unroll
            for (int nb = 0; nb < 4; ++nb)
                acc[mb][nb] = __builtin_amdgcn_mfma_f32_16x16x32_bf16(af[mb], bf[nb], acc[mb][nb], 0, 0, 0);
    }
#pragma unroll
    for (int mb = 0; mb < 4; ++mb) {
        int r_ = row0 + wr + mb * 16 + kg * 4;
#pragma unroll
        for (int nb = 0; nb < 4; ++nb) {
            int c_ = col0 + wc + nb * 16 + fr;
            float bz = bias[c_];
#pragma unroll
            for (int r = 0; r < 4; ++r)
                Cout[(size_t)(r_ + r) * ldc + c_] = f2bf(acc[mb][nb][r] + bz);
        }
    }
}

// ---------------- depthwise causal conv + silu (ushort2-vectorized) ----------------
__global__ __launch_bounds__(256) void conv_k(const ushort* __restrict__ xz,
                                              const float* __restrict__ cw,
                                              const float* __restrict__ cb,
                                              ushort* __restrict__ xcb) {
    int gid = blockIdx.x * 256 + threadIdx.x;   // pair index over TT*DI/2
    int p = gid & (DI / 2 - 1);
    int d = p * 2;
    int t = gid >> 9;
    int n = t & (N - 1);
    float acc0 = cb[d], acc1 = cb[d + 1];
    const ushort* base = xz + (size_t)t * (2 * DI) + d;
    float4 w0 = *(const float4*)(cw + d * DC);
    float4 w1 = *(const float4*)(cw + (d + 1) * DC);
    float wk0[4] = {w0.x, w0.y, w0.z, w0.w};
    float wk1[4] = {w1.x, w1.y, w1.z, w1.w};
#pragma unroll
    for (int k = 0; k < DC; ++k) {
        int nn = n - (DC - 1) + k;
        if (nn >= 0) {
            unsigned u = *(const unsigned*)(base + (long)(nn - n) * (2 * DI));
            acc0 = fmaf(bf2f((ushort)(u & 0xffff)), wk0[k], acc0);
            acc1 = fmaf(bf2f((ushort)(u >> 16)), wk1[k], acc1);
        }
    }
    float s0 = acc0 / (1.f + __expf(-acc0));
    float s1 = acc1 / (1.f + __expf(-acc1));
    unsigned o = (unsigned)f2bf(s0) | ((unsigned)f2bf(s1) << 16);
    *(unsigned*)(xcb + (size_t)t * DI + d) = o;
}

// ================= segmented scan =================
// Phase A: per-segment local scan (h0=0) + transfer product P = prod(a).
__global__ __launch_bounds__(256) void scanA_k(const ushort* __restrict__ modl,
                                               const ushort* __restrict__ xcb,
                                               const float* __restrict__ xssmT,
                                               const float* __restrict__ Alog,
                                               const float* __restrict__ dtw,
                                               const float* __restrict__ dtb,
                                               float* __restrict__ hloc,
                                               float* __restrict__ Pp) {
    int blk = blockIdx.x;
    int seg = blk & 15;
    int dblk = (blk >> 4) & 63;
    int b = blk >> 10;
    int d0 = dblk * 16;
    int tid = threadIdx.x;
    int lane = tid & 63, wave = tid >> 6;
    int s = lane & 15, dd = lane >> 4;
    int dl = wave * 4 + dd, d = d0 + dl;
    float A = -__expf(Alog[d * DS + s]);
    size_t tokbase = (size_t)b * N + (size_t)seg * SLEN;

    __shared__ float sdl[16][68];   // [dl][t] delta
    __shared__ float sxc[16][68];   // [dl][t] xc
    __shared__ float sBv[16][68];   // [s][t]  B

    int lc = tid & 15, lr = tid >> 4;
    float dtwv = dtw[d0 + lc], dtbv = dtb[d0 + lc];
    const ushort* mbase = modl + tokbase * DI + d0 + lc;
    const ushort* xbase = xcb + tokbase * DI + d0 + lc;
    const float* drow = xssmT + tokbase;
    const float* Brow = xssmT + (size_t)(1 + lc) * TT + tokbase;
#pragma unroll
    for (int q = 0; q < 4; ++q) {
        int tok = q * 16 + lr;
        float mo   = bf2f(mbase[(size_t)tok * DI]);
        float draw = drow[tok];
        float xcv  = bf2f(xbase[(size_t)tok * DI]);
        float Bv   = Brow[tok];
        float a = draw * dtwv + dtbv;
        float sp = (a > 20.f) ? a : log1pf(__expf(a));
        float mod = 1.f / (1.f + __expf(-mo));
        sdl[lc][tok] = sp * (1.f + mod);
        sxc[lc][tok] = xcv;
        sBv[lc][tok] = Bv;
    }
    __syncthreads();
    float h = 0.f, P = 1.f;
#pragma unroll
    for (int g = 0; g < 8; ++g) {
        float4 dl4a = *(const float4*)&sdl[dl][g * 8];
        float4 dl4b = *(const float4*)&sdl[dl][g * 8 + 4];
        float4 xc4a = *(const float4*)&sxc[dl][g * 8];
        float4 xc4b = *(const float4*)&sxc[dl][g * 8 + 4];
        float4 B4a  = *(const float4*)&sBv[s][g * 8];
        float4 B4b  = *(const float4*)&sBv[s][g * 8 + 4];
        float dlt[8] = {dl4a.x, dl4a.y, dl4a.z, dl4a.w, dl4b.x, dl4b.y, dl4b.z, dl4b.w};
        float xcv[8] = {xc4a.x, xc4a.y, xc4a.z, xc4a.w, xc4b.x, xc4b.y, xc4b.z, xc4b.w};
        float Bv8[8] = {B4a.x, B4a.y, B4a.z, B4a.w, B4b.x, B4b.y, B4b.z, B4b.w};
        float a8[8], b8[8];
#pragma unroll
        for (int j = 0; j < 8; ++j) {
            a8[j] = __expf(dlt[j] * A);
            b8[j] = (dlt[j] * Bv8[j]) * xcv[j];
        }
#pragma unroll
        for (int j = 0; j < 8; ++j) { h = fmaf(a8[j], h, b8[j]); P *= a8[j]; }
    }
    size_t idx = (size_t)blk * 256 + tid;
    hloc[idx] = h;
    Pp[idx] = P;
}

// Phase B: sequential combine across 16 segments per (b,d,s); writes per-segment h0.
__global__ __launch_bounds__(256) void scanB_k(const float* __restrict__ hloc,
                                               const float* __restrict__ Pp,
                                               float* __restrict__ h0g) {
    int blk = blockIdx.x;
    int tid = threadIdx.x;
    size_t base = (size_t)blk * SEG * 256 + tid;
    float h = 0.f;
    for (int g = 0; g < SEG; ++g) {
        size_t i = base + (size_t)g * 256;
        h0g[i] = h;
        h = fmaf(Pp[i], h, hloc[i]);
    }
}

// Phase C: re-run segment from true h0; deferred sP reduce (float4).
__global__ __launch_bounds__(256) void scanC_k(const ushort* __restrict__ modl,
                                               const ushort* __restrict__ xcb,
                                               const float* __restrict__ xssmT,
                                               const float* __restrict__ Alog,
                                               const float* __restrict__ Dp,
                                               const ushort* __restrict__ xz,
                                               const float* __restrict__ dtw,
                                               const float* __restrict__ dtb,
                                               const float* __restrict__ h0g,
                                               ushort* __restrict__ y) {
    int blk = blockIdx.x;
    int seg = blk & 15;
    int dblk = (blk >> 4) & 63;
    int b = blk >> 10;
    int d0 = dblk * 16;
    int tid = threadIdx.x;
    int lane = tid & 63, wave = tid >> 6;
    int s = lane & 15, dd = lane >> 4;
    int dl = wave * 4 + dd, d = d0 + dl;
    float A = -__expf(Alog[d * DS + s]);
    size_t tokbase = (size_t)b * N + (size_t)seg * SLEN;

    __shared__ float sdl[16][68];   // [dl][t]
    __shared__ float sxc[16][68];   // [dl][t]
    __shared__ float sBv[16][68];   // [s][t]
    __shared__ float sCv[16][68];   // [s][t]
    __shared__ float szv[16][68];   // [dl][t]
    __shared__ float sP[16][16][20];   // [step-in-group][dl][s], float4-aligned pad

    int lc = tid & 15, lr = tid >> 4;
    float dtwv = dtw[d0 + lc], dtbv = dtb[d0 + lc];
    float dpv_lc = Dp[d0 + lc];
    const ushort* mbase = modl + tokbase * DI + d0 + lc;
    const ushort* xbase = xcb + tokbase * DI + d0 + lc;
    const ushort* zbase = xz + tokbase * (2 * DI) + DI + d0 + lc;
    const float* drow = xssmT + tokbase;
    const float* Brow = xssmT + (size_t)(1 + lc) * TT + tokbase;
    const float* Crow = xssmT + (size_t)(1 + DS + lc) * TT + tokbase;
#pragma unroll
    for (int q = 0; q < 4; ++q) {
        int tok = q * 16 + lr;
        float mo   = bf2f(mbase[(size_t)tok * DI]);
        float draw = drow[tok];
        float xcv  = bf2f(xbase[(size_t)tok * DI]);
        float Bv   = Brow[tok];
        float Cv   = Crow[tok];
        float zv   = bf2f(zbase[(size_t)tok * (2 * DI)]);
        float a = draw * dtwv + dtbv;
        float sp = (a > 20.f) ? a : log1pf(__expf(a));
        float mod = 1.f / (1.f + __expf(-mo));
        sdl[lc][tok] = sp * (1.f + mod);
        sxc[lc][tok] = xcv;
        sBv[lc][tok] = Bv;
        sCv[lc][tok] = Cv;
        szv[lc][tok] = zv;
    }
    __syncthreads();
    float h = h0g[(size_t)blk * 256 + tid];
    for (int g = 0; g < 4; ++g) {              // 16-token groups
#pragma unroll
        for (int half = 0; half < 2; ++half) {
            int t0 = g * 16 + half * 8;
            float4 dl4a = *(const float4*)&sdl[dl][t0];
            float4 dl4b = *(const float4*)&sdl[dl][t0 + 4];
            float4 xc4a = *(const float4*)&sxc[dl][t0];
            float4 xc4b = *(const float4*)&sxc[dl][t0 + 4];
            float4 B4a  = *(const float4*)&sBv[s][t0];
            float4 B4b  = *(const float4*)&sBv[s][t0 + 4];
            float4 C4a  = *(const float4*)&sCv[s][t0];
            float4 C4b  = *(const float4*)&sCv[s][t0 + 4];
            float dlt[8] = {dl4a.x, dl4a.y, dl4a.z, dl4a.w, dl4b.x, dl4b.y, dl4b.z, dl4b.w};
            float xcv[8] = {xc4a.x, xc4a.y, xc4a.z, xc4a.w, xc4b.x, xc4b.y, xc4b.z, xc4b.w};
            float Bv8[8] = {B4a.x, B4a.y, B4a.z, B4a.w, B4b.x, B4b.y, B4b.z, B4b.w};
            float Cv8[8] = {C4a.x, C4a.y, C4a.z, C4a.w, C4b.x, C4b.y, C4b.z, C4b.w};
            float a8[8], b8[8];
#pragma unroll
            for (int j = 0; j < 8; ++j) {
                a8[j] = __expf(dlt[j] * A);
                b8[j] = (dlt[j] * Bv8[j]) * xcv[j];
            }
#pragma unroll
            for (int j = 0; j < 8; ++j) {
                h = fmaf(a8[j], h, b8[j]);
                sP[half * 8 + j][dl][s] = h * Cv8[j];
            }
        }
        __syncthreads();
        {   // parallel s-reduce (float4) + gate + store
            int t = g * 16 + lr;
            const float4* pr = (const float4*)&sP[lr][lc][0];
            float4 p0 = pr[0], p1 = pr[1], p2 = pr[2], p3 = pr[3];
            float ssum = ((p0.x + p0.y) + (p0.z + p0.w)) + ((p1.x + p1.y) + (p1.z + p1.w))
                       + ((p2.x + p2.y) + (p2.z + p2.w)) + ((p3.x + p3.y) + (p3.z + p3.w));
            float xcv = sxc[lc][t];
            float zv  = szv[lc][t];
            float sg = 1.f / (1.f + __expf(-zv));
            y[(tokbase + t) * DI + d0 + lc] = f2bf((ssum + xcv * dpv_lc) * (zv * sg));
        }
        __syncthreads();
    }
}

// ---------------- concat [xf | flip(xb)] -> bf16 ----------------
__global__ __launch_bounds__(256) void concat_k(const float* __restrict__ xf,
                                                const float* __restrict__ xb,
                                                ushort* __restrict__ cat) {
    int gid = blockIdx.x * 256 + threadIdx.x;   // TT*DM
    int t = gid >> 9;
    int c = gid & (DM - 1);
    int b = t >> 10, j = t & (N - 1);
    cat[(size_t)t * (2 * DM) + c] = f2bf(xf[gid]);
    cat[(size_t)t * (2 * DM) + DM + c] = f2bf(xb[((size_t)(b << 10) + (N - 1 - j)) * DM + c]);
}

// ---------------- final: scatter by ridx + layernorm ----------------
__global__ __launch_bounds__(256) void final_k(const float* __restrict__ fus,
                                               const int* __restrict__ ridx,
                                               const float* __restrict__ g,
                                               const float* __restrict__ bt,
                                               float* __restrict__ out) {
    int t = blockIdx.x, tid = threadIdx.x;
    int b = t >> 10;
    int r = ridx[t];
    const float* xr = fus + (size_t)t * DM;
    __shared__ float red[256];
    float v0 = xr[tid], v1 = xr[tid + 256];
    red[tid] = v0 + v1; __syncthreads();
    for (int st = 128; st > 0; st >>= 1) { if (tid < st) red[tid] += red[tid + st]; __syncthreads(); }
    float mu = red[0] * (1.f / DM); __syncthreads();
    float d0 = v0 - mu, d1 = v1 - mu;
    red[tid] = d0 * d0 + d1 * d1; __syncthreads();
    for (int st = 128; st > 0; st >>= 1) { if (tid < st) red[tid] += red[tid + st]; __syncthreads(); }
    float rs = rsqrtf(red[0] * (1.f / DM) + 1e-5f);
    float* orow = out + ((size_t)(b << 10) + r) * DM;
    orow[tid] = d0 * rs * g[tid] + bt[tid];
    orow[tid + 256] = d1 * rs * g[tid + 256] + bt[tid + 256];
}

// ---------------- host ----------------
extern "C" void kernel_launch(void* const* d_in, const int* in_sizes, int n_in,
                              void* d_out, int out_size, void* d_ws, size_t ws_size,
                              hipStream_t stream) {
    const float* x            = (const float*)d_in[0];
    const float* centers_init = (const float*)d_in[1];
    const float* in_w         = (const float*)d_in[2];
    const float* conv_w       = (const float*)d_in[3];
    const float* conv_b       = (const float*)d_in[4];
    const float* xp_w         = (const float*)d_in[5];
    const float* dt_w         = (const float*)d_in[6];
    const float* dt_b         = (const float*)d_in[7];
    const float* cm_w1        = (const float*)d_in[8];
    const float* cm_b1        = (const float*)d_in[9];
    const float* cm_w2        = (const float*)d_in[10];
    const float* cm_b2        = (const float*)d_in[11];
    const float* A_log        = (const float*)d_in[12];
    const float* D_p          = (const float*)d_in[13];
    const float* out_w        = (const float*)d_in[14];
    const float* ln_g         = (const float*)d_in[15];
    const float* ln_b         = (const float*)d_in[16];
    const float* fusion_w     = (const float*)d_in[17];
    const float* fusion_b     = (const float*)d_in[18];
    const float* fn_g         = (const float*)d_in[19];
    const float* fn_b         = (const float*)d_in[20];

    float* W = (float*)d_ws;
    size_t off = 0;
    auto alloc = [&](size_t n) { float* p = W + off; off += (n + 15) & ~(size_t)15; return p; };
    auto allocU = [&](size_t n) { ushort* p = (ushort*)(W + off); off += ((n + 1) / 2 + 15) & ~(size_t)15; return p; };
    float* centers = alloc((size_t)Bb * KC * DM);
    float* wgt     = alloc((size_t)TT * KC);
    float* mind    = alloc(TT);
    float* keys    = alloc(TT);
    float* imp     = alloc(TT);
    float* rimp    = alloc(TT);
    float* fimp    = alloc(TT);
    float* denp    = alloc((size_t)Bb * KC * SEGU);
    float* rx      = alloc((size_t)TT * DM);
    float* rxf     = alloc((size_t)TT * DM);
    float* tmp     = alloc((size_t)TT * DM);
    float* fus     = alloc((size_t)TT * DM);       // fusion output f32
    float* xssmT   = alloc((size_t)TT * 33);
    float* hloc    = alloc((size_t)Bb * 64 * SEG * 256);   // hloc+Pp aliased by xssmP (8MB)
    float* Pp      = alloc((size_t)Bb * 64 * SEG * 256);
    float* h0g     = alloc((size_t)Bb * 64 * SEG * 256);
    ushort* xz     = allocU((size_t)TT * 2 * DI);  // bf16 xz; reused as bf16 cat
    ushort* modl   = allocU((size_t)TT * DI);      // bf16; aliased by kmeans 'part'
    ushort* xnb    = allocU((size_t)TT * DM);
    ushort* yb     = allocU((size_t)TT * DI);
    ushort* xcb    = allocU((size_t)TT * DI);
    ushort* inwT   = allocU((size_t)L4 * 2 * DI * DM);
    ushort* cmw2T  = allocU((size_t)L4 * DI * DI4);
    ushort* outwT  = allocU((size_t)L4 * DM * DI);
    ushort* fusT   = allocU((size_t)DM * 2 * DM);
    ushort* xpwT   = allocU((size_t)L4 * 128 * DI);
    int* ridx = (int*)(W + off); off += TT;
    float* part = (float*)modl;   // kmeans partials alias modl region (disjoint in time)
    float* xssmP = hloc;          // 4 split-K partials (8MB) alias hloc+Pp (8.4MB), disjoint in time

    // ---- merged weight prep ----
    prep_k<<<7696, 256, 0, stream>>>(in_w, cm_w2, out_w, fusion_w, xp_w,
                                     inwT, cmw2T, outwT, fusT, xpwT);

    // ---- k-means ----
    for (int it = 0; it < 3; ++it) {
        if (it == 0) assign_k<false><<<TT / 4, 256, 0, stream>>>(x, centers_init, 0, wgt, nullptr, nullptr);
        else         assign_k<false><<<TT / 4, 256, 0, stream>>>(x, centers, KC * DM, wgt, nullptr, nullptr);
        updp_k<<<Bb * SEGU, 512, 0, stream>>>(x, wgt, part, denp);
        updr_k<<<Bb * KC, 512, 0, stream>>>(part, denp, centers);
    }
    assign_k<true><<<TT / 4, 256, 0, stream>>>(x, centers, KC * DM, wgt, mind, keys);
    sortimp_k<<<8, 1024, 0, stream>>>(keys, mind, ridx, imp);
    gather_k<<<TT, 512, 0, stream>>>(x, imp, ridx, rx, rxf, rimp, fimp);

    auto gemmF = [&](const ushort* Ap, int lda, const ushort* Bp, int ldb,
                     const float* bias, const float* add, int ldadd,
                     float* Cp, int ldc, int Kd, int Nn) {
        dim3 g(Nn / 128, TT / 128, 1);
        mgemm_k<false><<<g, 256, 0, stream>>>(Ap, lda, Bp, ldb, bias, add, ldadd, Cp, ldc, Kd, 0);
    };
    auto gemmB = [&](const ushort* Ap, int lda, const ushort* Bp, int ldb,
                     const float* bias,
                     ushort* Cp, int ldc, int Kd, int Nn) {
        dim3 g(Nn / 128, TT / 128, 1);
        mgemm_k<true><<<g, 256, 0, stream>>>(Ap, lda, Bp, ldb, bias, nullptr, 0, Cp, ldc, Kd, 0);
    };

    // ---- 4 mamba layers (2 fwd, 2 bwd on flipped) ----
    const float* lay_in[4]  = {rx, tmp, rxf, tmp};
    float*       lay_out[4] = {tmp, rx, tmp, rxf};
    for (int l = 0; l < L4; ++l) {
        const float* xin = lay_in[l];
        float* xout = lay_out[l];
        const float* impv = (l < 2) ? rimp : fimp;
        ln_k<<<TT / 4, 256, 0, stream>>>(xin, ln_g + (size_t)l * DM, ln_b + (size_t)l * DM, xnb);
        gemmB(xnb, DM, inwT + (size_t)l * 2 * DI * DM, DM, nullptr, xz, 2 * DI, DM, 2 * DI);
        conv_k<<<(TT * DI / 2) / 256, 256, 0, stream>>>(xz, conv_w + (size_t)l * DI * DC, conv_b + (size_t)l * DI, xcb);
        {   // xssm GEMM, split-K = 4
            dim3 g(1, TT / 128, 4);
            mgemm_k<false><<<g, 256, 0, stream>>>(xcb, DI, xpwT + (size_t)l * 128 * DI, DI,
                                                  nullptr, nullptr, 0, xssmP, 128, DI, (size_t)TT * 128);
        }
        tpose33_k<<<TT / 64, 256, 0, stream>>>(xssmP, xssmT);
        mgemmH_k<<<dim3(DI / 128, TT / 128), 256, 0, stream>>>(impv, cm_w1 + (size_t)l * DI4,
                                                               cm_b1 + (size_t)l * DI4,
                                                               cmw2T + (size_t)l * DI * DI4,
                                                               cm_b2 + (size_t)l * DI, modl, DI);
        scanA_k<<<Bb * 64 * SEG, 256, 0, stream>>>(modl, xcb, xssmT, A_log + (size_t)l * DI * DS,
                                                   dt_w + (size_t)l * DI, dt_b + (size_t)l * DI, hloc, Pp);
        scanB_k<<<Bb * 64, 256, 0, stream>>>(hloc, Pp, h0g);
        scanC_k<<<Bb * 64 * SEG, 256, 0, stream>>>(modl, xcb, xssmT, A_log + (size_t)l * DI * DS,
                                                   D_p + (size_t)l * DI, xz,
                                                   dt_w + (size_t)l * DI, dt_b + (size_t)l * DI,
                                                   h0g, yb);
        gemmF(yb, DI, outwT + (size_t)l * DM * DI, DI, nullptr, xin, DM, xout, DM, DI, DM);
    }

    // ---- fusion + restore + final LN ----
    ushort* catb = xz;
    concat_k<<<(TT * DM) / 256, 256, 0, stream>>>(rx /*xf final*/, rxf /*xb final*/, catb);
    gemmF(catb, 2 * DM, fusT, 2 * DM, fusion_b, nullptr, 0, fus, DM, 2 * DM, DM);
    final_k<<<TT, 256, 0, stream>>>(fus, ridx, fn_g, fn_b, (float*)d_out);
}

// Round 12
// 760.872 us; speedup vs baseline: 4.5043x; 1.0819x over previous
//
#include <hip/hip_runtime.h>
#include <math.h>

// ---------------- constants ----------------
constexpr int DM = 512, DS = 16, DC = 4, DI = 1024, DI4 = 256, KC = 5;
constexpr int Bb = 4, N = 1024, L4 = 4, TT = Bb * N;
constexpr float TEMP = 0.5f;
constexpr int SEG = 16;          // scan segments per sequence
constexpr int SLEN = N / SEG;    // 64 tokens per segment
constexpr int SEGU = 64;         // kmeans-update segments

typedef __attribute__((ext_vector_type(8))) short short8v;
typedef __attribute__((ext_vector_type(4))) float float4v;

__device__ inline ushort f2bf(float f) {
    union { float f; unsigned u; } v; v.f = f;
    unsigned r = v.u + 0x7FFFu + ((v.u >> 16) & 1u);
    return (ushort)(r >> 16);
}
__device__ inline float bf2f(ushort u) {
    union { unsigned u; float f; } v; v.u = ((unsigned)u) << 16;
    return v.f;
}
__device__ inline void gld16(const void* g, void* lds) {
    __builtin_amdgcn_global_load_lds(
        (const __attribute__((address_space(1))) unsigned int*)g,
        (__attribute__((address_space(3))) unsigned int*)lds, 16, 0, 0);
}

// ---------------- k-means assign (wave-per-token, float4) ----------------
template <bool FINAL>
__global__ __launch_bounds__(256) void assign_k(const float* __restrict__ x,
                                                const float* __restrict__ cen0,
                                                int cbstride,
                                                float* __restrict__ wgt,
                                                float* __restrict__ mind,
                                                float* __restrict__ keys) {
    int t = blockIdx.x * 4 + (threadIdx.x >> 6);   // token
    int b = t >> 10;
    int lane = threadIdx.x & 63;
    const float4* xr = (const float4*)(x + (size_t)t * DM);
    float4 xv0 = xr[lane], xv1 = xr[lane + 64];
    const float* cenb = cen0 + (size_t)b * cbstride;
    float d2[KC];
#pragma unroll
    for (int k = 0; k < KC; ++k) {
        const float4* cr = (const float4*)(cenb + k * DM);
        float4 c0 = cr[lane], c1 = cr[lane + 64];
        float dx = xv0.x - c0.x, dy = xv0.y - c0.y, dz = xv0.z - c0.z, dw = xv0.w - c0.w;
        float acc = dx * dx + dy * dy + dz * dz + dw * dw;
        dx = xv1.x - c1.x; dy = xv1.y - c1.y; dz = xv1.z - c1.z; dw = xv1.w - c1.w;
        acc += dx * dx + dy * dy + dz * dz + dw * dw;
        d2[k] = acc;
    }
#pragma unroll
    for (int k = 0; k < KC; ++k)
        for (int off = 32; off > 0; off >>= 1) d2[k] += __shfl_xor(d2[k], off);
    if (lane == 0) {
        float dist[KC], logit[KC], e[KC];
        float lm = -1e30f;
        for (int k = 0; k < KC; ++k) {
            dist[k] = sqrtf(d2[k] + 1e-12f);
            logit[k] = -dist[k] / TEMP;
            lm = fmaxf(lm, logit[k]);
        }
        float s = 0.f;
        for (int k = 0; k < KC; ++k) { e[k] = expf(logit[k] - lm); s += e[k]; }
        float inv = 1.f / s;
        for (int k = 0; k < KC; ++k) wgt[t * KC + k] = e[k] * inv;
        if (FINAL) {
            float md = dist[0];
            for (int k = 1; k < KC; ++k) md = fminf(md, dist[k]);
            int ca = 0; float best = e[0] * inv;
            for (int k = 1; k < KC; ++k) {
                float wv = e[k] * inv;
                if (wv > best) { best = wv; ca = k; }
            }
            mind[t] = md;
            keys[t] = (float)ca * 1000.0f + (1.0f - best);
        }
    }
}

// ---- update: pass1 partials over 16-token segments ----
__global__ __launch_bounds__(512) void updp_k(const float* __restrict__ x,
                                              const float* __restrict__ wgt,
                                              float* __restrict__ part,
                                              float* __restrict__ denp) {
    int blk = blockIdx.x;        // b*SEGU + seg
    int b = blk >> 6, seg = blk & 63;
    int c = threadIdx.x;
    constexpr int TSEG = N / SEGU;   // 16
    __shared__ float sw[TSEG][KC];
    int n0 = seg * TSEG;
    if (c < TSEG * KC) sw[c / KC][c % KC] = wgt[((size_t)(b << 10) + n0 + c / KC) * KC + c % KC];
    __syncthreads();
    const float* xb = x + ((size_t)(b << 10) + n0) * DM + c;
    float acc[KC] = {};
    for (int n = 0; n < TSEG; ++n) {
        float xv = xb[(size_t)n * DM];
#pragma unroll
        for (int k = 0; k < KC; ++k) acc[k] = fmaf(sw[n][k], xv, acc[k]);
    }
#pragma unroll
    for (int k = 0; k < KC; ++k)
        part[(((size_t)b * KC + k) * SEGU + seg) * DM + c] = acc[k];
    if (c < KC) {
        float dn = 0.f;
        for (int n = 0; n < TSEG; ++n) dn += sw[n][c];
        denp[((size_t)b * KC + c) * SEGU + seg] = dn;
    }
}

// ---- update: pass2 reduce ----
__global__ __launch_bounds__(512) void updr_k(const float* __restrict__ part,
                                              const float* __restrict__ denp,
                                              float* __restrict__ centers) {
    int bk = blockIdx.x;         // 0..B*KC-1
    int c = threadIdx.x;
    const float* pb = part + (size_t)bk * SEGU * DM + c;
    float acc = 0.f;
    for (int g = 0; g < SEGU; ++g) acc += pb[(size_t)g * DM];
    __shared__ float sden;
    if (c == 0) {
        float dn = 0.f;
        const float* db = denp + (size_t)bk * SEGU;
        for (int g = 0; g < SEGU; ++g) dn += db[g];
        sden = dn;
    }
    __syncthreads();
    centers[(size_t)bk * DM + c] = acc / (sden + 1e-8f);
}

// ---- merged sort (blocks 0..3) + importance (blocks 4..7) ----
__global__ __launch_bounds__(1024) void sortimp_k(const float* __restrict__ keys,
                                                  const float* __restrict__ mind,
                                                  int* __restrict__ ridx,
                                                  float* __restrict__ imp) {
    __shared__ unsigned long long a[1024];
    int tid = threadIdx.x;
    if (blockIdx.x < 4) {
        int b = blockIdx.x;
        unsigned int kb = __float_as_uint(keys[b * N + tid]);   // keys >= 0
        a[tid] = ((unsigned long long)kb << 32) | (unsigned int)tid;
        __syncthreads();
        for (int k = 2; k <= 1024; k <<= 1) {
            for (int j = k >> 1; j > 0; j >>= 1) {
                int ixj = tid ^ j;
                if (ixj > tid) {
                    unsigned long long x0 = a[tid], x1 = a[ixj];
                    bool up = ((tid & k) == 0);
                    bool sw = up ? (x0 > x1) : (x0 < x1);
                    if (sw) { a[tid] = x1; a[ixj] = x0; }
                }
                __syncthreads();
            }
        }
        ridx[b * N + tid] = (int)(a[tid] & 0xffffffffu);
    } else {
        int b = blockIdx.x - 4;
        float* red = (float*)a;
        float v = -mind[b * N + tid] / TEMP;
        red[tid] = v; __syncthreads();
        for (int s = 512; s > 0; s >>= 1) { if (tid < s) red[tid] = fmaxf(red[tid], red[tid + s]); __syncthreads(); }
        float m = red[0]; __syncthreads();
        float e = expf(v - m);
        red[tid] = e; __syncthreads();
        for (int s = 512; s > 0; s >>= 1) { if (tid < s) red[tid] += red[tid + s]; __syncthreads(); }
        imp[b * N + tid] = e / red[0];
    }
}

__global__ __launch_bounds__(512) void gather_k(const float* __restrict__ x,
                                                const float* __restrict__ imp,
                                                const int* __restrict__ ridx,
                                                float* __restrict__ rx, float* __restrict__ rxf,
                                                float* __restrict__ rimp, float* __restrict__ fimp) {
    int t = blockIdx.x;
    int b = t >> 10, j = t & (N - 1);
    int r = ridx[t];
    int c = threadIdx.x;
    float v = x[((size_t)(b << 10) + r) * DM + c];
    rx[(size_t)t * DM + c] = v;
    rxf[((size_t)(b << 10) + (N - 1 - j)) * DM + c] = v;
    if (c == 0) {
        float iv = imp[(b << 10) + r];
        rimp[t] = iv;
        fimp[(b << 10) + (N - 1 - j)] = iv;
    }
}

// ---------------- merged weight prep ----------------
__device__ inline void tconv_body(const float* __restrict__ src, ushort* __restrict__ dst,
                                  int R, int C, int c0, int r0, float* tile /*32x33*/) {
    int tx = threadIdx.x & 31, ty = threadIdx.x >> 5;
#pragma unroll
    for (int j = 0; j < 4; ++j)
        tile[(ty + j * 8) * 33 + tx] = src[(size_t)(r0 + ty + j * 8) * C + c0 + tx];
    __syncthreads();
#pragma unroll
    for (int j = 0; j < 4; ++j)
        dst[(size_t)(c0 + ty + j * 8) * R + r0 + tx] = f2bf(tile[tx * 33 + ty + j * 8]);
}

__global__ __launch_bounds__(256) void prep_k(const float* __restrict__ in_w,
                                              const float* __restrict__ cm_w2,
                                              const float* __restrict__ out_w,
                                              const float* __restrict__ fusion_w,
                                              const float* __restrict__ xp_w,
                                              ushort* __restrict__ inwT, ushort* __restrict__ cmw2T,
                                              ushort* __restrict__ outwT, ushort* __restrict__ fusT,
                                              ushort* __restrict__ xpwT) {
    __shared__ float lds[256 * 33];
    int bx = blockIdx.x;
    if (bx < 4096) {                       // in_w: 4 layers x (64 x 16)
        int l = bx >> 10, i = bx & 1023;
        tconv_body(in_w + (size_t)l * DM * 2 * DI, inwT + (size_t)l * 2 * DI * DM,
                   DM, 2 * DI, (i & 63) * 32, (i >> 6) * 32, lds);
        return;
    }
    bx -= 4096;
    if (bx < 1024) {                       // cm_w2: 4 x (32 x 8)
        int l = bx >> 8, i = bx & 255;
        tconv_body(cm_w2 + (size_t)l * DI4 * DI, cmw2T + (size_t)l * DI * DI4,
                   DI4, DI, (i & 31) * 32, (i >> 5) * 32, lds);
        return;
    }
    bx -= 1024;
    if (bx < 2048) {                       // out_w: 4 x (16 x 32)
        int l = bx >> 9, i = bx & 511;
        tconv_body(out_w + (size_t)l * DI * DM, outwT + (size_t)l * DM * DI,
                   DI, DM, (i & 15) * 32, (i >> 4) * 32, lds);
        return;
    }
    bx -= 2048;
    if (bx < 512) {                        // fusion: 16 x 32
        tconv_body(fusion_w, fusT, 2 * DM, DM, (bx & 15) * 32, (bx >> 4) * 32, lds);
        return;
    }
    bx -= 512;
    {                                      // xp_w prep: 16 blocks
        int l = bx >> 2, chunk = bx & 3;
        int c0 = chunk * 256, tid = threadIdx.x;
        const float* src = xp_w + (size_t)l * DI * 33 + (size_t)c0 * 33;
        for (int i = tid; i < 256 * 33; i += 256) lds[i] = src[i];
        __syncthreads();
        ushort* dst = xpwT + (size_t)l * 128 * DI;
        for (int j = 0; j < 128; ++j) {
            ushort v = (j < 33) ? f2bf(lds[tid * 33 + j]) : (ushort)0;
            dst[(size_t)j * DI + c0 + tid] = v;
        }
    }
}

// ---------------- xssmP partials [4][TT][128] -> xssmT [33][TT] ----------------
__global__ __launch_bounds__(256) void tpose33_k(const float* __restrict__ xssmP,
                                                 float* __restrict__ xssmT) {
    int t0 = blockIdx.x * 64, tid = threadIdx.x;
    __shared__ float lds[64 * 129];
    const float* src = xssmP + (size_t)t0 * 128;
    const size_t PS = (size_t)TT * 128;
    for (int i = tid; i < 64 * 128; i += 256) {
        float v = src[i] + src[i + PS] + src[i + 2 * PS] + src[i + 3 * PS];
        lds[(i >> 7) * 129 + (i & 127)] = v;
    }
    __syncthreads();
    int tk = tid & 63, jq = tid >> 6;
    for (int j = jq; j < 33; j += 4)
        xssmT[(size_t)j * TT + t0 + tk] = lds[tk * 129 + j];
}

// ---------------- layernorm: wave-per-token, shfl-only, packed bf16 stores ----------------
__global__ __launch_bounds__(256) void ln_k(const float* __restrict__ xin,
                                            const float* __restrict__ g,
                                            const float* __restrict__ bt,
                                            ushort* __restrict__ out) {
    int t = blockIdx.x * 4 + (threadIdx.x >> 6);
    int lane = threadIdx.x & 63;
    const float4* xr = (const float4*)(xin + (size_t)t * DM);
    float4 v0 = xr[lane * 2], v1 = xr[lane * 2 + 1];   // 8 contiguous floats
    float s = ((v0.x + v0.y) + (v0.z + v0.w)) + ((v1.x + v1.y) + (v1.z + v1.w));
#pragma unroll
    for (int off = 32; off > 0; off >>= 1) s += __shfl_xor(s, off);
    float mu = s * (1.f / DM);
    float d0 = v0.x - mu, d1 = v0.y - mu, d2 = v0.z - mu, d3 = v0.w - mu;
    float d4 = v1.x - mu, d5 = v1.y - mu, d6 = v1.z - mu, d7 = v1.w - mu;
    float q = ((d0 * d0 + d1 * d1) + (d2 * d2 + d3 * d3)) + ((d4 * d4 + d5 * d5) + (d6 * d6 + d7 * d7));
#pragma unroll
    for (int off = 32; off > 0; off >>= 1) q += __shfl_xor(q, off);
    float rs = rsqrtf(q * (1.f / DM) + 1e-5f);
    const float4* gr = (const float4*)g;
    const float4* br = (const float4*)bt;
    float4 g0 = gr[lane * 2], g1 = gr[lane * 2 + 1];
    float4 b0 = br[lane * 2], b1 = br[lane * 2 + 1];
    uint4 pk;
    pk.x = (unsigned)f2bf(d0 * rs * g0.x + b0.x) | ((unsigned)f2bf(d1 * rs * g0.y + b0.y) << 16);
    pk.y = (unsigned)f2bf(d2 * rs * g0.z + b0.z) | ((unsigned)f2bf(d3 * rs * g0.w + b0.w) << 16);
    pk.z = (unsigned)f2bf(d4 * rs * g1.x + b1.x) | ((unsigned)f2bf(d5 * rs * g1.y + b1.y) << 16);
    pk.w = (unsigned)f2bf(d6 * rs * g1.z + b1.z) | ((unsigned)f2bf(d7 * rs * g1.w + b1.w) << 16);
    *(uint4*)(out + (size_t)t * DM + lane * 8) = pk;
}

// ---------------- MFMA bf16 GEMM, double-buffered gld16 (2-phase), split-K via gridDim.z ----------------
template <bool BF16OUT>
__global__ __launch_bounds__(256) void mgemm_k(const ushort* __restrict__ A, int lda,
                                               const ushort* __restrict__ Bt, int ldb,
                                               const float* __restrict__ bias,
                                               const float* __restrict__ add, int ldadd,
                                               void* __restrict__ Cout, int ldc, int Kdim,
                                               size_t czs) {
    __shared__ short8v As[2][128 * 4];
    __shared__ short8v Bs[2][128 * 4];
    int tid = threadIdx.x;
    int lane = tid & 63, wid = tid >> 6;
    int row0 = blockIdx.y * 128, col0 = blockIdx.x * 128;
    int wr = (wid >> 1) * 64, wc = (wid & 1) * 64;
    float4v acc[4][4];
#pragma unroll
    for (int i = 0; i < 4; ++i)
#pragma unroll
        for (int j = 0; j < 4; ++j)
#pragma unroll
            for (int r = 0; r < 4; ++r) acc[i][j][r] = 0.f;

    int rq0 = wid * 32 + (lane >> 2);
    int rq1 = rq0 + 16;
    int clds = lane & 3;
    int cs0 = clds ^ ((rq0 >> 1) & 3);
    int cs1 = clds ^ ((rq1 >> 1) & 3);
    const ushort* aSrc0 = A + (size_t)(row0 + rq0) * lda + cs0 * 8;
    const ushort* aSrc1 = A + (size_t)(row0 + rq1) * lda + cs1 * 8;
    const ushort* bSrc0 = Bt + (size_t)(col0 + rq0) * ldb + cs0 * 8;
    const ushort* bSrc1 = Bt + (size_t)(col0 + rq1) * ldb + cs1 * 8;

    int fr = lane & 15, kg = lane >> 4;
    int sf = kg ^ ((fr >> 1) & 3);

    int kslice = Kdim / (int)gridDim.z;
    int kbeg = (int)blockIdx.z * kslice;
    int T = kslice / 32;

    // prologue: stage tile 0 into buf 0
    gld16(aSrc0 + kbeg, &As[0][wid * 128]);
    gld16(aSrc1 + kbeg, &As[0][wid * 128 + 64]);
    gld16(bSrc0 + kbeg, &Bs[0][wid * 128]);
    gld16(bSrc1 + kbeg, &Bs[0][wid * 128 + 64]);
    __syncthreads();
    int cur = 0;
    for (int i = 0; i < T; ++i) {
        if (i + 1 < T) {   // prefetch next tile into other buffer (overlaps with MFMA below)
            int kn = kbeg + (i + 1) * 32;
            gld16(aSrc0 + kn, &As[cur ^ 1][wid * 128]);
            gld16(aSrc1 + kn, &As[cur ^ 1][wid * 128 + 64]);
            gld16(bSrc0 + kn, &Bs[cur ^ 1][wid * 128]);
            gld16(bSrc1 + kn, &Bs[cur ^ 1][wid * 128 + 64]);
        }
        short8v af[4], bf[4];
#pragma unroll
        for (int mb = 0; mb < 4; ++mb) af[mb] = As[cur][(wr + mb * 16 + fr) * 4 + sf];
#pragma unroll
        for (int nb = 0; nb < 4; ++nb) bf[nb] = Bs[cur][(wc + nb * 16 + fr) * 4 + sf];
#pragma unroll
        for (int mb = 0; mb < 4; ++mb)
#pragma unroll
            for (int nb = 0; nb < 4; ++nb)
                acc[mb][nb] = __builtin_amdgcn_mfma_f32_16x16x32_bf16(af[mb], bf[nb], acc[mb][nb], 0, 0, 0);
        __syncthreads();   // drains prefetch (vmcnt 0) + all LDS reads of buf[cur]
        cur ^= 1;
    }
    ushort* cu = (ushort*)Cout + (size_t)blockIdx.z * czs;
    float* cf = (float*)Cout + (size_t)blockIdx.z * czs;
#pragma unroll
    for (int mb = 0; mb < 4; ++mb) {
        int r_ = row0 + wr + mb * 16 + kg * 4;
#pragma unroll
        for (int nb = 0; nb < 4; ++nb) {
            int c_ = col0 + wc + nb * 16 + fr;
            float bz = bias ? bias[c_] : 0.f;
#pragma unroll
            for (int r = 0; r < 4; ++r) {
                float o = acc[mb][nb][r] + bz;
                if (add) o += add[(size_t)(r_ + r) * ldadd + c_];
                if (BF16OUT) cu[(size_t)(r_ + r) * ldc + c_] = f2bf(o);
                else         cf[(size_t)(r_ + r) * ldc + c_] = o;
            }
        }
    }
}

// ---------------- h1-fused cm_w2 GEMM, double-buffered ----------------
__global__ __launch_bounds__(256) void mgemmH_k(const float* __restrict__ imp,
                                                const float* __restrict__ w1,
                                                const float* __restrict__ b1,
                                                const ushort* __restrict__ Bt,
                                                const float* __restrict__ bias,
                                                ushort* __restrict__ Cout, int ldc) {
    __shared__ short8v As[2][128 * 4];
    __shared__ short8v Bs[2][128 * 4];
    int tid = threadIdx.x;
    int lane = tid & 63, wid = tid >> 6;
    int row0 = blockIdx.y * 128, col0 = blockIdx.x * 128;
    int wr = (wid >> 1) * 64, wc = (wid & 1) * 64;
    float4v acc[4][4];
#pragma unroll
    for (int i = 0; i < 4; ++i)
#pragma unroll
        for (int j = 0; j < 4; ++j)
#pragma unroll
            for (int r = 0; r < 4; ++r) acc[i][j][r] = 0.f;

    int rq0 = wid * 32 + (lane >> 2);
    int rq1 = rq0 + 16;
    int clds = lane & 3;
    int cs0 = clds ^ ((rq0 >> 1) & 3);
    int cs1 = clds ^ ((rq1 >> 1) & 3);
    float imp0 = imp[row0 + rq0];
    float imp1 = imp[row0 + rq1];
    const ushort* bSrc0 = Bt + (size_t)(col0 + rq0) * DI4 + cs0 * 8;
    const ushort* bSrc1 = Bt + (size_t)(col0 + rq1) * DI4 + cs1 * 8;

    int fr = lane & 15, kg = lane >> 4;
    int sf = kg ^ ((fr >> 1) & 3);

    auto mkA = [&](int k0, float impv, int cs, short8v* dst) {
        float4 w0 = *(const float4*)(w1 + k0 + cs * 8);
        float4 w4 = *(const float4*)(w1 + k0 + cs * 8 + 4);
        float4 bq0 = *(const float4*)(b1 + k0 + cs * 8);
        float4 bq4 = *(const float4*)(b1 + k0 + cs * 8 + 4);
        short8v p;
        p[0] = (short)f2bf(fmaxf(fmaf(impv, w0.x, bq0.x), 0.f));
        p[1] = (short)f2bf(fmaxf(fmaf(impv, w0.y, bq0.y), 0.f));
        p[2] = (short)f2bf(fmaxf(fmaf(impv, w0.z, bq0.z), 0.f));
        p[3] = (short)f2bf(fmaxf(fmaf(impv, w0.w, bq0.w), 0.f));
        p[4] = (short)f2bf(fmaxf(fmaf(impv, w4.x, bq4.x), 0.f));
        p[5] = (short)f2bf(fmaxf(fmaf(impv, w4.y, bq4.y), 0.f));
        p[6] = (short)f2bf(fmaxf(fmaf(impv, w4.z, bq4.z), 0.f));
        p[7] = (short)f2bf(fmaxf(fmaf(impv, w4.w, bq4.w), 0.f));
        *dst = p;
    };

    // prologue: tile 0 into buf 0
    mkA(0, imp0, cs0, &As[0][rq0 * 4 + clds]);
    mkA(0, imp1, cs1, &As[0][rq1 * 4 + clds]);
    gld16(bSrc0, &Bs[0][wid * 128]);
    gld16(bSrc1, &Bs[0][wid * 128 + 64]);
    __syncthreads();
    int cur = 0;
    constexpr int T = DI4 / 32;   // 8
    for (int i = 0; i < T; ++i) {
        if (i + 1 < T) {
            int kn = (i + 1) * 32;
            mkA(kn, imp0, cs0, &As[cur ^ 1][rq0 * 4 + clds]);
            mkA(kn, imp1, cs1, &As[cur ^ 1][rq1 * 4 + clds]);
            gld16(bSrc0 + kn, &Bs[cur ^ 1][wid * 128]);
            gld16(bSrc1 + kn, &Bs[cur ^ 1][wid * 128 + 64]);
        }
        short8v af[4], bf[4];
#pragma unroll
        for (int mb = 0; mb < 4; ++mb) af[mb] = As[cur][(wr + mb * 16 + fr) * 4 + sf];
#pragma unroll
        for (int nb = 0; nb < 4; ++nb) bf[nb] = Bs[cur][(wc + nb * 16 + fr) * 4 + sf];
#pragma unroll
        for (int mb = 0; mb < 4; ++mb)
#pragma unroll
            for (int nb = 0; nb < 4; ++nb)
                acc[mb][nb] = __builtin_amdgcn_mfma_f32_16x16x32_bf16(af[mb], bf[nb], acc[mb][nb], 0, 0, 0);
        __syncthreads();
        cur ^= 1;
    }
#pragma unroll
    for (int mb = 0; mb < 4; ++mb) {
        int r_ = row0 + wr + mb * 16 + kg * 4;
#pragma unroll
        for (int nb = 0; nb < 4; ++nb) {
            int c_ = col0 + wc + nb * 16 + fr;
            float bz = bias[c_];
#pragma unroll
            for (int r = 0; r < 4; ++r)
                Cout[(size_t)(r_ + r) * ldc + c_] = f2bf(acc[mb][nb][r] + bz);
        }
    }
}

// ---------------- depthwise causal conv + silu (ushort2-vectorized) ----------------
__global__ __launch_bounds__(256) void conv_k(const ushort* __restrict__ xz,
                                              const float* __restrict__ cw,
                                              const float* __restrict__ cb,
                                              ushort* __restrict__ xcb) {
    int gid = blockIdx.x * 256 + threadIdx.x;   // pair index over TT*DI/2
    int p = gid & (DI / 2 - 1);
    int d = p * 2;
    int t = gid >> 9;
    int n = t & (N - 1);
    float acc0 = cb[d], acc1 = cb[d + 1];
    const ushort* base = xz + (size_t)t * (2 * DI) + d;
    float4 w0 = *(const float4*)(cw + d * DC);
    float4 w1 = *(const float4*)(cw + (d + 1) * DC);
    float wk0[4] = {w0.x, w0.y, w0.z, w0.w};
    float wk1[4] = {w1.x, w1.y, w1.z, w1.w};
#pragma unroll
    for (int k = 0; k < DC; ++k) {
        int nn = n - (DC - 1) + k;
        if (nn >= 0) {
            unsigned u = *(const unsigned*)(base + (long)(nn - n) * (2 * DI));
            acc0 = fmaf(bf2f((ushort)(u & 0xffff)), wk0[k], acc0);
            acc1 = fmaf(bf2f((ushort)(u >> 16)), wk1[k], acc1);
        }
    }
    float s0 = acc0 / (1.f + __expf(-acc0));
    float s1 = acc1 / (1.f + __expf(-acc1));
    unsigned o = (unsigned)f2bf(s0) | ((unsigned)f2bf(s1) << 16);
    *(unsigned*)(xcb + (size_t)t * DI + d) = o;
}

// ================= segmented scan =================
// Phase A: per-segment local scan + transfer product; also materializes delta (f32).
__global__ __launch_bounds__(256) void scanA_k(const ushort* __restrict__ modl,
                                               const ushort* __restrict__ xcb,
                                               const float* __restrict__ xssmT,
                                               const float* __restrict__ Alog,
                                               const float* __restrict__ dtw,
                                               const float* __restrict__ dtb,
                                               float* __restrict__ delf,
                                               float* __restrict__ hloc,
                                               float* __restrict__ Pp) {
    int blk = blockIdx.x;
    int seg = blk & 15;
    int dblk = (blk >> 4) & 63;
    int b = blk >> 10;
    int d0 = dblk * 16;
    int tid = threadIdx.x;
    int lane = tid & 63, wave = tid >> 6;
    int s = lane & 15, dd = lane >> 4;
    int dl = wave * 4 + dd, d = d0 + dl;
    float A = -__expf(Alog[d * DS + s]);
    size_t tokbase = (size_t)b * N + (size_t)seg * SLEN;

    __shared__ float sdl[16][68];   // [dl][t] delta
    __shared__ float sxc[16][68];   // [dl][t] xc
    __shared__ float sBv[16][68];   // [s][t]  B

    int lc = tid & 15, lr = tid >> 4;
    float dtwv = dtw[d0 + lc], dtbv = dtb[d0 + lc];
    const ushort* mbase = modl + tokbase * DI + d0 + lc;
    const ushort* xbase = xcb + tokbase * DI + d0 + lc;
    const float* drow = xssmT + tokbase;
    const float* Brow = xssmT + (size_t)(1 + lc) * TT + tokbase;
#pragma unroll
    for (int q = 0; q < 4; ++q) {
        int tok = q * 16 + lr;
        float mo   = bf2f(mbase[(size_t)tok * DI]);
        float draw = drow[tok];
        float xcv  = bf2f(xbase[(size_t)tok * DI]);
        float Bv   = Brow[tok];
        float a = draw * dtwv + dtbv;
        float sp = (a > 20.f) ? a : log1pf(__expf(a));
        float mod = 1.f / (1.f + __expf(-mo));
        float dlv = sp * (1.f + mod);
        sdl[lc][tok] = dlv;
        delf[(tokbase + tok) * DI + d0 + lc] = dlv;
        sxc[lc][tok] = xcv;
        sBv[lc][tok] = Bv;
    }
    __syncthreads();
    float h = 0.f, P = 1.f;
#pragma unroll
    for (int g = 0; g < 8; ++g) {
        float4 dl4a = *(const float4*)&sdl[dl][g * 8];
        float4 dl4b = *(const float4*)&sdl[dl][g * 8 + 4];
        float4 xc4a = *(const float4*)&sxc[dl][g * 8];
        float4 xc4b = *(const float4*)&sxc[dl][g * 8 + 4];
        float4 B4a  = *(const float4*)&sBv[s][g * 8];
        float4 B4b  = *(const float4*)&sBv[s][g * 8 + 4];
        float dlt[8] = {dl4a.x, dl4a.y, dl4a.z, dl4a.w, dl4b.x, dl4b.y, dl4b.z, dl4b.w};
        float xcv[8] = {xc4a.x, xc4a.y, xc4a.z, xc4a.w, xc4b.x, xc4b.y, xc4b.z, xc4b.w};
        float Bv8[8] = {B4a.x, B4a.y, B4a.z, B4a.w, B4b.x, B4b.y, B4b.z, B4b.w};
        float a8[8], b8[8];
#pragma unroll
        for (int j = 0; j < 8; ++j) {
            a8[j] = __expf(dlt[j] * A);
            b8[j] = (dlt[j] * Bv8[j]) * xcv[j];
        }
#pragma unroll
        for (int j = 0; j < 8; ++j) { h = fmaf(a8[j], h, b8[j]); P *= a8[j]; }
    }
    size_t idx = (size_t)blk * 256 + tid;
    hloc[idx] = h;
    Pp[idx] = P;
}

// Phase B: sequential combine across 16 segments per (b,d,s); writes per-segment h0.
__global__ __launch_bounds__(256) void scanB_k(const float* __restrict__ hloc,
                                               const float* __restrict__ Pp,
                                               float* __restrict__ h0g) {
    int blk = blockIdx.x;
    int tid = threadIdx.x;
    size_t base = (size_t)blk * SEG * 256 + tid;
    float h = 0.f;
    for (int g = 0; g < SEG; ++g) {
        size_t i = base + (size_t)g * 256;
        h0g[i] = h;
        h = fmaf(Pp[i], h, hloc[i]);
    }
}

// Phase C: re-run segment from true h0; stages precomputed delta; scalar sP reduce (17-pad).
__global__ __launch_bounds__(256) void scanC_k(const float* __restrict__ delf,
                                               const ushort* __restrict__ xcb,
                                               const float* __restrict__ xssmT,
                                               const float* __restrict__ Alog,
                                               const float* __restrict__ Dp,
                                               const ushort* __restrict__ xz,
                                               const float* __restrict__ h0g,
                                               ushort* __restrict__ y) {
    int blk = blockIdx.x;
    int seg = blk & 15;
    int dblk = (blk >> 4) & 63;
    int b = blk >> 10;
    int d0 = dblk * 16;
    int tid = threadIdx.x;
    int lane = tid & 63, wave = tid >> 6;
    int s = lane & 15, dd = lane >> 4;
    int dl = wave * 4 + dd, d = d0 + dl;
    float A = -__expf(Alog[d * DS + s]);
    size_t tokbase = (size_t)b * N + (size_t)seg * SLEN;

    __shared__ float sdl[16][68];   // [dl][t]
    __shared__ float sxc[16][68];   // [dl][t]
    __shared__ float sBv[16][68];   // [s][t]
    __shared__ float sCv[16][68];   // [s][t]
    __shared__ float szv[16][68];   // [dl][t]
    __shared__ float sP[16][16][17];   // [step-in-group][dl][s]

    int lc = tid & 15, lr = tid >> 4;
    float dpv_lc = Dp[d0 + lc];
    const float* dbase = delf + tokbase * DI + d0 + lc;
    const ushort* xbase = xcb + tokbase * DI + d0 + lc;
    const ushort* zbase = xz + tokbase * (2 * DI) + DI + d0 + lc;
    const float* Brow = xssmT + (size_t)(1 + lc) * TT + tokbase;
    const float* Crow = xssmT + (size_t)(1 + DS + lc) * TT + tokbase;
#pragma unroll
    for (int q = 0; q < 4; ++q) {
        int tok = q * 16 + lr;
        sdl[lc][tok] = dbase[(size_t)tok * DI];
        sxc[lc][tok] = bf2f(xbase[(size_t)tok * DI]);
        sBv[lc][tok] = Brow[tok];
        sCv[lc][tok] = Crow[tok];
        szv[lc][tok] = bf2f(zbase[(size_t)tok * (2 * DI)]);
    }
    __syncthreads();
    float h = h0g[(size_t)blk * 256 + tid];
    for (int g = 0; g < 4; ++g) {              // 16-token groups
#pragma unroll
        for (int half = 0; half < 2; ++half) {
            int t0 = g * 16 + half * 8;
            float4 dl4a = *(const float4*)&sdl[dl][t0];
            float4 dl4b = *(const float4*)&sdl[dl][t0 + 4];
            float4 xc4a = *(const float4*)&sxc[dl][t0];
            float4 xc4b = *(const float4*)&sxc[dl][t0 + 4];
            float4 B4a  = *(const float4*)&sBv[s][t0];
            float4 B4b  = *(const float4*)&sBv[s][t0 + 4];
            float4 C4a  = *(const float4*)&sCv[s][t0];
            float4 C4b  = *(const float4*)&sCv[s][t0 + 4];
            float dlt[8] = {dl4a.x, dl4a.y, dl4a.z, dl4a.w, dl4b.x, dl4b.y, dl4b.z, dl4b.w};
            float xcv[8] = {xc4a.x, xc4a.y, xc4a.z, xc4a.w, xc4b.x, xc4b.y, xc4b.z, xc4b.w};
            float Bv8[8] = {B4a.x, B4a.y, B4a.z, B4a.w, B4b.x, B4b.y, B4b.z, B4b.w};
            float Cv8[8] = {C4a.x, C4a.y, C4a.z, C4a.w, C4b.x, C4b.y, C4b.z, C4b.w};
            float a8[8], b8[8];
#pragma unroll
            for (int j = 0; j < 8; ++j) {
                a8[j] = __expf(dlt[j] * A);
                b8[j] = (dlt[j] * Bv8[j]) * xcv[j];
            }
#pragma unroll
            for (int j = 0; j < 8; ++j) {
                h = fmaf(a8[j], h, b8[j]);
                sP[half * 8 + j][dl][s] = h * Cv8[j];
            }
        }
        __syncthreads();
        {   // parallel s-reduce + gate + store
            int t = g * 16 + lr;
            float ssum = 0.f;
#pragma unroll
            for (int s2 = 0; s2 < 16; ++s2) ssum += sP[lr][lc][s2];
            float xcv = sxc[lc][t];
            float zv  = szv[lc][t];
            float sg = 1.f / (1.f + __expf(-zv));
            y[(tokbase + t) * DI + d0 + lc] = f2bf((ssum + xcv * dpv_lc) * (zv * sg));
        }
        __syncthreads();
    }
}

// ---------------- concat [xf | flip(xb)] -> bf16 ----------------
__global__ __launch_bounds__(256) void concat_k(const float* __restrict__ xf,
                                                const float* __restrict__ xb,
                                                ushort* __restrict__ cat) {
    int gid = blockIdx.x * 256 + threadIdx.x;   // TT*DM
    int t = gid >> 9;
    int c = gid & (DM - 1);
    int b = t >> 10, j = t & (N - 1);
    cat[(size_t)t * (2 * DM) + c] = f2bf(xf[gid]);
    cat[(size_t)t * (2 * DM) + DM + c] = f2bf(xb[((size_t)(b << 10) + (N - 1 - j)) * DM + c]);
}

// ---------------- final: scatter by ridx + layernorm ----------------
__global__ __launch_bounds__(256) void final_k(const float* __restrict__ fus,
                                               const int* __restrict__ ridx,
                                               const float* __restrict__ g,
                                               const float* __restrict__ bt,
                                               float* __restrict__ out) {
    int t = blockIdx.x, tid = threadIdx.x;
    int b = t >> 10;
    int r = ridx[t];
    const float* xr = fus + (size_t)t * DM;
    __shared__ float red[256];
    float v0 = xr[tid], v1 = xr[tid + 256];
    red[tid] = v0 + v1; __syncthreads();
    for (int st = 128; st > 0; st >>= 1) { if (tid < st) red[tid] += red[tid + st]; __syncthreads(); }
    float mu = red[0] * (1.f / DM); __syncthreads();
    float d0 = v0 - mu, d1 = v1 - mu;
    red[tid] = d0 * d0 + d1 * d1; __syncthreads();
    for (int st = 128; st > 0; st >>= 1) { if (tid < st) red[tid] += red[tid + st]; __syncthreads(); }
    float rs = rsqrtf(red[0] * (1.f / DM) + 1e-5f);
    float* orow = out + ((size_t)(b << 10) + r) * DM;
    orow[tid] = d0 * rs * g[tid] + bt[tid];
    orow[tid + 256] = d1 * rs * g[tid + 256] + bt[tid + 256];
}

// ---------------- host ----------------
extern "C" void kernel_launch(void* const* d_in, const int* in_sizes, int n_in,
                              void* d_out, int out_size, void* d_ws, size_t ws_size,
                              hipStream_t stream) {
    const float* x            = (const float*)d_in[0];
    const float* centers_init = (const float*)d_in[1];
    const float* in_w         = (const float*)d_in[2];
    const float* conv_w       = (const float*)d_in[3];
    const float* conv_b       = (const float*)d_in[4];
    const float* xp_w         = (const float*)d_in[5];
    const float* dt_w         = (const float*)d_in[6];
    const float* dt_b         = (const float*)d_in[7];
    const float* cm_w1        = (const float*)d_in[8];
    const float* cm_b1        = (const float*)d_in[9];
    const float* cm_w2        = (const float*)d_in[10];
    const float* cm_b2        = (const float*)d_in[11];
    const float* A_log        = (const float*)d_in[12];
    const float* D_p          = (const float*)d_in[13];
    const float* out_w        = (const float*)d_in[14];
    const float* ln_g         = (const float*)d_in[15];
    const float* ln_b         = (const float*)d_in[16];
    const float* fusion_w     = (const float*)d_in[17];
    const float* fusion_b     = (const float*)d_in[18];
    const float* fn_g         = (const float*)d_in[19];
    const float* fn_b         = (const float*)d_in[20];

    float* W = (float*)d_ws;
    size_t off = 0;
    auto alloc = [&](size_t n) { float* p = W + off; off += (n + 15) & ~(size_t)15; return p; };
    auto allocU = [&](size_t n) { ushort* p = (ushort*)(W + off); off += ((n + 1) / 2 + 15) & ~(size_t)15; return p; };
    float* centers = alloc((size_t)Bb * KC * DM);
    float* wgt     = alloc((size_t)TT * KC);
    float* mind    = alloc(TT);
    float* keys    = alloc(TT);
    float* imp     = alloc(TT);
    float* rimp    = alloc(TT);
    float* fimp    = alloc(TT);
    float* denp    = alloc((size_t)Bb * KC * SEGU);
    float* rx      = alloc((size_t)TT * DM);
    float* rxf     = alloc((size_t)TT * DM);
    float* tmp     = alloc((size_t)TT * DM);
    float* fus     = alloc((size_t)TT * DM);       // fusion output f32
    float* xssmT   = alloc((size_t)TT * 33);
    float* delf    = alloc((size_t)TT * DI);       // f32 delta (scanA -> scanC)
    float* hloc    = alloc((size_t)Bb * 64 * SEG * 256);   // hloc+Pp aliased by xssmP (8MB)
    float* Pp      = alloc((size_t)Bb * 64 * SEG * 256);
    float* h0g     = alloc((size_t)Bb * 64 * SEG * 256);
    ushort* xz     = allocU((size_t)TT * 2 * DI);  // bf16 xz; reused as bf16 cat
    ushort* modl   = allocU((size_t)TT * DI);      // bf16; aliased by kmeans 'part'
    ushort* xnb    = allocU((size_t)TT * DM);
    ushort* yb     = allocU((size_t)TT * DI);
    ushort* xcb    = allocU((size_t)TT * DI);
    ushort* inwT   = allocU((size_t)L4 * 2 * DI * DM);
    ushort* cmw2T  = allocU((size_t)L4 * DI * DI4);
    ushort* outwT  = allocU((size_t)L4 * DM * DI);
    ushort* fusT   = allocU((size_t)DM * 2 * DM);
    ushort* xpwT   = allocU((size_t)L4 * 128 * DI);
    int* ridx = (int*)(W + off); off += TT;
    float* part = (float*)modl;   // kmeans partials alias modl region (disjoint in time)
    float* xssmP = hloc;          // 4 split-K partials (8MB) alias hloc+Pp, disjoint in time

    // ---- merged weight prep ----
    prep_k<<<7696, 256, 0, stream>>>(in_w, cm_w2, out_w, fusion_w, xp_w,
                                     inwT, cmw2T, outwT, fusT, xpwT);

    // ---- k-means ----
    for (int it = 0; it < 3; ++it) {
        if (it == 0) assign_k<false><<<TT / 4, 256, 0, stream>>>(x, centers_init, 0, wgt, nullptr, nullptr);
        else         assign_k<false><<<TT / 4, 256, 0, stream>>>(x, centers, KC * DM, wgt, nullptr, nullptr);
        updp_k<<<Bb * SEGU, 512, 0, stream>>>(x, wgt, part, denp);
        updr_k<<<Bb * KC, 512, 0, stream>>>(part, denp, centers);
    }
    assign_k<true><<<TT / 4, 256, 0, stream>>>(x, centers, KC * DM, wgt, mind, keys);
    sortimp_k<<<8, 1024, 0, stream>>>(keys, mind, ridx, imp);
    gather_k<<<TT, 512, 0, stream>>>(x, imp, ridx, rx, rxf, rimp, fimp);

    auto gemmF = [&](const ushort* Ap, int lda, const ushort* Bp, int ldb,
                     const float* bias, const float* add, int ldadd,
                     float* Cp, int ldc, int Kd, int Nn) {
        dim3 g(Nn / 128, TT / 128, 1);
        mgemm_k<false><<<g, 256, 0, stream>>>(Ap, lda, Bp, ldb, bias, add, ldadd, Cp, ldc, Kd, 0);
    };
    auto gemmB = [&](const ushort* Ap, int lda, const ushort* Bp, int ldb,
                     const float* bias,
                     ushort* Cp, int ldc, int Kd, int Nn) {
        dim3 g(Nn / 128, TT / 128, 1);
        mgemm_k<true><<<g, 256, 0, stream>>>(Ap, lda, Bp, ldb, bias, nullptr, 0, Cp, ldc, Kd, 0);
    };

    // ---- 4 mamba layers (2 fwd, 2 bwd on flipped) ----
    const float* lay_in[4]  = {rx, tmp, rxf, tmp};
    float*       lay_out[4] = {tmp, rx, tmp, rxf};
    for (int l = 0; l < L4; ++l) {
        const float* xin = lay_in[l];
        float* xout = lay_out[l];
        const float* impv = (l < 2) ? rimp : fimp;
        ln_k<<<TT / 4, 256, 0, stream>>>(xin, ln_g + (size_t)l * DM, ln_b + (size_t)l * DM, xnb);
        gemmB(xnb, DM, inwT + (size_t)l * 2 * DI * DM, DM, nullptr, xz, 2 * DI, DM, 2 * DI);
        conv_k<<<(TT * DI / 2) / 256, 256, 0, stream>>>(xz, conv_w + (size_t)l * DI * DC, conv_b + (size_t)l * DI, xcb);
        {   // xssm GEMM, split-K = 4
            dim3 g(1, TT / 128, 4);
            mgemm_k<false><<<g, 256, 0, stream>>>(xcb, DI, xpwT + (size_t)l * 128 * DI, DI,
                                                  nullptr, nullptr, 0, xssmP, 128, DI, (size_t)TT * 128);
        }
        tpose33_k<<<TT / 64, 256, 0, stream>>>(xssmP, xssmT);
        mgemmH_k<<<dim3(DI / 128, TT / 128), 256, 0, stream>>>(impv, cm_w1 + (size_t)l * DI4,
                                                               cm_b1 + (size_t)l * DI4,
                                                               cmw2T + (size_t)l * DI * DI4,
                                                               cm_b2 + (size_t)l * DI, modl, DI);
        scanA_k<<<Bb * 64 * SEG, 256, 0, stream>>>(modl, xcb, xssmT, A_log + (size_t)l * DI * DS,
                                                   dt_w + (size_t)l * DI, dt_b + (size_t)l * DI,
                                                   delf, hloc, Pp);
        scanB_k<<<Bb * 64, 256, 0, stream>>>(hloc, Pp, h0g);
        scanC_k<<<Bb * 64 * SEG, 256, 0, stream>>>(delf, xcb, xssmT, A_log + (size_t)l * DI * DS,
                                                   D_p + (size_t)l * DI, xz, h0g, yb);
        gemmF(yb, DI, outwT + (size_t)l * DM * DI, DI, nullptr, xin, DM, xout, DM, DI, DM);
    }

    // ---- fusion + restore + final LN ----
    ushort* catb = xz;
    concat_k<<<(TT * DM) / 256, 256, 0, stream>>>(rx /*xf final*/, rxf /*xb final*/, catb);
    gemmF(catb, 2 * DM, fusT, 2 * DM, fusion_b, nullptr, 0, fus, DM, 2 * DM, DM);
    final_k<<<TT, 256, 0, stream>>>(fus, ridx, fn_g, fn_b, (float*)d_out);
}